// Round 1
// baseline (4762.484 us; speedup 1.0000x reference)
//
#include <hip/hip_runtime.h>
#include <stdint.h>

#define NOBJ 2048
#define NREL 32768

typedef __attribute__((ext_vector_type(8))) short short8;
typedef __attribute__((ext_vector_type(4))) float f32x4;

__device__ __forceinline__ unsigned short f2bs(float x){
  unsigned u = __float_as_uint(x);
  unsigned v = u + 0x7fffu + ((u >> 16) & 1u);
  return (unsigned short)(v >> 16);
}
__device__ __forceinline__ short f2bss(float x){ return (short)f2bs(x); }
__device__ __forceinline__ float sigf(float x){ return 1.0f / (1.0f + expf(-x)); }

// =====================  GEMM: C = act(A * B^T + bias [+C])  =====================
// A: MxK row-major (f32 if !ABF16, bf16 if ABF16). B: NxK bf16 row-major.
// C: MxN (f32, or bf16 if OUTB). M,N multiples of 128; K multiple of 32 (and 8).
template<bool ABF16, bool RELU, bool ACCUM, bool OUTB>
__global__ __launch_bounds__(256, 2)
void gemm_bt(const void* __restrict__ Ap, const unsigned short* __restrict__ B,
             const float* __restrict__ bias, void* __restrict__ Cp,
             int M, int N, int K)
{
  __shared__ __align__(16) unsigned short As[128 * 32];
  __shared__ __align__(16) unsigned short Bs[128 * 32];
  const int t = threadIdx.x;
  const int lane = t & 63;
  const int w = t >> 6;
  const int ntile = N >> 7;
  const int bm = blockIdx.x / ntile;
  const int bn = blockIdx.x - bm * ntile;
  const int m0 = bm << 7, n0 = bn << 7;
  const int wm = (w & 1) << 6, wn = (w >> 1) << 6;
  const int lrow = lane & 15, kg = lane >> 4;
  const int srow = t >> 1;           // 0..127: tile row this thread stages
  const int skoff = (t & 1) << 4;    // 0 or 16 elements within BK=32

  const float* Af = (const float*)Ap;
  const unsigned short* Ab = (const unsigned short*)Ap;
  const long aoff = (long)(m0 + srow) * K + skoff;
  const long boff = (long)(n0 + srow) * K + skoff;
  unsigned short* asw = As + srow * 32 + skoff;
  unsigned short* bsw = Bs + srow * 32 + skoff;

  f32x4 acc[4][4] = {};

  for (int k0 = 0; k0 < K; k0 += 32) {
    if constexpr (ABF16) {
      short8 a0 = *(const short8*)(Ab + aoff + k0);
      short8 a1 = *(const short8*)(Ab + aoff + k0 + 8);
      *(short8*)asw = a0;
      *(short8*)(asw + 8) = a1;
    } else {
      const float* ap = Af + aoff + k0;
      f32x4 f0 = *(const f32x4*)(ap + 0);
      f32x4 f1 = *(const f32x4*)(ap + 4);
      f32x4 f2 = *(const f32x4*)(ap + 8);
      f32x4 f3 = *(const f32x4*)(ap + 12);
      short8 v0, v1;
      v0[0]=f2bss(f0[0]); v0[1]=f2bss(f0[1]); v0[2]=f2bss(f0[2]); v0[3]=f2bss(f0[3]);
      v0[4]=f2bss(f1[0]); v0[5]=f2bss(f1[1]); v0[6]=f2bss(f1[2]); v0[7]=f2bss(f1[3]);
      v1[0]=f2bss(f2[0]); v1[1]=f2bss(f2[1]); v1[2]=f2bss(f2[2]); v1[3]=f2bss(f2[3]);
      v1[4]=f2bss(f3[0]); v1[5]=f2bss(f3[1]); v1[6]=f2bss(f3[2]); v1[7]=f2bss(f3[3]);
      *(short8*)asw = v0;
      *(short8*)(asw + 8) = v1;
    }
    {
      short8 b0 = *(const short8*)(B + boff + k0);
      short8 b1 = *(const short8*)(B + boff + k0 + 8);
      *(short8*)bsw = b0;
      *(short8*)(bsw + 8) = b1;
    }
    __syncthreads();
    short8 afr[4], bfr[4];
#pragma unroll
    for (int i = 0; i < 4; i++) afr[i] = *(const short8*)(As + (wm + i * 16 + lrow) * 32 + kg * 8);
#pragma unroll
    for (int j = 0; j < 4; j++) bfr[j] = *(const short8*)(Bs + (wn + j * 16 + lrow) * 32 + kg * 8);
#pragma unroll
    for (int i = 0; i < 4; i++)
#pragma unroll
      for (int j = 0; j < 4; j++)
        acc[i][j] = __builtin_amdgcn_mfma_f32_16x16x32_bf16(afr[i], bfr[j], acc[i][j], 0, 0, 0);
    __syncthreads();
  }

  float* Cf = (float*)Cp;
  unsigned short* Cb = (unsigned short*)Cp;
#pragma unroll
  for (int i = 0; i < 4; i++) {
#pragma unroll
    for (int j = 0; j < 4; j++) {
      const int col = n0 + wn + j * 16 + lrow;
      const float bv = bias[col];
#pragma unroll
      for (int q = 0; q < 4; q++) {
        const long row = m0 + wm + i * 16 + kg * 4 + q;
        float v = acc[i][j][q] + bv;
        if constexpr (ACCUM) v += Cf[row * N + col];
        if constexpr (RELU) v = fmaxf(v, 0.0f);
        if constexpr (OUTB) Cb[row * N + col] = f2bs(v);
        else Cf[row * N + col] = v;
      }
    }
  }
}

// ===================== small kernels =====================

// f32 -> bf16 with row padding K0 -> Kp (pad zeros)
__global__ void cvt_pad(const float* __restrict__ src, unsigned short* __restrict__ dst,
                        int rows, int K0, int Kp)
{
  const long total = (long)rows * Kp;
  for (long i = blockIdx.x * (long)blockDim.x + threadIdx.x; i < total; i += (long)gridDim.x * blockDim.x) {
    int r = (int)(i / Kp), k = (int)(i - (long)r * Kp);
    dst[i] = (k < K0) ? f2bs(src[(long)r * K0 + k]) : (unsigned short)0;
  }
}

__global__ void obox_k(const float* __restrict__ boxes, float* __restrict__ obox)
{
  int i = blockIdx.x * blockDim.x + threadIdx.x;
  if (i >= NOBJ) return;
  float x1 = boxes[i*4], y1 = boxes[i*4+1], x2 = boxes[i*4+2], y2 = boxes[i*4+3];
  float wdt = x2 - x1 + 1.0f, hgt = y2 - y1 + 1.0f;
  float cx = x1 + 0.5f * wdt, cy = y1 + 0.5f * hgt;
  const float inv = 1.0f / 1024.0f;  // max(IMG_W, IMG_H, 100)
  float* o = obox + i * 8;
  o[0]=x1*inv; o[1]=y1*inv; o[2]=x2*inv; o[3]=y2*inv;
  o[4]=cx*inv; o[5]=cy*inv; o[6]=wdt*inv; o[7]=hgt*inv;
}

// pos_embed = relu( pos2( bn( pos1( encode_box ) ) ) )   -- block 128 = one object
__global__ void posembed_k(const float* __restrict__ boxes,
                           const float* __restrict__ w1, const float* __restrict__ b1,
                           const float* __restrict__ g, const float* __restrict__ bb,
                           const float* __restrict__ mm, const float* __restrict__ vv,
                           const float* __restrict__ w2, const float* __restrict__ b2,
                           float* __restrict__ out)
{
  int o = blockIdx.x, t = threadIdx.x;
  __shared__ float e[9];
  __shared__ float p[32];
  if (t == 0) {
    float x1 = boxes[o*4], y1 = boxes[o*4+1], x2 = boxes[o*4+2], y2 = boxes[o*4+3];
    float wdt = x2 - x1 + 1.0f, hgt = y2 - y1 + 1.0f;
    float cx = x1 + 0.5f * wdt, cy = y1 + 0.5f * hgt;
    e[0]=wdt/1024.0f; e[1]=hgt/768.0f; e[2]=cx/1024.0f; e[3]=cy/768.0f;
    e[4]=x1/1024.0f;  e[5]=y1/768.0f;  e[6]=x2/1024.0f; e[7]=y2/768.0f;
    e[8]=wdt*hgt/(1024.0f*768.0f);
  }
  __syncthreads();
  if (t < 32) {
    float s = b1[t];
#pragma unroll
    for (int j = 0; j < 9; j++) s += w1[t*9+j] * e[j];
    s = (s - mm[t]) * g[t] / sqrtf(vv[t] + 1e-5f) + bb[t];
    p[t] = s;
  }
  __syncthreads();
  float s = b2[t];
#pragma unroll
  for (int j = 0; j < 32; j++) s += w2[t*32+j] * p[j];
  out[o*128 + t] = fmaxf(s, 0.0f);
}

// X1 = [inst(4096) | emb_dist(200) | pos(128) | pad->4480]  as bf16
__global__ void build_x1(const float* __restrict__ inst, const float* __restrict__ embd,
                         const int* __restrict__ labels, const float* __restrict__ pose,
                         unsigned short* __restrict__ X1b)
{
  const long total = (long)NOBJ * 4480;
  for (long i = blockIdx.x * (long)blockDim.x + threadIdx.x; i < total; i += (long)gridDim.x * blockDim.x) {
    int r = (int)(i / 4480), c = (int)(i - (long)r * 4480);
    float v;
    if (c < 4096)      v = inst[(long)r * 4096 + c];
    else if (c < 4296) v = embd[labels[r] * 200 + (c - 4096)];
    else if (c < 4424) v = pose[r * 128 + (c - 4296)];
    else               v = 0.0f;
    X1b[i] = f2bs(v);
  }
}

// augment = [emb_label(200) | inst(4096) | aug(512) | pad->4864]  as bf16
__global__ void build_aug(const float* __restrict__ embl, const int* __restrict__ labels,
                          const float* __restrict__ inst, const float* __restrict__ aug,
                          unsigned short* __restrict__ augb)
{
  const long total = (long)NOBJ * 4864;
  for (long i = blockIdx.x * (long)blockDim.x + threadIdx.x; i < total; i += (long)gridDim.x * blockDim.x) {
    int r = (int)(i / 4864), c = (int)(i - (long)r * 4864);
    float v;
    if (c < 200)       v = embl[labels[r] * 200 + c];
    else if (c < 4296) v = inst[(long)r * 4096 + (c - 200)];
    else if (c < 4808) v = aug[r * 512 + (c - 4296)];
    else               v = 0.0f;
    augb[i] = f2bs(v);
  }
}

// geo pair features (32 dims, padded to 64) as bf16
__global__ void build_geo(const float* __restrict__ obox, const int* __restrict__ sub,
                          const int* __restrict__ obj, unsigned short* __restrict__ geob)
{
  int r = blockIdx.x * blockDim.x + threadIdx.x;
  if (r >= NREL) return;
  const float* b1 = obox + sub[r] * 8;
  const float* b2 = obox + obj[r] * 8;
  float o[32];
#pragma unroll
  for (int j = 0; j < 8; j++) { o[j] = b1[j]; o[8+j] = b2[j]; }
  float ux1 = fminf(b1[0], b2[0]), uy1 = fminf(b1[1], b2[1]);
  float ux2 = fmaxf(b1[2], b2[2]), uy2 = fmaxf(b1[3], b2[3]);
  float uw = ux2 - ux1 + 1.0f, uh = uy2 - uy1 + 1.0f;
  o[16]=ux1; o[17]=uy1; o[18]=ux2; o[19]=uy2;
  o[20]=ux1+0.5f*uw; o[21]=uy1+0.5f*uh; o[22]=uw; o[23]=uh;
  float ix1 = fmaxf(b1[0], b2[0]), iy1 = fmaxf(b1[1], b2[1]);
  float ix2 = fminf(b1[2], b2[2]), iy2 = fminf(b1[3], b2[3]);
  bool bad = (ix2 < ix1) || (iy2 < iy1);
  float iw = ix2 - ix1 + 1.0f, ih = iy2 - iy1 + 1.0f;
  if (bad) {
#pragma unroll
    for (int j = 24; j < 32; j++) o[j] = 0.0f;
  } else {
    o[24]=ix1; o[25]=iy1; o[26]=ix2; o[27]=iy2;
    o[28]=ix1+0.5f*iw; o[29]=iy1+0.5f*ih; o[30]=iw; o[31]=ih;
  }
  unsigned short* gp = geob + (long)r * 64;
#pragma unroll
  for (int j = 0; j < 32; j++) gp[j] = f2bs(o[j]);
#pragma unroll
  for (int j = 32; j < 64; j++) gp[j] = 0;
}

// prodb[r][c] = pair[r][c] * spt[r][c]  (pair gathered from fused)
__global__ void build_prod(const float* __restrict__ fused, const float* __restrict__ spt,
                           const int* __restrict__ sub, const int* __restrict__ obj,
                           unsigned short* __restrict__ prodb)
{
  const long total = (long)NREL * 1024;
  for (long i = blockIdx.x * (long)blockDim.x + threadIdx.x; i < total; i += (long)gridDim.x * blockDim.x) {
    int r = (int)(i >> 10), c = (int)(i & 1023);
    int row = (c < 512) ? sub[r] : obj[r];
    prodb[i] = f2bs(fused[(long)row * 1024 + c] * spt[i]);
  }
}

// GRU with h=0: gi already has bih; gh = bhh. out = (1-z)*n
__global__ void gru_init(const float* __restrict__ gi, const float* __restrict__ bhh,
                         float* __restrict__ h, int n)
{
  const long total = (long)n * 512;
  for (long i = blockIdx.x * (long)blockDim.x + threadIdx.x; i < total; i += (long)gridDim.x * blockDim.x) {
    int r = (int)(i >> 9), c = (int)(i & 511);
    const float* gr = gi + (long)r * 1536;
    float rr = sigf(gr[c] + bhh[c]);
    float z  = sigf(gr[512 + c] + bhh[512 + c]);
    float nn = tanhf(gr[1024 + c] + rr * bhh[1024 + c]);
    h[i] = (1.0f - z) * nn;
  }
}

// GRU step (gi includes bih, gh includes bhh). In-place safe (elementwise).
__global__ void gru_step(const float* __restrict__ gi, const float* __restrict__ gh,
                         float* __restrict__ h, int n)
{
  const long total = (long)n * 512;
  for (long i = blockIdx.x * (long)blockDim.x + threadIdx.x; i < total; i += (long)gridDim.x * blockDim.x) {
    int r = (int)(i >> 9), c = (int)(i & 511);
    const float* gr = gi + (long)r * 1536;
    const float* hr = gh + (long)r * 1536;
    float rr = sigf(gr[c] + hr[c]);
    float z  = sigf(gr[512 + c] + hr[512 + c]);
    float nn = tanhf(gr[1024 + c] + rr * hr[1024 + c]);
    h[i] = (1.0f - z) * nn + z * h[i];
  }
}

// Fused per-relation: ws/wo dots, xb = ws*sv+wo*ov (bf16), ctx scatter-adds.
// One wave (64 lanes) per relation.
__global__ __launch_bounds__(256)
void edge_weights(const float* __restrict__ vert, const float* __restrict__ edge,
                  const int* __restrict__ sub, const int* __restrict__ obj,
                  const float* __restrict__ svwW, const float* __restrict__ svwb,
                  const float* __restrict__ ovwW, const float* __restrict__ ovwb,
                  unsigned short* __restrict__ xb, float* __restrict__ ctx)
{
  long gid = blockIdx.x * (long)blockDim.x + threadIdx.x;
  int r = (int)(gid >> 6);
  int l = (int)(gid & 63);
  if (r >= NREL) return;
  int s = sub[r], o = obj[r];
  const float* sv = vert + (long)s * 512;
  const float* ov = vert + (long)o * 512;
  const float* e  = edge + (long)r * 512;
  float svv[8], ovv[8], ev[8];
  float as = 0.0f, ao = 0.0f;
#pragma unroll
  for (int k = 0; k < 8; k++) {
    int c = l + k * 64;
    svv[k] = sv[c]; ovv[k] = ov[c]; ev[k] = e[c];
    as += svwW[c] * svv[k] + svwW[512 + c] * ev[k];
    ao += ovwW[c] * ovv[k] + ovwW[512 + c] * ev[k];
  }
#pragma unroll
  for (int off = 32; off > 0; off >>= 1) {
    as += __shfl_xor(as, off);
    ao += __shfl_xor(ao, off);
  }
  float ws = sigf(as + svwb[0]);
  float wo = sigf(ao + ovwb[0]);
#pragma unroll
  for (int k = 0; k < 8; k++) {
    int c = l + k * 64;
    xb[(long)r * 512 + c] = f2bs(ws * svv[k] + wo * ovv[k]);
    atomicAdd(ctx + (long)s * 512 + c, ws * ev[k]);
    atomicAdd(ctx + (long)o * 512 + c, wo * ev[k]);
  }
}

// ===================== driver =====================

static inline int nblk(long total) {
  long b = (total + 255) / 256;
  return (int)(b > 16384 ? 16384 : b);
}

extern "C" void kernel_launch(void* const* d_in, const int* in_sizes, int n_in,
                              void* d_out, int out_size, void* d_ws, size_t ws_size,
                              hipStream_t stream)
{
  const float* inst     = (const float*)d_in[0];
  const float* unionf   = (const float*)d_in[1];
  const float* boxes    = (const float*)d_in[2];
  const float* embd_W   = (const float*)d_in[3];
  const float* embl_W   = (const float*)d_in[4];
  const float* up_W     = (const float*)d_in[5];
  const float* up_b     = (const float*)d_in[6];
  const float* pairup_W = (const float*)d_in[7];
  const float* pairup_b = (const float*)d_in[8];
  const float* pos1_W   = (const float*)d_in[9];
  const float* pos1_b   = (const float*)d_in[10];
  const float* bn_g     = (const float*)d_in[11];
  const float* bn_b     = (const float*)d_in[12];
  const float* bn_m     = (const float*)d_in[13];
  const float* bn_v     = (const float*)d_in[14];
  const float* pos2_W   = (const float*)d_in[15];
  const float* pos2_b   = (const float*)d_in[16];
  const float* spt1_W   = (const float*)d_in[17];
  const float* spt1_b   = (const float*)d_in[18];
  const float* spt2_W   = (const float*)d_in[19];
  const float* spt2_b   = (const float*)d_in[20];
  const float* pairfin_W= (const float*)d_in[21];
  const float* pairfin_b= (const float*)d_in[22];
  const float* objhid_W = (const float*)d_in[23];
  const float* objhid_b = (const float*)d_in[24];
  const float* objfin_W = (const float*)d_in[25];
  const float* objfin_b = (const float*)d_in[26];
  const float* objU_W   = (const float*)d_in[27];
  const float* objU_b   = (const float*)d_in[28];
  const float* edgeU_W  = (const float*)d_in[29];
  const float* edgeU_b  = (const float*)d_in[30];
  const float* egru_Wih = (const float*)d_in[31];
  const float* egru_Whh = (const float*)d_in[32];
  const float* egru_bih = (const float*)d_in[33];
  const float* egru_bhh = (const float*)d_in[34];
  const float* ngru_Wih = (const float*)d_in[35];
  const float* ngru_Whh = (const float*)d_in[36];
  const float* ngru_bih = (const float*)d_in[37];
  const float* ngru_bhh = (const float*)d_in[38];
  const float* svw_W    = (const float*)d_in[39];
  const float* svw_b    = (const float*)d_in[40];
  const float* ovw_W    = (const float*)d_in[41];
  const float* ovw_b    = (const float*)d_in[42];
  const int*   labels   = (const int*)d_in[43];
  const int*   sub      = (const int*)d_in[44];
  const int*   obj      = (const int*)d_in[45];
  (void)in_sizes; (void)n_in; (void)out_size; (void)ws_size;

  char* base = (char*)d_ws;
  size_t off = 0;
  auto alloc = [&](size_t bytes) -> void* {
    void* p = base + off;
    off += (bytes + 255) & ~(size_t)255;
    return p;
  };

  // bf16 weight buffers (K padded to multiple of 64 where needed)
  unsigned short* objhid_Wb  = (unsigned short*)alloc(512L  * 4480 * 2);
  unsigned short* pairup_Wb  = (unsigned short*)alloc(1024L * 4864 * 2);
  unsigned short* objfin_Wb  = (unsigned short*)alloc(2048L * 4864 * 2);
  unsigned short* up_Wb      = (unsigned short*)alloc(2048L * 4096 * 2);
  unsigned short* pairfin_Wb = (unsigned short*)alloc(2048L * 1024 * 2);
  unsigned short* spt1_Wb    = (unsigned short*)alloc(512L  * 64   * 2);
  unsigned short* spt2_Wb    = (unsigned short*)alloc(1024L * 512  * 2);
  unsigned short* objU_Wb    = (unsigned short*)alloc(512L  * 2048 * 2);
  unsigned short* edgeU_Wb   = (unsigned short*)alloc(512L  * 2048 * 2);
  unsigned short* egru_Wihb  = (unsigned short*)alloc(1536L * 512  * 2);
  unsigned short* egru_Whhb  = (unsigned short*)alloc(1536L * 512  * 2);
  unsigned short* ngru_Wihb  = (unsigned short*)alloc(1536L * 512  * 2);
  unsigned short* ngru_Whhb  = (unsigned short*)alloc(1536L * 512  * 2);

  // activations
  float*          obox     = (float*)alloc(NOBJ * 8L * 4);
  float*          pose     = (float*)alloc(NOBJ * 128L * 4);
  unsigned short* X1b      = (unsigned short*)alloc((long)NOBJ * 4480 * 2);
  float*          aug      = (float*)alloc((long)NOBJ * 512 * 4);
  unsigned short* augb     = (unsigned short*)alloc((long)NOBJ * 4864 * 2);
  float*          fused    = (float*)alloc((long)NOBJ * 1024 * 4);
  float*          obj_feats= (float*)alloc((long)NOBJ * 2048 * 4);
  float*          obj_rep  = (float*)alloc((long)NOBJ * 512 * 4);
  float*          giv      = (float*)alloc((long)NOBJ * 1536 * 4);
  float*          ghv      = (float*)alloc((long)NOBJ * 1536 * 4);
  float*          vert     = (float*)alloc((long)NOBJ * 512 * 4);
  float*          ctx      = (float*)alloc((long)NOBJ * 512 * 4);
  unsigned short* geob     = (unsigned short*)alloc((long)NREL * 64 * 2);
  unsigned short* spt1b    = (unsigned short*)alloc((long)NREL * 512 * 2);
  float*          rel_rep  = (float*)alloc((long)NREL * 512 * 4);
  float*          edge     = (float*)alloc((long)NREL * 512 * 4);
  unsigned short* xb       = (unsigned short*)alloc((long)NREL * 512 * 2);
  // BIG1: spt (f32 NRELx1024) + prodb (bf16 NRELx1024); later reused as gh_e (NRELx1536 f32)
  char*  big1  = (char*)alloc((long)NREL * 1024 * 4 + (long)NREL * 1024 * 2);
  float*          spt   = (float*)big1;
  unsigned short* prodb = (unsigned short*)(big1 + (long)NREL * 1024 * 4);
  float*          gh_e  = (float*)big1;
  // BIG2: R (f32 NRELx2048); later reused as gi_e (NRELx1536 f32)
  char*  big2 = (char*)alloc((long)NREL * 2048 * 4);
  float* R    = (float*)big2;
  float* gi_e = (float*)big2;

  // ---- weight conversions ----
  cvt_pad<<<nblk(512L*4480),  256, 0, stream>>>(objhid_W,  objhid_Wb,  512,  4424, 4480);
  cvt_pad<<<nblk(1024L*4864), 256, 0, stream>>>(pairup_W,  pairup_Wb,  1024, 4808, 4864);
  cvt_pad<<<nblk(2048L*4864), 256, 0, stream>>>(objfin_W,  objfin_Wb,  2048, 4808, 4864);
  cvt_pad<<<nblk(2048L*4096), 256, 0, stream>>>(up_W,      up_Wb,      2048, 4096, 4096);
  cvt_pad<<<nblk(2048L*1024), 256, 0, stream>>>(pairfin_W, pairfin_Wb, 2048, 1024, 1024);
  cvt_pad<<<nblk(512L*64),    256, 0, stream>>>(spt1_W,    spt1_Wb,    512,  32,   64);
  cvt_pad<<<nblk(1024L*512),  256, 0, stream>>>(spt2_W,    spt2_Wb,    1024, 512,  512);
  cvt_pad<<<nblk(512L*2048),  256, 0, stream>>>(objU_W,    objU_Wb,    512,  2048, 2048);
  cvt_pad<<<nblk(512L*2048),  256, 0, stream>>>(edgeU_W,   edgeU_Wb,   512,  2048, 2048);
  cvt_pad<<<nblk(1536L*512),  256, 0, stream>>>(egru_Wih,  egru_Wihb,  1536, 512,  512);
  cvt_pad<<<nblk(1536L*512),  256, 0, stream>>>(egru_Whh,  egru_Whhb,  1536, 512,  512);
  cvt_pad<<<nblk(1536L*512),  256, 0, stream>>>(ngru_Wih,  ngru_Wihb,  1536, 512,  512);
  cvt_pad<<<nblk(1536L*512),  256, 0, stream>>>(ngru_Whh,  ngru_Whhb,  1536, 512,  512);

  // ---- object stream ----
  obox_k<<<(NOBJ + 255) / 256, 256, 0, stream>>>(boxes, obox);
  posembed_k<<<NOBJ, 128, 0, stream>>>(boxes, pos1_W, pos1_b, bn_g, bn_b, bn_m, bn_v,
                                       pos2_W, pos2_b, pose);
  build_x1<<<nblk((long)NOBJ*4480), 256, 0, stream>>>(inst, embd_W, labels, pose, X1b);
  // aug = X1 @ objhid^T + b
  gemm_bt<true,  false, false, false><<<dim3((NOBJ>>7)*(512>>7)),  256, 0, stream>>>(X1b, objhid_Wb, objhid_b, aug, NOBJ, 512, 4480);
  build_aug<<<nblk((long)NOBJ*4864), 256, 0, stream>>>(embl_W, labels, inst, aug, augb);
  // fused = augment @ pairup^T + b
  gemm_bt<true,  false, false, false><<<dim3((NOBJ>>7)*(1024>>7)), 256, 0, stream>>>(augb, pairup_Wb, pairup_b, fused, NOBJ, 1024, 4864);
  // obj_feats = relu(augment @ objfin^T + b)
  gemm_bt<true,  true,  false, false><<<dim3((NOBJ>>7)*(2048>>7)), 256, 0, stream>>>(augb, objfin_Wb, objfin_b, obj_feats, NOBJ, 2048, 4864);
  // obj_rep = obj_feats @ objU^T + b
  gemm_bt<false, false, false, false><<<dim3((NOBJ>>7)*(512>>7)),  256, 0, stream>>>(obj_feats, objU_Wb, objU_b, obj_rep, NOBJ, 512, 2048);
  // vert = GRU(obj_rep, 0)
  gemm_bt<false, false, false, false><<<dim3((NOBJ>>7)*(1536>>7)), 256, 0, stream>>>(obj_rep, ngru_Wihb, ngru_bih, giv, NOBJ, 1536, 512);
  gru_init<<<nblk((long)NOBJ*512), 256, 0, stream>>>(giv, ngru_bhh, vert, NOBJ);

  // ---- relation stream ----
  build_geo<<<(NREL + 255) / 256, 256, 0, stream>>>(obox, sub, obj, geob);
  // spt1 = relu(geo @ spt1^T + b)  -> bf16
  gemm_bt<true,  true,  false, true ><<<dim3((NREL>>7)*(512>>7)),  256, 0, stream>>>(geob, spt1_Wb, spt1_b, spt1b, NREL, 512, 64);
  // spt = relu(spt1 @ spt2^T + b)
  gemm_bt<true,  true,  false, false><<<dim3((NREL>>7)*(1024>>7)), 256, 0, stream>>>(spt1b, spt2_Wb, spt2_b, spt, NREL, 1024, 512);
  build_prod<<<nblk((long)NREL*1024), 256, 0, stream>>>(fused, spt, sub, obj, prodb);
  // R = relu(prod @ pairfin^T + b)
  gemm_bt<true,  true,  false, false><<<dim3((NREL>>7)*(2048>>7)), 256, 0, stream>>>(prodb, pairfin_Wb, pairfin_b, R, NREL, 2048, 1024);
  // R += union @ up^T + b
  gemm_bt<false, false, true,  false><<<dim3((NREL>>7)*(2048>>7)), 256, 0, stream>>>(unionf, up_Wb, up_b, R, NREL, 2048, 4096);
  // rel_rep = relu(R @ edgeU^T + b)
  gemm_bt<false, true,  false, false><<<dim3((NREL>>7)*(512>>7)),  256, 0, stream>>>(R, edgeU_Wb, edgeU_b, rel_rep, NREL, 512, 2048);
  // edge = GRU(rel_rep, 0)
  gemm_bt<false, false, false, false><<<dim3((NREL>>7)*(1536>>7)), 256, 0, stream>>>(rel_rep, egru_Wihb, egru_bih, gi_e, NREL, 1536, 512);
  gru_init<<<nblk((long)NREL*512), 256, 0, stream>>>(gi_e, egru_bhh, edge, NREL);

  // ---- message-passing loop ----
  for (int it = 0; it < 3; it++) {
    hipMemsetAsync(ctx, 0, (long)NOBJ * 512 * 4, stream);
    edge_weights<<<(NREL * 64) / 256, 256, 0, stream>>>(vert, edge, sub, obj,
                                                        svw_W, svw_b, ovw_W, ovw_b, xb, ctx);
    gemm_bt<true,  false, false, false><<<dim3((NREL>>7)*(1536>>7)), 256, 0, stream>>>(xb,   egru_Wihb, egru_bih, gi_e, NREL, 1536, 512);
    gemm_bt<false, false, false, false><<<dim3((NREL>>7)*(1536>>7)), 256, 0, stream>>>(edge, egru_Whhb, egru_bhh, gh_e, NREL, 1536, 512);
    gemm_bt<false, false, false, false><<<dim3((NOBJ>>7)*(1536>>7)), 256, 0, stream>>>(ctx,  ngru_Wihb, ngru_bih, giv, NOBJ, 1536, 512);
    gemm_bt<false, false, false, false><<<dim3((NOBJ>>7)*(1536>>7)), 256, 0, stream>>>(vert, ngru_Whhb, ngru_bhh, ghv, NOBJ, 1536, 512);
    gru_step<<<nblk((long)NREL*512), 256, 0, stream>>>(gi_e, gh_e, edge, NREL);
    gru_step<<<nblk((long)NOBJ*512), 256, 0, stream>>>(giv, ghv, vert, NOBJ);
  }

  // ---- output: concat(vert, edge) ----
  hipMemcpyAsync(d_out, vert, (long)NOBJ * 512 * 4, hipMemcpyDeviceToDevice, stream);
  hipMemcpyAsync((char*)d_out + (long)NOBJ * 512 * 4, edge, (long)NREL * 512 * 4,
                 hipMemcpyDeviceToDevice, stream);
}

// Round 2
// 2872.720 us; speedup vs baseline: 1.6578x; 1.6578x over previous
//
#include <hip/hip_runtime.h>
#include <stdint.h>

#define NOBJ 2048
#define NREL 32768

typedef __attribute__((ext_vector_type(8))) short short8;
typedef __attribute__((ext_vector_type(4))) float f32x4;
typedef __attribute__((ext_vector_type(4))) unsigned short ushort4v;

__device__ __forceinline__ unsigned short f2bs(float x){
  unsigned u = __float_as_uint(x);
  unsigned v = u + 0x7fffu + ((u >> 16) & 1u);
  return (unsigned short)(v >> 16);
}
__device__ __forceinline__ float sigf(float x){ return 1.0f / (1.0f + expf(-x)); }

// async global->LDS, 16B per lane. LDS dest = wave-uniform base + lane*16.
__device__ __forceinline__ void gload16(const unsigned short* g, unsigned short* l) {
  __builtin_amdgcn_global_load_lds(
      (const __attribute__((address_space(1))) unsigned int*)(uintptr_t)g,
      (__attribute__((address_space(3))) unsigned int*)(uintptr_t)l,
      16, 0, 0);
}

// =====================  GEMM: C = f(A * B^T + bias [+Cin])  =====================
// A: MxK bf16 row-major. B: NxK bf16 row-major. M,N mult of 128; K mult of 32.
// RMODE: 0 = none; 1 = relu(acc+bias) then (+Cin); 2 = relu(acc+bias+Cin).
// LDS tile [128][32] bf16, staged with global_load_lds; 16B slots XOR-swizzled by
// (row>>1)&3 on BOTH the global source and the ds_read (rule #21) -> 2 lanes/bank.
template<int RMODE, bool ACCUM, bool OUTB>
__global__ __launch_bounds__(256, 2)
void gemm_bt(const unsigned short* __restrict__ A, const unsigned short* __restrict__ B,
             const float* __restrict__ bias, const float* __restrict__ Cin,
             void* __restrict__ Cp, int M, int N, int K)
{
  __shared__ __align__(16) unsigned short As[128 * 32];
  __shared__ __align__(16) unsigned short Bs[128 * 32];
  const int t = threadIdx.x;
  const int lane = t & 63;
  const int w = t >> 6;
  const int ntile = N >> 7;
  const int bm = blockIdx.x / ntile;
  const int bn = blockIdx.x - bm * ntile;
  const int m0 = bm << 7, n0 = bn << 7;
  const int wm = (w & 1) << 6, wn = (w >> 1) << 6;
  const int lrow = lane & 15, kg = lane >> 4;

  // staging geometry: wave w fills 1KB chunks {2w,2w+1} of As and Bs.
  const int c0 = w << 1;
  const int srow = (c0 << 4) + (lane >> 2);            // tile row for chunk c0
  const int selem = (((lane & 3) ^ ((lane >> 3) & 3)) << 3);  // swizzled source slot
  const unsigned short* ag0 = A + (long)(m0 + srow) * K + selem;
  const unsigned short* ag1 = ag0 + (long)16 * K;
  const unsigned short* bg0 = B + (long)(n0 + srow) * K + selem;
  const unsigned short* bg1 = bg0 + (long)16 * K;
  unsigned short* al0 = As + (c0 << 9);
  unsigned short* al1 = al0 + 512;
  unsigned short* bl0 = Bs + (c0 << 9);
  unsigned short* bl1 = bl0 + 512;

  // fragment-read slot swizzle (same involution)
  const int fslotA = ((lrow >> 1) & 3);

  f32x4 acc[4][4] = {};

  for (int k0 = 0; k0 < K; k0 += 32) {
    gload16(ag0 + k0, al0);
    gload16(ag1 + k0, al1);
    gload16(bg0 + k0, bl0);
    gload16(bg1 + k0, bl1);
    __syncthreads();   // drains vmcnt before barrier (compiler-inserted)
    short8 afr[4], bfr[4];
#pragma unroll
    for (int i = 0; i < 4; i++)
      afr[i] = *(const short8*)(As + (wm + i * 16 + lrow) * 32 + ((kg ^ fslotA) << 3));
#pragma unroll
    for (int j = 0; j < 4; j++)
      bfr[j] = *(const short8*)(Bs + (wn + j * 16 + lrow) * 32 + ((kg ^ fslotA) << 3));
#pragma unroll
    for (int i = 0; i < 4; i++)
#pragma unroll
      for (int j = 0; j < 4; j++)
        acc[i][j] = __builtin_amdgcn_mfma_f32_16x16x32_bf16(afr[i], bfr[j], acc[i][j], 0, 0, 0);
    __syncthreads();
  }

  float* Cf = (float*)Cp;
  unsigned short* Cb = (unsigned short*)Cp;
#pragma unroll
  for (int i = 0; i < 4; i++) {
#pragma unroll
    for (int j = 0; j < 4; j++) {
      const int col = n0 + wn + j * 16 + lrow;
      const float bv = bias[col];
#pragma unroll
      for (int q = 0; q < 4; q++) {
        const long row = m0 + wm + i * 16 + kg * 4 + q;
        float v = acc[i][j][q] + bv;
        if constexpr (RMODE == 1) v = fmaxf(v, 0.0f);
        if constexpr (ACCUM) v += Cin[row * (long)N + col];
        if constexpr (RMODE == 2) v = fmaxf(v, 0.0f);
        if constexpr (OUTB) Cb[row * (long)N + col] = f2bs(v);
        else Cf[row * (long)N + col] = v;
      }
    }
  }
}

// ===================== small kernels =====================

// f32 -> bf16 with row padding K0 -> Kp (pad zeros), scalar
__global__ void cvt_pad(const float* __restrict__ src, unsigned short* __restrict__ dst,
                        int rows, int K0, int Kp)
{
  const long total = (long)rows * Kp;
  for (long i = blockIdx.x * (long)blockDim.x + threadIdx.x; i < total; i += (long)gridDim.x * blockDim.x) {
    int r = (int)(i / Kp), k = (int)(i - (long)r * Kp);
    dst[i] = (k < K0) ? f2bs(src[(long)r * K0 + k]) : (unsigned short)0;
  }
}

// f32 -> bf16, vectorized x4 (count must be multiple of 4)
__global__ void cvt4(const float* __restrict__ src, unsigned short* __restrict__ dst, long n4)
{
  for (long i = blockIdx.x * (long)blockDim.x + threadIdx.x; i < n4; i += (long)gridDim.x * blockDim.x) {
    f32x4 v = ((const f32x4*)src)[i];
    ushort4v o;
    o[0] = f2bs(v[0]); o[1] = f2bs(v[1]); o[2] = f2bs(v[2]); o[3] = f2bs(v[3]);
    ((ushort4v*)dst)[i] = o;
  }
}

// dst[c][r] = bf16(src[r][c]);  R,C multiples of 32. block (32,8), grid (C/32, R/32)
__global__ void transpose_cvt(const float* __restrict__ src, unsigned short* __restrict__ dst,
                              int R, int C)
{
  __shared__ float tile[32][33];
  int c0 = blockIdx.x * 32, r0 = blockIdx.y * 32;
  for (int i = threadIdx.y; i < 32; i += 8)
    tile[i][threadIdx.x] = src[(long)(r0 + i) * C + c0 + threadIdx.x];
  __syncthreads();
  for (int i = threadIdx.y; i < 32; i += 8)
    dst[(long)(c0 + i) * R + r0 + threadIdx.x] = f2bs(tile[threadIdx.x][i]);
}

// b_comp[j] = edgeU_b[j] + sum_k edgeU_W[j][k] * up_b[k];  one wave per j
__global__ void comp_bias(const float* __restrict__ edgeU_W, const float* __restrict__ up_b,
                          const float* __restrict__ edgeU_b, float* __restrict__ b_comp)
{
  int j = (int)((blockIdx.x * (long)blockDim.x + threadIdx.x) >> 6);
  int l = threadIdx.x & 63;
  if (j >= 512) return;
  float s = 0.0f;
  for (int k = l; k < 2048; k += 64) s += edgeU_W[(long)j * 2048 + k] * up_b[k];
#pragma unroll
  for (int off = 32; off > 0; off >>= 1) s += __shfl_xor(s, off);
  if (l == 0) b_comp[j] = s + edgeU_b[j];
}

__global__ void obox_k(const float* __restrict__ boxes, float* __restrict__ obox)
{
  int i = blockIdx.x * blockDim.x + threadIdx.x;
  if (i >= NOBJ) return;
  float x1 = boxes[i*4], y1 = boxes[i*4+1], x2 = boxes[i*4+2], y2 = boxes[i*4+3];
  float wdt = x2 - x1 + 1.0f, hgt = y2 - y1 + 1.0f;
  float cx = x1 + 0.5f * wdt, cy = y1 + 0.5f * hgt;
  const float inv = 1.0f / 1024.0f;
  float* o = obox + i * 8;
  o[0]=x1*inv; o[1]=y1*inv; o[2]=x2*inv; o[3]=y2*inv;
  o[4]=cx*inv; o[5]=cy*inv; o[6]=wdt*inv; o[7]=hgt*inv;
}

__global__ void posembed_k(const float* __restrict__ boxes,
                           const float* __restrict__ w1, const float* __restrict__ b1,
                           const float* __restrict__ g, const float* __restrict__ bb,
                           const float* __restrict__ mm, const float* __restrict__ vv,
                           const float* __restrict__ w2, const float* __restrict__ b2,
                           float* __restrict__ out)
{
  int o = blockIdx.x, t = threadIdx.x;
  __shared__ float e[9];
  __shared__ float p[32];
  if (t == 0) {
    float x1 = boxes[o*4], y1 = boxes[o*4+1], x2 = boxes[o*4+2], y2 = boxes[o*4+3];
    float wdt = x2 - x1 + 1.0f, hgt = y2 - y1 + 1.0f;
    float cx = x1 + 0.5f * wdt, cy = y1 + 0.5f * hgt;
    e[0]=wdt/1024.0f; e[1]=hgt/768.0f; e[2]=cx/1024.0f; e[3]=cy/768.0f;
    e[4]=x1/1024.0f;  e[5]=y1/768.0f;  e[6]=x2/1024.0f; e[7]=y2/768.0f;
    e[8]=wdt*hgt/(1024.0f*768.0f);
  }
  __syncthreads();
  if (t < 32) {
    float s = b1[t];
#pragma unroll
    for (int j = 0; j < 9; j++) s += w1[t*9+j] * e[j];
    s = (s - mm[t]) * g[t] / sqrtf(vv[t] + 1e-5f) + bb[t];
    p[t] = s;
  }
  __syncthreads();
  float s = b2[t];
#pragma unroll
  for (int j = 0; j < 32; j++) s += w2[t*32+j] * p[j];
  out[o*128 + t] = fmaxf(s, 0.0f);
}

// X1 = [inst(4096) | emb_dist(200) | pos(128) | pad->4480]  as bf16
__global__ void build_x1(const float* __restrict__ inst, const float* __restrict__ embd,
                         const int* __restrict__ labels, const float* __restrict__ pose,
                         unsigned short* __restrict__ X1b)
{
  const long total = (long)NOBJ * 4480;
  for (long i = blockIdx.x * (long)blockDim.x + threadIdx.x; i < total; i += (long)gridDim.x * blockDim.x) {
    int r = (int)(i / 4480), c = (int)(i - (long)r * 4480);
    float v;
    if (c < 4096)      v = inst[(long)r * 4096 + c];
    else if (c < 4296) v = embd[labels[r] * 200 + (c - 4096)];
    else if (c < 4424) v = pose[r * 128 + (c - 4296)];
    else               v = 0.0f;
    X1b[i] = f2bs(v);
  }
}

// augment = [emb_label(200) | inst(4096) | aug(512) | pad->4864]  as bf16
__global__ void build_aug(const float* __restrict__ embl, const int* __restrict__ labels,
                          const float* __restrict__ inst, const float* __restrict__ aug,
                          unsigned short* __restrict__ augb)
{
  const long total = (long)NOBJ * 4864;
  for (long i = blockIdx.x * (long)blockDim.x + threadIdx.x; i < total; i += (long)gridDim.x * blockDim.x) {
    int r = (int)(i / 4864), c = (int)(i - (long)r * 4864);
    float v;
    if (c < 200)       v = embl[labels[r] * 200 + c];
    else if (c < 4296) v = inst[(long)r * 4096 + (c - 200)];
    else if (c < 4808) v = aug[r * 512 + (c - 4296)];
    else               v = 0.0f;
    augb[i] = f2bs(v);
  }
}

// geo pair features (32 dims, padded to 64) as bf16
__global__ void build_geo(const float* __restrict__ obox, const int* __restrict__ sub,
                          const int* __restrict__ obj, unsigned short* __restrict__ geob)
{
  int r = blockIdx.x * blockDim.x + threadIdx.x;
  if (r >= NREL) return;
  const float* b1 = obox + sub[r] * 8;
  const float* b2 = obox + obj[r] * 8;
  float o[32];
#pragma unroll
  for (int j = 0; j < 8; j++) { o[j] = b1[j]; o[8+j] = b2[j]; }
  float ux1 = fminf(b1[0], b2[0]), uy1 = fminf(b1[1], b2[1]);
  float ux2 = fmaxf(b1[2], b2[2]), uy2 = fmaxf(b1[3], b2[3]);
  float uw = ux2 - ux1 + 1.0f, uh = uy2 - uy1 + 1.0f;
  o[16]=ux1; o[17]=uy1; o[18]=ux2; o[19]=uy2;
  o[20]=ux1+0.5f*uw; o[21]=uy1+0.5f*uh; o[22]=uw; o[23]=uh;
  float ix1 = fmaxf(b1[0], b2[0]), iy1 = fmaxf(b1[1], b2[1]);
  float ix2 = fminf(b1[2], b2[2]), iy2 = fminf(b1[3], b2[3]);
  bool bad = (ix2 < ix1) || (iy2 < iy1);
  float iw = ix2 - ix1 + 1.0f, ih = iy2 - iy1 + 1.0f;
  if (bad) {
#pragma unroll
    for (int j = 24; j < 32; j++) o[j] = 0.0f;
  } else {
    o[24]=ix1; o[25]=iy1; o[26]=ix2; o[27]=iy2;
    o[28]=ix1+0.5f*iw; o[29]=iy1+0.5f*ih; o[30]=iw; o[31]=ih;
  }
  unsigned short* gp = geob + (long)r * 64;
#pragma unroll
  for (int j = 0; j < 32; j++) gp[j] = f2bs(o[j]);
#pragma unroll
  for (int j = 32; j < 64; j++) gp[j] = 0;
}

// prodb[r][c] = pair[r][c] * spt[r][c]
__global__ void build_prod(const float* __restrict__ fused, const float* __restrict__ spt,
                           const int* __restrict__ sub, const int* __restrict__ obj,
                           unsigned short* __restrict__ prodb)
{
  const long total = (long)NREL * 1024;
  for (long i = blockIdx.x * (long)blockDim.x + threadIdx.x; i < total; i += (long)gridDim.x * blockDim.x) {
    int r = (int)(i >> 10), c = (int)(i & 1023);
    int row = (c < 512) ? sub[r] : obj[r];
    prodb[i] = f2bs(fused[(long)row * 1024 + c] * spt[i]);
  }
}

// GRU with h=0: out = (1-z)*n  (writes f32 + bf16 mirror)
__global__ void gru_init(const float* __restrict__ gi, const float* __restrict__ bhh,
                         float* __restrict__ h, unsigned short* __restrict__ hb, int n)
{
  const long total = (long)n * 512;
  for (long i = blockIdx.x * (long)blockDim.x + threadIdx.x; i < total; i += (long)gridDim.x * blockDim.x) {
    int r = (int)(i >> 9), c = (int)(i & 511);
    const float* gr = gi + (long)r * 1536;
    float rr = sigf(gr[c] + bhh[c]);
    float z  = sigf(gr[512 + c] + bhh[512 + c]);
    float nn = tanhf(gr[1024 + c] + rr * bhh[1024 + c]);
    float v = (1.0f - z) * nn;
    h[i] = v;
    hb[i] = f2bs(v);
  }
}

// GRU step (gi includes bih, gh includes bhh). In-place safe.
__global__ void gru_step(const float* __restrict__ gi, const float* __restrict__ gh,
                         float* __restrict__ h, unsigned short* __restrict__ hb, int n)
{
  const long total = (long)n * 512;
  for (long i = blockIdx.x * (long)blockDim.x + threadIdx.x; i < total; i += (long)gridDim.x * blockDim.x) {
    int r = (int)(i >> 9), c = (int)(i & 511);
    const float* gr = gi + (long)r * 1536;
    const float* hr = gh + (long)r * 1536;
    float rr = sigf(gr[c] + hr[c]);
    float z  = sigf(gr[512 + c] + hr[512 + c]);
    float nn = tanhf(gr[1024 + c] + rr * hr[1024 + c]);
    float v = (1.0f - z) * nn + z * h[i];
    h[i] = v;
    hb[i] = f2bs(v);
  }
}

// Fused per-relation: ws/wo dots, xb = ws*sv+wo*ov (bf16), ctx scatter-adds.
__global__ __launch_bounds__(256)
void edge_weights(const float* __restrict__ vert, const float* __restrict__ edge,
                  const int* __restrict__ sub, const int* __restrict__ obj,
                  const float* __restrict__ svwW, const float* __restrict__ svwb,
                  const float* __restrict__ ovwW, const float* __restrict__ ovwb,
                  unsigned short* __restrict__ xb, float* __restrict__ ctx)
{
  long gid = blockIdx.x * (long)blockDim.x + threadIdx.x;
  int r = (int)(gid >> 6);
  int l = (int)(gid & 63);
  if (r >= NREL) return;
  int s = sub[r], o = obj[r];
  const float* sv = vert + (long)s * 512;
  const float* ov = vert + (long)o * 512;
  const float* e  = edge + (long)r * 512;
  float svv[8], ovv[8], ev[8];
  float as = 0.0f, ao = 0.0f;
#pragma unroll
  for (int k = 0; k < 8; k++) {
    int c = l + k * 64;
    svv[k] = sv[c]; ovv[k] = ov[c]; ev[k] = e[c];
    as += svwW[c] * svv[k] + svwW[512 + c] * ev[k];
    ao += ovwW[c] * ovv[k] + ovwW[512 + c] * ev[k];
  }
#pragma unroll
  for (int off = 32; off > 0; off >>= 1) {
    as += __shfl_xor(as, off);
    ao += __shfl_xor(ao, off);
  }
  float ws = sigf(as + svwb[0]);
  float wo = sigf(ao + ovwb[0]);
#pragma unroll
  for (int k = 0; k < 8; k++) {
    int c = l + k * 64;
    xb[(long)r * 512 + c] = f2bs(ws * svv[k] + wo * ovv[k]);
    atomicAdd(ctx + (long)s * 512 + c, ws * ev[k]);
    atomicAdd(ctx + (long)o * 512 + c, wo * ev[k]);
  }
}

// ===================== driver =====================

static inline int nblk(long total) {
  long b = (total + 255) / 256;
  return (int)(b > 16384 ? 16384 : b);
}

extern "C" void kernel_launch(void* const* d_in, const int* in_sizes, int n_in,
                              void* d_out, int out_size, void* d_ws, size_t ws_size,
                              hipStream_t stream)
{
  const float* inst     = (const float*)d_in[0];
  const float* unionf   = (const float*)d_in[1];
  const float* boxes    = (const float*)d_in[2];
  const float* embd_W   = (const float*)d_in[3];
  const float* embl_W   = (const float*)d_in[4];
  const float* up_W     = (const float*)d_in[5];
  const float* up_b     = (const float*)d_in[6];
  const float* pairup_W = (const float*)d_in[7];
  const float* pairup_b = (const float*)d_in[8];
  const float* pos1_W   = (const float*)d_in[9];
  const float* pos1_b   = (const float*)d_in[10];
  const float* bn_g     = (const float*)d_in[11];
  const float* bn_b     = (const float*)d_in[12];
  const float* bn_m     = (const float*)d_in[13];
  const float* bn_v     = (const float*)d_in[14];
  const float* pos2_W   = (const float*)d_in[15];
  const float* pos2_b   = (const float*)d_in[16];
  const float* spt1_W   = (const float*)d_in[17];
  const float* spt1_b   = (const float*)d_in[18];
  const float* spt2_W   = (const float*)d_in[19];
  const float* spt2_b   = (const float*)d_in[20];
  const float* pairfin_W= (const float*)d_in[21];
  const float* pairfin_b= (const float*)d_in[22];
  const float* objhid_W = (const float*)d_in[23];
  const float* objhid_b = (const float*)d_in[24];
  const float* objfin_W = (const float*)d_in[25];
  const float* objfin_b = (const float*)d_in[26];
  const float* objU_W   = (const float*)d_in[27];
  const float* objU_b   = (const float*)d_in[28];
  const float* edgeU_W  = (const float*)d_in[29];
  const float* edgeU_b  = (const float*)d_in[30];
  const float* egru_Wih = (const float*)d_in[31];
  const float* egru_Whh = (const float*)d_in[32];
  const float* egru_bih = (const float*)d_in[33];
  const float* egru_bhh = (const float*)d_in[34];
  const float* ngru_Wih = (const float*)d_in[35];
  const float* ngru_Whh = (const float*)d_in[36];
  const float* ngru_bih = (const float*)d_in[37];
  const float* ngru_bhh = (const float*)d_in[38];
  const float* svw_W    = (const float*)d_in[39];
  const float* svw_b    = (const float*)d_in[40];
  const float* ovw_W    = (const float*)d_in[41];
  const float* ovw_b    = (const float*)d_in[42];
  const int*   labels   = (const int*)d_in[43];
  const int*   sub      = (const int*)d_in[44];
  const int*   obj      = (const int*)d_in[45];
  (void)in_sizes; (void)n_in; (void)out_size; (void)ws_size;

  char* base = (char*)d_ws;
  size_t off = 0;
  auto alloc = [&](size_t bytes) -> void* {
    void* p = base + off;
    off += (bytes + 255) & ~(size_t)255;
    return p;
  };

  // ---- weights (bf16) ----
  unsigned short* objhid_Wb  = (unsigned short*)alloc(512L  * 4480 * 2);
  unsigned short* pairup_Wb  = (unsigned short*)alloc(1024L * 4864 * 2);
  unsigned short* objfin_Wb  = (unsigned short*)alloc(2048L * 4864 * 2);
  unsigned short* up_Wtb     = (unsigned short*)alloc(4096L * 2048 * 2);  // up_W transposed
  unsigned short* pairfin_Wb = (unsigned short*)alloc(2048L * 1024 * 2);
  unsigned short* spt1_Wb    = (unsigned short*)alloc(512L  * 64   * 2);
  unsigned short* spt2_Wb    = (unsigned short*)alloc(1024L * 512  * 2);
  unsigned short* objU_Wb    = (unsigned short*)alloc(512L  * 2048 * 2);
  unsigned short* edgeU_Wb   = (unsigned short*)alloc(512L  * 2048 * 2);
  unsigned short* egru_Wihb  = (unsigned short*)alloc(1536L * 512  * 2);
  unsigned short* egru_Whhb  = (unsigned short*)alloc(1536L * 512  * 2);
  unsigned short* ngru_Wihb  = (unsigned short*)alloc(1536L * 512  * 2);
  unsigned short* ngru_Whhb  = (unsigned short*)alloc(1536L * 512  * 2);
  unsigned short* W_compb    = (unsigned short*)alloc(512L  * 4096 * 2);  // edgeU@up
  float*          b_comp     = (float*)alloc(512L * 4);
  float*          zbias      = (float*)alloc(4096L * 4);

  // ---- activations ----
  float*          obox      = (float*)alloc(NOBJ * 8L * 4);
  float*          pose      = (float*)alloc(NOBJ * 128L * 4);
  float*          aug       = (float*)alloc((long)NOBJ * 512 * 4);
  unsigned short* obj_featsb= (unsigned short*)alloc((long)NOBJ * 2048 * 2);
  unsigned short* obj_repb  = (unsigned short*)alloc((long)NOBJ * 512 * 2);
  float*          giv       = (float*)alloc((long)NOBJ * 1536 * 4);
  float*          ghv       = (float*)alloc((long)NOBJ * 1536 * 4);
  float*          vert      = (float*)alloc((long)NOBJ * 512 * 4);
  unsigned short* vertb     = (unsigned short*)alloc((long)NOBJ * 512 * 2);
  float*          ctx       = (float*)alloc((long)NOBJ * 512 * 4);
  unsigned short* ctxb      = (unsigned short*)alloc((long)NOBJ * 512 * 2);
  unsigned short* geob      = (unsigned short*)alloc((long)NREL * 64 * 2);
  float*          edge      = (float*)alloc((long)NREL * 512 * 4);

  // REGION_A (64MB): X1b (early) -> T1 (f32 NRELx512)
  char* regA = (char*)alloc((long)NREL * 512 * 4);
  unsigned short* X1b = (unsigned short*)regA;
  float*          T1  = (float*)regA;
  // REGION_B (32MB): augb (early) -> rel_repb (bf16 NRELx512)
  char* regB = (char*)alloc((long)NREL * 512 * 2);
  unsigned short* augb     = (unsigned short*)regB;
  unsigned short* rel_repb = (unsigned short*)regB;
  // REGION_C (32MB): fused (f32 NOBJx1024) -> xb (bf16 NRELx512)
  char* regC = (char*)alloc((long)NREL * 512 * 2);
  float*          fused = (float*)regC;
  unsigned short* xb    = (unsigned short*)regC;
  // REGION_D (32MB): spt1b -> edgeb
  char* regD = (char*)alloc((long)NREL * 512 * 2);
  unsigned short* spt1b = (unsigned short*)regD;
  unsigned short* edgeb = (unsigned short*)regD;
  // BIG1 (192MB): [sptf f32 NRELx1024 | prodb bf16 NRELx1024] -> G1 (bf16 NRELx2048 @0) -> gi_e
  char* big1 = (char*)alloc((long)NREL * 1536 * 4);
  float*          sptf  = (float*)big1;
  unsigned short* prodb = (unsigned short*)(big1 + (long)NREL * 1024 * 4);
  unsigned short* G1    = (unsigned short*)big1;
  float*          gi_e  = (float*)big1;
  // REGION_U (256MB): unionb (bf16 NRELx4096) -> gh_e (f32 NRELx1536)
  char* regU = (char*)alloc((long)NREL * 4096 * 2);
  unsigned short* unionb = (unsigned short*)regU;
  float*          gh_e   = (float*)regU;

  // ---- weight conversions ----
  cvt_pad<<<nblk(512L*4480),  256, 0, stream>>>(objhid_W,  objhid_Wb,  512,  4424, 4480);
  cvt_pad<<<nblk(1024L*4864), 256, 0, stream>>>(pairup_W,  pairup_Wb,  1024, 4808, 4864);
  cvt_pad<<<nblk(2048L*4864), 256, 0, stream>>>(objfin_W,  objfin_Wb,  2048, 4808, 4864);
  cvt_pad<<<nblk(512L*64),    256, 0, stream>>>(spt1_W,    spt1_Wb,    512,  32,   64);
  cvt4<<<nblk(2048L*1024/4), 256, 0, stream>>>(pairfin_W, pairfin_Wb, 2048L*1024/4);
  cvt4<<<nblk(1024L*512/4),  256, 0, stream>>>(spt2_W,    spt2_Wb,    1024L*512/4);
  cvt4<<<nblk(512L*2048/4),  256, 0, stream>>>(objU_W,    objU_Wb,    512L*2048/4);
  cvt4<<<nblk(512L*2048/4),  256, 0, stream>>>(edgeU_W,   edgeU_Wb,   512L*2048/4);
  cvt4<<<nblk(1536L*512/4),  256, 0, stream>>>(egru_Wih,  egru_Wihb,  1536L*512/4);
  cvt4<<<nblk(1536L*512/4),  256, 0, stream>>>(egru_Whh,  egru_Whhb,  1536L*512/4);
  cvt4<<<nblk(1536L*512/4),  256, 0, stream>>>(ngru_Wih,  ngru_Wihb,  1536L*512/4);
  cvt4<<<nblk(1536L*512/4),  256, 0, stream>>>(ngru_Whh,  ngru_Whhb,  1536L*512/4);
  transpose_cvt<<<dim3(4096/32, 2048/32), dim3(32, 8), 0, stream>>>(up_W, up_Wtb, 2048, 4096);
  hipMemsetAsync(zbias, 0, 4096L * 4, stream);
  comp_bias<<<128, 256, 0, stream>>>(edgeU_W, up_b, edgeU_b, b_comp);
  // W_comp = edgeU_W @ up_W : A=edgeU_Wb (512x2048), B=up_Wtb (4096x2048) -> bf16 (512x4096)
  gemm_bt<0,false,true><<<dim3((512>>7)*(4096>>7)), 256, 0, stream>>>(edgeU_Wb, up_Wtb, zbias, nullptr, W_compb, 512, 4096, 2048);
  // union -> bf16
  cvt4<<<16384, 256, 0, stream>>>(unionf, unionb, (long)NREL*4096/4);

  // ---- object stream ----
  obox_k<<<(NOBJ + 255) / 256, 256, 0, stream>>>(boxes, obox);
  posembed_k<<<NOBJ, 128, 0, stream>>>(boxes, pos1_W, pos1_b, bn_g, bn_b, bn_m, bn_v,
                                       pos2_W, pos2_b, pose);
  build_x1<<<nblk((long)NOBJ*4480), 256, 0, stream>>>(inst, embd_W, labels, pose, X1b);
  gemm_bt<0,false,false><<<dim3((NOBJ>>7)*(512>>7)),  256, 0, stream>>>(X1b, objhid_Wb, objhid_b, nullptr, aug, NOBJ, 512, 4480);
  build_aug<<<nblk((long)NOBJ*4864), 256, 0, stream>>>(embl_W, labels, inst, aug, augb);
  gemm_bt<0,false,false><<<dim3((NOBJ>>7)*(1024>>7)), 256, 0, stream>>>(augb, pairup_Wb, pairup_b, nullptr, fused, NOBJ, 1024, 4864);
  gemm_bt<1,false,true ><<<dim3((NOBJ>>7)*(2048>>7)), 256, 0, stream>>>(augb, objfin_Wb, objfin_b, nullptr, obj_featsb, NOBJ, 2048, 4864);
  gemm_bt<0,false,true ><<<dim3((NOBJ>>7)*(512>>7)),  256, 0, stream>>>(obj_featsb, objU_Wb, objU_b, nullptr, obj_repb, NOBJ, 512, 2048);
  gemm_bt<0,false,false><<<dim3((NOBJ>>7)*(1536>>7)), 256, 0, stream>>>(obj_repb, ngru_Wihb, ngru_bih, nullptr, giv, NOBJ, 1536, 512);
  gru_init<<<nblk((long)NOBJ*512), 256, 0, stream>>>(giv, ngru_bhh, vert, vertb, NOBJ);

  // ---- relation stream ----
  build_geo<<<(NREL + 255) / 256, 256, 0, stream>>>(obox, sub, obj, geob);
  gemm_bt<1,false,true ><<<dim3((NREL>>7)*(512>>7)),  256, 0, stream>>>(geob, spt1_Wb, spt1_b, nullptr, spt1b, NREL, 512, 64);
  gemm_bt<1,false,false><<<dim3((NREL>>7)*(1024>>7)), 256, 0, stream>>>(spt1b, spt2_Wb, spt2_b, nullptr, sptf, NREL, 1024, 512);
  build_prod<<<nblk((long)NREL*1024), 256, 0, stream>>>(fused, sptf, sub, obj, prodb);
  // G1 = relu(prod @ pairfin^T + b)   (bf16, at big1+0; prodb at big1+128MB)
  gemm_bt<1,false,true ><<<dim3((NREL>>7)*(2048>>7)), 256, 0, stream>>>(prodb, pairfin_Wb, pairfin_b, nullptr, G1, NREL, 2048, 1024);
  // T1 = union @ W_comp^T + b_comp   (f32, REGION_A)
  gemm_bt<0,false,false><<<dim3((NREL>>7)*(512>>7)),  256, 0, stream>>>(unionb, W_compb, b_comp, nullptr, T1, NREL, 512, 4096);
  // rel_rep = relu(G1 @ edgeU^T + T1)  (bf16, REGION_B)
  gemm_bt<2,true ,true ><<<dim3((NREL>>7)*(512>>7)),  256, 0, stream>>>(G1, edgeU_Wb, zbias, T1, rel_repb, NREL, 512, 2048);
  // edge = GRU(rel_rep, 0)
  gemm_bt<0,false,false><<<dim3((NREL>>7)*(1536>>7)), 256, 0, stream>>>(rel_repb, egru_Wihb, egru_bih, nullptr, gi_e, NREL, 1536, 512);
  gru_init<<<nblk((long)NREL*512), 256, 0, stream>>>(gi_e, egru_bhh, edge, edgeb, NREL);

  // ---- message-passing loop ----
  for (int it = 0; it < 3; it++) {
    hipMemsetAsync(ctx, 0, (long)NOBJ * 512 * 4, stream);
    edge_weights<<<(NREL * 64) / 256, 256, 0, stream>>>(vert, edge, sub, obj,
                                                        svw_W, svw_b, ovw_W, ovw_b, xb, ctx);
    cvt4<<<nblk((long)NOBJ*512/4), 256, 0, stream>>>(ctx, ctxb, (long)NOBJ*512/4);
    gemm_bt<0,false,false><<<dim3((NREL>>7)*(1536>>7)), 256, 0, stream>>>(xb,    egru_Wihb, egru_bih, nullptr, gi_e, NREL, 1536, 512);
    gemm_bt<0,false,false><<<dim3((NREL>>7)*(1536>>7)), 256, 0, stream>>>(edgeb, egru_Whhb, egru_bhh, nullptr, gh_e, NREL, 1536, 512);
    gemm_bt<0,false,false><<<dim3((NOBJ>>7)*(1536>>7)), 256, 0, stream>>>(ctxb,  ngru_Wihb, ngru_bih, nullptr, giv, NOBJ, 1536, 512);
    gemm_bt<0,false,false><<<dim3((NOBJ>>7)*(1536>>7)), 256, 0, stream>>>(vertb, ngru_Whhb, ngru_bhh, nullptr, ghv, NOBJ, 1536, 512);
    gru_step<<<nblk((long)NREL*512), 256, 0, stream>>>(gi_e, gh_e, edge, edgeb, NREL);
    gru_step<<<nblk((long)NOBJ*512), 256, 0, stream>>>(giv, ghv, vert, vertb, NOBJ);
  }

  // ---- output: concat(vert, edge) ----
  hipMemcpyAsync(d_out, vert, (long)NOBJ * 512 * 4, hipMemcpyDeviceToDevice, stream);
  hipMemcpyAsync((char*)d_out + (long)NOBJ * 512 * 4, edge, (long)NREL * 512 * 4,
                 hipMemcpyDeviceToDevice, stream);
}

// Round 3
// 2421.244 us; speedup vs baseline: 1.9670x; 1.1865x over previous
//
#include <hip/hip_runtime.h>
#include <stdint.h>

#define NOBJ 2048
#define NREL 32768

typedef __attribute__((ext_vector_type(8))) short short8;
typedef __attribute__((ext_vector_type(4))) float f32x4;
typedef __attribute__((ext_vector_type(4))) unsigned short ushort4v;

__device__ __forceinline__ unsigned short f2bs(float x){
  unsigned u = __float_as_uint(x);
  unsigned v = u + 0x7fffu + ((u >> 16) & 1u);
  return (unsigned short)(v >> 16);
}
__device__ __forceinline__ float b2f(unsigned short u){
  return __uint_as_float(((unsigned)u) << 16);
}
__device__ __forceinline__ float sigf(float x){ return 1.0f / (1.0f + expf(-x)); }

// async global->LDS, 16B per lane. LDS dest = wave-uniform base + lane*16.
__device__ __forceinline__ void gload16(const unsigned short* g, unsigned short* l) {
  __builtin_amdgcn_global_load_lds(
      (const __attribute__((address_space(1))) unsigned int*)(uintptr_t)g,
      (__attribute__((address_space(3))) unsigned int*)(uintptr_t)l,
      16, 0, 0);
}

// =====================  GEMM: C = f(A * B^T + bias [+Cin])  =====================
// A: MxK bf16 row-major. B: NxK bf16 row-major. M,N mult of 128; K mult of 32.
// RMODE: 0 none; 1 relu(acc+bias) [then PRODF mult, then +Cin]; 2 relu(acc+bias+Cin).
// PRODF: v *= fused[(col<512? sub[row]:obj[row])*1024 + col]  (bf16 table)
// XCD-aware bijective block swizzle (m204). LDS [128][32], 16B slots XOR-swizzled
// on BOTH gload source and ds_read (rule #21) -> 2 lanes/bank (free, m136).
template<int RMODE, bool ACCUM, bool OUTB, bool PRODF>
__global__ __launch_bounds__(256, 2)
void gemm_bt(const unsigned short* __restrict__ A, const unsigned short* __restrict__ B,
             const float* __restrict__ bias, const float* __restrict__ Cin,
             void* __restrict__ Cp, int M, int N, int K,
             const unsigned short* __restrict__ fusedp,
             const int* __restrict__ subp, const int* __restrict__ objp)
{
  __shared__ __align__(16) unsigned short As[128 * 32];
  __shared__ __align__(16) unsigned short Bs[128 * 32];
  const int t = threadIdx.x;
  const int lane = t & 63;
  const int w = t >> 6;
  // XCD-aware bijective swizzle: physical blockIdx -> logical tile id
  const int nwg = gridDim.x;
  const int q8 = nwg >> 3, r8 = nwg & 7;
  const int xcd = blockIdx.x & 7, bidx = blockIdx.x >> 3;
  const int wgid = (xcd < r8 ? xcd * (q8 + 1) : r8 * (q8 + 1) + (xcd - r8) * q8) + bidx;
  const int ntile = N >> 7;
  const int bm = wgid / ntile;
  const int bn = wgid - bm * ntile;
  const int m0 = bm << 7, n0 = bn << 7;
  const int wm = (w & 1) << 6, wn = (w >> 1) << 6;
  const int lrow = lane & 15, kg = lane >> 4;

  // staging geometry: wave w fills 1KB chunks {2w,2w+1} of As and Bs.
  const int c0 = w << 1;
  const int srow = (c0 << 4) + (lane >> 2);
  const int selem = (((lane & 3) ^ ((lane >> 3) & 3)) << 3);  // swizzled source slot
  const unsigned short* ag0 = A + (long)(m0 + srow) * K + selem;
  const unsigned short* ag1 = ag0 + (long)16 * K;
  const unsigned short* bg0 = B + (long)(n0 + srow) * K + selem;
  const unsigned short* bg1 = bg0 + (long)16 * K;
  unsigned short* al0 = As + (c0 << 9);
  unsigned short* al1 = al0 + 512;
  unsigned short* bl0 = Bs + (c0 << 9);
  unsigned short* bl1 = bl0 + 512;

  const int fslotA = ((lrow >> 1) & 3);

  f32x4 acc[4][4] = {};

  for (int k0 = 0; k0 < K; k0 += 32) {
    gload16(ag0 + k0, al0);
    gload16(ag1 + k0, al1);
    gload16(bg0 + k0, bl0);
    gload16(bg1 + k0, bl1);
    __syncthreads();
    short8 afr[4], bfr[4];
#pragma unroll
    for (int i = 0; i < 4; i++)
      afr[i] = *(const short8*)(As + (wm + i * 16 + lrow) * 32 + ((kg ^ fslotA) << 3));
#pragma unroll
    for (int j = 0; j < 4; j++)
      bfr[j] = *(const short8*)(Bs + (wn + j * 16 + lrow) * 32 + ((kg ^ fslotA) << 3));
#pragma unroll
    for (int i = 0; i < 4; i++)
#pragma unroll
      for (int j = 0; j < 4; j++)
        acc[i][j] = __builtin_amdgcn_mfma_f32_16x16x32_bf16(afr[i], bfr[j], acc[i][j], 0, 0, 0);
    __syncthreads();
  }

  float* Cf = (float*)Cp;
  unsigned short* Cb = (unsigned short*)Cp;
#pragma unroll
  for (int i = 0; i < 4; i++) {
#pragma unroll
    for (int j = 0; j < 4; j++) {
      const int col = n0 + wn + j * 16 + lrow;
      const float bv = bias[col];
#pragma unroll
      for (int q = 0; q < 4; q++) {
        const long row = m0 + wm + i * 16 + kg * 4 + q;
        float v = acc[i][j][q] + bv;
        if constexpr (RMODE == 1) v = fmaxf(v, 0.0f);
        if constexpr (PRODF) {
          int gr = (col < 512) ? subp[row] : objp[row];
          v *= b2f(fusedp[(long)gr * 1024 + col]);
        }
        if constexpr (ACCUM) v += Cin[row * (long)N + col];
        if constexpr (RMODE == 2) v = fmaxf(v, 0.0f);
        if constexpr (OUTB) Cb[row * (long)N + col] = f2bs(v);
        else Cf[row * (long)N + col] = v;
      }
    }
  }
}

// ===================== small kernels =====================

// f32 -> bf16 with row padding K0 -> Kp (both mult of 4), vectorized x4
__global__ void cvt_pad4(const float* __restrict__ src, unsigned short* __restrict__ dst,
                         int rows, int K0, int Kp)
{
  const int kp4 = Kp >> 2;
  const long total = (long)rows * kp4;
  for (long i = blockIdx.x * (long)blockDim.x + threadIdx.x; i < total; i += (long)gridDim.x * blockDim.x) {
    int r = (int)(i / kp4), k = (int)(i - (long)r * kp4) << 2;
    ushort4v o;
    if (k < K0) {
      f32x4 v = *(const f32x4*)(src + (long)r * K0 + k);
      o[0] = f2bs(v[0]); o[1] = f2bs(v[1]); o[2] = f2bs(v[2]); o[3] = f2bs(v[3]);
    } else {
      o[0] = 0; o[1] = 0; o[2] = 0; o[3] = 0;
    }
    *(ushort4v*)(dst + (long)r * Kp + k) = o;
  }
}

// f32 -> bf16, vectorized x4
__global__ void cvt4(const float* __restrict__ src, unsigned short* __restrict__ dst, long n4)
{
  for (long i = blockIdx.x * (long)blockDim.x + threadIdx.x; i < n4; i += (long)gridDim.x * blockDim.x) {
    f32x4 v = ((const f32x4*)src)[i];
    ushort4v o;
    o[0] = f2bs(v[0]); o[1] = f2bs(v[1]); o[2] = f2bs(v[2]); o[3] = f2bs(v[3]);
    ((ushort4v*)dst)[i] = o;
  }
}

// dst[c][r] = bf16(src[r][c])
__global__ void transpose_cvt(const float* __restrict__ src, unsigned short* __restrict__ dst,
                              int R, int C)
{
  __shared__ float tile[32][33];
  int c0 = blockIdx.x * 32, r0 = blockIdx.y * 32;
  for (int i = threadIdx.y; i < 32; i += 8)
    tile[i][threadIdx.x] = src[(long)(r0 + i) * C + c0 + threadIdx.x];
  __syncthreads();
  for (int i = threadIdx.y; i < 32; i += 8)
    dst[(long)(c0 + i) * R + r0 + threadIdx.x] = f2bs(tile[threadIdx.x][i]);
}

// b_comp[j] = edgeU_b[j] + sum_k edgeU_W[j][k] * up_b[k]
__global__ void comp_bias(const float* __restrict__ edgeU_W, const float* __restrict__ up_b,
                          const float* __restrict__ edgeU_b, float* __restrict__ b_comp)
{
  int j = (int)((blockIdx.x * (long)blockDim.x + threadIdx.x) >> 6);
  int l = threadIdx.x & 63;
  if (j >= 512) return;
  float s = 0.0f;
  for (int k = l; k < 2048; k += 64) s += edgeU_W[(long)j * 2048 + k] * up_b[k];
#pragma unroll
  for (int off = 32; off > 0; off >>= 1) s += __shfl_xor(s, off);
  if (l == 0) b_comp[j] = s + edgeU_b[j];
}

__global__ void obox_k(const float* __restrict__ boxes, float* __restrict__ obox)
{
  int i = blockIdx.x * blockDim.x + threadIdx.x;
  if (i >= NOBJ) return;
  float x1 = boxes[i*4], y1 = boxes[i*4+1], x2 = boxes[i*4+2], y2 = boxes[i*4+3];
  float wdt = x2 - x1 + 1.0f, hgt = y2 - y1 + 1.0f;
  float cx = x1 + 0.5f * wdt, cy = y1 + 0.5f * hgt;
  const float inv = 1.0f / 1024.0f;
  float* o = obox + i * 8;
  o[0]=x1*inv; o[1]=y1*inv; o[2]=x2*inv; o[3]=y2*inv;
  o[4]=cx*inv; o[5]=cy*inv; o[6]=wdt*inv; o[7]=hgt*inv;
}

__global__ void posembed_k(const float* __restrict__ boxes,
                           const float* __restrict__ w1, const float* __restrict__ b1,
                           const float* __restrict__ g, const float* __restrict__ bb,
                           const float* __restrict__ mm, const float* __restrict__ vv,
                           const float* __restrict__ w2, const float* __restrict__ b2,
                           float* __restrict__ out)
{
  int o = blockIdx.x, t = threadIdx.x;
  __shared__ float e[9];
  __shared__ float p[32];
  if (t == 0) {
    float x1 = boxes[o*4], y1 = boxes[o*4+1], x2 = boxes[o*4+2], y2 = boxes[o*4+3];
    float wdt = x2 - x1 + 1.0f, hgt = y2 - y1 + 1.0f;
    float cx = x1 + 0.5f * wdt, cy = y1 + 0.5f * hgt;
    e[0]=wdt/1024.0f; e[1]=hgt/768.0f; e[2]=cx/1024.0f; e[3]=cy/768.0f;
    e[4]=x1/1024.0f;  e[5]=y1/768.0f;  e[6]=x2/1024.0f; e[7]=y2/768.0f;
    e[8]=wdt*hgt/(1024.0f*768.0f);
  }
  __syncthreads();
  if (t < 32) {
    float s = b1[t];
#pragma unroll
    for (int j = 0; j < 9; j++) s += w1[t*9+j] * e[j];
    s = (s - mm[t]) * g[t] / sqrtf(vv[t] + 1e-5f) + bb[t];
    p[t] = s;
  }
  __syncthreads();
  float s = b2[t];
#pragma unroll
  for (int j = 0; j < 32; j++) s += w2[t*32+j] * p[j];
  out[o*128 + t] = fmaxf(s, 0.0f);
}

__device__ __forceinline__ void pack8_store(unsigned short* dst, f32x4 a, f32x4 b)
{
  ushort4v o0, o1;
  o0[0]=f2bs(a[0]); o0[1]=f2bs(a[1]); o0[2]=f2bs(a[2]); o0[3]=f2bs(a[3]);
  o1[0]=f2bs(b[0]); o1[1]=f2bs(b[1]); o1[2]=f2bs(b[2]); o1[3]=f2bs(b[3]);
  *(ushort4v*)dst = o0;
  *(ushort4v*)(dst + 4) = o1;
}

// X1 = [inst(4096) | emb_dist(200) | pos(128) | pad->4480]  bf16, 8-wide
__global__ void build_x1(const float* __restrict__ inst, const float* __restrict__ embd,
                         const int* __restrict__ labels, const float* __restrict__ pose,
                         unsigned short* __restrict__ X1b)
{
  const long total = (long)NOBJ * 560;   // 4480/8
  for (long i = blockIdx.x * (long)blockDim.x + threadIdx.x; i < total; i += (long)gridDim.x * blockDim.x) {
    int r = (int)(i / 560), c = ((int)(i - (long)r * 560)) << 3;
    unsigned short* dst = X1b + (long)r * 4480 + c;
    const float* src;
    if (c < 4096)      src = inst + (long)r * 4096 + c;
    else if (c < 4296) src = embd + (long)labels[r] * 200 + (c - 4096);
    else if (c < 4424) src = pose + r * 128 + (c - 4296);
    else { ushort4v z = {0,0,0,0}; *(ushort4v*)dst = z; *(ushort4v*)(dst+4) = z; continue; }
    pack8_store(dst, *(const f32x4*)src, *((const f32x4*)src + 1));
  }
}

// augment = [emb_label(200) | inst(4096) | aug(512) | pad->4864]  bf16, 8-wide
__global__ void build_aug(const float* __restrict__ embl, const int* __restrict__ labels,
                          const float* __restrict__ inst, const float* __restrict__ aug,
                          unsigned short* __restrict__ augb)
{
  const long total = (long)NOBJ * 608;   // 4864/8
  for (long i = blockIdx.x * (long)blockDim.x + threadIdx.x; i < total; i += (long)gridDim.x * blockDim.x) {
    int r = (int)(i / 608), c = ((int)(i - (long)r * 608)) << 3;
    unsigned short* dst = augb + (long)r * 4864 + c;
    const float* src;
    if (c < 200)       src = embl + (long)labels[r] * 200 + c;
    else if (c < 4296) src = inst + (long)r * 4096 + (c - 200);
    else if (c < 4808) src = aug + (long)r * 512 + (c - 4296);
    else { ushort4v z = {0,0,0,0}; *(ushort4v*)dst = z; *(ushort4v*)(dst+4) = z; continue; }
    pack8_store(dst, *(const f32x4*)src, *((const f32x4*)src + 1));
  }
}

// geo pair features (32 dims, padded to 64) as bf16
__global__ void build_geo(const float* __restrict__ obox, const int* __restrict__ sub,
                          const int* __restrict__ obj, unsigned short* __restrict__ geob)
{
  int r = blockIdx.x * blockDim.x + threadIdx.x;
  if (r >= NREL) return;
  const float* b1 = obox + sub[r] * 8;
  const float* b2 = obox + obj[r] * 8;
  float o[32];
#pragma unroll
  for (int j = 0; j < 8; j++) { o[j] = b1[j]; o[8+j] = b2[j]; }
  float ux1 = fminf(b1[0], b2[0]), uy1 = fminf(b1[1], b2[1]);
  float ux2 = fmaxf(b1[2], b2[2]), uy2 = fmaxf(b1[3], b2[3]);
  float uw = ux2 - ux1 + 1.0f, uh = uy2 - uy1 + 1.0f;
  o[16]=ux1; o[17]=uy1; o[18]=ux2; o[19]=uy2;
  o[20]=ux1+0.5f*uw; o[21]=uy1+0.5f*uh; o[22]=uw; o[23]=uh;
  float ix1 = fmaxf(b1[0], b2[0]), iy1 = fmaxf(b1[1], b2[1]);
  float ix2 = fminf(b1[2], b2[2]), iy2 = fminf(b1[3], b2[3]);
  bool bad = (ix2 < ix1) || (iy2 < iy1);
  float iw = ix2 - ix1 + 1.0f, ih = iy2 - iy1 + 1.0f;
  if (bad) {
#pragma unroll
    for (int j = 24; j < 32; j++) o[j] = 0.0f;
  } else {
    o[24]=ix1; o[25]=iy1; o[26]=ix2; o[27]=iy2;
    o[28]=ix1+0.5f*iw; o[29]=iy1+0.5f*ih; o[30]=iw; o[31]=ih;
  }
  unsigned short* gp = geob + (long)r * 64;
#pragma unroll
  for (int j = 0; j < 32; j++) gp[j] = f2bs(o[j]);
#pragma unroll
  for (int j = 32; j < 64; j++) gp[j] = 0;
}

// GRU h=0: h = (1-z)*n, gates bf16 [r|z|n] stride 1536. 8-wide.
__global__ void gru_init(const unsigned short* __restrict__ gi, const float* __restrict__ bhh,
                         float* __restrict__ h, unsigned short* __restrict__ hb, int n)
{
  const long total = (long)n * 64;   // groups of 8
  for (long i = blockIdx.x * (long)blockDim.x + threadIdx.x; i < total; i += (long)gridDim.x * blockDim.x) {
    int r = (int)(i >> 6), c = ((int)(i & 63)) << 3;
    const unsigned short* gr = gi + (long)r * 1536;
    short8 vr = *(const short8*)(gr + c);
    short8 vz = *(const short8*)(gr + 512 + c);
    short8 vn = *(const short8*)(gr + 1024 + c);
    float hv[8];
#pragma unroll
    for (int k = 0; k < 8; k++) {
      float rr = sigf(b2f((unsigned short)vr[k]) + bhh[c + k]);
      float z  = sigf(b2f((unsigned short)vz[k]) + bhh[512 + c + k]);
      float nn = tanhf(b2f((unsigned short)vn[k]) + rr * bhh[1024 + c + k]);
      hv[k] = (1.0f - z) * nn;
    }
    float* hp = h + (long)r * 512 + c;
    *(f32x4*)hp = *(f32x4*)hv;
    *(f32x4*)(hp + 4) = *(f32x4*)(hv + 4);
    pack8_store(hb + (long)r * 512 + c, *(f32x4*)hv, *(f32x4*)(hv + 4));
  }
}

// GRU step: gates bf16, hin f32 -> hout f32 + hb bf16. 8-wide.
__global__ void gru_step(const unsigned short* __restrict__ gi, const unsigned short* __restrict__ gh,
                         const float* __restrict__ hin, float* __restrict__ hout,
                         unsigned short* __restrict__ hb, int n)
{
  const long total = (long)n * 64;
  for (long i = blockIdx.x * (long)blockDim.x + threadIdx.x; i < total; i += (long)gridDim.x * blockDim.x) {
    int r = (int)(i >> 6), c = ((int)(i & 63)) << 3;
    const unsigned short* gr = gi + (long)r * 1536;
    const unsigned short* hr = gh + (long)r * 1536;
    short8 ir = *(const short8*)(gr + c);
    short8 iz = *(const short8*)(gr + 512 + c);
    short8 in_ = *(const short8*)(gr + 1024 + c);
    short8 hrr = *(const short8*)(hr + c);
    short8 hz = *(const short8*)(hr + 512 + c);
    short8 hn = *(const short8*)(hr + 1024 + c);
    const float* hi = hin + (long)r * 512 + c;
    f32x4 h0 = *(const f32x4*)hi;
    f32x4 h1 = *(const f32x4*)(hi + 4);
    float hv[8];
#pragma unroll
    for (int k = 0; k < 8; k++) {
      float rr = sigf(b2f((unsigned short)ir[k]) + b2f((unsigned short)hrr[k]));
      float z  = sigf(b2f((unsigned short)iz[k]) + b2f((unsigned short)hz[k]));
      float nn = tanhf(b2f((unsigned short)in_[k]) + rr * b2f((unsigned short)hn[k]));
      float old = (k < 4) ? h0[k] : h1[k - 4];
      hv[k] = (1.0f - z) * nn + z * old;
    }
    float* hp = hout + (long)r * 512 + c;
    *(f32x4*)hp = *(f32x4*)hv;
    *(f32x4*)(hp + 4) = *(f32x4*)(hv + 4);
    pack8_store(hb + (long)r * 512 + c, *(f32x4*)hv, *(f32x4*)(hv + 4));
  }
}

// Fused per-relation: ws/wo dots, xb = ws*sv+wo*ov (bf16), ctx scatter-adds.
__global__ __launch_bounds__(256)
void edge_weights(const float* __restrict__ vert, const float* __restrict__ edge,
                  const int* __restrict__ sub, const int* __restrict__ obj,
                  const float* __restrict__ svwW, const float* __restrict__ svwb,
                  const float* __restrict__ ovwW, const float* __restrict__ ovwb,
                  unsigned short* __restrict__ xb, float* __restrict__ ctx)
{
  long gid = blockIdx.x * (long)blockDim.x + threadIdx.x;
  int r = (int)(gid >> 6);
  int l = (int)(gid & 63);
  if (r >= NREL) return;
  int s = sub[r], o = obj[r];
  const float* sv = vert + (long)s * 512;
  const float* ov = vert + (long)o * 512;
  const float* e  = edge + (long)r * 512;
  float svv[8], ovv[8], ev[8];
  float as = 0.0f, ao = 0.0f;
#pragma unroll
  for (int k = 0; k < 8; k++) {
    int c = l + k * 64;
    svv[k] = sv[c]; ovv[k] = ov[c]; ev[k] = e[c];
    as += svwW[c] * svv[k] + svwW[512 + c] * ev[k];
    ao += ovwW[c] * ovv[k] + ovwW[512 + c] * ev[k];
  }
#pragma unroll
  for (int off = 32; off > 0; off >>= 1) {
    as += __shfl_xor(as, off);
    ao += __shfl_xor(ao, off);
  }
  float ws = sigf(as + svwb[0]);
  float wo = sigf(ao + ovwb[0]);
#pragma unroll
  for (int k = 0; k < 8; k++) {
    int c = l + k * 64;
    xb[(long)r * 512 + c] = f2bs(ws * svv[k] + wo * ovv[k]);
    atomicAdd(ctx + (long)s * 512 + c, ws * ev[k]);
    atomicAdd(ctx + (long)o * 512 + c, wo * ev[k]);
  }
}

// ===================== driver =====================

static inline int nblk(long total) {
  long b = (total + 255) / 256;
  return (int)(b > 16384 ? 16384 : b);
}

#define GEMM(RM, AC, OB, PF, grid, Aa, Bb, bb, Ci, Cc, Mm, Nn, Kk, fp, sp, op) \
  gemm_bt<RM, AC, OB, PF><<<grid, 256, 0, stream>>>(Aa, Bb, bb, Ci, Cc, Mm, Nn, Kk, fp, sp, op)

extern "C" void kernel_launch(void* const* d_in, const int* in_sizes, int n_in,
                              void* d_out, int out_size, void* d_ws, size_t ws_size,
                              hipStream_t stream)
{
  const float* inst     = (const float*)d_in[0];
  const float* unionf   = (const float*)d_in[1];
  const float* boxes    = (const float*)d_in[2];
  const float* embd_W   = (const float*)d_in[3];
  const float* embl_W   = (const float*)d_in[4];
  const float* up_W     = (const float*)d_in[5];
  const float* up_b     = (const float*)d_in[6];
  const float* pairup_W = (const float*)d_in[7];
  const float* pairup_b = (const float*)d_in[8];
  const float* pos1_W   = (const float*)d_in[9];
  const float* pos1_b   = (const float*)d_in[10];
  const float* bn_g     = (const float*)d_in[11];
  const float* bn_b     = (const float*)d_in[12];
  const float* bn_m     = (const float*)d_in[13];
  const float* bn_v     = (const float*)d_in[14];
  const float* pos2_W   = (const float*)d_in[15];
  const float* pos2_b   = (const float*)d_in[16];
  const float* spt1_W   = (const float*)d_in[17];
  const float* spt1_b   = (const float*)d_in[18];
  const float* spt2_W   = (const float*)d_in[19];
  const float* spt2_b   = (const float*)d_in[20];
  const float* pairfin_W= (const float*)d_in[21];
  const float* pairfin_b= (const float*)d_in[22];
  const float* objhid_W = (const float*)d_in[23];
  const float* objhid_b = (const float*)d_in[24];
  const float* objfin_W = (const float*)d_in[25];
  const float* objfin_b = (const float*)d_in[26];
  const float* objU_W   = (const float*)d_in[27];
  const float* objU_b   = (const float*)d_in[28];
  const float* edgeU_W  = (const float*)d_in[29];
  const float* edgeU_b  = (const float*)d_in[30];
  const float* egru_Wih = (const float*)d_in[31];
  const float* egru_Whh = (const float*)d_in[32];
  const float* egru_bih = (const float*)d_in[33];
  const float* egru_bhh = (const float*)d_in[34];
  const float* ngru_Wih = (const float*)d_in[35];
  const float* ngru_Whh = (const float*)d_in[36];
  const float* ngru_bih = (const float*)d_in[37];
  const float* ngru_bhh = (const float*)d_in[38];
  const float* svw_W    = (const float*)d_in[39];
  const float* svw_b    = (const float*)d_in[40];
  const float* ovw_W    = (const float*)d_in[41];
  const float* ovw_b    = (const float*)d_in[42];
  const int*   labels   = (const int*)d_in[43];
  const int*   sub      = (const int*)d_in[44];
  const int*   obj      = (const int*)d_in[45];
  (void)in_sizes; (void)n_in; (void)out_size; (void)ws_size;

  char* base = (char*)d_ws;
  size_t off = 0;
  auto alloc = [&](size_t bytes) -> void* {
    void* p = base + off;
    off += (bytes + 255) & ~(size_t)255;
    return p;
  };

  // ---- weights (bf16) ----
  unsigned short* objhid_Wb  = (unsigned short*)alloc(512L  * 4480 * 2);
  unsigned short* pairup_Wb  = (unsigned short*)alloc(1024L * 4864 * 2);
  unsigned short* objfin_Wb  = (unsigned short*)alloc(2048L * 4864 * 2);
  unsigned short* up_Wtb     = (unsigned short*)alloc(4096L * 2048 * 2);
  unsigned short* pairfin_Wb = (unsigned short*)alloc(2048L * 1024 * 2);
  unsigned short* spt1_Wb    = (unsigned short*)alloc(512L  * 64   * 2);
  unsigned short* spt2_Wb    = (unsigned short*)alloc(1024L * 512  * 2);
  unsigned short* objU_Wb    = (unsigned short*)alloc(512L  * 2048 * 2);
  unsigned short* edgeU_Wb   = (unsigned short*)alloc(512L  * 2048 * 2);
  unsigned short* egru_Wihb  = (unsigned short*)alloc(1536L * 512  * 2);
  unsigned short* egru_Whhb  = (unsigned short*)alloc(1536L * 512  * 2);
  unsigned short* ngru_Wihb  = (unsigned short*)alloc(1536L * 512  * 2);
  unsigned short* ngru_Whhb  = (unsigned short*)alloc(1536L * 512  * 2);
  unsigned short* W_compb    = (unsigned short*)alloc(512L  * 4096 * 2);
  float*          b_comp     = (float*)alloc(512L * 4);
  float*          zbias      = (float*)alloc(4096L * 4);

  // ---- activations ----
  float*          obox      = (float*)alloc(NOBJ * 8L * 4);
  float*          pose      = (float*)alloc(NOBJ * 128L * 4);
  float*          aug       = (float*)alloc((long)NOBJ * 512 * 4);
  unsigned short* obj_featsb= (unsigned short*)alloc((long)NOBJ * 2048 * 2);
  unsigned short* obj_repb  = (unsigned short*)alloc((long)NOBJ * 512 * 2);
  unsigned short* giv       = (unsigned short*)alloc((long)NOBJ * 1536 * 2);
  unsigned short* ghv       = (unsigned short*)alloc((long)NOBJ * 1536 * 2);
  float*          vert      = (float*)alloc((long)NOBJ * 512 * 4);
  unsigned short* vertb     = (unsigned short*)alloc((long)NOBJ * 512 * 2);
  float*          ctx       = (float*)alloc((long)NOBJ * 512 * 4);
  unsigned short* ctxb      = (unsigned short*)alloc((long)NOBJ * 512 * 2);
  unsigned short* geob      = (unsigned short*)alloc((long)NREL * 64 * 2);
  float*          edge      = (float*)alloc((long)NREL * 512 * 4);

  // REGION_A: X1b (17.5MB) -> T1 (f32 64MB)
  char* regA = (char*)alloc((long)NREL * 512 * 4);
  unsigned short* X1b = (unsigned short*)regA;
  float*          T1  = (float*)regA;
  // REGION_B: augb (19MB) -> rel_repb (32MB)
  char* regB = (char*)alloc((long)NREL * 512 * 2);
  unsigned short* augb     = (unsigned short*)regB;
  unsigned short* rel_repb = (unsigned short*)regB;
  // REGION_C: fusedb (bf16 4MB) -> xb (32MB)
  char* regC = (char*)alloc((long)NREL * 512 * 2);
  unsigned short* fusedb = (unsigned short*)regC;
  unsigned short* xb     = (unsigned short*)regC;
  // REGION_D: spt1b -> edgeb
  char* regD = (char*)alloc((long)NREL * 512 * 2);
  unsigned short* spt1b = (unsigned short*)regD;
  unsigned short* edgeb = (unsigned short*)regD;
  // BIG1 (192MB): [G1 bf16 128MB @0 | prodb bf16 64MB @128MB] -> gi_e (bf16 96MB)
  char* big1 = (char*)alloc((long)NREL * 1536 * 4);
  unsigned short* G1    = (unsigned short*)big1;
  unsigned short* prodb = (unsigned short*)(big1 + (long)NREL * 1024 * 4);
  unsigned short* gi_e  = (unsigned short*)big1;
  // REGION_U (256MB): unionb (bf16) -> gh_e (bf16 96MB)
  char* regU = (char*)alloc((long)NREL * 4096 * 2);
  unsigned short* unionb = (unsigned short*)regU;
  unsigned short* gh_e   = (unsigned short*)regU;

  float* d_out_vert = (float*)d_out;
  float* d_out_edge = (float*)d_out + (long)NOBJ * 512;

  // ---- weight conversions ----
  cvt_pad4<<<nblk(512L*4480/4),  256, 0, stream>>>(objhid_W,  objhid_Wb,  512,  4424, 4480);
  cvt_pad4<<<nblk(1024L*4864/4), 256, 0, stream>>>(pairup_W,  pairup_Wb,  1024, 4808, 4864);
  cvt_pad4<<<nblk(2048L*4864/4), 256, 0, stream>>>(objfin_W,  objfin_Wb,  2048, 4808, 4864);
  cvt_pad4<<<nblk(512L*64/4),    256, 0, stream>>>(spt1_W,    spt1_Wb,    512,  32,   64);
  cvt4<<<nblk(2048L*1024/4), 256, 0, stream>>>(pairfin_W, pairfin_Wb, 2048L*1024/4);
  cvt4<<<nblk(1024L*512/4),  256, 0, stream>>>(spt2_W,    spt2_Wb,    1024L*512/4);
  cvt4<<<nblk(512L*2048/4),  256, 0, stream>>>(objU_W,    objU_Wb,    512L*2048/4);
  cvt4<<<nblk(512L*2048/4),  256, 0, stream>>>(edgeU_W,   edgeU_Wb,   512L*2048/4);
  cvt4<<<nblk(1536L*512/4),  256, 0, stream>>>(egru_Wih,  egru_Wihb,  1536L*512/4);
  cvt4<<<nblk(1536L*512/4),  256, 0, stream>>>(egru_Whh,  egru_Whhb,  1536L*512/4);
  cvt4<<<nblk(1536L*512/4),  256, 0, stream>>>(ngru_Wih,  ngru_Wihb,  1536L*512/4);
  cvt4<<<nblk(1536L*512/4),  256, 0, stream>>>(ngru_Whh,  ngru_Whhb,  1536L*512/4);
  transpose_cvt<<<dim3(4096/32, 2048/32), dim3(32, 8), 0, stream>>>(up_W, up_Wtb, 2048, 4096);
  hipMemsetAsync(zbias, 0, 4096L * 4, stream);
  comp_bias<<<128, 256, 0, stream>>>(edgeU_W, up_b, edgeU_b, b_comp);
  GEMM(0,false,true,false, dim3((512>>7)*(4096>>7)), edgeU_Wb, up_Wtb, zbias, nullptr, W_compb, 512, 4096, 2048, nullptr, nullptr, nullptr);
  cvt4<<<16384, 256, 0, stream>>>(unionf, unionb, (long)NREL*4096/4);

  // ---- object stream ----
  obox_k<<<(NOBJ + 255) / 256, 256, 0, stream>>>(boxes, obox);
  posembed_k<<<NOBJ, 128, 0, stream>>>(boxes, pos1_W, pos1_b, bn_g, bn_b, bn_m, bn_v,
                                       pos2_W, pos2_b, pose);
  build_x1<<<nblk((long)NOBJ*560), 256, 0, stream>>>(inst, embd_W, labels, pose, X1b);
  GEMM(0,false,false,false, dim3((NOBJ>>7)*(512>>7)),  X1b, objhid_Wb, objhid_b, nullptr, aug, NOBJ, 512, 4480, nullptr, nullptr, nullptr);
  build_aug<<<nblk((long)NOBJ*608), 256, 0, stream>>>(embl_W, labels, inst, aug, augb);
  GEMM(0,false,true ,false, dim3((NOBJ>>7)*(1024>>7)), augb, pairup_Wb, pairup_b, nullptr, fusedb, NOBJ, 1024, 4864, nullptr, nullptr, nullptr);
  GEMM(1,false,true ,false, dim3((NOBJ>>7)*(2048>>7)), augb, objfin_Wb, objfin_b, nullptr, obj_featsb, NOBJ, 2048, 4864, nullptr, nullptr, nullptr);
  GEMM(0,false,true ,false, dim3((NOBJ>>7)*(512>>7)),  obj_featsb, objU_Wb, objU_b, nullptr, obj_repb, NOBJ, 512, 2048, nullptr, nullptr, nullptr);
  GEMM(0,false,true ,false, dim3((NOBJ>>7)*(1536>>7)), obj_repb, ngru_Wihb, ngru_bih, nullptr, giv, NOBJ, 1536, 512, nullptr, nullptr, nullptr);
  gru_init<<<nblk((long)NOBJ*64), 256, 0, stream>>>(giv, ngru_bhh, vert, vertb, NOBJ);

  // ---- relation stream ----
  build_geo<<<(NREL + 255) / 256, 256, 0, stream>>>(obox, sub, obj, geob);
  GEMM(1,false,true ,false, dim3((NREL>>7)*(512>>7)),  geob, spt1_Wb, spt1_b, nullptr, spt1b, NREL, 512, 64, nullptr, nullptr, nullptr);
  // prod = relu(spt1b@spt2^T + b) * pair-gather(fusedb)   [PRODF epilogue]
  GEMM(1,false,true ,true , dim3((NREL>>7)*(1024>>7)), spt1b, spt2_Wb, spt2_b, nullptr, prodb, NREL, 1024, 512, fusedb, sub, obj);
  GEMM(1,false,true ,false, dim3((NREL>>7)*(2048>>7)), prodb, pairfin_Wb, pairfin_b, nullptr, G1, NREL, 2048, 1024, nullptr, nullptr, nullptr);
  GEMM(0,false,false,false, dim3((NREL>>7)*(512>>7)),  unionb, W_compb, b_comp, nullptr, T1, NREL, 512, 4096, nullptr, nullptr, nullptr);
  GEMM(2,true ,true ,false, dim3((NREL>>7)*(512>>7)),  G1, edgeU_Wb, zbias, T1, rel_repb, NREL, 512, 2048, nullptr, nullptr, nullptr);
  GEMM(0,false,true ,false, dim3((NREL>>7)*(1536>>7)), rel_repb, egru_Wihb, egru_bih, nullptr, gi_e, NREL, 1536, 512, nullptr, nullptr, nullptr);
  gru_init<<<nblk((long)NREL*64), 256, 0, stream>>>(gi_e, egru_bhh, edge, edgeb, NREL);

  // ---- message-passing loop ----
  for (int it = 0; it < 3; it++) {
    const bool last = (it == 2);
    hipMemsetAsync(ctx, 0, (long)NOBJ * 512 * 4, stream);
    edge_weights<<<(NREL * 64) / 256, 256, 0, stream>>>(vert, edge, sub, obj,
                                                        svw_W, svw_b, ovw_W, ovw_b, xb, ctx);
    cvt4<<<nblk((long)NOBJ*512/4), 256, 0, stream>>>(ctx, ctxb, (long)NOBJ*512/4);
    GEMM(0,false,true,false, dim3((NREL>>7)*(1536>>7)), xb,    egru_Wihb, egru_bih, nullptr, gi_e, NREL, 1536, 512, nullptr, nullptr, nullptr);
    GEMM(0,false,true,false, dim3((NREL>>7)*(1536>>7)), edgeb, egru_Whhb, egru_bhh, nullptr, gh_e, NREL, 1536, 512, nullptr, nullptr, nullptr);
    GEMM(0,false,true,false, dim3((NOBJ>>7)*(1536>>7)), ctxb,  ngru_Wihb, ngru_bih, nullptr, giv, NOBJ, 1536, 512, nullptr, nullptr, nullptr);
    GEMM(0,false,true,false, dim3((NOBJ>>7)*(1536>>7)), vertb, ngru_Whhb, ngru_bhh, nullptr, ghv, NOBJ, 1536, 512, nullptr, nullptr, nullptr);
    gru_step<<<nblk((long)NREL*64), 256, 0, stream>>>(gi_e, gh_e, edge, last ? d_out_edge : edge, edgeb, NREL);
    gru_step<<<nblk((long)NOBJ*64), 256, 0, stream>>>(giv, ghv, vert, last ? d_out_vert : vert, vertb, NOBJ);
  }
}

// Round 4
// 2332.056 us; speedup vs baseline: 2.0422x; 1.0382x over previous
//
#include <hip/hip_runtime.h>
#include <stdint.h>

#define NOBJ 2048
#define NREL 32768

typedef __attribute__((ext_vector_type(8))) short short8;
typedef __attribute__((ext_vector_type(4))) float f32x4;
typedef __attribute__((ext_vector_type(4))) unsigned short ushort4v;

__device__ __forceinline__ unsigned short f2bs(float x){
  unsigned u = __float_as_uint(x);
  unsigned v = u + 0x7fffu + ((u >> 16) & 1u);
  return (unsigned short)(v >> 16);
}
__device__ __forceinline__ float b2f(unsigned short u){
  return __uint_as_float(((unsigned)u) << 16);
}
__device__ __forceinline__ float sigf(float x){ return 1.0f / (1.0f + expf(-x)); }

// async global->LDS, 16B per lane. LDS dest = wave-uniform base + lane*16.
__device__ __forceinline__ void gload16(const unsigned short* g, unsigned short* l) {
  __builtin_amdgcn_global_load_lds(
      (const __attribute__((address_space(1))) unsigned int*)(uintptr_t)g,
      (__attribute__((address_space(3))) unsigned int*)(uintptr_t)l,
      16, 0, 0);
}

// =====================  GEMM: C = f(A * B^T + bias [+Cin])  =====================
// A: MxK row-major, bf16 (AF32=false, staged via global_load_lds + slot swizzle)
//    or f32 (AF32=true, reg-staged with in-flight cvt, linear LDS).
// B: NxK bf16 row-major (always gload_lds + swizzle).
// RMODE: 0 none; 1 relu(acc+bias) [then PRODF mult, then +Cin]; 2 relu(acc+bias+Cin).
// PRODF: v *= fused[(col<512? sub[row]:obj[row])*1024 + col]  (bf16 table)
// XCD-aware bijective block swizzle (m204).
template<int RMODE, bool ACCUM, bool OUTB, bool PRODF, bool AF32>
__global__ __launch_bounds__(256, 2)
void gemm_bt(const void* __restrict__ Ap, const unsigned short* __restrict__ B,
             const float* __restrict__ bias, const float* __restrict__ Cin,
             void* __restrict__ Cp, int M, int N, int K,
             const unsigned short* __restrict__ fusedp,
             const int* __restrict__ subp, const int* __restrict__ objp)
{
  __shared__ __align__(16) unsigned short As[128 * 32];
  __shared__ __align__(16) unsigned short Bs[128 * 32];
  const int t = threadIdx.x;
  const int lane = t & 63;
  const int w = t >> 6;
  // XCD-aware bijective swizzle: physical blockIdx -> logical tile id
  const int nwg = gridDim.x;
  const int q8 = nwg >> 3, r8 = nwg & 7;
  const int xcd = blockIdx.x & 7, bidx = blockIdx.x >> 3;
  const int wgid = (xcd < r8 ? xcd * (q8 + 1) : r8 * (q8 + 1) + (xcd - r8) * q8) + bidx;
  const int ntile = N >> 7;
  const int bm = wgid / ntile;
  const int bn = wgid - bm * ntile;
  const int m0 = bm << 7, n0 = bn << 7;
  const int wm = (w & 1) << 6, wn = (w >> 1) << 6;
  const int lrow = lane & 15, kg = lane >> 4;

  // gload staging geometry: wave w fills 1KB chunks {2w,2w+1}.
  const int c0 = w << 1;
  const int srow = (c0 << 4) + (lane >> 2);
  const int selem = (((lane & 3) ^ ((lane >> 3) & 3)) << 3);  // swizzled source slot
  const unsigned short* bg0 = B + (long)(n0 + srow) * K + selem;
  const unsigned short* bg1 = bg0 + (long)16 * K;
  unsigned short* bl0 = Bs + (c0 << 9);
  unsigned short* bl1 = bl0 + 512;

  const unsigned short* ag0 = nullptr; const unsigned short* ag1 = nullptr;
  unsigned short* al0 = nullptr; unsigned short* al1 = nullptr;
  const float* afp = nullptr; unsigned short* afl = nullptr;
  if constexpr (AF32) {
    // reg-staging: thread t handles row t>>1, 16 floats at col (t&1)*16
    afp = (const float*)Ap + (long)(m0 + (t >> 1)) * K + ((t & 1) << 4);
    afl = As + (t >> 1) * 32 + ((t & 1) << 4);
  } else {
    ag0 = (const unsigned short*)Ap + (long)(m0 + srow) * K + selem;
    ag1 = ag0 + (long)16 * K;
    al0 = As + (c0 << 9);
    al1 = al0 + 512;
  }

  const int fslot = ((lrow >> 1) & 3);

  f32x4 acc[4][4] = {};

  for (int k0 = 0; k0 < K; k0 += 32) {
    gload16(bg0 + k0, bl0);
    gload16(bg1 + k0, bl1);
    if constexpr (AF32) {
      const float* ap = afp + k0;
      f32x4 f0 = *(const f32x4*)(ap);
      f32x4 f1 = *(const f32x4*)(ap + 4);
      f32x4 f2 = *(const f32x4*)(ap + 8);
      f32x4 f3 = *(const f32x4*)(ap + 12);
      ushort4v u0, u1, u2, u3;
      u0[0]=f2bs(f0[0]); u0[1]=f2bs(f0[1]); u0[2]=f2bs(f0[2]); u0[3]=f2bs(f0[3]);
      u1[0]=f2bs(f1[0]); u1[1]=f2bs(f1[1]); u1[2]=f2bs(f1[2]); u1[3]=f2bs(f1[3]);
      u2[0]=f2bs(f2[0]); u2[1]=f2bs(f2[1]); u2[2]=f2bs(f2[2]); u2[3]=f2bs(f2[3]);
      u3[0]=f2bs(f3[0]); u3[1]=f2bs(f3[1]); u3[2]=f2bs(f3[2]); u3[3]=f2bs(f3[3]);
      *(ushort4v*)afl = u0;
      *(ushort4v*)(afl + 4) = u1;
      *(ushort4v*)(afl + 8) = u2;
      *(ushort4v*)(afl + 12) = u3;
    } else {
      gload16(ag0 + k0, al0);
      gload16(ag1 + k0, al1);
    }
    __syncthreads();
    short8 afr[4], bfr[4];
#pragma unroll
    for (int i = 0; i < 4; i++) {
      if constexpr (AF32)
        afr[i] = *(const short8*)(As + (wm + i * 16 + lrow) * 32 + (kg << 3));
      else
        afr[i] = *(const short8*)(As + (wm + i * 16 + lrow) * 32 + ((kg ^ fslot) << 3));
    }
#pragma unroll
    for (int j = 0; j < 4; j++)
      bfr[j] = *(const short8*)(Bs + (wn + j * 16 + lrow) * 32 + ((kg ^ fslot) << 3));
#pragma unroll
    for (int i = 0; i < 4; i++)
#pragma unroll
      for (int j = 0; j < 4; j++)
        acc[i][j] = __builtin_amdgcn_mfma_f32_16x16x32_bf16(afr[i], bfr[j], acc[i][j], 0, 0, 0);
    __syncthreads();
  }

  float* Cf = (float*)Cp;
  unsigned short* Cb = (unsigned short*)Cp;
#pragma unroll
  for (int i = 0; i < 4; i++) {
#pragma unroll
    for (int j = 0; j < 4; j++) {
      const int col = n0 + wn + j * 16 + lrow;
      const float bv = bias[col];
#pragma unroll
      for (int q = 0; q < 4; q++) {
        const long row = m0 + wm + i * 16 + kg * 4 + q;
        float v = acc[i][j][q] + bv;
        if constexpr (RMODE == 1) v = fmaxf(v, 0.0f);
        if constexpr (PRODF) {
          int gr = (col < 512) ? subp[row] : objp[row];
          v *= b2f(fusedp[(long)gr * 1024 + col]);
        }
        if constexpr (ACCUM) v += Cin[row * (long)N + col];
        if constexpr (RMODE == 2) v = fmaxf(v, 0.0f);
        if constexpr (OUTB) Cb[row * (long)N + col] = f2bs(v);
        else Cf[row * (long)N + col] = v;
      }
    }
  }
}

// ===================== small kernels =====================

// f32 -> bf16 with row padding K0 -> Kp (both mult of 4), vectorized x4
__global__ void cvt_pad4(const float* __restrict__ src, unsigned short* __restrict__ dst,
                         int rows, int K0, int Kp)
{
  const int kp4 = Kp >> 2;
  const long total = (long)rows * kp4;
  for (long i = blockIdx.x * (long)blockDim.x + threadIdx.x; i < total; i += (long)gridDim.x * blockDim.x) {
    int r = (int)(i / kp4), k = (int)(i - (long)r * kp4) << 2;
    ushort4v o;
    if (k < K0) {
      f32x4 v = *(const f32x4*)(src + (long)r * K0 + k);
      o[0] = f2bs(v[0]); o[1] = f2bs(v[1]); o[2] = f2bs(v[2]); o[3] = f2bs(v[3]);
    } else {
      o[0] = 0; o[1] = 0; o[2] = 0; o[3] = 0;
    }
    *(ushort4v*)(dst + (long)r * Kp + k) = o;
  }
}

// f32 -> bf16, vectorized x4
__global__ void cvt4(const float* __restrict__ src, unsigned short* __restrict__ dst, long n4)
{
  for (long i = blockIdx.x * (long)blockDim.x + threadIdx.x; i < n4; i += (long)gridDim.x * blockDim.x) {
    f32x4 v = ((const f32x4*)src)[i];
    ushort4v o;
    o[0] = f2bs(v[0]); o[1] = f2bs(v[1]); o[2] = f2bs(v[2]); o[3] = f2bs(v[3]);
    ((ushort4v*)dst)[i] = o;
  }
}

// dst[c][r] = bf16(src[r][c])
__global__ void transpose_cvt(const float* __restrict__ src, unsigned short* __restrict__ dst,
                              int R, int C)
{
  __shared__ float tile[32][33];
  int c0 = blockIdx.x * 32, r0 = blockIdx.y * 32;
  for (int i = threadIdx.y; i < 32; i += 8)
    tile[i][threadIdx.x] = src[(long)(r0 + i) * C + c0 + threadIdx.x];
  __syncthreads();
  for (int i = threadIdx.y; i < 32; i += 8)
    dst[(long)(c0 + i) * R + r0 + threadIdx.x] = f2bs(tile[threadIdx.x][i]);
}

// b_comp[j] = edgeU_b[j] + sum_k edgeU_W[j][k] * up_b[k]
__global__ void comp_bias(const float* __restrict__ edgeU_W, const float* __restrict__ up_b,
                          const float* __restrict__ edgeU_b, float* __restrict__ b_comp)
{
  int j = (int)((blockIdx.x * (long)blockDim.x + threadIdx.x) >> 6);
  int l = threadIdx.x & 63;
  if (j >= 512) return;
  float s = 0.0f;
  for (int k = l; k < 2048; k += 64) s += edgeU_W[(long)j * 2048 + k] * up_b[k];
#pragma unroll
  for (int off = 32; off > 0; off >>= 1) s += __shfl_xor(s, off);
  if (l == 0) b_comp[j] = s + edgeU_b[j];
}

__global__ void obox_k(const float* __restrict__ boxes, float* __restrict__ obox)
{
  int i = blockIdx.x * blockDim.x + threadIdx.x;
  if (i >= NOBJ) return;
  float x1 = boxes[i*4], y1 = boxes[i*4+1], x2 = boxes[i*4+2], y2 = boxes[i*4+3];
  float wdt = x2 - x1 + 1.0f, hgt = y2 - y1 + 1.0f;
  float cx = x1 + 0.5f * wdt, cy = y1 + 0.5f * hgt;
  const float inv = 1.0f / 1024.0f;
  float* o = obox + i * 8;
  o[0]=x1*inv; o[1]=y1*inv; o[2]=x2*inv; o[3]=y2*inv;
  o[4]=cx*inv; o[5]=cy*inv; o[6]=wdt*inv; o[7]=hgt*inv;
}

__global__ void posembed_k(const float* __restrict__ boxes,
                           const float* __restrict__ w1, const float* __restrict__ b1,
                           const float* __restrict__ g, const float* __restrict__ bb,
                           const float* __restrict__ mm, const float* __restrict__ vv,
                           const float* __restrict__ w2, const float* __restrict__ b2,
                           float* __restrict__ out)
{
  int o = blockIdx.x, t = threadIdx.x;
  __shared__ float e[9];
  __shared__ float p[32];
  if (t == 0) {
    float x1 = boxes[o*4], y1 = boxes[o*4+1], x2 = boxes[o*4+2], y2 = boxes[o*4+3];
    float wdt = x2 - x1 + 1.0f, hgt = y2 - y1 + 1.0f;
    float cx = x1 + 0.5f * wdt, cy = y1 + 0.5f * hgt;
    e[0]=wdt/1024.0f; e[1]=hgt/768.0f; e[2]=cx/1024.0f; e[3]=cy/768.0f;
    e[4]=x1/1024.0f;  e[5]=y1/768.0f;  e[6]=x2/1024.0f; e[7]=y2/768.0f;
    e[8]=wdt*hgt/(1024.0f*768.0f);
  }
  __syncthreads();
  if (t < 32) {
    float s = b1[t];
#pragma unroll
    for (int j = 0; j < 9; j++) s += w1[t*9+j] * e[j];
    s = (s - mm[t]) * g[t] / sqrtf(vv[t] + 1e-5f) + bb[t];
    p[t] = s;
  }
  __syncthreads();
  float s = b2[t];
#pragma unroll
  for (int j = 0; j < 32; j++) s += w2[t*32+j] * p[j];
  out[o*128 + t] = fmaxf(s, 0.0f);
}

__device__ __forceinline__ void pack8_store(unsigned short* dst, f32x4 a, f32x4 b)
{
  ushort4v o0, o1;
  o0[0]=f2bs(a[0]); o0[1]=f2bs(a[1]); o0[2]=f2bs(a[2]); o0[3]=f2bs(a[3]);
  o1[0]=f2bs(b[0]); o1[1]=f2bs(b[1]); o1[2]=f2bs(b[2]); o1[3]=f2bs(b[3]);
  *(ushort4v*)dst = o0;
  *(ushort4v*)(dst + 4) = o1;
}

// X1 = [inst(4096) | emb_dist(200) | pos(128) | pad->4480]  bf16, 8-wide
__global__ void build_x1(const float* __restrict__ inst, const float* __restrict__ embd,
                         const int* __restrict__ labels, const float* __restrict__ pose,
                         unsigned short* __restrict__ X1b)
{
  const long total = (long)NOBJ * 560;
  for (long i = blockIdx.x * (long)blockDim.x + threadIdx.x; i < total; i += (long)gridDim.x * blockDim.x) {
    int r = (int)(i / 560), c = ((int)(i - (long)r * 560)) << 3;
    unsigned short* dst = X1b + (long)r * 4480 + c;
    const float* src;
    if (c < 4096)      src = inst + (long)r * 4096 + c;
    else if (c < 4296) src = embd + (long)labels[r] * 200 + (c - 4096);
    else if (c < 4424) src = pose + r * 128 + (c - 4296);
    else { ushort4v z = {0,0,0,0}; *(ushort4v*)dst = z; *(ushort4v*)(dst+4) = z; continue; }
    pack8_store(dst, *(const f32x4*)src, *((const f32x4*)src + 1));
  }
}

// augment = [emb_label(200) | inst(4096) | aug(512) | pad->4864]  bf16, 8-wide
__global__ void build_aug(const float* __restrict__ embl, const int* __restrict__ labels,
                          const float* __restrict__ inst, const float* __restrict__ aug,
                          unsigned short* __restrict__ augb)
{
  const long total = (long)NOBJ * 608;
  for (long i = blockIdx.x * (long)blockDim.x + threadIdx.x; i < total; i += (long)gridDim.x * blockDim.x) {
    int r = (int)(i / 608), c = ((int)(i - (long)r * 608)) << 3;
    unsigned short* dst = augb + (long)r * 4864 + c;
    const float* src;
    if (c < 200)       src = embl + (long)labels[r] * 200 + c;
    else if (c < 4296) src = inst + (long)r * 4096 + (c - 200);
    else if (c < 4808) src = aug + (long)r * 512 + (c - 4296);
    else { ushort4v z = {0,0,0,0}; *(ushort4v*)dst = z; *(ushort4v*)(dst+4) = z; continue; }
    pack8_store(dst, *(const f32x4*)src, *((const f32x4*)src + 1));
  }
}

// geo pair features (32 dims, padded to 64) as bf16
__global__ void build_geo(const float* __restrict__ obox, const int* __restrict__ sub,
                          const int* __restrict__ obj, unsigned short* __restrict__ geob)
{
  int r = blockIdx.x * blockDim.x + threadIdx.x;
  if (r >= NREL) return;
  const float* b1 = obox + sub[r] * 8;
  const float* b2 = obox + obj[r] * 8;
  float o[32];
#pragma unroll
  for (int j = 0; j < 8; j++) { o[j] = b1[j]; o[8+j] = b2[j]; }
  float ux1 = fminf(b1[0], b2[0]), uy1 = fminf(b1[1], b2[1]);
  float ux2 = fmaxf(b1[2], b2[2]), uy2 = fmaxf(b1[3], b2[3]);
  float uw = ux2 - ux1 + 1.0f, uh = uy2 - uy1 + 1.0f;
  o[16]=ux1; o[17]=uy1; o[18]=ux2; o[19]=uy2;
  o[20]=ux1+0.5f*uw; o[21]=uy1+0.5f*uh; o[22]=uw; o[23]=uh;
  float ix1 = fmaxf(b1[0], b2[0]), iy1 = fmaxf(b1[1], b2[1]);
  float ix2 = fminf(b1[2], b2[2]), iy2 = fminf(b1[3], b2[3]);
  bool bad = (ix2 < ix1) || (iy2 < iy1);
  float iw = ix2 - ix1 + 1.0f, ih = iy2 - iy1 + 1.0f;
  if (bad) {
#pragma unroll
    for (int j = 24; j < 32; j++) o[j] = 0.0f;
  } else {
    o[24]=ix1; o[25]=iy1; o[26]=ix2; o[27]=iy2;
    o[28]=ix1+0.5f*iw; o[29]=iy1+0.5f*ih; o[30]=iw; o[31]=ih;
  }
  unsigned short* gp = geob + (long)r * 64;
#pragma unroll
  for (int j = 0; j < 32; j++) gp[j] = f2bs(o[j]);
#pragma unroll
  for (int j = 32; j < 64; j++) gp[j] = 0;
}

// GRU h=0: h = (1-z)*n, gates bf16 [r|z|n] stride 1536. 8-wide.
__global__ void gru_init(const unsigned short* __restrict__ gi, const float* __restrict__ bhh,
                         float* __restrict__ h, unsigned short* __restrict__ hb, int n)
{
  const long total = (long)n * 64;
  for (long i = blockIdx.x * (long)blockDim.x + threadIdx.x; i < total; i += (long)gridDim.x * blockDim.x) {
    int r = (int)(i >> 6), c = ((int)(i & 63)) << 3;
    const unsigned short* gr = gi + (long)r * 1536;
    short8 vr = *(const short8*)(gr + c);
    short8 vz = *(const short8*)(gr + 512 + c);
    short8 vn = *(const short8*)(gr + 1024 + c);
    float hv[8];
#pragma unroll
    for (int k = 0; k < 8; k++) {
      float rr = sigf(b2f((unsigned short)vr[k]) + bhh[c + k]);
      float z  = sigf(b2f((unsigned short)vz[k]) + bhh[512 + c + k]);
      float nn = tanhf(b2f((unsigned short)vn[k]) + rr * bhh[1024 + c + k]);
      hv[k] = (1.0f - z) * nn;
    }
    float* hp = h + (long)r * 512 + c;
    *(f32x4*)hp = *(f32x4*)hv;
    *(f32x4*)(hp + 4) = *(f32x4*)(hv + 4);
    pack8_store(hb + (long)r * 512 + c, *(f32x4*)hv, *(f32x4*)(hv + 4));
  }
}

// GRU step: gates bf16, hin f32 -> hout f32 + hb bf16. 8-wide.
__global__ void gru_step(const unsigned short* __restrict__ gi, const unsigned short* __restrict__ gh,
                         const float* __restrict__ hin, float* __restrict__ hout,
                         unsigned short* __restrict__ hb, int n)
{
  const long total = (long)n * 64;
  for (long i = blockIdx.x * (long)blockDim.x + threadIdx.x; i < total; i += (long)gridDim.x * blockDim.x) {
    int r = (int)(i >> 6), c = ((int)(i & 63)) << 3;
    const unsigned short* gr = gi + (long)r * 1536;
    const unsigned short* hr = gh + (long)r * 1536;
    short8 ir = *(const short8*)(gr + c);
    short8 iz = *(const short8*)(gr + 512 + c);
    short8 in_ = *(const short8*)(gr + 1024 + c);
    short8 hrr = *(const short8*)(hr + c);
    short8 hz = *(const short8*)(hr + 512 + c);
    short8 hn = *(const short8*)(hr + 1024 + c);
    const float* hi = hin + (long)r * 512 + c;
    f32x4 h0 = *(const f32x4*)hi;
    f32x4 h1 = *(const f32x4*)(hi + 4);
    float hv[8];
#pragma unroll
    for (int k = 0; k < 8; k++) {
      float rr = sigf(b2f((unsigned short)ir[k]) + b2f((unsigned short)hrr[k]));
      float z  = sigf(b2f((unsigned short)iz[k]) + b2f((unsigned short)hz[k]));
      float nn = tanhf(b2f((unsigned short)in_[k]) + rr * b2f((unsigned short)hn[k]));
      float old = (k < 4) ? h0[k] : h1[k - 4];
      hv[k] = (1.0f - z) * nn + z * old;
    }
    float* hp = hout + (long)r * 512 + c;
    *(f32x4*)hp = *(f32x4*)hv;
    *(f32x4*)(hp + 4) = *(f32x4*)(hv + 4);
    pack8_store(hb + (long)r * 512 + c, *(f32x4*)hv, *(f32x4*)(hv + 4));
  }
}

// Fused per-relation: ws/wo dots, xb = ws*sv+wo*ov (bf16), ctx scatter-adds.
// Reads bf16 mirrors (vertb/edgeb); dots and atomics in f32.
__global__ __launch_bounds__(256)
void edge_weights(const unsigned short* __restrict__ vertb, const unsigned short* __restrict__ edgeb,
                  const int* __restrict__ sub, const int* __restrict__ obj,
                  const float* __restrict__ svwW, const float* __restrict__ svwb,
                  const float* __restrict__ ovwW, const float* __restrict__ ovwb,
                  unsigned short* __restrict__ xb, float* __restrict__ ctx)
{
  long gid = blockIdx.x * (long)blockDim.x + threadIdx.x;
  int r = (int)(gid >> 6);
  int l = (int)(gid & 63);
  if (r >= NREL) return;
  int s = sub[r], o = obj[r];
  const unsigned short* sv = vertb + (long)s * 512;
  const unsigned short* ov = vertb + (long)o * 512;
  const unsigned short* e  = edgeb + (long)r * 512;
  float svv[8], ovv[8], ev[8];
  float as = 0.0f, ao = 0.0f;
#pragma unroll
  for (int k = 0; k < 8; k++) {
    int c = l + k * 64;
    svv[k] = b2f(sv[c]); ovv[k] = b2f(ov[c]); ev[k] = b2f(e[c]);
    as += svwW[c] * svv[k] + svwW[512 + c] * ev[k];
    ao += ovwW[c] * ovv[k] + ovwW[512 + c] * ev[k];
  }
#pragma unroll
  for (int off = 32; off > 0; off >>= 1) {
    as += __shfl_xor(as, off);
    ao += __shfl_xor(ao, off);
  }
  float ws = sigf(as + svwb[0]);
  float wo = sigf(ao + ovwb[0]);
#pragma unroll
  for (int k = 0; k < 8; k++) {
    int c = l + k * 64;
    xb[(long)r * 512 + c] = f2bs(ws * svv[k] + wo * ovv[k]);
    atomicAdd(ctx + (long)s * 512 + c, ws * ev[k]);
    atomicAdd(ctx + (long)o * 512 + c, wo * ev[k]);
  }
}

// ===================== driver =====================

static inline int nblk(long total) {
  long b = (total + 255) / 256;
  return (int)(b > 16384 ? 16384 : b);
}

#define GEMM(RM, AC, OB, PF, grid, Aa, Bb, bb, Ci, Cc, Mm, Nn, Kk, fp, sp, op) \
  gemm_bt<RM, AC, OB, PF, false><<<grid, 256, 0, stream>>>(Aa, Bb, bb, Ci, Cc, Mm, Nn, Kk, fp, sp, op)
#define GEMMF(RM, AC, OB, grid, Aa, Bb, bb, Ci, Cc, Mm, Nn, Kk) \
  gemm_bt<RM, AC, OB, false, true><<<grid, 256, 0, stream>>>(Aa, Bb, bb, Ci, Cc, Mm, Nn, Kk, nullptr, nullptr, nullptr)

extern "C" void kernel_launch(void* const* d_in, const int* in_sizes, int n_in,
                              void* d_out, int out_size, void* d_ws, size_t ws_size,
                              hipStream_t stream)
{
  const float* inst     = (const float*)d_in[0];
  const float* unionf   = (const float*)d_in[1];
  const float* boxes    = (const float*)d_in[2];
  const float* embd_W   = (const float*)d_in[3];
  const float* embl_W   = (const float*)d_in[4];
  const float* up_W     = (const float*)d_in[5];
  const float* up_b     = (const float*)d_in[6];
  const float* pairup_W = (const float*)d_in[7];
  const float* pairup_b = (const float*)d_in[8];
  const float* pos1_W   = (const float*)d_in[9];
  const float* pos1_b   = (const float*)d_in[10];
  const float* bn_g     = (const float*)d_in[11];
  const float* bn_b     = (const float*)d_in[12];
  const float* bn_m     = (const float*)d_in[13];
  const float* bn_v     = (const float*)d_in[14];
  const float* pos2_W   = (const float*)d_in[15];
  const float* pos2_b   = (const float*)d_in[16];
  const float* spt1_W   = (const float*)d_in[17];
  const float* spt1_b   = (const float*)d_in[18];
  const float* spt2_W   = (const float*)d_in[19];
  const float* spt2_b   = (const float*)d_in[20];
  const float* pairfin_W= (const float*)d_in[21];
  const float* pairfin_b= (const float*)d_in[22];
  const float* objhid_W = (const float*)d_in[23];
  const float* objhid_b = (const float*)d_in[24];
  const float* objfin_W = (const float*)d_in[25];
  const float* objfin_b = (const float*)d_in[26];
  const float* objU_W   = (const float*)d_in[27];
  const float* objU_b   = (const float*)d_in[28];
  const float* edgeU_W  = (const float*)d_in[29];
  const float* edgeU_b  = (const float*)d_in[30];
  const float* egru_Wih = (const float*)d_in[31];
  const float* egru_Whh = (const float*)d_in[32];
  const float* egru_bih = (const float*)d_in[33];
  const float* egru_bhh = (const float*)d_in[34];
  const float* ngru_Wih = (const float*)d_in[35];
  const float* ngru_Whh = (const float*)d_in[36];
  const float* ngru_bih = (const float*)d_in[37];
  const float* ngru_bhh = (const float*)d_in[38];
  const float* svw_W    = (const float*)d_in[39];
  const float* svw_b    = (const float*)d_in[40];
  const float* ovw_W    = (const float*)d_in[41];
  const float* ovw_b    = (const float*)d_in[42];
  const int*   labels   = (const int*)d_in[43];
  const int*   sub      = (const int*)d_in[44];
  const int*   obj      = (const int*)d_in[45];
  (void)in_sizes; (void)n_in; (void)out_size; (void)ws_size;

  char* base = (char*)d_ws;
  size_t off = 0;
  auto alloc = [&](size_t bytes) -> void* {
    void* p = base + off;
    off += (bytes + 255) & ~(size_t)255;
    return p;
  };

  // ---- weights (bf16) ----
  unsigned short* objhid_Wb  = (unsigned short*)alloc(512L  * 4480 * 2);
  unsigned short* pairup_Wb  = (unsigned short*)alloc(1024L * 4864 * 2);
  unsigned short* objfin_Wb  = (unsigned short*)alloc(2048L * 4864 * 2);
  unsigned short* up_Wtb     = (unsigned short*)alloc(4096L * 2048 * 2);
  unsigned short* pairfin_Wb = (unsigned short*)alloc(2048L * 1024 * 2);
  unsigned short* spt1_Wb    = (unsigned short*)alloc(512L  * 64   * 2);
  unsigned short* spt2_Wb    = (unsigned short*)alloc(1024L * 512  * 2);
  unsigned short* objU_Wb    = (unsigned short*)alloc(512L  * 2048 * 2);
  unsigned short* edgeU_Wb   = (unsigned short*)alloc(512L  * 2048 * 2);
  unsigned short* egru_Wihb  = (unsigned short*)alloc(1536L * 512  * 2);
  unsigned short* egru_Whhb  = (unsigned short*)alloc(1536L * 512  * 2);
  unsigned short* ngru_Wihb  = (unsigned short*)alloc(1536L * 512  * 2);
  unsigned short* ngru_Whhb  = (unsigned short*)alloc(1536L * 512  * 2);
  unsigned short* W_compb    = (unsigned short*)alloc(512L  * 4096 * 2);
  float*          b_comp     = (float*)alloc(512L * 4);
  float*          zbias      = (float*)alloc(4096L * 4);

  // ---- activations ----
  float*          obox      = (float*)alloc(NOBJ * 8L * 4);
  float*          pose      = (float*)alloc(NOBJ * 128L * 4);
  float*          aug       = (float*)alloc((long)NOBJ * 512 * 4);
  unsigned short* obj_featsb= (unsigned short*)alloc((long)NOBJ * 2048 * 2);
  unsigned short* obj_repb  = (unsigned short*)alloc((long)NOBJ * 512 * 2);
  unsigned short* giv       = (unsigned short*)alloc((long)NOBJ * 1536 * 2);
  unsigned short* ghv       = (unsigned short*)alloc((long)NOBJ * 1536 * 2);
  float*          vert      = (float*)alloc((long)NOBJ * 512 * 4);
  unsigned short* vertb     = (unsigned short*)alloc((long)NOBJ * 512 * 2);
  float*          ctx       = (float*)alloc((long)NOBJ * 512 * 4);
  unsigned short* ctxb      = (unsigned short*)alloc((long)NOBJ * 512 * 2);
  unsigned short* geob      = (unsigned short*)alloc((long)NREL * 64 * 2);
  float*          edge      = (float*)alloc((long)NREL * 512 * 4);

  // REGION_A: X1b (17.5MB) -> T1 (f32 64MB)
  char* regA = (char*)alloc((long)NREL * 512 * 4);
  unsigned short* X1b = (unsigned short*)regA;
  float*          T1  = (float*)regA;
  // REGION_B: augb (19MB) -> rel_repb (32MB)
  char* regB = (char*)alloc((long)NREL * 512 * 2);
  unsigned short* augb     = (unsigned short*)regB;
  unsigned short* rel_repb = (unsigned short*)regB;
  // REGION_C: fusedb (bf16 4MB) -> xb (32MB)
  char* regC = (char*)alloc((long)NREL * 512 * 2);
  unsigned short* fusedb = (unsigned short*)regC;
  unsigned short* xb     = (unsigned short*)regC;
  // REGION_D: spt1b -> edgeb
  char* regD = (char*)alloc((long)NREL * 512 * 2);
  unsigned short* spt1b = (unsigned short*)regD;
  unsigned short* edgeb = (unsigned short*)regD;
  // BIG1 (192MB): [G1 bf16 128MB @0 | prodb bf16 64MB @128MB] -> gi_e (bf16 96MB)
  char* big1 = (char*)alloc((long)NREL * 1536 * 4);
  unsigned short* G1    = (unsigned short*)big1;
  unsigned short* prodb = (unsigned short*)(big1 + (long)NREL * 1024 * 4);
  unsigned short* gi_e  = (unsigned short*)big1;
  // gh_e (bf16 96MB)
  unsigned short* gh_e = (unsigned short*)alloc((long)NREL * 1536 * 2);

  float* d_out_vert = (float*)d_out;
  float* d_out_edge = (float*)d_out + (long)NOBJ * 512;

  // ---- weight conversions ----
  cvt_pad4<<<nblk(512L*4480/4),  256, 0, stream>>>(objhid_W,  objhid_Wb,  512,  4424, 4480);
  cvt_pad4<<<nblk(1024L*4864/4), 256, 0, stream>>>(pairup_W,  pairup_Wb,  1024, 4808, 4864);
  cvt_pad4<<<nblk(2048L*4864/4), 256, 0, stream>>>(objfin_W,  objfin_Wb,  2048, 4808, 4864);
  cvt_pad4<<<nblk(512L*64/4),    256, 0, stream>>>(spt1_W,    spt1_Wb,    512,  32,   64);
  cvt4<<<nblk(2048L*1024/4), 256, 0, stream>>>(pairfin_W, pairfin_Wb, 2048L*1024/4);
  cvt4<<<nblk(1024L*512/4),  256, 0, stream>>>(spt2_W,    spt2_Wb,    1024L*512/4);
  cvt4<<<nblk(512L*2048/4),  256, 0, stream>>>(objU_W,    objU_Wb,    512L*2048/4);
  cvt4<<<nblk(512L*2048/4),  256, 0, stream>>>(edgeU_W,   edgeU_Wb,   512L*2048/4);
  cvt4<<<nblk(1536L*512/4),  256, 0, stream>>>(egru_Wih,  egru_Wihb,  1536L*512/4);
  cvt4<<<nblk(1536L*512/4),  256, 0, stream>>>(egru_Whh,  egru_Whhb,  1536L*512/4);
  cvt4<<<nblk(1536L*512/4),  256, 0, stream>>>(ngru_Wih,  ngru_Wihb,  1536L*512/4);
  cvt4<<<nblk(1536L*512/4),  256, 0, stream>>>(ngru_Whh,  ngru_Whhb,  1536L*512/4);
  transpose_cvt<<<dim3(4096/32, 2048/32), dim3(32, 8), 0, stream>>>(up_W, up_Wtb, 2048, 4096);
  hipMemsetAsync(zbias, 0, 4096L * 4, stream);
  comp_bias<<<128, 256, 0, stream>>>(edgeU_W, up_b, edgeU_b, b_comp);
  GEMM(0,false,true,false, dim3((512>>7)*(4096>>7)), edgeU_Wb, up_Wtb, zbias, nullptr, W_compb, 512, 4096, 2048, nullptr, nullptr, nullptr);

  // ---- object stream ----
  obox_k<<<(NOBJ + 255) / 256, 256, 0, stream>>>(boxes, obox);
  posembed_k<<<NOBJ, 128, 0, stream>>>(boxes, pos1_W, pos1_b, bn_g, bn_b, bn_m, bn_v,
                                       pos2_W, pos2_b, pose);
  build_x1<<<nblk((long)NOBJ*560), 256, 0, stream>>>(inst, embd_W, labels, pose, X1b);
  GEMM(0,false,false,false, dim3((NOBJ>>7)*(512>>7)),  X1b, objhid_Wb, objhid_b, nullptr, aug, NOBJ, 512, 4480, nullptr, nullptr, nullptr);
  build_aug<<<nblk((long)NOBJ*608), 256, 0, stream>>>(embl_W, labels, inst, aug, augb);
  GEMM(0,false,true ,false, dim3((NOBJ>>7)*(1024>>7)), augb, pairup_Wb, pairup_b, nullptr, fusedb, NOBJ, 1024, 4864, nullptr, nullptr, nullptr);
  GEMM(1,false,true ,false, dim3((NOBJ>>7)*(2048>>7)), augb, objfin_Wb, objfin_b, nullptr, obj_featsb, NOBJ, 2048, 4864, nullptr, nullptr, nullptr);
  GEMM(0,false,true ,false, dim3((NOBJ>>7)*(512>>7)),  obj_featsb, objU_Wb, objU_b, nullptr, obj_repb, NOBJ, 512, 2048, nullptr, nullptr, nullptr);
  GEMM(0,false,true ,false, dim3((NOBJ>>7)*(1536>>7)), obj_repb, ngru_Wihb, ngru_bih, nullptr, giv, NOBJ, 1536, 512, nullptr, nullptr, nullptr);
  gru_init<<<nblk((long)NOBJ*64), 256, 0, stream>>>(giv, ngru_bhh, vert, vertb, NOBJ);

  // ---- relation stream ----
  build_geo<<<(NREL + 255) / 256, 256, 0, stream>>>(obox, sub, obj, geob);
  GEMM(1,false,true ,false, dim3((NREL>>7)*(512>>7)),  geob, spt1_Wb, spt1_b, nullptr, spt1b, NREL, 512, 64, nullptr, nullptr, nullptr);
  // prod = relu(spt1b@spt2^T + b) * pair-gather(fusedb)   [PRODF epilogue]
  GEMM(1,false,true ,true , dim3((NREL>>7)*(1024>>7)), spt1b, spt2_Wb, spt2_b, nullptr, prodb, NREL, 1024, 512, fusedb, sub, obj);
  GEMM(1,false,true ,false, dim3((NREL>>7)*(2048>>7)), prodb, pairfin_Wb, pairfin_b, nullptr, G1, NREL, 2048, 1024, nullptr, nullptr, nullptr);
  // T1 = union(f32, in-GEMM cvt) @ W_comp^T + b_comp
  GEMMF(0,false,false, dim3((NREL>>7)*(512>>7)), unionf, W_compb, b_comp, nullptr, T1, NREL, 512, 4096);
  GEMM(2,true ,true ,false, dim3((NREL>>7)*(512>>7)),  G1, edgeU_Wb, zbias, T1, rel_repb, NREL, 512, 2048, nullptr, nullptr, nullptr);
  GEMM(0,false,true ,false, dim3((NREL>>7)*(1536>>7)), rel_repb, egru_Wihb, egru_bih, nullptr, gi_e, NREL, 1536, 512, nullptr, nullptr, nullptr);
  gru_init<<<nblk((long)NREL*64), 256, 0, stream>>>(gi_e, egru_bhh, edge, edgeb, NREL);

  // ---- message-passing loop ----
  for (int it = 0; it < 3; it++) {
    const bool last = (it == 2);
    hipMemsetAsync(ctx, 0, (long)NOBJ * 512 * 4, stream);
    edge_weights<<<(NREL * 64) / 256, 256, 0, stream>>>(vertb, edgeb, sub, obj,
                                                        svw_W, svw_b, ovw_W, ovw_b, xb, ctx);
    cvt4<<<nblk((long)NOBJ*512/4), 256, 0, stream>>>(ctx, ctxb, (long)NOBJ*512/4);
    GEMM(0,false,true,false, dim3((NREL>>7)*(1536>>7)), xb,    egru_Wihb, egru_bih, nullptr, gi_e, NREL, 1536, 512, nullptr, nullptr, nullptr);
    GEMM(0,false,true,false, dim3((NREL>>7)*(1536>>7)), edgeb, egru_Whhb, egru_bhh, nullptr, gh_e, NREL, 1536, 512, nullptr, nullptr, nullptr);
    GEMM(0,false,true,false, dim3((NOBJ>>7)*(1536>>7)), ctxb,  ngru_Wihb, ngru_bih, nullptr, giv, NOBJ, 1536, 512, nullptr, nullptr, nullptr);
    GEMM(0,false,true,false, dim3((NOBJ>>7)*(1536>>7)), vertb, ngru_Whhb, ngru_bhh, nullptr, ghv, NOBJ, 1536, 512, nullptr, nullptr, nullptr);
    gru_step<<<nblk((long)NREL*64), 256, 0, stream>>>(gi_e, gh_e, edge, last ? d_out_edge : edge, edgeb, NREL);
    gru_step<<<nblk((long)NOBJ*64), 256, 0, stream>>>(giv, ghv, vert, last ? d_out_vert : vert, vertb, NOBJ);
  }
}

// Round 5
// 2078.646 us; speedup vs baseline: 2.2911x; 1.1219x over previous
//
#include <hip/hip_runtime.h>
#include <stdint.h>

#define NOBJ 2048
#define NREL 32768

typedef __attribute__((ext_vector_type(8))) short short8;
typedef __attribute__((ext_vector_type(4))) float f32x4;
typedef __attribute__((ext_vector_type(4))) unsigned short ushort4v;

__device__ __forceinline__ unsigned short f2bs(float x){
  unsigned u = __float_as_uint(x);
  unsigned v = u + 0x7fffu + ((u >> 16) & 1u);
  return (unsigned short)(v >> 16);
}
__device__ __forceinline__ float b2f(unsigned short u){
  return __uint_as_float(((unsigned)u) << 16);
}
__device__ __forceinline__ float sigf(float x){ return 1.0f / (1.0f + expf(-x)); }

// async global->LDS, 16B per lane. LDS dest = wave-uniform base + lane*16.
__device__ __forceinline__ void gload16(const unsigned short* g, unsigned short* l) {
  __builtin_amdgcn_global_load_lds(
      (const __attribute__((address_space(1))) unsigned int*)(uintptr_t)g,
      (__attribute__((address_space(3))) unsigned int*)(uintptr_t)l,
      16, 0, 0);
}

// =====================  GEMM: C = f(A * B^T + bias [+Cin])  =====================
// A: MxK(lda) row-major, bf16 (gload_lds + slot swizzle) or f32 (AF32: reg-staged cvt).
// B: NxK bf16 packed. Out stride ldc. RMODE: 0 none; 1 relu then [PRODF][+Cin];
// 2 relu(acc+bias+Cin). Cin stride = N. XCD-bijective block swizzle (m204).
template<int RMODE, bool ACCUM, bool OUTB, bool PRODF, bool AF32>
__global__ __launch_bounds__(256, 2)
void gemm_bt(const void* __restrict__ Ap, const unsigned short* __restrict__ B,
             const float* __restrict__ bias, const float* __restrict__ Cin,
             void* __restrict__ Cp, int M, int N, int K, int lda, int ldc,
             const unsigned short* __restrict__ fusedp,
             const int* __restrict__ subp, const int* __restrict__ objp)
{
  __shared__ __align__(16) unsigned short As[128 * 32];
  __shared__ __align__(16) unsigned short Bs[128 * 32];
  const int t = threadIdx.x;
  const int lane = t & 63;
  const int w = t >> 6;
  const int nwg = gridDim.x;
  const int q8 = nwg >> 3, r8 = nwg & 7;
  const int xcd = blockIdx.x & 7, bidx = blockIdx.x >> 3;
  const int wgid = (xcd < r8 ? xcd * (q8 + 1) : r8 * (q8 + 1) + (xcd - r8) * q8) + bidx;
  const int ntile = N >> 7;
  const int bm = wgid / ntile;
  const int bn = wgid - bm * ntile;
  const int m0 = bm << 7, n0 = bn << 7;
  const int wm = (w & 1) << 6, wn = (w >> 1) << 6;
  const int lrow = lane & 15, kg = lane >> 4;

  const int c0 = w << 1;
  const int srow = (c0 << 4) + (lane >> 2);
  const int selem = (((lane & 3) ^ ((lane >> 3) & 3)) << 3);
  const unsigned short* bg0 = B + (long)(n0 + srow) * K + selem;
  const unsigned short* bg1 = bg0 + (long)16 * K;
  unsigned short* bl0 = Bs + (c0 << 9);
  unsigned short* bl1 = bl0 + 512;

  const unsigned short* ag0 = nullptr; const unsigned short* ag1 = nullptr;
  unsigned short* al0 = nullptr; unsigned short* al1 = nullptr;
  const float* afp = nullptr; unsigned short* afl = nullptr;
  if constexpr (AF32) {
    afp = (const float*)Ap + (long)(m0 + (t >> 1)) * lda + ((t & 1) << 4);
    afl = As + (t >> 1) * 32 + ((t & 1) << 4);
  } else {
    ag0 = (const unsigned short*)Ap + (long)(m0 + srow) * lda + selem;
    ag1 = ag0 + (long)16 * lda;
    al0 = As + (c0 << 9);
    al1 = al0 + 512;
  }

  const int fslot = ((lrow >> 1) & 3);

  f32x4 acc[4][4] = {};

  for (int k0 = 0; k0 < K; k0 += 32) {
    gload16(bg0 + k0, bl0);
    gload16(bg1 + k0, bl1);
    if constexpr (AF32) {
      const float* ap = afp + k0;
      f32x4 f0 = *(const f32x4*)(ap);
      f32x4 f1 = *(const f32x4*)(ap + 4);
      f32x4 f2 = *(const f32x4*)(ap + 8);
      f32x4 f3 = *(const f32x4*)(ap + 12);
      ushort4v u0, u1, u2, u3;
      u0[0]=f2bs(f0[0]); u0[1]=f2bs(f0[1]); u0[2]=f2bs(f0[2]); u0[3]=f2bs(f0[3]);
      u1[0]=f2bs(f1[0]); u1[1]=f2bs(f1[1]); u1[2]=f2bs(f1[2]); u1[3]=f2bs(f1[3]);
      u2[0]=f2bs(f2[0]); u2[1]=f2bs(f2[1]); u2[2]=f2bs(f2[2]); u2[3]=f2bs(f2[3]);
      u3[0]=f2bs(f3[0]); u3[1]=f2bs(f3[1]); u3[2]=f2bs(f3[2]); u3[3]=f2bs(f3[3]);
      *(ushort4v*)afl = u0;
      *(ushort4v*)(afl + 4) = u1;
      *(ushort4v*)(afl + 8) = u2;
      *(ushort4v*)(afl + 12) = u3;
    } else {
      gload16(ag0 + k0, al0);
      gload16(ag1 + k0, al1);
    }
    __syncthreads();
    short8 afr[4], bfr[4];
#pragma unroll
    for (int i = 0; i < 4; i++) {
      if constexpr (AF32)
        afr[i] = *(const short8*)(As + (wm + i * 16 + lrow) * 32 + (kg << 3));
      else
        afr[i] = *(const short8*)(As + (wm + i * 16 + lrow) * 32 + ((kg ^ fslot) << 3));
    }
#pragma unroll
    for (int j = 0; j < 4; j++)
      bfr[j] = *(const short8*)(Bs + (wn + j * 16 + lrow) * 32 + ((kg ^ fslot) << 3));
#pragma unroll
    for (int i = 0; i < 4; i++)
#pragma unroll
      for (int j = 0; j < 4; j++)
        acc[i][j] = __builtin_amdgcn_mfma_f32_16x16x32_bf16(afr[i], bfr[j], acc[i][j], 0, 0, 0);
    __syncthreads();
  }

  float* Cf = (float*)Cp;
  unsigned short* Cb = (unsigned short*)Cp;
#pragma unroll
  for (int i = 0; i < 4; i++) {
#pragma unroll
    for (int j = 0; j < 4; j++) {
      const int col = n0 + wn + j * 16 + lrow;
      const float bv = bias[col];
#pragma unroll
      for (int q = 0; q < 4; q++) {
        const long row = m0 + wm + i * 16 + kg * 4 + q;
        float v = acc[i][j][q] + bv;
        if constexpr (RMODE == 1) v = fmaxf(v, 0.0f);
        if constexpr (PRODF) {
          int gr = (col < 512) ? subp[row] : objp[row];
          v *= b2f(fusedp[(long)gr * 1024 + col]);
        }
        if constexpr (ACCUM) v += Cin[row * (long)N + col];
        if constexpr (RMODE == 2) v = fmaxf(v, 0.0f);
        if constexpr (OUTB) Cb[row * (long)ldc + col] = f2bs(v);
        else Cf[row * (long)ldc + col] = v;
      }
    }
  }
}

// ===================== small kernels =====================

__global__ void cvt_pad4(const float* __restrict__ src, unsigned short* __restrict__ dst,
                         int rows, int K0, int Kp)
{
  const int kp4 = Kp >> 2;
  const long total = (long)rows * kp4;
  for (long i = blockIdx.x * (long)blockDim.x + threadIdx.x; i < total; i += (long)gridDim.x * blockDim.x) {
    int r = (int)(i / kp4), k = (int)(i - (long)r * kp4) << 2;
    ushort4v o;
    if (k < K0) {
      f32x4 v = *(const f32x4*)(src + (long)r * K0 + k);
      o[0] = f2bs(v[0]); o[1] = f2bs(v[1]); o[2] = f2bs(v[2]); o[3] = f2bs(v[3]);
    } else {
      o[0] = 0; o[1] = 0; o[2] = 0; o[3] = 0;
    }
    *(ushort4v*)(dst + (long)r * Kp + k) = o;
  }
}

__global__ void cvt4(const float* __restrict__ src, unsigned short* __restrict__ dst, long n4)
{
  for (long i = blockIdx.x * (long)blockDim.x + threadIdx.x; i < n4; i += (long)gridDim.x * blockDim.x) {
    f32x4 v = ((const f32x4*)src)[i];
    ushort4v o;
    o[0] = f2bs(v[0]); o[1] = f2bs(v[1]); o[2] = f2bs(v[2]); o[3] = f2bs(v[3]);
    ((ushort4v*)dst)[i] = o;
  }
}

// Wcat_rz[j][k] (1024x1024): k<512 ? eWih[j][k] : eWhh[j][k-512]   (j<1024 = r,z rows)
__global__ void build_wcat(const float* __restrict__ wih, const float* __restrict__ whh,
                           unsigned short* __restrict__ dst)
{
  const long total = 1024L * 256;   // quads
  for (long i = blockIdx.x * (long)blockDim.x + threadIdx.x; i < total; i += (long)gridDim.x * blockDim.x) {
    int j = (int)(i >> 8), k = ((int)(i & 255)) << 2;
    const float* s = (k < 512) ? (wih + (long)j * 512 + k) : (whh + (long)j * 512 + (k - 512));
    f32x4 v = *(const f32x4*)s;
    ushort4v o;
    o[0] = f2bs(v[0]); o[1] = f2bs(v[1]); o[2] = f2bs(v[2]); o[3] = f2bs(v[3]);
    *(ushort4v*)(dst + (long)j * 1024 + k) = o;
  }
}

__global__ void bias_rz_k(const float* __restrict__ bih, const float* __restrict__ bhh,
                          float* __restrict__ out)
{
  int j = blockIdx.x * blockDim.x + threadIdx.x;
  if (j < 1024) out[j] = bih[j] + bhh[j];
}

__global__ void transpose_cvt(const float* __restrict__ src, unsigned short* __restrict__ dst,
                              int R, int C)
{
  __shared__ float tile[32][33];
  int c0 = blockIdx.x * 32, r0 = blockIdx.y * 32;
  for (int i = threadIdx.y; i < 32; i += 8)
    tile[i][threadIdx.x] = src[(long)(r0 + i) * C + c0 + threadIdx.x];
  __syncthreads();
  for (int i = threadIdx.y; i < 32; i += 8)
    dst[(long)(c0 + i) * R + r0 + threadIdx.x] = f2bs(tile[threadIdx.x][i]);
}

__global__ void comp_bias(const float* __restrict__ edgeU_W, const float* __restrict__ up_b,
                          const float* __restrict__ edgeU_b, float* __restrict__ b_comp)
{
  int j = (int)((blockIdx.x * (long)blockDim.x + threadIdx.x) >> 6);
  int l = threadIdx.x & 63;
  if (j >= 512) return;
  float s = 0.0f;
  for (int k = l; k < 2048; k += 64) s += edgeU_W[(long)j * 2048 + k] * up_b[k];
#pragma unroll
  for (int off = 32; off > 0; off >>= 1) s += __shfl_xor(s, off);
  if (l == 0) b_comp[j] = s + edgeU_b[j];
}

__global__ void obox_k(const float* __restrict__ boxes, float* __restrict__ obox)
{
  int i = blockIdx.x * blockDim.x + threadIdx.x;
  if (i >= NOBJ) return;
  float x1 = boxes[i*4], y1 = boxes[i*4+1], x2 = boxes[i*4+2], y2 = boxes[i*4+3];
  float wdt = x2 - x1 + 1.0f, hgt = y2 - y1 + 1.0f;
  float cx = x1 + 0.5f * wdt, cy = y1 + 0.5f * hgt;
  const float inv = 1.0f / 1024.0f;
  float* o = obox + i * 8;
  o[0]=x1*inv; o[1]=y1*inv; o[2]=x2*inv; o[3]=y2*inv;
  o[4]=cx*inv; o[5]=cy*inv; o[6]=wdt*inv; o[7]=hgt*inv;
}

__global__ void posembed_k(const float* __restrict__ boxes,
                           const float* __restrict__ w1, const float* __restrict__ b1,
                           const float* __restrict__ g, const float* __restrict__ bb,
                           const float* __restrict__ mm, const float* __restrict__ vv,
                           const float* __restrict__ w2, const float* __restrict__ b2,
                           float* __restrict__ out)
{
  int o = blockIdx.x, t = threadIdx.x;
  __shared__ float e[9];
  __shared__ float p[32];
  if (t == 0) {
    float x1 = boxes[o*4], y1 = boxes[o*4+1], x2 = boxes[o*4+2], y2 = boxes[o*4+3];
    float wdt = x2 - x1 + 1.0f, hgt = y2 - y1 + 1.0f;
    float cx = x1 + 0.5f * wdt, cy = y1 + 0.5f * hgt;
    e[0]=wdt/1024.0f; e[1]=hgt/768.0f; e[2]=cx/1024.0f; e[3]=cy/768.0f;
    e[4]=x1/1024.0f;  e[5]=y1/768.0f;  e[6]=x2/1024.0f; e[7]=y2/768.0f;
    e[8]=wdt*hgt/(1024.0f*768.0f);
  }
  __syncthreads();
  if (t < 32) {
    float s = b1[t];
#pragma unroll
    for (int j = 0; j < 9; j++) s += w1[t*9+j] * e[j];
    s = (s - mm[t]) * g[t] / sqrtf(vv[t] + 1e-5f) + bb[t];
    p[t] = s;
  }
  __syncthreads();
  float s = b2[t];
#pragma unroll
  for (int j = 0; j < 32; j++) s += w2[t*32+j] * p[j];
  out[o*128 + t] = fmaxf(s, 0.0f);
}

__device__ __forceinline__ void pack8_store(unsigned short* dst, f32x4 a, f32x4 b)
{
  ushort4v o0, o1;
  o0[0]=f2bs(a[0]); o0[1]=f2bs(a[1]); o0[2]=f2bs(a[2]); o0[3]=f2bs(a[3]);
  o1[0]=f2bs(b[0]); o1[1]=f2bs(b[1]); o1[2]=f2bs(b[2]); o1[3]=f2bs(b[3]);
  *(ushort4v*)dst = o0;
  *(ushort4v*)(dst + 4) = o1;
}

// X1 = [inst(4096) | emb_dist(200) | pos(128) | pad->4480]  bf16, 8-wide
__global__ void build_x1(const float* __restrict__ inst, const float* __restrict__ embd,
                         const int* __restrict__ labels, const float* __restrict__ pose,
                         unsigned short* __restrict__ X1b)
{
  const long total = (long)NOBJ * 560;
  for (long i = blockIdx.x * (long)blockDim.x + threadIdx.x; i < total; i += (long)gridDim.x * blockDim.x) {
    int r = (int)(i / 560), c = ((int)(i - (long)r * 560)) << 3;
    unsigned short* dst = X1b + (long)r * 4480 + c;
    const float* src;
    if (c < 4096)      src = inst + (long)r * 4096 + c;
    else if (c < 4296) src = embd + (long)labels[r] * 200 + (c - 4096);
    else if (c < 4424) src = pose + r * 128 + (c - 4296);
    else { ushort4v z = {0,0,0,0}; *(ushort4v*)dst = z; *(ushort4v*)(dst+4) = z; continue; }
    pack8_store(dst, *(const f32x4*)src, *((const f32x4*)src + 1));
  }
}

// augment = [emb_label(200) | inst(4096) | (aug: GEMM-written) | pad->4864]
// groups 537..600 (cols 4296..4808) are skipped (objhid GEMM writes them).
__global__ void build_aug(const float* __restrict__ embl, const int* __restrict__ labels,
                          const float* __restrict__ inst, unsigned short* __restrict__ augb)
{
  const long total = (long)NOBJ * 608;
  for (long i = blockIdx.x * (long)blockDim.x + threadIdx.x; i < total; i += (long)gridDim.x * blockDim.x) {
    int r = (int)(i / 608), c = ((int)(i - (long)r * 608)) << 3;
    if (c >= 4296 && c < 4808) continue;
    unsigned short* dst = augb + (long)r * 4864 + c;
    const float* src;
    if (c < 200)       src = embl + (long)labels[r] * 200 + c;
    else if (c < 4296) src = inst + (long)r * 4096 + (c - 200);
    else { ushort4v z = {0,0,0,0}; *(ushort4v*)dst = z; *(ushort4v*)(dst+4) = z; continue; }
    pack8_store(dst, *(const f32x4*)src, *((const f32x4*)src + 1));
  }
}

__global__ void build_geo(const float* __restrict__ obox, const int* __restrict__ sub,
                          const int* __restrict__ obj, unsigned short* __restrict__ geob)
{
  int r = blockIdx.x * blockDim.x + threadIdx.x;
  if (r >= NREL) return;
  const float* b1 = obox + sub[r] * 8;
  const float* b2 = obox + obj[r] * 8;
  float o[32];
#pragma unroll
  for (int j = 0; j < 8; j++) { o[j] = b1[j]; o[8+j] = b2[j]; }
  float ux1 = fminf(b1[0], b2[0]), uy1 = fminf(b1[1], b2[1]);
  float ux2 = fmaxf(b1[2], b2[2]), uy2 = fmaxf(b1[3], b2[3]);
  float uw = ux2 - ux1 + 1.0f, uh = uy2 - uy1 + 1.0f;
  o[16]=ux1; o[17]=uy1; o[18]=ux2; o[19]=uy2;
  o[20]=ux1+0.5f*uw; o[21]=uy1+0.5f*uh; o[22]=uw; o[23]=uh;
  float ix1 = fmaxf(b1[0], b2[0]), iy1 = fmaxf(b1[1], b2[1]);
  float ix2 = fminf(b1[2], b2[2]), iy2 = fminf(b1[3], b2[3]);
  bool bad = (ix2 < ix1) || (iy2 < iy1);
  float iw = ix2 - ix1 + 1.0f, ih = iy2 - iy1 + 1.0f;
  if (bad) {
#pragma unroll
    for (int j = 24; j < 32; j++) o[j] = 0.0f;
  } else {
    o[24]=ix1; o[25]=iy1; o[26]=ix2; o[27]=iy2;
    o[28]=ix1+0.5f*iw; o[29]=iy1+0.5f*ih; o[30]=iw; o[31]=ih;
  }
  unsigned short* gp = geob + (long)r * 64;
#pragma unroll
  for (int j = 0; j < 32; j++) gp[j] = f2bs(o[j]);
#pragma unroll
  for (int j = 32; j < 64; j++) gp[j] = 0;
}

// GRU h=0: h=(1-z)*n; gates bf16 [r|z|n] stride 1536; hb stride hstride.
__global__ void gru_init(const unsigned short* __restrict__ gi, const float* __restrict__ bhh,
                         float* __restrict__ h, unsigned short* __restrict__ hb, int hstride, int n)
{
  const long total = (long)n * 64;
  for (long i = blockIdx.x * (long)blockDim.x + threadIdx.x; i < total; i += (long)gridDim.x * blockDim.x) {
    int r = (int)(i >> 6), c = ((int)(i & 63)) << 3;
    const unsigned short* gr = gi + (long)r * 1536;
    short8 vr = *(const short8*)(gr + c);
    short8 vz = *(const short8*)(gr + 512 + c);
    short8 vn = *(const short8*)(gr + 1024 + c);
    float hv[8];
#pragma unroll
    for (int k = 0; k < 8; k++) {
      float rr = sigf(b2f((unsigned short)vr[k]) + bhh[c + k]);
      float z  = sigf(b2f((unsigned short)vz[k]) + bhh[512 + c + k]);
      float nn = tanhf(b2f((unsigned short)vn[k]) + rr * bhh[1024 + c + k]);
      hv[k] = (1.0f - z) * nn;
    }
    float* hp = h + (long)r * 512 + c;
    *(f32x4*)hp = *(f32x4*)hv;
    *(f32x4*)(hp + 4) = *(f32x4*)(hv + 4);
    pack8_store(hb + (long)r * hstride + c, *(f32x4*)hv, *(f32x4*)(hv + 4));
  }
}

// vertex GRU step: gi/gh bf16 stride 1536, hin/hout f32, hb stride 512.
__global__ void gru_step_v(const unsigned short* __restrict__ gi, const unsigned short* __restrict__ gh,
                           const float* __restrict__ hin, float* __restrict__ hout,
                           unsigned short* __restrict__ hb, int n)
{
  const long total = (long)n * 64;
  for (long i = blockIdx.x * (long)blockDim.x + threadIdx.x; i < total; i += (long)gridDim.x * blockDim.x) {
    int r = (int)(i >> 6), c = ((int)(i & 63)) << 3;
    const unsigned short* gr = gi + (long)r * 1536;
    const unsigned short* hr = gh + (long)r * 1536;
    short8 ir = *(const short8*)(gr + c);
    short8 iz = *(const short8*)(gr + 512 + c);
    short8 in_ = *(const short8*)(gr + 1024 + c);
    short8 hrr = *(const short8*)(hr + c);
    short8 hz = *(const short8*)(hr + 512 + c);
    short8 hn = *(const short8*)(hr + 1024 + c);
    const float* hi = hin + (long)r * 512 + c;
    f32x4 h0 = *(const f32x4*)hi;
    f32x4 h1 = *(const f32x4*)(hi + 4);
    float hv[8];
#pragma unroll
    for (int k = 0; k < 8; k++) {
      float rr = sigf(b2f((unsigned short)ir[k]) + b2f((unsigned short)hrr[k]));
      float z  = sigf(b2f((unsigned short)iz[k]) + b2f((unsigned short)hz[k]));
      float nn = tanhf(b2f((unsigned short)in_[k]) + rr * b2f((unsigned short)hn[k]));
      float old = (k < 4) ? h0[k] : h1[k - 4];
      hv[k] = (1.0f - z) * nn + z * old;
    }
    float* hp = hout + (long)r * 512 + c;
    *(f32x4*)hp = *(f32x4*)hv;
    *(f32x4*)(hp + 4) = *(f32x4*)(hv + 4);
    pack8_store(hb + (long)r * 512 + c, *(f32x4*)hv, *(f32x4*)(hv + 4));
  }
}

// edge GRU step: gates[r][2048] = [r(512)|z(512)|gi_n(512)|gh_n(512)] bf16.
// h' = (1-z)*tanh(gi_n + r*gh_n) + z*h. Writes hout f32 and xe[r][512..1024) bf16.
__global__ void gru_step_e(const unsigned short* __restrict__ gates,
                           const float* __restrict__ hin, float* __restrict__ hout,
                           unsigned short* __restrict__ xe, int n)
{
  const long total = (long)n * 64;
  for (long i = blockIdx.x * (long)blockDim.x + threadIdx.x; i < total; i += (long)gridDim.x * blockDim.x) {
    int r = (int)(i >> 6), c = ((int)(i & 63)) << 3;
    const unsigned short* g = gates + (long)r * 2048;
    short8 vr = *(const short8*)(g + c);
    short8 vz = *(const short8*)(g + 512 + c);
    short8 vi = *(const short8*)(g + 1024 + c);
    short8 vh = *(const short8*)(g + 1536 + c);
    const float* hi = hin + (long)r * 512 + c;
    f32x4 h0 = *(const f32x4*)hi;
    f32x4 h1 = *(const f32x4*)(hi + 4);
    float hv[8];
#pragma unroll
    for (int k = 0; k < 8; k++) {
      float rr = sigf(b2f((unsigned short)vr[k]));
      float z  = sigf(b2f((unsigned short)vz[k]));
      float nn = tanhf(b2f((unsigned short)vi[k]) + rr * b2f((unsigned short)vh[k]));
      float old = (k < 4) ? h0[k] : h1[k - 4];
      hv[k] = (1.0f - z) * nn + z * old;
    }
    float* hp = hout + (long)r * 512 + c;
    *(f32x4*)hp = *(f32x4*)hv;
    *(f32x4*)(hp + 4) = *(f32x4*)(hv + 4);
    pack8_store(xe + (long)r * 1024 + 512 + c, *(f32x4*)hv, *(f32x4*)(hv + 4));
  }
}

// Per-relation: ws/wo dots; xb = ws*sv+wo*ov into xe[r][0..512); store ws,wo. No atomics.
__global__ __launch_bounds__(256)
void edge_weights(const unsigned short* __restrict__ vertb, unsigned short* __restrict__ xe,
                  const int* __restrict__ sub, const int* __restrict__ obj,
                  const float* __restrict__ svwW, const float* __restrict__ svwb,
                  const float* __restrict__ ovwW, const float* __restrict__ ovwb,
                  float* __restrict__ ws_arr, float* __restrict__ wo_arr)
{
  long gid = blockIdx.x * (long)blockDim.x + threadIdx.x;
  int r = (int)(gid >> 6);
  int l = (int)(gid & 63);
  if (r >= NREL) return;
  int s = sub[r], o = obj[r];
  const unsigned short* sv = vertb + (long)s * 512;
  const unsigned short* ov = vertb + (long)o * 512;
  const unsigned short* e  = xe + (long)r * 1024 + 512;
  float svv[8], ovv[8], ev[8];
  float as = 0.0f, ao = 0.0f;
#pragma unroll
  for (int k = 0; k < 8; k++) {
    int c = l + k * 64;
    svv[k] = b2f(sv[c]); ovv[k] = b2f(ov[c]); ev[k] = b2f(e[c]);
    as += svwW[c] * svv[k] + svwW[512 + c] * ev[k];
    ao += ovwW[c] * ovv[k] + ovwW[512 + c] * ev[k];
  }
#pragma unroll
  for (int off = 32; off > 0; off >>= 1) {
    as += __shfl_xor(as, off);
    ao += __shfl_xor(ao, off);
  }
  float ws = sigf(as + svwb[0]);
  float wo = sigf(ao + ovwb[0]);
  unsigned short* xr = xe + (long)r * 1024;
#pragma unroll
  for (int k = 0; k < 8; k++) {
    int c = l + k * 64;
    xr[c] = f2bs(ws * svv[k] + wo * ovv[k]);
  }
  if (l == 0) { ws_arr[r] = ws; wo_arr[r] = wo; }
}

// ===================== CSR (static per-call; sub/obj are fixed inputs) =====================

__global__ void csr_count(const int* __restrict__ sub, const int* __restrict__ obj,
                          int* __restrict__ cnt)
{
  int r = blockIdx.x * blockDim.x + threadIdx.x;
  if (r >= NREL) return;
  atomicAdd(&cnt[sub[r]], 1);
  atomicAdd(&cnt[obj[r]], 1);
}

// 1 block, 1024 threads: exclusive scan of cnt[2048] -> off[0..2048]
__global__ __launch_bounds__(1024)
void csr_scan(const int* __restrict__ cnt, int* __restrict__ off)
{
  __shared__ int a[1024], b[1024];
  int t = threadIdx.x;
  int c0 = cnt[2*t], c1 = cnt[2*t+1];
  a[t] = c0 + c1;
  __syncthreads();
  int* src = a; int* dst = b;
  for (int s = 1; s < 1024; s <<= 1) {
    int v = src[t];
    if (t >= s) v += src[t - s];
    dst[t] = v;
    __syncthreads();
    int* tmp = src; src = dst; dst = tmp;
  }
  int incl = src[t];
  int excl = incl - (c0 + c1);
  off[2*t] = excl;
  off[2*t+1] = excl + c0;
  if (t == 1023) off[2048] = incl;
}

__global__ void csr_fill(const int* __restrict__ sub, const int* __restrict__ obj,
                         const int* __restrict__ off, int* __restrict__ rcur,
                         int* __restrict__ lists)
{
  int r = blockIdx.x * blockDim.x + threadIdx.x;
  if (r >= NREL) return;
  int s = sub[r];
  int p = atomicAdd(&rcur[s], 1);
  lists[off[s] + p] = (r << 1);
  int o = obj[r];
  int q = atomicAdd(&rcur[o], 1);
  lists[off[o] + q] = (r << 1) | 1;
}

// ctx[o] = sum ws[r]*edge[r] (sub hits) + wo[r]*edge[r] (obj hits); writes ctxb bf16.
// Block = 1 object, 2 waves split the list; LDS combine.
__global__ __launch_bounds__(128)
void ctx_gather(const unsigned short* __restrict__ xe, const float* __restrict__ ws,
                const float* __restrict__ wo, const int* __restrict__ off,
                const int* __restrict__ lists, unsigned short* __restrict__ ctxb)
{
  __shared__ float part[512];
  int o = blockIdx.x;
  int l = threadIdx.x & 63;
  int w = threadIdx.x >> 6;
  int i0 = off[o], i1 = off[o + 1];
  float acc[8] = {0.f,0.f,0.f,0.f,0.f,0.f,0.f,0.f};
  for (int i = i0 + w; i < i1; i += 2) {
    int e = lists[i];
    int r = e >> 1;
    float sc = (e & 1) ? wo[r] : ws[r];
    short8 row = *(const short8*)(xe + (long)r * 1024 + 512 + l * 8);
#pragma unroll
    for (int k = 0; k < 8; k++) acc[k] += sc * b2f((unsigned short)row[k]);
  }
  if (w == 1) {
    *(f32x4*)&part[l*8]     = *(f32x4*)&acc[0];
    *(f32x4*)&part[l*8 + 4] = *(f32x4*)&acc[4];
  }
  __syncthreads();
  if (w == 0) {
#pragma unroll
    for (int k = 0; k < 8; k++) acc[k] += part[l*8 + k];
    pack8_store(ctxb + (long)o * 512 + l * 8, *(f32x4*)&acc[0], *(f32x4*)&acc[4]);
  }
}

// ===================== driver =====================

static inline int nblk(long total) {
  long b = (total + 255) / 256;
  return (int)(b > 16384 ? 16384 : b);
}

#define GEMM(RM, AC, OB, PF, grid, Aa, Bb, bb, Ci, Cc, Mm, Nn, Kk, ldA, ldC, fp, sp, op) \
  gemm_bt<RM, AC, OB, PF, false><<<grid, 256, 0, stream>>>(Aa, Bb, bb, Ci, Cc, Mm, Nn, Kk, ldA, ldC, fp, sp, op)
#define GEMMF(RM, AC, OB, grid, Aa, Bb, bb, Ci, Cc, Mm, Nn, Kk, ldA, ldC) \
  gemm_bt<RM, AC, OB, false, true><<<grid, 256, 0, stream>>>(Aa, Bb, bb, Ci, Cc, Mm, Nn, Kk, ldA, ldC, nullptr, nullptr, nullptr)

extern "C" void kernel_launch(void* const* d_in, const int* in_sizes, int n_in,
                              void* d_out, int out_size, void* d_ws, size_t ws_size,
                              hipStream_t stream)
{
  const float* inst     = (const float*)d_in[0];
  const float* unionf   = (const float*)d_in[1];
  const float* boxes    = (const float*)d_in[2];
  const float* embd_W   = (const float*)d_in[3];
  const float* embl_W   = (const float*)d_in[4];
  const float* up_W     = (const float*)d_in[5];
  const float* up_b     = (const float*)d_in[6];
  const float* pairup_W = (const float*)d_in[7];
  const float* pairup_b = (const float*)d_in[8];
  const float* pos1_W   = (const float*)d_in[9];
  const float* pos1_b   = (const float*)d_in[10];
  const float* bn_g     = (const float*)d_in[11];
  const float* bn_b     = (const float*)d_in[12];
  const float* bn_m     = (const float*)d_in[13];
  const float* bn_v     = (const float*)d_in[14];
  const float* pos2_W   = (const float*)d_in[15];
  const float* pos2_b   = (const float*)d_in[16];
  const float* spt1_W   = (const float*)d_in[17];
  const float* spt1_b   = (const float*)d_in[18];
  const float* spt2_W   = (const float*)d_in[19];
  const float* spt2_b   = (const float*)d_in[20];
  const float* pairfin_W= (const float*)d_in[21];
  const float* pairfin_b= (const float*)d_in[22];
  const float* objhid_W = (const float*)d_in[23];
  const float* objhid_b = (const float*)d_in[24];
  const float* objfin_W = (const float*)d_in[25];
  const float* objfin_b = (const float*)d_in[26];
  const float* objU_W   = (const float*)d_in[27];
  const float* objU_b   = (const float*)d_in[28];
  const float* edgeU_W  = (const float*)d_in[29];
  const float* edgeU_b  = (const float*)d_in[30];
  const float* egru_Wih = (const float*)d_in[31];
  const float* egru_Whh = (const float*)d_in[32];
  const float* egru_bih = (const float*)d_in[33];
  const float* egru_bhh = (const float*)d_in[34];
  const float* ngru_Wih = (const float*)d_in[35];
  const float* ngru_Whh = (const float*)d_in[36];
  const float* ngru_bih = (const float*)d_in[37];
  const float* ngru_bhh = (const float*)d_in[38];
  const float* svw_W    = (const float*)d_in[39];
  const float* svw_b    = (const float*)d_in[40];
  const float* ovw_W    = (const float*)d_in[41];
  const float* ovw_b    = (const float*)d_in[42];
  const int*   labels   = (const int*)d_in[43];
  const int*   sub      = (const int*)d_in[44];
  const int*   obj      = (const int*)d_in[45];
  (void)in_sizes; (void)n_in; (void)out_size; (void)ws_size;

  char* base = (char*)d_ws;
  size_t off = 0;
  auto alloc = [&](size_t bytes) -> void* {
    void* p = base + off;
    off += (bytes + 255) & ~(size_t)255;
    return p;
  };

  // ---- weights (bf16) ----
  unsigned short* objhid_Wb  = (unsigned short*)alloc(512L  * 4480 * 2);
  unsigned short* pairup_Wb  = (unsigned short*)alloc(1024L * 4864 * 2);
  unsigned short* objfin_Wb  = (unsigned short*)alloc(2048L * 4864 * 2);
  unsigned short* up_Wtb     = (unsigned short*)alloc(4096L * 2048 * 2);
  unsigned short* pairfin_Wb = (unsigned short*)alloc(2048L * 1024 * 2);
  unsigned short* spt1_Wb    = (unsigned short*)alloc(512L  * 64   * 2);
  unsigned short* spt2_Wb    = (unsigned short*)alloc(1024L * 512  * 2);
  unsigned short* objU_Wb    = (unsigned short*)alloc(512L  * 2048 * 2);
  unsigned short* edgeU_Wb   = (unsigned short*)alloc(512L  * 2048 * 2);
  unsigned short* egru_Wihb  = (unsigned short*)alloc(1536L * 512  * 2);
  unsigned short* egru_Whhb  = (unsigned short*)alloc(1536L * 512  * 2);
  unsigned short* ngru_Wihb  = (unsigned short*)alloc(1536L * 512  * 2);
  unsigned short* ngru_Whhb  = (unsigned short*)alloc(1536L * 512  * 2);
  unsigned short* Wcat_rzb   = (unsigned short*)alloc(1024L * 1024 * 2);
  unsigned short* W_compb    = (unsigned short*)alloc(512L  * 4096 * 2);
  float*          b_comp     = (float*)alloc(512L * 4);
  float*          zbias      = (float*)alloc(4096L * 4);
  float*          bias_rz    = (float*)alloc(1024L * 4);

  // ---- activations ----
  float*          obox      = (float*)alloc(NOBJ * 8L * 4);
  float*          pose      = (float*)alloc(NOBJ * 128L * 4);
  unsigned short* obj_featsb= (unsigned short*)alloc((long)NOBJ * 2048 * 2);
  unsigned short* obj_repb  = (unsigned short*)alloc((long)NOBJ * 512 * 2);
  unsigned short* giv       = (unsigned short*)alloc((long)NOBJ * 1536 * 2);
  unsigned short* ghv       = (unsigned short*)alloc((long)NOBJ * 1536 * 2);
  float*          vert      = (float*)alloc((long)NOBJ * 512 * 4);
  unsigned short* vertb     = (unsigned short*)alloc((long)NOBJ * 512 * 2);
  unsigned short* ctxb      = (unsigned short*)alloc((long)NOBJ * 512 * 2);
  unsigned short* geob      = (unsigned short*)alloc((long)NREL * 64 * 2);
  float*          edge      = (float*)alloc((long)NREL * 512 * 4);
  unsigned short* xe        = (unsigned short*)alloc((long)NREL * 1024 * 2);  // [xb | edge_bf16]
  float*          ws_arr    = (float*)alloc((long)NREL * 4);
  float*          wo_arr    = (float*)alloc((long)NREL * 4);

  // CSR
  int* cnt   = (int*)alloc(NOBJ * 4);
  int* coff  = (int*)alloc((NOBJ + 1) * 4);
  int* rcur  = (int*)alloc(NOBJ * 4);
  int* lists = (int*)alloc(2L * NREL * 4);

  // REGION_A: X1b (17.9MB) -> T1 (f32 64MB)
  char* regA = (char*)alloc((long)NREL * 512 * 4);
  unsigned short* X1b = (unsigned short*)regA;
  float*          T1  = (float*)regA;
  // REGION_B: augb (19.9MB) -> rel_repb (32MB)
  char* regB = (char*)alloc((long)NOBJ * 4864 * 2 > (long)NREL * 512 * 2
                            ? (long)NOBJ * 4864 * 2 : (long)NREL * 512 * 2);
  unsigned short* augb     = (unsigned short*)regB;
  unsigned short* rel_repb = (unsigned short*)regB;
  // fusedb + spt1b standalone
  unsigned short* fusedb = (unsigned short*)alloc((long)NOBJ * 1024 * 2);
  unsigned short* spt1b  = (unsigned short*)alloc((long)NREL * 512 * 2);
  // BIG1 (192MB): [G1 128MB | prodb 64MB] -> gi_e(init, 96MB) -> gates (128MB)
  char* big1 = (char*)alloc((long)NREL * 1536 * 4);
  unsigned short* G1    = (unsigned short*)big1;
  unsigned short* prodb = (unsigned short*)(big1 + (long)NREL * 1024 * 4);
  unsigned short* gi_e  = (unsigned short*)big1;
  unsigned short* gates = (unsigned short*)big1;

  float* d_out_vert = (float*)d_out;
  float* d_out_edge = (float*)d_out + (long)NOBJ * 512;

  // ---- weight conversions ----
  cvt_pad4<<<nblk(512L*4480/4),  256, 0, stream>>>(objhid_W,  objhid_Wb,  512,  4424, 4480);
  cvt_pad4<<<nblk(1024L*4864/4), 256, 0, stream>>>(pairup_W,  pairup_Wb,  1024, 4808, 4864);
  cvt_pad4<<<nblk(2048L*4864/4), 256, 0, stream>>>(objfin_W,  objfin_Wb,  2048, 4808, 4864);
  cvt_pad4<<<nblk(512L*64/4),    256, 0, stream>>>(spt1_W,    spt1_Wb,    512,  32,   64);
  cvt4<<<nblk(2048L*1024/4), 256, 0, stream>>>(pairfin_W, pairfin_Wb, 2048L*1024/4);
  cvt4<<<nblk(1024L*512/4),  256, 0, stream>>>(spt2_W,    spt2_Wb,    1024L*512/4);
  cvt4<<<nblk(512L*2048/4),  256, 0, stream>>>(objU_W,    objU_Wb,    512L*2048/4);
  cvt4<<<nblk(512L*2048/4),  256, 0, stream>>>(edgeU_W,   edgeU_Wb,   512L*2048/4);
  cvt4<<<nblk(1536L*512/4),  256, 0, stream>>>(egru_Wih,  egru_Wihb,  1536L*512/4);
  cvt4<<<nblk(1536L*512/4),  256, 0, stream>>>(egru_Whh,  egru_Whhb,  1536L*512/4);
  cvt4<<<nblk(1536L*512/4),  256, 0, stream>>>(ngru_Wih,  ngru_Wihb,  1536L*512/4);
  cvt4<<<nblk(1536L*512/4),  256, 0, stream>>>(ngru_Whh,  ngru_Whhb,  1536L*512/4);
  build_wcat<<<nblk(1024L*256), 256, 0, stream>>>(egru_Wih, egru_Whh, Wcat_rzb);
  bias_rz_k<<<4, 256, 0, stream>>>(egru_bih, egru_bhh, bias_rz);
  transpose_cvt<<<dim3(4096/32, 2048/32), dim3(32, 8), 0, stream>>>(up_W, up_Wtb, 2048, 4096);
  hipMemsetAsync(zbias, 0, 4096L * 4, stream);
  comp_bias<<<128, 256, 0, stream>>>(edgeU_W, up_b, edgeU_b, b_comp);
  GEMM(0,false,true,false, dim3((512>>7)*(4096>>7)), edgeU_Wb, up_Wtb, zbias, nullptr, W_compb, 512, 4096, 2048, 2048, 4096, nullptr, nullptr, nullptr);

  // ---- CSR build (static) ----
  hipMemsetAsync(cnt, 0, NOBJ * 4, stream);
  hipMemsetAsync(rcur, 0, NOBJ * 4, stream);
  csr_count<<<NREL/256, 256, 0, stream>>>(sub, obj, cnt);
  csr_scan<<<1, 1024, 0, stream>>>(cnt, coff);
  csr_fill<<<NREL/256, 256, 0, stream>>>(sub, obj, coff, rcur, lists);

  // ---- object stream ----
  obox_k<<<(NOBJ + 255) / 256, 256, 0, stream>>>(boxes, obox);
  posembed_k<<<NOBJ, 128, 0, stream>>>(boxes, pos1_W, pos1_b, bn_g, bn_b, bn_m, bn_v,
                                       pos2_W, pos2_b, pose);
  build_x1<<<nblk((long)NOBJ*560), 256, 0, stream>>>(inst, embd_W, labels, pose, X1b);
  build_aug<<<nblk((long)NOBJ*608), 256, 0, stream>>>(embl_W, labels, inst, augb);
  // aug -> bf16 straight into augb cols [4296,4808)
  GEMM(0,false,true ,false, dim3((NOBJ>>7)*(512>>7)),  X1b, objhid_Wb, objhid_b, nullptr, augb + 4296, NOBJ, 512, 4480, 4480, 4864, nullptr, nullptr, nullptr);
  GEMM(0,false,true ,false, dim3((NOBJ>>7)*(1024>>7)), augb, pairup_Wb, pairup_b, nullptr, fusedb, NOBJ, 1024, 4864, 4864, 1024, nullptr, nullptr, nullptr);
  GEMM(1,false,true ,false, dim3((NOBJ>>7)*(2048>>7)), augb, objfin_Wb, objfin_b, nullptr, obj_featsb, NOBJ, 2048, 4864, 4864, 2048, nullptr, nullptr, nullptr);
  GEMM(0,false,true ,false, dim3((NOBJ>>7)*(512>>7)),  obj_featsb, objU_Wb, objU_b, nullptr, obj_repb, NOBJ, 512, 2048, 2048, 512, nullptr, nullptr, nullptr);
  GEMM(0,false,true ,false, dim3((NOBJ>>7)*(1536>>7)), obj_repb, ngru_Wihb, ngru_bih, nullptr, giv, NOBJ, 1536, 512, 512, 1536, nullptr, nullptr, nullptr);
  gru_init<<<nblk((long)NOBJ*64), 256, 0, stream>>>(giv, ngru_bhh, vert, vertb, 512, NOBJ);

  // ---- relation stream ----
  build_geo<<<(NREL + 255) / 256, 256, 0, stream>>>(obox, sub, obj, geob);
  GEMM(1,false,true ,false, dim3((NREL>>7)*(512>>7)),  geob, spt1_Wb, spt1_b, nullptr, spt1b, NREL, 512, 64, 64, 512, nullptr, nullptr, nullptr);
  GEMM(1,false,true ,true , dim3((NREL>>7)*(1024>>7)), spt1b, spt2_Wb, spt2_b, nullptr, prodb, NREL, 1024, 512, 512, 1024, fusedb, sub, obj);
  GEMM(1,false,true ,false, dim3((NREL>>7)*(2048>>7)), prodb, pairfin_Wb, pairfin_b, nullptr, G1, NREL, 2048, 1024, 1024, 2048, nullptr, nullptr, nullptr);
  GEMMF(0,false,false, dim3((NREL>>7)*(512>>7)), unionf, W_compb, b_comp, nullptr, T1, NREL, 512, 4096, 4096, 512);
  GEMM(2,true ,true ,false, dim3((NREL>>7)*(512>>7)),  G1, edgeU_Wb, zbias, T1, rel_repb, NREL, 512, 2048, 2048, 512, nullptr, nullptr, nullptr);
  GEMM(0,false,true ,false, dim3((NREL>>7)*(1536>>7)), rel_repb, egru_Wihb, egru_bih, nullptr, gi_e, NREL, 1536, 512, 512, 1536, nullptr, nullptr, nullptr);
  gru_init<<<nblk((long)NREL*64), 256, 0, stream>>>(gi_e, egru_bhh, edge, xe + 512, 1024, NREL);

  // ---- message-passing loop ----
  for (int it = 0; it < 3; it++) {
    const bool last = (it == 2);
    edge_weights<<<(NREL * 64) / 256, 256, 0, stream>>>(vertb, xe, sub, obj,
                                                        svw_W, svw_b, ovw_W, ovw_b, ws_arr, wo_arr);
    ctx_gather<<<NOBJ, 128, 0, stream>>>(xe, ws_arr, wo_arr, coff, lists, ctxb);
    // edge gates: rz (K=1024 over [xb|edge]), gi_n, gh_n
    GEMM(0,false,true,false, dim3((NREL>>7)*(1024>>7)), xe,       Wcat_rzb, bias_rz, nullptr, gates, NREL, 1024, 1024, 1024, 2048, nullptr, nullptr, nullptr);
    GEMM(0,false,true,false, dim3((NREL>>7)*(512>>7)),  xe,       egru_Wihb + 1024L*512, egru_bih + 1024, nullptr, gates + 1024, NREL, 512, 512, 1024, 2048, nullptr, nullptr, nullptr);
    GEMM(0,false,true,false, dim3((NREL>>7)*(512>>7)),  xe + 512, egru_Whhb + 1024L*512, egru_bhh + 1024, nullptr, gates + 1536, NREL, 512, 512, 1024, 2048, nullptr, nullptr, nullptr);
    // vertex gates
    GEMM(0,false,true,false, dim3((NOBJ>>7)*(1536>>7)), ctxb,  ngru_Wihb, ngru_bih, nullptr, giv, NOBJ, 1536, 512, 512, 1536, nullptr, nullptr, nullptr);
    GEMM(0,false,true,false, dim3((NOBJ>>7)*(1536>>7)), vertb, ngru_Whhb, ngru_bhh, nullptr, ghv, NOBJ, 1536, 512, 512, 1536, nullptr, nullptr, nullptr);
    gru_step_e<<<nblk((long)NREL*64), 256, 0, stream>>>(gates, edge, last ? d_out_edge : edge, xe, NREL);
    gru_step_v<<<nblk((long)NOBJ*64), 256, 0, stream>>>(giv, ghv, vert, last ? d_out_vert : vert, vertb, NOBJ);
  }
}

// Round 6
// 2059.350 us; speedup vs baseline: 2.3126x; 1.0094x over previous
//
#include <hip/hip_runtime.h>
#include <stdint.h>

#define NOBJ 2048
#define NREL 32768

typedef __attribute__((ext_vector_type(8))) short short8;
typedef __attribute__((ext_vector_type(4))) float f32x4;
typedef __attribute__((ext_vector_type(4))) unsigned short ushort4v;

__device__ __forceinline__ unsigned short f2bs(float x){
  unsigned u = __float_as_uint(x);
  unsigned v = u + 0x7fffu + ((u >> 16) & 1u);
  return (unsigned short)(v >> 16);
}
__device__ __forceinline__ float b2f(unsigned short u){
  return __uint_as_float(((unsigned)u) << 16);
}
__device__ __forceinline__ float sigf(float x){ return 1.0f / (1.0f + expf(-x)); }

// async global->LDS, 16B per lane. LDS dest = wave-uniform base + lane*16.
__device__ __forceinline__ void gload16(const unsigned short* g, unsigned short* l) {
  __builtin_amdgcn_global_load_lds(
      (const __attribute__((address_space(1))) unsigned int*)(uintptr_t)g,
      (__attribute__((address_space(3))) unsigned int*)(uintptr_t)l,
      16, 0, 0);
}

// ============ 256x256 BK=64 double-buffered engine, counted vmcnt (T3/T4) ============
// A: MxK(lda) bf16. B: NxK bf16 packed. Always bf16 out (stride ldc).
// RMODE: 0 none; 1 relu [then PRODF]; 2 relu(acc+bias+Cin). ACCUM: +Cin (f32, stride N).
// LDS [buf][A/B][256 rows][8 slot16], slot s holds global col-slot s^(row&7) (both-sides swizzle).
// Pipeline: stage kt0,kt1; loop: vmcnt(8) (counted, never 0 in steady state) -> barrier ->
// 4 sub-phases of {ds_read, setprio(1), 16 MFMA, setprio(0)} -> barrier -> stage kt+2.
template<int RMODE, bool ACCUM, bool PRODF>
__global__ __launch_bounds__(512, 2)
void gemm256(const unsigned short* __restrict__ A, const unsigned short* __restrict__ B,
             const float* __restrict__ bias, const float* __restrict__ Cin,
             unsigned short* __restrict__ C, int M, int N, int K, int lda, int ldc,
             const unsigned short* __restrict__ fusedp,
             const int* __restrict__ subp, const int* __restrict__ objp)
{
  __shared__ __align__(16) unsigned short lds[2][2][16384];   // 128 KiB
  const int t = threadIdx.x;
  const int l = t & 63;
  const int w = t >> 6;                 // 0..7
  const int wr = w >> 2, wc = w & 3;    // 2M x 4N waves
  const int lrow = l & 15, kg = l >> 4;

  // XCD bijective swizzle (m204)
  const int nwg = gridDim.x;
  const int q8 = nwg >> 3, r8 = nwg & 7;
  const int xcd = blockIdx.x & 7, bidx = blockIdx.x >> 3;
  const int wgid = (xcd < r8 ? xcd * (q8 + 1) : r8 * (q8 + 1) + (xcd - r8) * q8) + bidx;
  const int ntile = N >> 8;
  const int bm = wgid / ntile, bn = wgid - bm * ntile;
  const int m0 = bm << 8, n0 = bn << 8;

  // staging: thread covers row srow(+64g+128h), source 16B slot pre-swizzled
  const int srow = w * 8 + (l >> 3);
  const int sel  = ((l & 7) ^ ((l >> 3) & 7)) << 3;
  const unsigned short* Ab0 = A + (long)(m0 + srow) * lda + sel;
  const unsigned short* Bb0 = B + (long)(n0 + srow) * K + sel;
  const long lda64 = (long)64 * lda;
  const long ldb64 = (long)64 * K;
  const int NT = K >> 6;

#define STG256(pA, pB, kt) do { \
    const unsigned short* a_ = Ab0 + (long)(kt) * 64; \
    const unsigned short* b_ = Bb0 + (long)(kt) * 64; \
    gload16(a_,              (pA)); \
    gload16(a_ + lda64,      (pA) + 4096); \
    gload16(a_ + 2 * lda64,  (pA) + 8192); \
    gload16(a_ + 3 * lda64,  (pA) + 12288); \
    gload16(b_,              (pB)); \
    gload16(b_ + ldb64,      (pB) + 4096); \
    gload16(b_ + 2 * ldb64,  (pB) + 8192); \
    gload16(b_ + 3 * ldb64,  (pB) + 12288); \
  } while (0)

  unsigned short* sA0 = &lds[0][0][w * 512];
  unsigned short* sB0 = &lds[0][1][w * 512];
  unsigned short* sA1 = &lds[1][0][w * 512];
  unsigned short* sB1 = &lds[1][1][w * 512];

  f32x4 acc[8][4] = {};

  STG256(sA0, sB0, 0);
  if (NT > 1) STG256(sA1, sB1, 1);

  for (int kt = 0; kt < NT; ++kt) {
    const int cur = kt & 1;
    // own-wave loads for buf[cur] are the oldest; barrier after => all waves' slices landed
    if (kt + 1 < NT) asm volatile("s_waitcnt vmcnt(8)" ::: "memory");
    else             asm volatile("s_waitcnt vmcnt(0)" ::: "memory");
    __builtin_amdgcn_s_barrier();
    asm volatile("" ::: "memory");

    const unsigned short* As_ = &lds[cur][0][0];
    const unsigned short* Bs_ = &lds[cur][1][0];

    short8 bfr[4][2];
#pragma unroll
    for (int j = 0; j < 4; j++) {
      const int rb = wc * 64 + j * 16 + lrow;
#pragma unroll
      for (int ks = 0; ks < 2; ks++) {
        const int a16 = rb * 8 + ((ks * 4 + kg) ^ (rb & 7));
        bfr[j][ks] = *(const short8*)(Bs_ + a16 * 8);
      }
    }
#pragma unroll
    for (int p = 0; p < 4; p++) {
      short8 afr[2][2];
#pragma unroll
      for (int ii = 0; ii < 2; ii++) {
        const int ra = wr * 128 + (p * 2 + ii) * 16 + lrow;
#pragma unroll
        for (int ks = 0; ks < 2; ks++) {
          const int a16 = ra * 8 + ((ks * 4 + kg) ^ (ra & 7));
          afr[ii][ks] = *(const short8*)(As_ + a16 * 8);
        }
      }
      __builtin_amdgcn_s_setprio(1);
#pragma unroll
      for (int ii = 0; ii < 2; ii++)
#pragma unroll
        for (int j = 0; j < 4; j++)
#pragma unroll
          for (int ks = 0; ks < 2; ks++)
            acc[p * 2 + ii][j] = __builtin_amdgcn_mfma_f32_16x16x32_bf16(
                afr[ii][ks], bfr[j][ks], acc[p * 2 + ii][j], 0, 0, 0);
      __builtin_amdgcn_s_setprio(0);
    }
    asm volatile("" ::: "memory");
    __builtin_amdgcn_s_barrier();   // all waves done reading buf[cur]
    asm volatile("" ::: "memory");
    if (kt + 2 < NT) {
      unsigned short* pa = (cur == 0) ? sA0 : sA1;
      unsigned short* pb = (cur == 0) ? sB0 : sB1;
      STG256(pa, pb, kt + 2);       // overlaps compute of kt+1
    }
  }
#undef STG256

#pragma unroll
  for (int i = 0; i < 8; i++) {
#pragma unroll
    for (int j = 0; j < 4; j++) {
      const int col = n0 + wc * 64 + j * 16 + lrow;
      const float bv = bias[col];
#pragma unroll
      for (int q = 0; q < 4; q++) {
        const long row = m0 + wr * 128 + i * 16 + kg * 4 + q;
        float v = acc[i][j][q] + bv;
        if constexpr (RMODE == 1) v = fmaxf(v, 0.0f);
        if constexpr (PRODF) {
          int gr = (col < 512) ? subp[row] : objp[row];
          v *= b2f(fusedp[(long)gr * 1024 + col]);
        }
        if constexpr (ACCUM) v += Cin[row * (long)N + col];
        if constexpr (RMODE == 2) v = fmaxf(v, 0.0f);
        C[row * (long)ldc + col] = f2bs(v);
      }
    }
  }
}

// =====================  128x128 engine (object stream, f32-A, small shapes)  ============
template<int RMODE, bool ACCUM, bool OUTB, bool PRODF, bool AF32>
__global__ __launch_bounds__(256, 2)
void gemm_bt(const void* __restrict__ Ap, const unsigned short* __restrict__ B,
             const float* __restrict__ bias, const float* __restrict__ Cin,
             void* __restrict__ Cp, int M, int N, int K, int lda, int ldc,
             const unsigned short* __restrict__ fusedp,
             const int* __restrict__ subp, const int* __restrict__ objp)
{
  __shared__ __align__(16) unsigned short As[128 * 32];
  __shared__ __align__(16) unsigned short Bs[128 * 32];
  const int t = threadIdx.x;
  const int lane = t & 63;
  const int w = t >> 6;
  const int nwg = gridDim.x;
  const int q8 = nwg >> 3, r8 = nwg & 7;
  const int xcd = blockIdx.x & 7, bidx = blockIdx.x >> 3;
  const int wgid = (xcd < r8 ? xcd * (q8 + 1) : r8 * (q8 + 1) + (xcd - r8) * q8) + bidx;
  const int ntile = N >> 7;
  const int bm = wgid / ntile;
  const int bn = wgid - bm * ntile;
  const int m0 = bm << 7, n0 = bn << 7;
  const int wm = (w & 1) << 6, wn = (w >> 1) << 6;
  const int lrow = lane & 15, kg = lane >> 4;

  const int c0 = w << 1;
  const int srow = (c0 << 4) + (lane >> 2);
  const int selem = (((lane & 3) ^ ((lane >> 3) & 3)) << 3);
  const unsigned short* bg0 = B + (long)(n0 + srow) * K + selem;
  const unsigned short* bg1 = bg0 + (long)16 * K;
  unsigned short* bl0 = Bs + (c0 << 9);
  unsigned short* bl1 = bl0 + 512;

  const unsigned short* ag0 = nullptr; const unsigned short* ag1 = nullptr;
  unsigned short* al0 = nullptr; unsigned short* al1 = nullptr;
  const float* afp = nullptr; unsigned short* afl = nullptr;
  if constexpr (AF32) {
    afp = (const float*)Ap + (long)(m0 + (t >> 1)) * lda + ((t & 1) << 4);
    afl = As + (t >> 1) * 32 + ((t & 1) << 4);
  } else {
    ag0 = (const unsigned short*)Ap + (long)(m0 + srow) * lda + selem;
    ag1 = ag0 + (long)16 * lda;
    al0 = As + (c0 << 9);
    al1 = al0 + 512;
  }

  const int fslot = ((lrow >> 1) & 3);

  f32x4 acc[4][4] = {};

  for (int k0 = 0; k0 < K; k0 += 32) {
    gload16(bg0 + k0, bl0);
    gload16(bg1 + k0, bl1);
    if constexpr (AF32) {
      const float* ap = afp + k0;
      f32x4 f0 = *(const f32x4*)(ap);
      f32x4 f1 = *(const f32x4*)(ap + 4);
      f32x4 f2 = *(const f32x4*)(ap + 8);
      f32x4 f3 = *(const f32x4*)(ap + 12);
      ushort4v u0, u1, u2, u3;
      u0[0]=f2bs(f0[0]); u0[1]=f2bs(f0[1]); u0[2]=f2bs(f0[2]); u0[3]=f2bs(f0[3]);
      u1[0]=f2bs(f1[0]); u1[1]=f2bs(f1[1]); u1[2]=f2bs(f1[2]); u1[3]=f2bs(f1[3]);
      u2[0]=f2bs(f2[0]); u2[1]=f2bs(f2[1]); u2[2]=f2bs(f2[2]); u2[3]=f2bs(f2[3]);
      u3[0]=f2bs(f3[0]); u3[1]=f2bs(f3[1]); u3[2]=f2bs(f3[2]); u3[3]=f2bs(f3[3]);
      *(ushort4v*)afl = u0;
      *(ushort4v*)(afl + 4) = u1;
      *(ushort4v*)(afl + 8) = u2;
      *(ushort4v*)(afl + 12) = u3;
    } else {
      gload16(ag0 + k0, al0);
      gload16(ag1 + k0, al1);
    }
    __syncthreads();
    short8 afr[4], bfr[4];
#pragma unroll
    for (int i = 0; i < 4; i++) {
      if constexpr (AF32)
        afr[i] = *(const short8*)(As + (wm + i * 16 + lrow) * 32 + (kg << 3));
      else
        afr[i] = *(const short8*)(As + (wm + i * 16 + lrow) * 32 + ((kg ^ fslot) << 3));
    }
#pragma unroll
    for (int j = 0; j < 4; j++)
      bfr[j] = *(const short8*)(Bs + (wn + j * 16 + lrow) * 32 + ((kg ^ fslot) << 3));
#pragma unroll
    for (int i = 0; i < 4; i++)
#pragma unroll
      for (int j = 0; j < 4; j++)
        acc[i][j] = __builtin_amdgcn_mfma_f32_16x16x32_bf16(afr[i], bfr[j], acc[i][j], 0, 0, 0);
    __syncthreads();
  }

  float* Cf = (float*)Cp;
  unsigned short* Cb = (unsigned short*)Cp;
#pragma unroll
  for (int i = 0; i < 4; i++) {
#pragma unroll
    for (int j = 0; j < 4; j++) {
      const int col = n0 + wn + j * 16 + lrow;
      const float bv = bias[col];
#pragma unroll
      for (int q = 0; q < 4; q++) {
        const long row = m0 + wm + i * 16 + kg * 4 + q;
        float v = acc[i][j][q] + bv;
        if constexpr (RMODE == 1) v = fmaxf(v, 0.0f);
        if constexpr (PRODF) {
          int gr = (col < 512) ? subp[row] : objp[row];
          v *= b2f(fusedp[(long)gr * 1024 + col]);
        }
        if constexpr (ACCUM) v += Cin[row * (long)N + col];
        if constexpr (RMODE == 2) v = fmaxf(v, 0.0f);
        if constexpr (OUTB) Cb[row * (long)ldc + col] = f2bs(v);
        else Cf[row * (long)ldc + col] = v;
      }
    }
  }
}

// ===================== small kernels =====================

__global__ void cvt_pad4(const float* __restrict__ src, unsigned short* __restrict__ dst,
                         int rows, int K0, int Kp)
{
  const int kp4 = Kp >> 2;
  const long total = (long)rows * kp4;
  for (long i = blockIdx.x * (long)blockDim.x + threadIdx.x; i < total; i += (long)gridDim.x * blockDim.x) {
    int r = (int)(i / kp4), k = (int)(i - (long)r * kp4) << 2;
    ushort4v o;
    if (k < K0) {
      f32x4 v = *(const f32x4*)(src + (long)r * K0 + k);
      o[0] = f2bs(v[0]); o[1] = f2bs(v[1]); o[2] = f2bs(v[2]); o[3] = f2bs(v[3]);
    } else {
      o[0] = 0; o[1] = 0; o[2] = 0; o[3] = 0;
    }
    *(ushort4v*)(dst + (long)r * Kp + k) = o;
  }
}

__global__ void cvt4(const float* __restrict__ src, unsigned short* __restrict__ dst, long n4)
{
  for (long i = blockIdx.x * (long)blockDim.x + threadIdx.x; i < n4; i += (long)gridDim.x * blockDim.x) {
    f32x4 v = ((const f32x4*)src)[i];
    ushort4v o;
    o[0] = f2bs(v[0]); o[1] = f2bs(v[1]); o[2] = f2bs(v[2]); o[3] = f2bs(v[3]);
    ((ushort4v*)dst)[i] = o;
  }
}

__global__ void build_wcat(const float* __restrict__ wih, const float* __restrict__ whh,
                           unsigned short* __restrict__ dst)
{
  const long total = 1024L * 256;
  for (long i = blockIdx.x * (long)blockDim.x + threadIdx.x; i < total; i += (long)gridDim.x * blockDim.x) {
    int j = (int)(i >> 8), k = ((int)(i & 255)) << 2;
    const float* s = (k < 512) ? (wih + (long)j * 512 + k) : (whh + (long)j * 512 + (k - 512));
    f32x4 v = *(const f32x4*)s;
    ushort4v o;
    o[0] = f2bs(v[0]); o[1] = f2bs(v[1]); o[2] = f2bs(v[2]); o[3] = f2bs(v[3]);
    *(ushort4v*)(dst + (long)j * 1024 + k) = o;
  }
}

__global__ void bias_rz_k(const float* __restrict__ bih, const float* __restrict__ bhh,
                          float* __restrict__ out)
{
  int j = blockIdx.x * blockDim.x + threadIdx.x;
  if (j < 1024) out[j] = bih[j] + bhh[j];
}

__global__ void transpose_cvt(const float* __restrict__ src, unsigned short* __restrict__ dst,
                              int R, int C)
{
  __shared__ float tile[32][33];
  int c0 = blockIdx.x * 32, r0 = blockIdx.y * 32;
  for (int i = threadIdx.y; i < 32; i += 8)
    tile[i][threadIdx.x] = src[(long)(r0 + i) * C + c0 + threadIdx.x];
  __syncthreads();
  for (int i = threadIdx.y; i < 32; i += 8)
    dst[(long)(c0 + i) * R + r0 + threadIdx.x] = f2bs(tile[threadIdx.x][i]);
}

__global__ void comp_bias(const float* __restrict__ edgeU_W, const float* __restrict__ up_b,
                          const float* __restrict__ edgeU_b, float* __restrict__ b_comp)
{
  int j = (int)((blockIdx.x * (long)blockDim.x + threadIdx.x) >> 6);
  int l = threadIdx.x & 63;
  if (j >= 512) return;
  float s = 0.0f;
  for (int k = l; k < 2048; k += 64) s += edgeU_W[(long)j * 2048 + k] * up_b[k];
#pragma unroll
  for (int off = 32; off > 0; off >>= 1) s += __shfl_xor(s, off);
  if (l == 0) b_comp[j] = s + edgeU_b[j];
}

__global__ void obox_k(const float* __restrict__ boxes, float* __restrict__ obox)
{
  int i = blockIdx.x * blockDim.x + threadIdx.x;
  if (i >= NOBJ) return;
  float x1 = boxes[i*4], y1 = boxes[i*4+1], x2 = boxes[i*4+2], y2 = boxes[i*4+3];
  float wdt = x2 - x1 + 1.0f, hgt = y2 - y1 + 1.0f;
  float cx = x1 + 0.5f * wdt, cy = y1 + 0.5f * hgt;
  const float inv = 1.0f / 1024.0f;
  float* o = obox + i * 8;
  o[0]=x1*inv; o[1]=y1*inv; o[2]=x2*inv; o[3]=y2*inv;
  o[4]=cx*inv; o[5]=cy*inv; o[6]=wdt*inv; o[7]=hgt*inv;
}

__global__ void posembed_k(const float* __restrict__ boxes,
                           const float* __restrict__ w1, const float* __restrict__ b1,
                           const float* __restrict__ g, const float* __restrict__ bb,
                           const float* __restrict__ mm, const float* __restrict__ vv,
                           const float* __restrict__ w2, const float* __restrict__ b2,
                           float* __restrict__ out)
{
  int o = blockIdx.x, t = threadIdx.x;
  __shared__ float e[9];
  __shared__ float p[32];
  if (t == 0) {
    float x1 = boxes[o*4], y1 = boxes[o*4+1], x2 = boxes[o*4+2], y2 = boxes[o*4+3];
    float wdt = x2 - x1 + 1.0f, hgt = y2 - y1 + 1.0f;
    float cx = x1 + 0.5f * wdt, cy = y1 + 0.5f * hgt;
    e[0]=wdt/1024.0f; e[1]=hgt/768.0f; e[2]=cx/1024.0f; e[3]=cy/768.0f;
    e[4]=x1/1024.0f;  e[5]=y1/768.0f;  e[6]=x2/1024.0f; e[7]=y2/768.0f;
    e[8]=wdt*hgt/(1024.0f*768.0f);
  }
  __syncthreads();
  if (t < 32) {
    float s = b1[t];
#pragma unroll
    for (int j = 0; j < 9; j++) s += w1[t*9+j] * e[j];
    s = (s - mm[t]) * g[t] / sqrtf(vv[t] + 1e-5f) + bb[t];
    p[t] = s;
  }
  __syncthreads();
  float s = b2[t];
#pragma unroll
  for (int j = 0; j < 32; j++) s += w2[t*32+j] * p[j];
  out[o*128 + t] = fmaxf(s, 0.0f);
}

__device__ __forceinline__ void pack8_store(unsigned short* dst, f32x4 a, f32x4 b)
{
  ushort4v o0, o1;
  o0[0]=f2bs(a[0]); o0[1]=f2bs(a[1]); o0[2]=f2bs(a[2]); o0[3]=f2bs(a[3]);
  o1[0]=f2bs(b[0]); o1[1]=f2bs(b[1]); o1[2]=f2bs(b[2]); o1[3]=f2bs(b[3]);
  *(ushort4v*)dst = o0;
  *(ushort4v*)(dst + 4) = o1;
}

__global__ void build_x1(const float* __restrict__ inst, const float* __restrict__ embd,
                         const int* __restrict__ labels, const float* __restrict__ pose,
                         unsigned short* __restrict__ X1b)
{
  const long total = (long)NOBJ * 560;
  for (long i = blockIdx.x * (long)blockDim.x + threadIdx.x; i < total; i += (long)gridDim.x * blockDim.x) {
    int r = (int)(i / 560), c = ((int)(i - (long)r * 560)) << 3;
    unsigned short* dst = X1b + (long)r * 4480 + c;
    const float* src;
    if (c < 4096)      src = inst + (long)r * 4096 + c;
    else if (c < 4296) src = embd + (long)labels[r] * 200 + (c - 4096);
    else if (c < 4424) src = pose + r * 128 + (c - 4296);
    else { ushort4v z = {0,0,0,0}; *(ushort4v*)dst = z; *(ushort4v*)(dst+4) = z; continue; }
    pack8_store(dst, *(const f32x4*)src, *((const f32x4*)src + 1));
  }
}

__global__ void build_aug(const float* __restrict__ embl, const int* __restrict__ labels,
                          const float* __restrict__ inst, unsigned short* __restrict__ augb)
{
  const long total = (long)NOBJ * 608;
  for (long i = blockIdx.x * (long)blockDim.x + threadIdx.x; i < total; i += (long)gridDim.x * blockDim.x) {
    int r = (int)(i / 608), c = ((int)(i - (long)r * 608)) << 3;
    if (c >= 4296 && c < 4808) continue;
    unsigned short* dst = augb + (long)r * 4864 + c;
    const float* src;
    if (c < 200)       src = embl + (long)labels[r] * 200 + c;
    else if (c < 4296) src = inst + (long)r * 4096 + (c - 200);
    else { ushort4v z = {0,0,0,0}; *(ushort4v*)dst = z; *(ushort4v*)(dst+4) = z; continue; }
    pack8_store(dst, *(const f32x4*)src, *((const f32x4*)src + 1));
  }
}

__global__ void build_geo(const float* __restrict__ obox, const int* __restrict__ sub,
                          const int* __restrict__ obj, unsigned short* __restrict__ geob)
{
  int r = blockIdx.x * blockDim.x + threadIdx.x;
  if (r >= NREL) return;
  const float* b1 = obox + sub[r] * 8;
  const float* b2 = obox + obj[r] * 8;
  float o[32];
#pragma unroll
  for (int j = 0; j < 8; j++) { o[j] = b1[j]; o[8+j] = b2[j]; }
  float ux1 = fminf(b1[0], b2[0]), uy1 = fminf(b1[1], b2[1]);
  float ux2 = fmaxf(b1[2], b2[2]), uy2 = fmaxf(b1[3], b2[3]);
  float uw = ux2 - ux1 + 1.0f, uh = uy2 - uy1 + 1.0f;
  o[16]=ux1; o[17]=uy1; o[18]=ux2; o[19]=uy2;
  o[20]=ux1+0.5f*uw; o[21]=uy1+0.5f*uh; o[22]=uw; o[23]=uh;
  float ix1 = fmaxf(b1[0], b2[0]), iy1 = fmaxf(b1[1], b2[1]);
  float ix2 = fminf(b1[2], b2[2]), iy2 = fminf(b1[3], b2[3]);
  bool bad = (ix2 < ix1) || (iy2 < iy1);
  float iw = ix2 - ix1 + 1.0f, ih = iy2 - iy1 + 1.0f;
  if (bad) {
#pragma unroll
    for (int j = 24; j < 32; j++) o[j] = 0.0f;
  } else {
    o[24]=ix1; o[25]=iy1; o[26]=ix2; o[27]=iy2;
    o[28]=ix1+0.5f*iw; o[29]=iy1+0.5f*ih; o[30]=iw; o[31]=ih;
  }
  unsigned short* gp = geob + (long)r * 64;
#pragma unroll
  for (int j = 0; j < 32; j++) gp[j] = f2bs(o[j]);
#pragma unroll
  for (int j = 32; j < 64; j++) gp[j] = 0;
}

__global__ void gru_init(const unsigned short* __restrict__ gi, const float* __restrict__ bhh,
                         float* __restrict__ h, unsigned short* __restrict__ hb, int hstride, int n)
{
  const long total = (long)n * 64;
  for (long i = blockIdx.x * (long)blockDim.x + threadIdx.x; i < total; i += (long)gridDim.x * blockDim.x) {
    int r = (int)(i >> 6), c = ((int)(i & 63)) << 3;
    const unsigned short* gr = gi + (long)r * 1536;
    short8 vr = *(const short8*)(gr + c);
    short8 vz = *(const short8*)(gr + 512 + c);
    short8 vn = *(const short8*)(gr + 1024 + c);
    float hv[8];
#pragma unroll
    for (int k = 0; k < 8; k++) {
      float rr = sigf(b2f((unsigned short)vr[k]) + bhh[c + k]);
      float z  = sigf(b2f((unsigned short)vz[k]) + bhh[512 + c + k]);
      float nn = tanhf(b2f((unsigned short)vn[k]) + rr * bhh[1024 + c + k]);
      hv[k] = (1.0f - z) * nn;
    }
    float* hp = h + (long)r * 512 + c;
    *(f32x4*)hp = *(f32x4*)hv;
    *(f32x4*)(hp + 4) = *(f32x4*)(hv + 4);
    pack8_store(hb + (long)r * hstride + c, *(f32x4*)hv, *(f32x4*)(hv + 4));
  }
}

__global__ void gru_step_v(const unsigned short* __restrict__ gi, const unsigned short* __restrict__ gh,
                           const float* __restrict__ hin, float* __restrict__ hout,
                           unsigned short* __restrict__ hb, int n)
{
  const long total = (long)n * 64;
  for (long i = blockIdx.x * (long)blockDim.x + threadIdx.x; i < total; i += (long)gridDim.x * blockDim.x) {
    int r = (int)(i >> 6), c = ((int)(i & 63)) << 3;
    const unsigned short* gr = gi + (long)r * 1536;
    const unsigned short* hr = gh + (long)r * 1536;
    short8 ir = *(const short8*)(gr + c);
    short8 iz = *(const short8*)(gr + 512 + c);
    short8 in_ = *(const short8*)(gr + 1024 + c);
    short8 hrr = *(const short8*)(hr + c);
    short8 hz = *(const short8*)(hr + 512 + c);
    short8 hn = *(const short8*)(hr + 1024 + c);
    const float* hi = hin + (long)r * 512 + c;
    f32x4 h0 = *(const f32x4*)hi;
    f32x4 h1 = *(const f32x4*)(hi + 4);
    float hv[8];
#pragma unroll
    for (int k = 0; k < 8; k++) {
      float rr = sigf(b2f((unsigned short)ir[k]) + b2f((unsigned short)hrr[k]));
      float z  = sigf(b2f((unsigned short)iz[k]) + b2f((unsigned short)hz[k]));
      float nn = tanhf(b2f((unsigned short)in_[k]) + rr * b2f((unsigned short)hn[k]));
      float old = (k < 4) ? h0[k] : h1[k - 4];
      hv[k] = (1.0f - z) * nn + z * old;
    }
    float* hp = hout + (long)r * 512 + c;
    *(f32x4*)hp = *(f32x4*)hv;
    *(f32x4*)(hp + 4) = *(f32x4*)(hv + 4);
    pack8_store(hb + (long)r * 512 + c, *(f32x4*)hv, *(f32x4*)(hv + 4));
  }
}

__global__ void gru_step_e(const unsigned short* __restrict__ gates,
                           const float* __restrict__ hin, float* __restrict__ hout,
                           unsigned short* __restrict__ xe, int n)
{
  const long total = (long)n * 64;
  for (long i = blockIdx.x * (long)blockDim.x + threadIdx.x; i < total; i += (long)gridDim.x * blockDim.x) {
    int r = (int)(i >> 6), c = ((int)(i & 63)) << 3;
    const unsigned short* g = gates + (long)r * 2048;
    short8 vr = *(const short8*)(g + c);
    short8 vz = *(const short8*)(g + 512 + c);
    short8 vi = *(const short8*)(g + 1024 + c);
    short8 vh = *(const short8*)(g + 1536 + c);
    const float* hi = hin + (long)r * 512 + c;
    f32x4 h0 = *(const f32x4*)hi;
    f32x4 h1 = *(const f32x4*)(hi + 4);
    float hv[8];
#pragma unroll
    for (int k = 0; k < 8; k++) {
      float rr = sigf(b2f((unsigned short)vr[k]));
      float z  = sigf(b2f((unsigned short)vz[k]));
      float nn = tanhf(b2f((unsigned short)vi[k]) + rr * b2f((unsigned short)vh[k]));
      float old = (k < 4) ? h0[k] : h1[k - 4];
      hv[k] = (1.0f - z) * nn + z * old;
    }
    float* hp = hout + (long)r * 512 + c;
    *(f32x4*)hp = *(f32x4*)hv;
    *(f32x4*)(hp + 4) = *(f32x4*)(hv + 4);
    pack8_store(xe + (long)r * 1024 + 512 + c, *(f32x4*)hv, *(f32x4*)(hv + 4));
  }
}

__global__ __launch_bounds__(256)
void edge_weights(const unsigned short* __restrict__ vertb, unsigned short* __restrict__ xe,
                  const int* __restrict__ sub, const int* __restrict__ obj,
                  const float* __restrict__ svwW, const float* __restrict__ svwb,
                  const float* __restrict__ ovwW, const float* __restrict__ ovwb,
                  float* __restrict__ ws_arr, float* __restrict__ wo_arr)
{
  long gid = blockIdx.x * (long)blockDim.x + threadIdx.x;
  int r = (int)(gid >> 6);
  int l = (int)(gid & 63);
  if (r >= NREL) return;
  int s = sub[r], o = obj[r];
  const unsigned short* sv = vertb + (long)s * 512;
  const unsigned short* ov = vertb + (long)o * 512;
  const unsigned short* e  = xe + (long)r * 1024 + 512;
  float svv[8], ovv[8], ev[8];
  float as = 0.0f, ao = 0.0f;
#pragma unroll
  for (int k = 0; k < 8; k++) {
    int c = l + k * 64;
    svv[k] = b2f(sv[c]); ovv[k] = b2f(ov[c]); ev[k] = b2f(e[c]);
    as += svwW[c] * svv[k] + svwW[512 + c] * ev[k];
    ao += ovwW[c] * ovv[k] + ovwW[512 + c] * ev[k];
  }
#pragma unroll
  for (int off = 32; off > 0; off >>= 1) {
    as += __shfl_xor(as, off);
    ao += __shfl_xor(ao, off);
  }
  float ws = sigf(as + svwb[0]);
  float wo = sigf(ao + ovwb[0]);
  unsigned short* xr = xe + (long)r * 1024;
#pragma unroll
  for (int k = 0; k < 8; k++) {
    int c = l + k * 64;
    xr[c] = f2bs(ws * svv[k] + wo * ovv[k]);
  }
  if (l == 0) { ws_arr[r] = ws; wo_arr[r] = wo; }
}

// ===================== CSR =====================

__global__ void csr_count(const int* __restrict__ sub, const int* __restrict__ obj,
                          int* __restrict__ cnt)
{
  int r = blockIdx.x * blockDim.x + threadIdx.x;
  if (r >= NREL) return;
  atomicAdd(&cnt[sub[r]], 1);
  atomicAdd(&cnt[obj[r]], 1);
}

__global__ __launch_bounds__(1024)
void csr_scan(const int* __restrict__ cnt, int* __restrict__ off)
{
  __shared__ int a[1024], b[1024];
  int t = threadIdx.x;
  int c0 = cnt[2*t], c1 = cnt[2*t+1];
  a[t] = c0 + c1;
  __syncthreads();
  int* src = a; int* dst = b;
  for (int s = 1; s < 1024; s <<= 1) {
    int v = src[t];
    if (t >= s) v += src[t - s];
    dst[t] = v;
    __syncthreads();
    int* tmp = src; src = dst; dst = tmp;
  }
  int incl = src[t];
  int excl = incl - (c0 + c1);
  off[2*t] = excl;
  off[2*t+1] = excl + c0;
  if (t == 1023) off[2048] = incl;
}

__global__ void csr_fill(const int* __restrict__ sub, const int* __restrict__ obj,
                         const int* __restrict__ off, int* __restrict__ rcur,
                         int* __restrict__ lists)
{
  int r = blockIdx.x * blockDim.x + threadIdx.x;
  if (r >= NREL) return;
  int s = sub[r];
  int p = atomicAdd(&rcur[s], 1);
  lists[off[s] + p] = (r << 1);
  int o = obj[r];
  int q = atomicAdd(&rcur[o], 1);
  lists[off[o] + q] = (r << 1) | 1;
}

__global__ __launch_bounds__(128)
void ctx_gather(const unsigned short* __restrict__ xe, const float* __restrict__ ws,
                const float* __restrict__ wo, const int* __restrict__ off,
                const int* __restrict__ lists, unsigned short* __restrict__ ctxb)
{
  __shared__ float part[512];
  int o = blockIdx.x;
  int l = threadIdx.x & 63;
  int w = threadIdx.x >> 6;
  int i0 = off[o], i1 = off[o + 1];
  float acc[8] = {0.f,0.f,0.f,0.f,0.f,0.f,0.f,0.f};
  for (int i = i0 + w; i < i1; i += 2) {
    int e = lists[i];
    int r = e >> 1;
    float sc = (e & 1) ? wo[r] : ws[r];
    short8 row = *(const short8*)(xe + (long)r * 1024 + 512 + l * 8);
#pragma unroll
    for (int k = 0; k < 8; k++) acc[k] += sc * b2f((unsigned short)row[k]);
  }
  if (w == 1) {
    *(f32x4*)&part[l*8]     = *(f32x4*)&acc[0];
    *(f32x4*)&part[l*8 + 4] = *(f32x4*)&acc[4];
  }
  __syncthreads();
  if (w == 0) {
#pragma unroll
    for (int k = 0; k < 8; k++) acc[k] += part[l*8 + k];
    pack8_store(ctxb + (long)o * 512 + l * 8, *(f32x4*)&acc[0], *(f32x4*)&acc[4]);
  }
}

// ===================== driver =====================

static inline int nblk(long total) {
  long b = (total + 255) / 256;
  return (int)(b > 16384 ? 16384 : b);
}

#define GEMM(RM, AC, OB, PF, grid, Aa, Bb, bb, Ci, Cc, Mm, Nn, Kk, ldA, ldC, fp, sp, op) \
  gemm_bt<RM, AC, OB, PF, false><<<grid, 256, 0, stream>>>(Aa, Bb, bb, Ci, Cc, Mm, Nn, Kk, ldA, ldC, fp, sp, op)
#define GEMMF(RM, AC, OB, grid, Aa, Bb, bb, Ci, Cc, Mm, Nn, Kk, ldA, ldC) \
  gemm_bt<RM, AC, OB, false, true><<<grid, 256, 0, stream>>>(Aa, Bb, bb, Ci, Cc, Mm, Nn, Kk, ldA, ldC, nullptr, nullptr, nullptr)
#define G256(RM, AC, PF, Aa, Bb, bb, Ci, Cc, Mm, Nn, Kk, ldA, ldC, fp, sp, op) \
  gemm256<RM, AC, PF><<<dim3(((Mm) >> 8) * ((Nn) >> 8)), 512, 0, stream>>>(Aa, Bb, bb, Ci, Cc, Mm, Nn, Kk, ldA, ldC, fp, sp, op)

extern "C" void kernel_launch(void* const* d_in, const int* in_sizes, int n_in,
                              void* d_out, int out_size, void* d_ws, size_t ws_size,
                              hipStream_t stream)
{
  const float* inst     = (const float*)d_in[0];
  const float* unionf   = (const float*)d_in[1];
  const float* boxes    = (const float*)d_in[2];
  const float* embd_W   = (const float*)d_in[3];
  const float* embl_W   = (const float*)d_in[4];
  const float* up_W     = (const float*)d_in[5];
  const float* up_b     = (const float*)d_in[6];
  const float* pairup_W = (const float*)d_in[7];
  const float* pairup_b = (const float*)d_in[8];
  const float* pos1_W   = (const float*)d_in[9];
  const float* pos1_b   = (const float*)d_in[10];
  const float* bn_g     = (const float*)d_in[11];
  const float* bn_b     = (const float*)d_in[12];
  const float* bn_m     = (const float*)d_in[13];
  const float* bn_v     = (const float*)d_in[14];
  const float* pos2_W   = (const float*)d_in[15];
  const float* pos2_b   = (const float*)d_in[16];
  const float* spt1_W   = (const float*)d_in[17];
  const float* spt1_b   = (const float*)d_in[18];
  const float* spt2_W   = (const float*)d_in[19];
  const float* spt2_b   = (const float*)d_in[20];
  const float* pairfin_W= (const float*)d_in[21];
  const float* pairfin_b= (const float*)d_in[22];
  const float* objhid_W = (const float*)d_in[23];
  const float* objhid_b = (const float*)d_in[24];
  const float* objfin_W = (const float*)d_in[25];
  const float* objfin_b = (const float*)d_in[26];
  const float* objU_W   = (const float*)d_in[27];
  const float* objU_b   = (const float*)d_in[28];
  const float* edgeU_W  = (const float*)d_in[29];
  const float* edgeU_b  = (const float*)d_in[30];
  const float* egru_Wih = (const float*)d_in[31];
  const float* egru_Whh = (const float*)d_in[32];
  const float* egru_bih = (const float*)d_in[33];
  const float* egru_bhh = (const float*)d_in[34];
  const float* ngru_Wih = (const float*)d_in[35];
  const float* ngru_Whh = (const float*)d_in[36];
  const float* ngru_bih = (const float*)d_in[37];
  const float* ngru_bhh = (const float*)d_in[38];
  const float* svw_W    = (const float*)d_in[39];
  const float* svw_b    = (const float*)d_in[40];
  const float* ovw_W    = (const float*)d_in[41];
  const float* ovw_b    = (const float*)d_in[42];
  const int*   labels   = (const int*)d_in[43];
  const int*   sub      = (const int*)d_in[44];
  const int*   obj      = (const int*)d_in[45];
  (void)in_sizes; (void)n_in; (void)out_size; (void)ws_size;

  char* base = (char*)d_ws;
  size_t off = 0;
  auto alloc = [&](size_t bytes) -> void* {
    void* p = base + off;
    off += (bytes + 255) & ~(size_t)255;
    return p;
  };

  // ---- weights (bf16) ----
  unsigned short* objhid_Wb  = (unsigned short*)alloc(512L  * 4480 * 2);
  unsigned short* pairup_Wb  = (unsigned short*)alloc(1024L * 4864 * 2);
  unsigned short* objfin_Wb  = (unsigned short*)alloc(2048L * 4864 * 2);
  unsigned short* up_Wtb     = (unsigned short*)alloc(4096L * 2048 * 2);
  unsigned short* pairfin_Wb = (unsigned short*)alloc(2048L * 1024 * 2);
  unsigned short* spt1_Wb    = (unsigned short*)alloc(512L  * 64   * 2);
  unsigned short* spt2_Wb    = (unsigned short*)alloc(1024L * 512  * 2);
  unsigned short* objU_Wb    = (unsigned short*)alloc(512L  * 2048 * 2);
  unsigned short* edgeU_Wb   = (unsigned short*)alloc(512L  * 2048 * 2);
  unsigned short* egru_Wihb  = (unsigned short*)alloc(1536L * 512  * 2);
  unsigned short* egru_Whhb  = (unsigned short*)alloc(1536L * 512  * 2);
  unsigned short* ngru_Wihb  = (unsigned short*)alloc(1536L * 512  * 2);
  unsigned short* ngru_Whhb  = (unsigned short*)alloc(1536L * 512  * 2);
  unsigned short* Wcat_rzb   = (unsigned short*)alloc(1024L * 1024 * 2);
  unsigned short* W_compb    = (unsigned short*)alloc(512L  * 4096 * 2);
  float*          b_comp     = (float*)alloc(512L * 4);
  float*          zbias      = (float*)alloc(4096L * 4);
  float*          bias_rz    = (float*)alloc(1024L * 4);

  // ---- activations ----
  float*          obox      = (float*)alloc(NOBJ * 8L * 4);
  float*          pose      = (float*)alloc(NOBJ * 128L * 4);
  unsigned short* obj_featsb= (unsigned short*)alloc((long)NOBJ * 2048 * 2);
  unsigned short* obj_repb  = (unsigned short*)alloc((long)NOBJ * 512 * 2);
  unsigned short* giv       = (unsigned short*)alloc((long)NOBJ * 1536 * 2);
  unsigned short* ghv       = (unsigned short*)alloc((long)NOBJ * 1536 * 2);
  float*          vert      = (float*)alloc((long)NOBJ * 512 * 4);
  unsigned short* vertb     = (unsigned short*)alloc((long)NOBJ * 512 * 2);
  unsigned short* ctxb      = (unsigned short*)alloc((long)NOBJ * 512 * 2);
  unsigned short* geob      = (unsigned short*)alloc((long)NREL * 64 * 2);
  float*          edge      = (float*)alloc((long)NREL * 512 * 4);
  unsigned short* xe        = (unsigned short*)alloc((long)NREL * 1024 * 2);  // [xb | edge_bf16]
  float*          ws_arr    = (float*)alloc((long)NREL * 4);
  float*          wo_arr    = (float*)alloc((long)NREL * 4);

  // CSR
  int* cnt   = (int*)alloc(NOBJ * 4);
  int* coff  = (int*)alloc((NOBJ + 1) * 4);
  int* rcur  = (int*)alloc(NOBJ * 4);
  int* lists = (int*)alloc(2L * NREL * 4);

  // REGION_A: X1b -> T1 (f32 64MB)
  char* regA = (char*)alloc((long)NREL * 512 * 4);
  unsigned short* X1b = (unsigned short*)regA;
  float*          T1  = (float*)regA;
  // REGION_B: augb -> rel_repb
  char* regB = (char*)alloc((long)NOBJ * 4864 * 2 > (long)NREL * 512 * 2
                            ? (long)NOBJ * 4864 * 2 : (long)NREL * 512 * 2);
  unsigned short* augb     = (unsigned short*)regB;
  unsigned short* rel_repb = (unsigned short*)regB;
  unsigned short* fusedb = (unsigned short*)alloc((long)NOBJ * 1024 * 2);
  unsigned short* spt1b  = (unsigned short*)alloc((long)NREL * 512 * 2);
  // BIG1: [G1 128MB | prodb 64MB] -> gi_e(init) -> gates (128MB)
  char* big1 = (char*)alloc((long)NREL * 1536 * 4);
  unsigned short* G1    = (unsigned short*)big1;
  unsigned short* prodb = (unsigned short*)(big1 + (long)NREL * 1024 * 4);
  unsigned short* gi_e  = (unsigned short*)big1;
  unsigned short* gates = (unsigned short*)big1;

  float* d_out_vert = (float*)d_out;
  float* d_out_edge = (float*)d_out + (long)NOBJ * 512;

  // ---- weight conversions ----
  cvt_pad4<<<nblk(512L*4480/4),  256, 0, stream>>>(objhid_W,  objhid_Wb,  512,  4424, 4480);
  cvt_pad4<<<nblk(1024L*4864/4), 256, 0, stream>>>(pairup_W,  pairup_Wb,  1024, 4808, 4864);
  cvt_pad4<<<nblk(2048L*4864/4), 256, 0, stream>>>(objfin_W,  objfin_Wb,  2048, 4808, 4864);
  cvt_pad4<<<nblk(512L*64/4),    256, 0, stream>>>(spt1_W,    spt1_Wb,    512,  32,   64);
  cvt4<<<nblk(2048L*1024/4), 256, 0, stream>>>(pairfin_W, pairfin_Wb, 2048L*1024/4);
  cvt4<<<nblk(1024L*512/4),  256, 0, stream>>>(spt2_W,    spt2_Wb,    1024L*512/4);
  cvt4<<<nblk(512L*2048/4),  256, 0, stream>>>(objU_W,    objU_Wb,    512L*2048/4);
  cvt4<<<nblk(512L*2048/4),  256, 0, stream>>>(edgeU_W,   edgeU_Wb,   512L*2048/4);
  cvt4<<<nblk(1536L*512/4),  256, 0, stream>>>(egru_Wih,  egru_Wihb,  1536L*512/4);
  cvt4<<<nblk(1536L*512/4),  256, 0, stream>>>(egru_Whh,  egru_Whhb,  1536L*512/4);
  cvt4<<<nblk(1536L*512/4),  256, 0, stream>>>(ngru_Wih,  ngru_Wihb,  1536L*512/4);
  cvt4<<<nblk(1536L*512/4),  256, 0, stream>>>(ngru_Whh,  ngru_Whhb,  1536L*512/4);
  build_wcat<<<nblk(1024L*256), 256, 0, stream>>>(egru_Wih, egru_Whh, Wcat_rzb);
  bias_rz_k<<<4, 256, 0, stream>>>(egru_bih, egru_bhh, bias_rz);
  transpose_cvt<<<dim3(4096/32, 2048/32), dim3(32, 8), 0, stream>>>(up_W, up_Wtb, 2048, 4096);
  hipMemsetAsync(zbias, 0, 4096L * 4, stream);
  comp_bias<<<128, 256, 0, stream>>>(edgeU_W, up_b, edgeU_b, b_comp);
  GEMM(0,false,true,false, dim3((512>>7)*(4096>>7)), edgeU_Wb, up_Wtb, zbias, nullptr, W_compb, 512, 4096, 2048, 2048, 4096, nullptr, nullptr, nullptr);

  // ---- CSR build ----
  hipMemsetAsync(cnt, 0, NOBJ * 4, stream);
  hipMemsetAsync(rcur, 0, NOBJ * 4, stream);
  csr_count<<<NREL/256, 256, 0, stream>>>(sub, obj, cnt);
  csr_scan<<<1, 1024, 0, stream>>>(cnt, coff);
  csr_fill<<<NREL/256, 256, 0, stream>>>(sub, obj, coff, rcur, lists);

  // ---- object stream (128^2 engine) ----
  obox_k<<<(NOBJ + 255) / 256, 256, 0, stream>>>(boxes, obox);
  posembed_k<<<NOBJ, 128, 0, stream>>>(boxes, pos1_W, pos1_b, bn_g, bn_b, bn_m, bn_v,
                                       pos2_W, pos2_b, pose);
  build_x1<<<nblk((long)NOBJ*560), 256, 0, stream>>>(inst, embd_W, labels, pose, X1b);
  build_aug<<<nblk((long)NOBJ*608), 256, 0, stream>>>(embl_W, labels, inst, augb);
  GEMM(0,false,true ,false, dim3((NOBJ>>7)*(512>>7)),  X1b, objhid_Wb, objhid_b, nullptr, augb + 4296, NOBJ, 512, 4480, 4480, 4864, nullptr, nullptr, nullptr);
  GEMM(0,false,true ,false, dim3((NOBJ>>7)*(1024>>7)), augb, pairup_Wb, pairup_b, nullptr, fusedb, NOBJ, 1024, 4864, 4864, 1024, nullptr, nullptr, nullptr);
  GEMM(1,false,true ,false, dim3((NOBJ>>7)*(2048>>7)), augb, objfin_Wb, objfin_b, nullptr, obj_featsb, NOBJ, 2048, 4864, 4864, 2048, nullptr, nullptr, nullptr);
  GEMM(0,false,true ,false, dim3((NOBJ>>7)*(512>>7)),  obj_featsb, objU_Wb, objU_b, nullptr, obj_repb, NOBJ, 512, 2048, 2048, 512, nullptr, nullptr, nullptr);
  GEMM(0,false,true ,false, dim3((NOBJ>>7)*(1536>>7)), obj_repb, ngru_Wihb, ngru_bih, nullptr, giv, NOBJ, 1536, 512, 512, 1536, nullptr, nullptr, nullptr);
  gru_init<<<nblk((long)NOBJ*64), 256, 0, stream>>>(giv, ngru_bhh, vert, vertb, 512, NOBJ);

  // ---- relation stream ----
  build_geo<<<(NREL + 255) / 256, 256, 0, stream>>>(obox, sub, obj, geob);
  GEMM(1,false,true ,false, dim3((NREL>>7)*(512>>7)),  geob, spt1_Wb, spt1_b, nullptr, spt1b, NREL, 512, 64, 64, 512, nullptr, nullptr, nullptr);
  // spt2 + PRODF on the 256^2 engine
  G256(1,false,true , spt1b, spt2_Wb, spt2_b, nullptr, prodb, NREL, 1024, 512, 512, 1024, fusedb, sub, obj);
  G256(1,false,false, prodb, pairfin_Wb, pairfin_b, nullptr, G1, NREL, 2048, 1024, 1024, 2048, nullptr, nullptr, nullptr);
  GEMMF(0,false,false, dim3((NREL>>7)*(512>>7)), unionf, W_compb, b_comp, nullptr, T1, NREL, 512, 4096, 4096, 512);
  G256(2,true ,false, G1, edgeU_Wb, zbias, T1, rel_repb, NREL, 512, 2048, 2048, 512, nullptr, nullptr, nullptr);
  G256(0,false,false, rel_repb, egru_Wihb, egru_bih, nullptr, gi_e, NREL, 1536, 512, 512, 1536, nullptr, nullptr, nullptr);
  gru_init<<<nblk((long)NREL*64), 256, 0, stream>>>(gi_e, egru_bhh, edge, xe + 512, 1024, NREL);

  // ---- message-passing loop ----
  for (int it = 0; it < 3; it++) {
    const bool last = (it == 2);
    edge_weights<<<(NREL * 64) / 256, 256, 0, stream>>>(vertb, xe, sub, obj,
                                                        svw_W, svw_b, ovw_W, ovw_b, ws_arr, wo_arr);
    ctx_gather<<<NOBJ, 128, 0, stream>>>(xe, ws_arr, wo_arr, coff, lists, ctxb);
    // edge gates on 256^2 engine
    G256(0,false,false, xe,       Wcat_rzb,              bias_rz,        nullptr, gates,        NREL, 1024, 1024, 1024, 2048, nullptr, nullptr, nullptr);
    G256(0,false,false, xe,       egru_Wihb + 1024L*512, egru_bih + 1024, nullptr, gates + 1024, NREL, 512,  512,  1024, 2048, nullptr, nullptr, nullptr);
    G256(0,false,false, xe + 512, egru_Whhb + 1024L*512, egru_bhh + 1024, nullptr, gates + 1536, NREL, 512,  512,  1024, 2048, nullptr, nullptr, nullptr);
    // vertex gates (M=2048 -> 128^2 engine)
    GEMM(0,false,true,false, dim3((NOBJ>>7)*(1536>>7)), ctxb,  ngru_Wihb, ngru_bih, nullptr, giv, NOBJ, 1536, 512, 512, 1536, nullptr, nullptr, nullptr);
    GEMM(0,false,true,false, dim3((NOBJ>>7)*(1536>>7)), vertb, ngru_Whhb, ngru_bhh, nullptr, ghv, NOBJ, 1536, 512, 512, 1536, nullptr, nullptr, nullptr);
    gru_step_e<<<nblk((long)NREL*64), 256, 0, stream>>>(gates, edge, last ? d_out_edge : edge, xe, NREL);
    gru_step_v<<<nblk((long)NOBJ*64), 256, 0, stream>>>(giv, ghv, vert, last ? d_out_vert : vert, vertb, NOBJ);
  }
}

// Round 7
// 2013.842 us; speedup vs baseline: 2.3649x; 1.0226x over previous
//
#include <hip/hip_runtime.h>
#include <stdint.h>

#define NOBJ 2048
#define NREL 32768

typedef __attribute__((ext_vector_type(8))) short short8;
typedef __attribute__((ext_vector_type(4))) float f32x4;
typedef __attribute__((ext_vector_type(4))) unsigned short ushort4v;

__device__ __forceinline__ unsigned short f2bs(float x){
  unsigned u = __float_as_uint(x);
  unsigned v = u + 0x7fffu + ((u >> 16) & 1u);
  return (unsigned short)(v >> 16);
}
__device__ __forceinline__ float b2f(unsigned short u){
  return __uint_as_float(((unsigned)u) << 16);
}
__device__ __forceinline__ float sigf(float x){ return 1.0f / (1.0f + expf(-x)); }

// async global->LDS, 16B per lane. LDS dest = wave-uniform base + lane*16.
__device__ __forceinline__ void gload16(const unsigned short* g, unsigned short* l) {
  __builtin_amdgcn_global_load_lds(
      (const __attribute__((address_space(1))) unsigned int*)(uintptr_t)g,
      (__attribute__((address_space(3))) unsigned int*)(uintptr_t)l,
      16, 0, 0);
}

// ====== 256x256 BK=32 TRIPLE-buffered engine, 1 barrier/kt, counted vmcnt ======
// A: MxK(lda) bf16. B: NxK bf16 packed. bf16 out (stride ldc).
// RMODE: 0 none; 1 relu [then PRODF]; 2 relu(acc+bias+Cin). ACCUM: +Cin (f32, stride N).
// LDS [3 buf][A/B][256 rows][4 slot16]; slot s holds global slot s^((row>>1)&3)
// (both-sides swizzle, rule #21) -> 2 lanes/bank on ds_read_b128 (free, m136).
// Invariant: one barrier per kt; stage(kt+2) -> buf[(kt+2)%3] == buf[(kt-1)%3],
// fully read by ALL waves before they passed barrier(kt). vmcnt(4) = own 4 loads
// of stage(kt) complete; barrier makes that all-waves. Never drains to 0 mid-loop.
template<int RMODE, bool ACCUM, bool PRODF>
__global__ __launch_bounds__(512, 2)
void gemm256(const unsigned short* __restrict__ A, const unsigned short* __restrict__ B,
             const float* __restrict__ bias, const float* __restrict__ Cin,
             unsigned short* __restrict__ C, int M, int N, int K, int lda, int ldc,
             const unsigned short* __restrict__ fusedp,
             const int* __restrict__ subp, const int* __restrict__ objp)
{
  __shared__ __align__(16) unsigned short lds[3][2][8192];   // 96 KiB
  const int t = threadIdx.x;
  const int l = t & 63;
  const int w = t >> 6;                 // 0..7
  const int wr = w >> 2, wc = w & 3;    // 2M x 4N waves
  const int lrow = l & 15, kg = l >> 4;

  // XCD bijective swizzle (m204)
  const int nwg = gridDim.x;
  const int q8 = nwg >> 3, r8 = nwg & 7;
  const int xcd = blockIdx.x & 7, bidx = blockIdx.x >> 3;
  const int wgid = (xcd < r8 ? xcd * (q8 + 1) : r8 * (q8 + 1) + (xcd - r8) * q8) + bidx;
  const int ntile = N >> 8;
  const int bm = wgid / ntile, bn = wgid - bm * ntile;
  const int m0 = bm << 8, n0 = bn << 8;

  // staging: gload q of wave w covers rows w*32+q*16 + (l>>2), slot (l&3);
  // source slot pre-swizzled: g = (l&3) ^ ((l>>3)&3)   [(row>>1)&3 with row=rb+(l>>2)]
  const int sel = ((l & 3) ^ ((l >> 3) & 3)) << 3;      // shorts
  const unsigned short* Ag = A + (long)(m0 + w * 32 + (l >> 2)) * lda + sel;
  const unsigned short* Bg = B + (long)(n0 + w * 32 + (l >> 2)) * K + sel;
  const long lda16 = (long)16 * lda;
  const long ldb16 = (long)16 * K;
  const int NT = K >> 5;

#define STG(tile) do { \
    const int bsel = (tile) % 3; \
    unsigned short* pA = &lds[bsel][0][w * 1024]; \
    unsigned short* pB = &lds[bsel][1][w * 1024]; \
    const unsigned short* a_ = Ag + (long)(tile) * 32; \
    const unsigned short* b_ = Bg + (long)(tile) * 32; \
    gload16(a_,         pA); \
    gload16(a_ + lda16, pA + 512); \
    gload16(b_,         pB); \
    gload16(b_ + ldb16, pB + 512); \
  } while (0)

  f32x4 acc[8][4] = {};

  STG(0);
  if (NT > 1) STG(1);

  for (int kt = 0; kt < NT; ++kt) {
    const int cur = kt % 3;
    if (kt + 1 < NT) asm volatile("s_waitcnt vmcnt(4)" ::: "memory");
    else             asm volatile("s_waitcnt vmcnt(0)" ::: "memory");
    __builtin_amdgcn_s_barrier();
    asm volatile("" ::: "memory");

    const unsigned short* As_ = &lds[cur][0][0];
    const unsigned short* Bs_ = &lds[cur][1][0];

    short8 bfr[4];
#pragma unroll
    for (int j = 0; j < 4; j++) {
      const int rb = wc * 64 + j * 16 + lrow;
      bfr[j] = *(const short8*)(Bs_ + rb * 32 + ((kg ^ ((rb >> 1) & 3)) << 3));
    }
    short8 afr[8];
#pragma unroll
    for (int i = 0; i < 8; i++) {
      const int ra = wr * 128 + i * 16 + lrow;
      afr[i] = *(const short8*)(As_ + ra * 32 + ((kg ^ ((ra >> 1) & 3)) << 3));
    }
    if (kt + 2 < NT) STG(kt + 2);       // overlaps the MFMAs below (buf[(kt+2)%3] is free)
    __builtin_amdgcn_s_setprio(1);
#pragma unroll
    for (int i = 0; i < 8; i++)
#pragma unroll
      for (int j = 0; j < 4; j++)
        acc[i][j] = __builtin_amdgcn_mfma_f32_16x16x32_bf16(afr[i], bfr[j], acc[i][j], 0, 0, 0);
    __builtin_amdgcn_s_setprio(0);
    asm volatile("" ::: "memory");
  }
#undef STG

#pragma unroll
  for (int i = 0; i < 8; i++) {
#pragma unroll
    for (int j = 0; j < 4; j++) {
      const int col = n0 + wc * 64 + j * 16 + lrow;
      const float bv = bias[col];
#pragma unroll
      for (int q = 0; q < 4; q++) {
        const long row = m0 + wr * 128 + i * 16 + kg * 4 + q;
        float v = acc[i][j][q] + bv;
        if constexpr (RMODE == 1) v = fmaxf(v, 0.0f);
        if constexpr (PRODF) {
          int gr = (col < 512) ? subp[row] : objp[row];
          v *= b2f(fusedp[(long)gr * 1024 + col]);
        }
        if constexpr (ACCUM) v += Cin[row * (long)N + col];
        if constexpr (RMODE == 2) v = fmaxf(v, 0.0f);
        C[row * (long)ldc + col] = f2bs(v);
      }
    }
  }
}

// =====================  128x128 engine (object stream, f32-A, small shapes)  ============
template<int RMODE, bool ACCUM, bool OUTB, bool PRODF, bool AF32>
__global__ __launch_bounds__(256, 2)
void gemm_bt(const void* __restrict__ Ap, const unsigned short* __restrict__ B,
             const float* __restrict__ bias, const float* __restrict__ Cin,
             void* __restrict__ Cp, int M, int N, int K, int lda, int ldc,
             const unsigned short* __restrict__ fusedp,
             const int* __restrict__ subp, const int* __restrict__ objp)
{
  __shared__ __align__(16) unsigned short As[128 * 32];
  __shared__ __align__(16) unsigned short Bs[128 * 32];
  const int t = threadIdx.x;
  const int lane = t & 63;
  const int w = t >> 6;
  const int nwg = gridDim.x;
  const int q8 = nwg >> 3, r8 = nwg & 7;
  const int xcd = blockIdx.x & 7, bidx = blockIdx.x >> 3;
  const int wgid = (xcd < r8 ? xcd * (q8 + 1) : r8 * (q8 + 1) + (xcd - r8) * q8) + bidx;
  const int ntile = N >> 7;
  const int bm = wgid / ntile;
  const int bn = wgid - bm * ntile;
  const int m0 = bm << 7, n0 = bn << 7;
  const int wm = (w & 1) << 6, wn = (w >> 1) << 6;
  const int lrow = lane & 15, kg = lane >> 4;

  const int c0 = w << 1;
  const int srow = (c0 << 4) + (lane >> 2);
  const int selem = (((lane & 3) ^ ((lane >> 3) & 3)) << 3);
  const unsigned short* bg0 = B + (long)(n0 + srow) * K + selem;
  const unsigned short* bg1 = bg0 + (long)16 * K;
  unsigned short* bl0 = Bs + (c0 << 9);
  unsigned short* bl1 = bl0 + 512;

  const unsigned short* ag0 = nullptr; const unsigned short* ag1 = nullptr;
  unsigned short* al0 = nullptr; unsigned short* al1 = nullptr;
  const float* afp = nullptr; unsigned short* afl = nullptr;
  if constexpr (AF32) {
    afp = (const float*)Ap + (long)(m0 + (t >> 1)) * lda + ((t & 1) << 4);
    afl = As + (t >> 1) * 32 + ((t & 1) << 4);
  } else {
    ag0 = (const unsigned short*)Ap + (long)(m0 + srow) * lda + selem;
    ag1 = ag0 + (long)16 * lda;
    al0 = As + (c0 << 9);
    al1 = al0 + 512;
  }

  const int fslot = ((lrow >> 1) & 3);

  f32x4 acc[4][4] = {};

  for (int k0 = 0; k0 < K; k0 += 32) {
    gload16(bg0 + k0, bl0);
    gload16(bg1 + k0, bl1);
    if constexpr (AF32) {
      const float* ap = afp + k0;
      f32x4 f0 = *(const f32x4*)(ap);
      f32x4 f1 = *(const f32x4*)(ap + 4);
      f32x4 f2 = *(const f32x4*)(ap + 8);
      f32x4 f3 = *(const f32x4*)(ap + 12);
      ushort4v u0, u1, u2, u3;
      u0[0]=f2bs(f0[0]); u0[1]=f2bs(f0[1]); u0[2]=f2bs(f0[2]); u0[3]=f2bs(f0[3]);
      u1[0]=f2bs(f1[0]); u1[1]=f2bs(f1[1]); u1[2]=f2bs(f1[2]); u1[3]=f2bs(f1[3]);
      u2[0]=f2bs(f2[0]); u2[1]=f2bs(f2[1]); u2[2]=f2bs(f2[2]); u2[3]=f2bs(f2[3]);
      u3[0]=f2bs(f3[0]); u3[1]=f2bs(f3[1]); u3[2]=f2bs(f3[2]); u3[3]=f2bs(f3[3]);
      *(ushort4v*)afl = u0;
      *(ushort4v*)(afl + 4) = u1;
      *(ushort4v*)(afl + 8) = u2;
      *(ushort4v*)(afl + 12) = u3;
    } else {
      gload16(ag0 + k0, al0);
      gload16(ag1 + k0, al1);
    }
    __syncthreads();
    short8 afr[4], bfr[4];
#pragma unroll
    for (int i = 0; i < 4; i++) {
      if constexpr (AF32)
        afr[i] = *(const short8*)(As + (wm + i * 16 + lrow) * 32 + (kg << 3));
      else
        afr[i] = *(const short8*)(As + (wm + i * 16 + lrow) * 32 + ((kg ^ fslot) << 3));
    }
#pragma unroll
    for (int j = 0; j < 4; j++)
      bfr[j] = *(const short8*)(Bs + (wn + j * 16 + lrow) * 32 + ((kg ^ fslot) << 3));
#pragma unroll
    for (int i = 0; i < 4; i++)
#pragma unroll
      for (int j = 0; j < 4; j++)
        acc[i][j] = __builtin_amdgcn_mfma_f32_16x16x32_bf16(afr[i], bfr[j], acc[i][j], 0, 0, 0);
    __syncthreads();
  }

  float* Cf = (float*)Cp;
  unsigned short* Cb = (unsigned short*)Cp;
#pragma unroll
  for (int i = 0; i < 4; i++) {
#pragma unroll
    for (int j = 0; j < 4; j++) {
      const int col = n0 + wn + j * 16 + lrow;
      const float bv = bias[col];
#pragma unroll
      for (int q = 0; q < 4; q++) {
        const long row = m0 + wm + i * 16 + kg * 4 + q;
        float v = acc[i][j][q] + bv;
        if constexpr (RMODE == 1) v = fmaxf(v, 0.0f);
        if constexpr (PRODF) {
          int gr = (col < 512) ? subp[row] : objp[row];
          v *= b2f(fusedp[(long)gr * 1024 + col]);
        }
        if constexpr (ACCUM) v += Cin[row * (long)N + col];
        if constexpr (RMODE == 2) v = fmaxf(v, 0.0f);
        if constexpr (OUTB) Cb[row * (long)ldc + col] = f2bs(v);
        else Cf[row * (long)ldc + col] = v;
      }
    }
  }
}

// ===================== small kernels =====================

__global__ void cvt_pad4(const float* __restrict__ src, unsigned short* __restrict__ dst,
                         int rows, int K0, int Kp)
{
  const int kp4 = Kp >> 2;
  const long total = (long)rows * kp4;
  for (long i = blockIdx.x * (long)blockDim.x + threadIdx.x; i < total; i += (long)gridDim.x * blockDim.x) {
    int r = (int)(i / kp4), k = (int)(i - (long)r * kp4) << 2;
    ushort4v o;
    if (k < K0) {
      f32x4 v = *(const f32x4*)(src + (long)r * K0 + k);
      o[0] = f2bs(v[0]); o[1] = f2bs(v[1]); o[2] = f2bs(v[2]); o[3] = f2bs(v[3]);
    } else {
      o[0] = 0; o[1] = 0; o[2] = 0; o[3] = 0;
    }
    *(ushort4v*)(dst + (long)r * Kp + k) = o;
  }
}

__global__ void cvt4(const float* __restrict__ src, unsigned short* __restrict__ dst, long n4)
{
  for (long i = blockIdx.x * (long)blockDim.x + threadIdx.x; i < n4; i += (long)gridDim.x * blockDim.x) {
    f32x4 v = ((const f32x4*)src)[i];
    ushort4v o;
    o[0] = f2bs(v[0]); o[1] = f2bs(v[1]); o[2] = f2bs(v[2]); o[3] = f2bs(v[3]);
    ((ushort4v*)dst)[i] = o;
  }
}

__global__ void transpose_cvt(const float* __restrict__ src, unsigned short* __restrict__ dst,
                              int R, int C)
{
  __shared__ float tile[32][33];
  int c0 = blockIdx.x * 32, r0 = blockIdx.y * 32;
  for (int i = threadIdx.y; i < 32; i += 8)
    tile[i][threadIdx.x] = src[(long)(r0 + i) * C + c0 + threadIdx.x];
  __syncthreads();
  for (int i = threadIdx.y; i < 32; i += 8)
    dst[(long)(c0 + i) * R + r0 + threadIdx.x] = f2bs(tile[threadIdx.x][i]);
}

__global__ void comp_bias(const float* __restrict__ edgeU_W, const float* __restrict__ up_b,
                          const float* __restrict__ edgeU_b, float* __restrict__ b_comp)
{
  int j = (int)((blockIdx.x * (long)blockDim.x + threadIdx.x) >> 6);
  int l = threadIdx.x & 63;
  if (j >= 512) return;
  float s = 0.0f;
  for (int k = l; k < 2048; k += 64) s += edgeU_W[(long)j * 2048 + k] * up_b[k];
#pragma unroll
  for (int off = 32; off > 0; off >>= 1) s += __shfl_xor(s, off);
  if (l == 0) b_comp[j] = s + edgeU_b[j];
}

__global__ void obox_k(const float* __restrict__ boxes, float* __restrict__ obox)
{
  int i = blockIdx.x * blockDim.x + threadIdx.x;
  if (i >= NOBJ) return;
  float x1 = boxes[i*4], y1 = boxes[i*4+1], x2 = boxes[i*4+2], y2 = boxes[i*4+3];
  float wdt = x2 - x1 + 1.0f, hgt = y2 - y1 + 1.0f;
  float cx = x1 + 0.5f * wdt, cy = y1 + 0.5f * hgt;
  const float inv = 1.0f / 1024.0f;
  float* o = obox + i * 8;
  o[0]=x1*inv; o[1]=y1*inv; o[2]=x2*inv; o[3]=y2*inv;
  o[4]=cx*inv; o[5]=cy*inv; o[6]=wdt*inv; o[7]=hgt*inv;
}

__global__ void posembed_k(const float* __restrict__ boxes,
                           const float* __restrict__ w1, const float* __restrict__ b1,
                           const float* __restrict__ g, const float* __restrict__ bb,
                           const float* __restrict__ mm, const float* __restrict__ vv,
                           const float* __restrict__ w2, const float* __restrict__ b2,
                           float* __restrict__ out)
{
  int o = blockIdx.x, t = threadIdx.x;
  __shared__ float e[9];
  __shared__ float p[32];
  if (t == 0) {
    float x1 = boxes[o*4], y1 = boxes[o*4+1], x2 = boxes[o*4+2], y2 = boxes[o*4+3];
    float wdt = x2 - x1 + 1.0f, hgt = y2 - y1 + 1.0f;
    float cx = x1 + 0.5f * wdt, cy = y1 + 0.5f * hgt;
    e[0]=wdt/1024.0f; e[1]=hgt/768.0f; e[2]=cx/1024.0f; e[3]=cy/768.0f;
    e[4]=x1/1024.0f;  e[5]=y1/768.0f;  e[6]=x2/1024.0f; e[7]=y2/768.0f;
    e[8]=wdt*hgt/(1024.0f*768.0f);
  }
  __syncthreads();
  if (t < 32) {
    float s = b1[t];
#pragma unroll
    for (int j = 0; j < 9; j++) s += w1[t*9+j] * e[j];
    s = (s - mm[t]) * g[t] / sqrtf(vv[t] + 1e-5f) + bb[t];
    p[t] = s;
  }
  __syncthreads();
  float s = b2[t];
#pragma unroll
  for (int j = 0; j < 32; j++) s += w2[t*32+j] * p[j];
  out[o*128 + t] = fmaxf(s, 0.0f);
}

__device__ __forceinline__ void pack8_store(unsigned short* dst, f32x4 a, f32x4 b)
{
  ushort4v o0, o1;
  o0[0]=f2bs(a[0]); o0[1]=f2bs(a[1]); o0[2]=f2bs(a[2]); o0[3]=f2bs(a[3]);
  o1[0]=f2bs(b[0]); o1[1]=f2bs(b[1]); o1[2]=f2bs(b[2]); o1[3]=f2bs(b[3]);
  *(ushort4v*)dst = o0;
  *(ushort4v*)(dst + 4) = o1;
}

__global__ void build_x1(const float* __restrict__ inst, const float* __restrict__ embd,
                         const int* __restrict__ labels, const float* __restrict__ pose,
                         unsigned short* __restrict__ X1b)
{
  const long total = (long)NOBJ * 560;
  for (long i = blockIdx.x * (long)blockDim.x + threadIdx.x; i < total; i += (long)gridDim.x * blockDim.x) {
    int r = (int)(i / 560), c = ((int)(i - (long)r * 560)) << 3;
    unsigned short* dst = X1b + (long)r * 4480 + c;
    const float* src;
    if (c < 4096)      src = inst + (long)r * 4096 + c;
    else if (c < 4296) src = embd + (long)labels[r] * 200 + (c - 4096);
    else if (c < 4424) src = pose + r * 128 + (c - 4296);
    else { ushort4v z = {0,0,0,0}; *(ushort4v*)dst = z; *(ushort4v*)(dst+4) = z; continue; }
    pack8_store(dst, *(const f32x4*)src, *((const f32x4*)src + 1));
  }
}

__global__ void build_aug(const float* __restrict__ embl, const int* __restrict__ labels,
                          const float* __restrict__ inst, unsigned short* __restrict__ augb)
{
  const long total = (long)NOBJ * 608;
  for (long i = blockIdx.x * (long)blockDim.x + threadIdx.x; i < total; i += (long)gridDim.x * blockDim.x) {
    int r = (int)(i / 608), c = ((int)(i - (long)r * 608)) << 3;
    if (c >= 4296 && c < 4808) continue;
    unsigned short* dst = augb + (long)r * 4864 + c;
    const float* src;
    if (c < 200)       src = embl + (long)labels[r] * 200 + c;
    else if (c < 4296) src = inst + (long)r * 4096 + (c - 200);
    else { ushort4v z = {0,0,0,0}; *(ushort4v*)dst = z; *(ushort4v*)(dst+4) = z; continue; }
    pack8_store(dst, *(const f32x4*)src, *((const f32x4*)src + 1));
  }
}

__global__ void build_geo(const float* __restrict__ obox, const int* __restrict__ sub,
                          const int* __restrict__ obj, unsigned short* __restrict__ geob)
{
  int r = blockIdx.x * blockDim.x + threadIdx.x;
  if (r >= NREL) return;
  const float* b1 = obox + sub[r] * 8;
  const float* b2 = obox + obj[r] * 8;
  float o[32];
#pragma unroll
  for (int j = 0; j < 8; j++) { o[j] = b1[j]; o[8+j] = b2[j]; }
  float ux1 = fminf(b1[0], b2[0]), uy1 = fminf(b1[1], b2[1]);
  float ux2 = fmaxf(b1[2], b2[2]), uy2 = fmaxf(b1[3], b2[3]);
  float uw = ux2 - ux1 + 1.0f, uh = uy2 - uy1 + 1.0f;
  o[16]=ux1; o[17]=uy1; o[18]=ux2; o[19]=uy2;
  o[20]=ux1+0.5f*uw; o[21]=uy1+0.5f*uh; o[22]=uw; o[23]=uh;
  float ix1 = fmaxf(b1[0], b2[0]), iy1 = fmaxf(b1[1], b2[1]);
  float ix2 = fminf(b1[2], b2[2]), iy2 = fminf(b1[3], b2[3]);
  bool bad = (ix2 < ix1) || (iy2 < iy1);
  float iw = ix2 - ix1 + 1.0f, ih = iy2 - iy1 + 1.0f;
  if (bad) {
#pragma unroll
    for (int j = 24; j < 32; j++) o[j] = 0.0f;
  } else {
    o[24]=ix1; o[25]=iy1; o[26]=ix2; o[27]=iy2;
    o[28]=ix1+0.5f*iw; o[29]=iy1+0.5f*ih; o[30]=iw; o[31]=ih;
  }
  unsigned short* gp = geob + (long)r * 64;
#pragma unroll
  for (int j = 0; j < 32; j++) gp[j] = f2bs(o[j]);
#pragma unroll
  for (int j = 32; j < 64; j++) gp[j] = 0;
}

__global__ void gru_init(const unsigned short* __restrict__ gi, const float* __restrict__ bhh,
                         float* __restrict__ h, unsigned short* __restrict__ hb, int hstride, int n)
{
  const long total = (long)n * 64;
  for (long i = blockIdx.x * (long)blockDim.x + threadIdx.x; i < total; i += (long)gridDim.x * blockDim.x) {
    int r = (int)(i >> 6), c = ((int)(i & 63)) << 3;
    const unsigned short* gr = gi + (long)r * 1536;
    short8 vr = *(const short8*)(gr + c);
    short8 vz = *(const short8*)(gr + 512 + c);
    short8 vn = *(const short8*)(gr + 1024 + c);
    float hv[8];
#pragma unroll
    for (int k = 0; k < 8; k++) {
      float rr = sigf(b2f((unsigned short)vr[k]) + bhh[c + k]);
      float z  = sigf(b2f((unsigned short)vz[k]) + bhh[512 + c + k]);
      float nn = tanhf(b2f((unsigned short)vn[k]) + rr * bhh[1024 + c + k]);
      hv[k] = (1.0f - z) * nn;
    }
    float* hp = h + (long)r * 512 + c;
    *(f32x4*)hp = *(f32x4*)hv;
    *(f32x4*)(hp + 4) = *(f32x4*)(hv + 4);
    pack8_store(hb + (long)r * hstride + c, *(f32x4*)hv, *(f32x4*)(hv + 4));
  }
}

__global__ void gru_step_v(const unsigned short* __restrict__ gi, const unsigned short* __restrict__ gh,
                           const float* __restrict__ hin, float* __restrict__ hout,
                           unsigned short* __restrict__ hb, int n)
{
  const long total = (long)n * 64;
  for (long i = blockIdx.x * (long)blockDim.x + threadIdx.x; i < total; i += (long)gridDim.x * blockDim.x) {
    int r = (int)(i >> 6), c = ((int)(i & 63)) << 3;
    const unsigned short* gr = gi + (long)r * 1536;
    const unsigned short* hr = gh + (long)r * 1536;
    short8 ir = *(const short8*)(gr + c);
    short8 iz = *(const short8*)(gr + 512 + c);
    short8 in_ = *(const short8*)(gr + 1024 + c);
    short8 hrr = *(const short8*)(hr + c);
    short8 hz = *(const short8*)(hr + 512 + c);
    short8 hn = *(const short8*)(hr + 1024 + c);
    const float* hi = hin + (long)r * 512 + c;
    f32x4 h0 = *(const f32x4*)hi;
    f32x4 h1 = *(const f32x4*)(hi + 4);
    float hv[8];
#pragma unroll
    for (int k = 0; k < 8; k++) {
      float rr = sigf(b2f((unsigned short)ir[k]) + b2f((unsigned short)hrr[k]));
      float z  = sigf(b2f((unsigned short)iz[k]) + b2f((unsigned short)hz[k]));
      float nn = tanhf(b2f((unsigned short)in_[k]) + rr * b2f((unsigned short)hn[k]));
      float old = (k < 4) ? h0[k] : h1[k - 4];
      hv[k] = (1.0f - z) * nn + z * old;
    }
    float* hp = hout + (long)r * 512 + c;
    *(f32x4*)hp = *(f32x4*)hv;
    *(f32x4*)(hp + 4) = *(f32x4*)(hv + 4);
    pack8_store(hb + (long)r * 512 + c, *(f32x4*)hv, *(f32x4*)(hv + 4));
  }
}

// edge GRU step via linearity: gi = ws*VW[sub] + wo*VW[obj] + bih ; gh = GH (incl bhh).
__global__ void gru_step_e2(const unsigned short* __restrict__ GH,   // [r][1536]
                            const unsigned short* __restrict__ VW,   // [2048][1536]
                            const float* __restrict__ ws_arr, const float* __restrict__ wo_arr,
                            const int* __restrict__ sub, const int* __restrict__ obj,
                            const float* __restrict__ bih,           // f32[1536]
                            const float* __restrict__ hin, float* __restrict__ hout,
                            unsigned short* __restrict__ hb, int n)
{
  const long total = (long)n * 64;
  for (long i = blockIdx.x * (long)blockDim.x + threadIdx.x; i < total; i += (long)gridDim.x * blockDim.x) {
    int r = (int)(i >> 6), c = ((int)(i & 63)) << 3;
    int s = sub[r], o = obj[r];
    float ws = ws_arr[r], wo = wo_arr[r];
    const unsigned short* gh = GH + (long)r * 1536;
    const unsigned short* vs = VW + (long)s * 1536;
    const unsigned short* vo = VW + (long)o * 1536;
    short8 ghr = *(const short8*)(gh + c);
    short8 ghz = *(const short8*)(gh + 512 + c);
    short8 ghn = *(const short8*)(gh + 1024 + c);
    short8 vsr = *(const short8*)(vs + c);
    short8 vsz = *(const short8*)(vs + 512 + c);
    short8 vsn = *(const short8*)(vs + 1024 + c);
    short8 vor_ = *(const short8*)(vo + c);
    short8 voz = *(const short8*)(vo + 512 + c);
    short8 von = *(const short8*)(vo + 1024 + c);
    const float* hi = hin + (long)r * 512 + c;
    f32x4 h0 = *(const f32x4*)hi;
    f32x4 h1 = *(const f32x4*)(hi + 4);
    float hv[8];
#pragma unroll
    for (int k = 0; k < 8; k++) {
      float gir = ws * b2f((unsigned short)vsr[k]) + wo * b2f((unsigned short)vor_[k]) + bih[c + k];
      float giz = ws * b2f((unsigned short)vsz[k]) + wo * b2f((unsigned short)voz[k]) + bih[512 + c + k];
      float gin = ws * b2f((unsigned short)vsn[k]) + wo * b2f((unsigned short)von[k]) + bih[1024 + c + k];
      float rr = sigf(gir + b2f((unsigned short)ghr[k]));
      float z  = sigf(giz + b2f((unsigned short)ghz[k]));
      float nn = tanhf(gin + rr * b2f((unsigned short)ghn[k]));
      float old = (k < 4) ? h0[k] : h1[k - 4];
      hv[k] = (1.0f - z) * nn + z * old;
    }
    float* hp = hout + (long)r * 512 + c;
    *(f32x4*)hp = *(f32x4*)hv;
    *(f32x4*)(hp + 4) = *(f32x4*)(hv + 4);
    pack8_store(hb + (long)r * 512 + c, *(f32x4*)hv, *(f32x4*)(hv + 4));
  }
}

// Per-relation ws/wo dots only (no xb materialization).
__global__ __launch_bounds__(256)
void edge_weights(const unsigned short* __restrict__ vertb, const unsigned short* __restrict__ edgeb,
                  const int* __restrict__ sub, const int* __restrict__ obj,
                  const float* __restrict__ svwW, const float* __restrict__ svwb,
                  const float* __restrict__ ovwW, const float* __restrict__ ovwb,
                  float* __restrict__ ws_arr, float* __restrict__ wo_arr)
{
  long gid = blockIdx.x * (long)blockDim.x + threadIdx.x;
  int r = (int)(gid >> 6);
  int l = (int)(gid & 63);
  if (r >= NREL) return;
  int s = sub[r], o = obj[r];
  const unsigned short* sv = vertb + (long)s * 512;
  const unsigned short* ov = vertb + (long)o * 512;
  const unsigned short* e  = edgeb + (long)r * 512;
  float as = 0.0f, ao = 0.0f;
#pragma unroll
  for (int k = 0; k < 8; k++) {
    int c = l + k * 64;
    float svv = b2f(sv[c]), ovv = b2f(ov[c]), ev = b2f(e[c]);
    as += svwW[c] * svv + svwW[512 + c] * ev;
    ao += ovwW[c] * ovv + ovwW[512 + c] * ev;
  }
#pragma unroll
  for (int off = 32; off > 0; off >>= 1) {
    as += __shfl_xor(as, off);
    ao += __shfl_xor(ao, off);
  }
  if (l == 0) {
    ws_arr[r] = sigf(as + svwb[0]);
    wo_arr[r] = sigf(ao + ovwb[0]);
  }
}

// ===================== CSR =====================

__global__ void csr_count(const int* __restrict__ sub, const int* __restrict__ obj,
                          int* __restrict__ cnt)
{
  int r = blockIdx.x * blockDim.x + threadIdx.x;
  if (r >= NREL) return;
  atomicAdd(&cnt[sub[r]], 1);
  atomicAdd(&cnt[obj[r]], 1);
}

__global__ __launch_bounds__(1024)
void csr_scan(const int* __restrict__ cnt, int* __restrict__ off)
{
  __shared__ int a[1024], b[1024];
  int t = threadIdx.x;
  int c0 = cnt[2*t], c1 = cnt[2*t+1];
  a[t] = c0 + c1;
  __syncthreads();
  int* src = a; int* dst = b;
  for (int s = 1; s < 1024; s <<= 1) {
    int v = src[t];
    if (t >= s) v += src[t - s];
    dst[t] = v;
    __syncthreads();
    int* tmp = src; src = dst; dst = tmp;
  }
  int incl = src[t];
  int excl = incl - (c0 + c1);
  off[2*t] = excl;
  off[2*t+1] = excl + c0;
  if (t == 1023) off[2048] = incl;
}

__global__ void csr_fill(const int* __restrict__ sub, const int* __restrict__ obj,
                         const int* __restrict__ off, int* __restrict__ rcur,
                         int* __restrict__ lists)
{
  int r = blockIdx.x * blockDim.x + threadIdx.x;
  if (r >= NREL) return;
  int s = sub[r];
  int p = atomicAdd(&rcur[s], 1);
  lists[off[s] + p] = (r << 1);
  int o = obj[r];
  int q = atomicAdd(&rcur[o], 1);
  lists[off[o] + q] = (r << 1) | 1;
}

__global__ __launch_bounds__(128)
void ctx_gather(const unsigned short* __restrict__ edgeb, const float* __restrict__ ws,
                const float* __restrict__ wo, const int* __restrict__ off,
                const int* __restrict__ lists, unsigned short* __restrict__ ctxb)
{
  __shared__ float part[512];
  int o = blockIdx.x;
  int l = threadIdx.x & 63;
  int w = threadIdx.x >> 6;
  int i0 = off[o], i1 = off[o + 1];
  float acc[8] = {0.f,0.f,0.f,0.f,0.f,0.f,0.f,0.f};
  for (int i = i0 + w; i < i1; i += 2) {
    int e = lists[i];
    int r = e >> 1;
    float sc = (e & 1) ? wo[r] : ws[r];
    short8 row = *(const short8*)(edgeb + (long)r * 512 + l * 8);
#pragma unroll
    for (int k = 0; k < 8; k++) acc[k] += sc * b2f((unsigned short)row[k]);
  }
  if (w == 1) {
    *(f32x4*)&part[l*8]     = *(f32x4*)&acc[0];
    *(f32x4*)&part[l*8 + 4] = *(f32x4*)&acc[4];
  }
  __syncthreads();
  if (w == 0) {
#pragma unroll
    for (int k = 0; k < 8; k++) acc[k] += part[l*8 + k];
    pack8_store(ctxb + (long)o * 512 + l * 8, *(f32x4*)&acc[0], *(f32x4*)&acc[4]);
  }
}

// ===================== driver =====================

static inline int nblk(long total) {
  long b = (total + 255) / 256;
  return (int)(b > 16384 ? 16384 : b);
}

#define GEMM(RM, AC, OB, PF, grid, Aa, Bb, bb, Ci, Cc, Mm, Nn, Kk, ldA, ldC, fp, sp, op) \
  gemm_bt<RM, AC, OB, PF, false><<<grid, 256, 0, stream>>>(Aa, Bb, bb, Ci, Cc, Mm, Nn, Kk, ldA, ldC, fp, sp, op)
#define GEMMF(RM, AC, OB, grid, Aa, Bb, bb, Ci, Cc, Mm, Nn, Kk, ldA, ldC) \
  gemm_bt<RM, AC, OB, false, true><<<grid, 256, 0, stream>>>(Aa, Bb, bb, Ci, Cc, Mm, Nn, Kk, ldA, ldC, nullptr, nullptr, nullptr)
#define G256(RM, AC, PF, Aa, Bb, bb, Ci, Cc, Mm, Nn, Kk, ldA, ldC, fp, sp, op) \
  gemm256<RM, AC, PF><<<dim3(((Mm) >> 8) * ((Nn) >> 8)), 512, 0, stream>>>(Aa, Bb, bb, Ci, Cc, Mm, Nn, Kk, ldA, ldC, fp, sp, op)

extern "C" void kernel_launch(void* const* d_in, const int* in_sizes, int n_in,
                              void* d_out, int out_size, void* d_ws, size_t ws_size,
                              hipStream_t stream)
{
  const float* inst     = (const float*)d_in[0];
  const float* unionf   = (const float*)d_in[1];
  const float* boxes    = (const float*)d_in[2];
  const float* embd_W   = (const float*)d_in[3];
  const float* embl_W   = (const float*)d_in[4];
  const float* up_W     = (const float*)d_in[5];
  const float* up_b     = (const float*)d_in[6];
  const float* pairup_W = (const float*)d_in[7];
  const float* pairup_b = (const float*)d_in[8];
  const float* pos1_W   = (const float*)d_in[9];
  const float* pos1_b   = (const float*)d_in[10];
  const float* bn_g     = (const float*)d_in[11];
  const float* bn_b     = (const float*)d_in[12];
  const float* bn_m     = (const float*)d_in[13];
  const float* bn_v     = (const float*)d_in[14];
  const float* pos2_W   = (const float*)d_in[15];
  const float* pos2_b   = (const float*)d_in[16];
  const float* spt1_W   = (const float*)d_in[17];
  const float* spt1_b   = (const float*)d_in[18];
  const float* spt2_W   = (const float*)d_in[19];
  const float* spt2_b   = (const float*)d_in[20];
  const float* pairfin_W= (const float*)d_in[21];
  const float* pairfin_b= (const float*)d_in[22];
  const float* objhid_W = (const float*)d_in[23];
  const float* objhid_b = (const float*)d_in[24];
  const float* objfin_W = (const float*)d_in[25];
  const float* objfin_b = (const float*)d_in[26];
  const float* objU_W   = (const float*)d_in[27];
  const float* objU_b   = (const float*)d_in[28];
  const float* edgeU_W  = (const float*)d_in[29];
  const float* edgeU_b  = (const float*)d_in[30];
  const float* egru_Wih = (const float*)d_in[31];
  const float* egru_Whh = (const float*)d_in[32];
  const float* egru_bih = (const float*)d_in[33];
  const float* egru_bhh = (const float*)d_in[34];
  const float* ngru_Wih = (const float*)d_in[35];
  const float* ngru_Whh = (const float*)d_in[36];
  const float* ngru_bih = (const float*)d_in[37];
  const float* ngru_bhh = (const float*)d_in[38];
  const float* svw_W    = (const float*)d_in[39];
  const float* svw_b    = (const float*)d_in[40];
  const float* ovw_W    = (const float*)d_in[41];
  const float* ovw_b    = (const float*)d_in[42];
  const int*   labels   = (const int*)d_in[43];
  const int*   sub      = (const int*)d_in[44];
  const int*   obj      = (const int*)d_in[45];
  (void)in_sizes; (void)n_in; (void)out_size; (void)ws_size;

  char* base = (char*)d_ws;
  size_t off = 0;
  auto alloc = [&](size_t bytes) -> void* {
    void* p = base + off;
    off += (bytes + 255) & ~(size_t)255;
    return p;
  };

  // ---- weights (bf16) ----
  unsigned short* objhid_Wb  = (unsigned short*)alloc(512L  * 4480 * 2);
  unsigned short* pairup_Wb  = (unsigned short*)alloc(1024L * 4864 * 2);
  unsigned short* objfin_Wb  = (unsigned short*)alloc(2048L * 4864 * 2);
  unsigned short* up_Wtb     = (unsigned short*)alloc(4096L * 2048 * 2);
  unsigned short* pairfin_Wb = (unsigned short*)alloc(2048L * 1024 * 2);
  unsigned short* spt1_Wb    = (unsigned short*)alloc(512L  * 64   * 2);
  unsigned short* spt2_Wb    = (unsigned short*)alloc(1024L * 512  * 2);
  unsigned short* objU_Wb    = (unsigned short*)alloc(512L  * 2048 * 2);
  unsigned short* edgeU_Wb   = (unsigned short*)alloc(512L  * 2048 * 2);
  unsigned short* egru_Wihb  = (unsigned short*)alloc(1536L * 512  * 2);
  unsigned short* egru_Whhb  = (unsigned short*)alloc(1536L * 512  * 2);
  unsigned short* ngru_Wihb  = (unsigned short*)alloc(1536L * 512  * 2);
  unsigned short* ngru_Whhb  = (unsigned short*)alloc(1536L * 512  * 2);
  unsigned short* W_compb    = (unsigned short*)alloc(512L  * 4096 * 2);
  float*          b_comp     = (float*)alloc(512L * 4);
  float*          zbias      = (float*)alloc(4096L * 4);

  // ---- activations ----
  float*          obox      = (float*)alloc(NOBJ * 8L * 4);
  float*          pose      = (float*)alloc(NOBJ * 128L * 4);
  unsigned short* obj_featsb= (unsigned short*)alloc((long)NOBJ * 2048 * 2);
  unsigned short* obj_repb  = (unsigned short*)alloc((long)NOBJ * 512 * 2);
  unsigned short* giv       = (unsigned short*)alloc((long)NOBJ * 1536 * 2);
  unsigned short* ghv       = (unsigned short*)alloc((long)NOBJ * 1536 * 2);
  unsigned short* VWb       = (unsigned short*)alloc((long)NOBJ * 1536 * 2);
  float*          vert      = (float*)alloc((long)NOBJ * 512 * 4);
  unsigned short* vertb     = (unsigned short*)alloc((long)NOBJ * 512 * 2);
  unsigned short* ctxb      = (unsigned short*)alloc((long)NOBJ * 512 * 2);
  unsigned short* geob      = (unsigned short*)alloc((long)NREL * 64 * 2);
  float*          edge      = (float*)alloc((long)NREL * 512 * 4);
  unsigned short* edgeb     = (unsigned short*)alloc((long)NREL * 512 * 2);
  float*          ws_arr    = (float*)alloc((long)NREL * 4);
  float*          wo_arr    = (float*)alloc((long)NREL * 4);

  // CSR
  int* cnt   = (int*)alloc(NOBJ * 4);
  int* coff  = (int*)alloc((NOBJ + 1) * 4);
  int* rcur  = (int*)alloc(NOBJ * 4);
  int* lists = (int*)alloc(2L * NREL * 4);

  // REGION_A: X1b -> T1 (f32 64MB)
  char* regA = (char*)alloc((long)NREL * 512 * 4);
  unsigned short* X1b = (unsigned short*)regA;
  float*          T1  = (float*)regA;
  // REGION_B: augb -> rel_repb
  char* regB = (char*)alloc((long)NOBJ * 4864 * 2 > (long)NREL * 512 * 2
                            ? (long)NOBJ * 4864 * 2 : (long)NREL * 512 * 2);
  unsigned short* augb     = (unsigned short*)regB;
  unsigned short* rel_repb = (unsigned short*)regB;
  unsigned short* fusedb = (unsigned short*)alloc((long)NOBJ * 1024 * 2);
  unsigned short* spt1b  = (unsigned short*)alloc((long)NREL * 512 * 2);
  // BIG1: [G1 128MB | prodb 64MB] -> gi_e(init) -> GH (96MB per loop iter)
  char* big1 = (char*)alloc((long)NREL * 1536 * 4);
  unsigned short* G1    = (unsigned short*)big1;
  unsigned short* prodb = (unsigned short*)(big1 + (long)NREL * 1024 * 4);
  unsigned short* gi_e  = (unsigned short*)big1;
  unsigned short* GHb   = (unsigned short*)big1;

  float* d_out_vert = (float*)d_out;
  float* d_out_edge = (float*)d_out + (long)NOBJ * 512;

  // ---- weight conversions ----
  cvt_pad4<<<nblk(512L*4480/4),  256, 0, stream>>>(objhid_W,  objhid_Wb,  512,  4424, 4480);
  cvt_pad4<<<nblk(1024L*4864/4), 256, 0, stream>>>(pairup_W,  pairup_Wb,  1024, 4808, 4864);
  cvt_pad4<<<nblk(2048L*4864/4), 256, 0, stream>>>(objfin_W,  objfin_Wb,  2048, 4808, 4864);
  cvt_pad4<<<nblk(512L*64/4),    256, 0, stream>>>(spt1_W,    spt1_Wb,    512,  32,   64);
  cvt4<<<nblk(2048L*1024/4), 256, 0, stream>>>(pairfin_W, pairfin_Wb, 2048L*1024/4);
  cvt4<<<nblk(1024L*512/4),  256, 0, stream>>>(spt2_W,    spt2_Wb,    1024L*512/4);
  cvt4<<<nblk(512L*2048/4),  256, 0, stream>>>(objU_W,    objU_Wb,    512L*2048/4);
  cvt4<<<nblk(512L*2048/4),  256, 0, stream>>>(edgeU_W,   edgeU_Wb,   512L*2048/4);
  cvt4<<<nblk(1536L*512/4),  256, 0, stream>>>(egru_Wih,  egru_Wihb,  1536L*512/4);
  cvt4<<<nblk(1536L*512/4),  256, 0, stream>>>(egru_Whh,  egru_Whhb,  1536L*512/4);
  cvt4<<<nblk(1536L*512/4),  256, 0, stream>>>(ngru_Wih,  ngru_Wihb,  1536L*512/4);
  cvt4<<<nblk(1536L*512/4),  256, 0, stream>>>(ngru_Whh,  ngru_Whhb,  1536L*512/4);
  transpose_cvt<<<dim3(4096/32, 2048/32), dim3(32, 8), 0, stream>>>(up_W, up_Wtb, 2048, 4096);
  hipMemsetAsync(zbias, 0, 4096L * 4, stream);
  comp_bias<<<128, 256, 0, stream>>>(edgeU_W, up_b, edgeU_b, b_comp);
  GEMM(0,false,true,false, dim3((512>>7)*(4096>>7)), edgeU_Wb, up_Wtb, zbias, nullptr, W_compb, 512, 4096, 2048, 2048, 4096, nullptr, nullptr, nullptr);

  // ---- CSR build ----
  hipMemsetAsync(cnt, 0, NOBJ * 4, stream);
  hipMemsetAsync(rcur, 0, NOBJ * 4, stream);
  csr_count<<<NREL/256, 256, 0, stream>>>(sub, obj, cnt);
  csr_scan<<<1, 1024, 0, stream>>>(cnt, coff);
  csr_fill<<<NREL/256, 256, 0, stream>>>(sub, obj, coff, rcur, lists);

  // ---- object stream (128^2 engine) ----
  obox_k<<<(NOBJ + 255) / 256, 256, 0, stream>>>(boxes, obox);
  posembed_k<<<NOBJ, 128, 0, stream>>>(boxes, pos1_W, pos1_b, bn_g, bn_b, bn_m, bn_v,
                                       pos2_W, pos2_b, pose);
  build_x1<<<nblk((long)NOBJ*560), 256, 0, stream>>>(inst, embd_W, labels, pose, X1b);
  build_aug<<<nblk((long)NOBJ*608), 256, 0, stream>>>(embl_W, labels, inst, augb);
  GEMM(0,false,true ,false, dim3((NOBJ>>7)*(512>>7)),  X1b, objhid_Wb, objhid_b, nullptr, augb + 4296, NOBJ, 512, 4480, 4480, 4864, nullptr, nullptr, nullptr);
  GEMM(0,false,true ,false, dim3((NOBJ>>7)*(1024>>7)), augb, pairup_Wb, pairup_b, nullptr, fusedb, NOBJ, 1024, 4864, 4864, 1024, nullptr, nullptr, nullptr);
  GEMM(1,false,true ,false, dim3((NOBJ>>7)*(2048>>7)), augb, objfin_Wb, objfin_b, nullptr, obj_featsb, NOBJ, 2048, 4864, 4864, 2048, nullptr, nullptr, nullptr);
  GEMM(0,false,true ,false, dim3((NOBJ>>7)*(512>>7)),  obj_featsb, objU_Wb, objU_b, nullptr, obj_repb, NOBJ, 512, 2048, 2048, 512, nullptr, nullptr, nullptr);
  GEMM(0,false,true ,false, dim3((NOBJ>>7)*(1536>>7)), obj_repb, ngru_Wihb, ngru_bih, nullptr, giv, NOBJ, 1536, 512, 512, 1536, nullptr, nullptr, nullptr);
  gru_init<<<nblk((long)NOBJ*64), 256, 0, stream>>>(giv, ngru_bhh, vert, vertb, 512, NOBJ);

  // ---- relation stream ----
  build_geo<<<(NREL + 255) / 256, 256, 0, stream>>>(obox, sub, obj, geob);
  GEMM(1,false,true ,false, dim3((NREL>>7)*(512>>7)),  geob, spt1_Wb, spt1_b, nullptr, spt1b, NREL, 512, 64, 64, 512, nullptr, nullptr, nullptr);
  G256(1,false,true , spt1b, spt2_Wb, spt2_b, nullptr, prodb, NREL, 1024, 512, 512, 1024, fusedb, sub, obj);
  G256(1,false,false, prodb, pairfin_Wb, pairfin_b, nullptr, G1, NREL, 2048, 1024, 1024, 2048, nullptr, nullptr, nullptr);
  GEMMF(0,false,false, dim3((NREL>>7)*(512>>7)), unionf, W_compb, b_comp, nullptr, T1, NREL, 512, 4096, 4096, 512);
  G256(2,true ,false, G1, edgeU_Wb, zbias, T1, rel_repb, NREL, 512, 2048, 2048, 512, nullptr, nullptr, nullptr);
  G256(0,false,false, rel_repb, egru_Wihb, egru_bih, nullptr, gi_e, NREL, 1536, 512, 512, 1536, nullptr, nullptr, nullptr);
  gru_init<<<nblk((long)NREL*64), 256, 0, stream>>>(gi_e, egru_bhh, edge, edgeb, 512, NREL);

  // ---- message-passing loop ----
  for (int it = 0; it < 3; it++) {
    const bool last = (it == 2);
    edge_weights<<<(NREL * 64) / 256, 256, 0, stream>>>(vertb, edgeb, sub, obj,
                                                        svw_W, svw_b, ovw_W, ovw_b, ws_arr, wo_arr);
    ctx_gather<<<NOBJ, 128, 0, stream>>>(edgeb, ws_arr, wo_arr, coff, lists, ctxb);
    // VW = vertb @ eWih^T (no bias; bih added in gru_step_e2)
    GEMM(0,false,true,false, dim3((NOBJ>>7)*(1536>>7)), vertb, egru_Wihb, zbias, nullptr, VWb, NOBJ, 1536, 512, 512, 1536, nullptr, nullptr, nullptr);
    // GH = edgeb @ eWhh^T + bhh
    G256(0,false,false, edgeb, egru_Whhb, egru_bhh, nullptr, GHb, NREL, 1536, 512, 512, 1536, nullptr, nullptr, nullptr);
    // vertex gates
    GEMM(0,false,true,false, dim3((NOBJ>>7)*(1536>>7)), ctxb,  ngru_Wihb, ngru_bih, nullptr, giv, NOBJ, 1536, 512, 512, 1536, nullptr, nullptr, nullptr);
    GEMM(0,false,true,false, dim3((NOBJ>>7)*(1536>>7)), vertb, ngru_Whhb, ngru_bhh, nullptr, ghv, NOBJ, 1536, 512, 512, 1536, nullptr, nullptr, nullptr);
    gru_step_e2<<<nblk((long)NREL*64), 256, 0, stream>>>(GHb, VWb, ws_arr, wo_arr, sub, obj,
                                                         egru_bih, edge, last ? d_out_edge : edge, edgeb, NREL);
    gru_step_v<<<nblk((long)NOBJ*64), 256, 0, stream>>>(giv, ghv, vert, last ? d_out_vert : vert, vertb, NOBJ);
  }
}

// Round 8
// 1935.576 us; speedup vs baseline: 2.4605x; 1.0404x over previous
//
#include <hip/hip_runtime.h>
#include <stdint.h>

#define NOBJ 2048
#define NREL 32768

typedef __attribute__((ext_vector_type(8))) short short8;
typedef __attribute__((ext_vector_type(4))) float f32x4;
typedef __attribute__((ext_vector_type(4))) unsigned short ushort4v;

__device__ __forceinline__ unsigned short f2bs(float x){
  unsigned u = __float_as_uint(x);
  unsigned v = u + 0x7fffu + ((u >> 16) & 1u);
  return (unsigned short)(v >> 16);
}
__device__ __forceinline__ float b2f(unsigned short u){
  return __uint_as_float(((unsigned)u) << 16);
}
__device__ __forceinline__ float sigf(float x){ return 1.0f / (1.0f + expf(-x)); }

// async global->LDS, 16B per lane. LDS dest = wave-uniform base + lane*16.
__device__ __forceinline__ void gload16(const unsigned short* g, unsigned short* l) {
  __builtin_amdgcn_global_load_lds(
      (const __attribute__((address_space(1))) unsigned int*)(uintptr_t)g,
      (__attribute__((address_space(3))) unsigned int*)(uintptr_t)l,
      16, 0, 0);
}

__device__ __forceinline__ short8 cvt8(const float* p) {
  f32x4 a = *(const f32x4*)p;
  f32x4 b = *(const f32x4*)(p + 4);
  short8 r;
  r[0]=(short)f2bs(a[0]); r[1]=(short)f2bs(a[1]); r[2]=(short)f2bs(a[2]); r[3]=(short)f2bs(a[3]);
  r[4]=(short)f2bs(b[0]); r[5]=(short)f2bs(b[1]); r[6]=(short)f2bs(b[2]); r[7]=(short)f2bs(b[3]);
  return r;
}

// ============ 128x128 BK=64 engine: 32 MFMA per barrier pair, 32 KiB LDS ============
// A: MxK(lda) bf16 (gload_lds) or f32 (AF32: reg-staged cvt, swizzled ds_write).
// B: NxK bf16 packed. LDS [128][64]; slot s of row r holds global slot s^(r&7)
// (both-sides swizzle, rule #21); read xor = lrow&7 -> 2 lanes/bank (free, m136).
// RMODE: 0 none; 1 relu [then PRODF]; 2 relu(acc+bias+Cin). ACCUM: +Cin (f32, stride N).
template<int RMODE, bool ACCUM, bool OUTB, bool PRODF, bool AF32>
__global__ __launch_bounds__(256, 2)
void gemm_bt(const void* __restrict__ Ap, const unsigned short* __restrict__ B,
             const float* __restrict__ bias, const float* __restrict__ Cin,
             void* __restrict__ Cp, int M, int N, int K, int lda, int ldc,
             const unsigned short* __restrict__ fusedp,
             const int* __restrict__ subp, const int* __restrict__ objp)
{
  __shared__ __align__(16) unsigned short As[128 * 64];
  __shared__ __align__(16) unsigned short Bs[128 * 64];
  const int t = threadIdx.x;
  const int lane = t & 63;
  const int w = t >> 6;
  // XCD bijective swizzle (m204)
  const int nwg = gridDim.x;
  const int q8 = nwg >> 3, r8 = nwg & 7;
  const int xcd = blockIdx.x & 7, bidx = blockIdx.x >> 3;
  const int wgid = (xcd < r8 ? xcd * (q8 + 1) : r8 * (q8 + 1) + (xcd - r8) * q8) + bidx;
  const int ntile = N >> 7;
  const int bm = wgid / ntile;
  const int bn = wgid - bm * ntile;
  const int m0 = bm << 7, n0 = bn << 7;
  const int wm = (w & 1) << 6, wn = (w >> 1) << 6;
  const int lrow = lane & 15, kg = lane >> 4;
  const int rx = lrow & 7;                    // read-side slot xor

  // gload staging: wave w, call q covers rows q*32 + w*8 + (lane>>3), slot lane&7,
  // source slot pre-swizzled by (lane>>3) == (row&7).
  const int srow8 = lane >> 3;
  const int sslot = ((lane & 7) ^ srow8) << 3;   // in shorts
  const unsigned short* Bg = B + (long)(n0 + w * 8 + srow8) * K + sslot;
  const long ldb32 = (long)32 * K;

  const unsigned short* Ag = nullptr;
  const float* afp = nullptr;
  int arow = 0, asb = 0;
  long lda32 = 0;
  if constexpr (AF32) {
    arow = t >> 1;
    asb = (t & 1) << 2;                         // base slot 0 or 4
    afp = (const float*)Ap + (long)(m0 + arow) * lda + ((t & 1) << 5);
  } else {
    Ag = (const unsigned short*)Ap + (long)(m0 + w * 8 + srow8) * lda + sslot;
    lda32 = (long)32 * lda;
  }

  f32x4 acc[4][4] = {};

  for (int k0 = 0; k0 < K; k0 += 64) {
#pragma unroll
    for (int q = 0; q < 4; q++)
      gload16(Bg + q * ldb32 + k0, Bs + (q * 32 + w * 8) * 64);
    if constexpr (AF32) {
      const float* ap = afp + k0;
      unsigned short* abase = As + arow * 64;
#pragma unroll
      for (int j = 0; j < 4; j++) {
        short8 v = cvt8(ap + j * 8);
        *(short8*)(abase + (((asb + j) ^ (arow & 7)) << 3)) = v;
      }
    } else {
#pragma unroll
      for (int q = 0; q < 4; q++)
        gload16(Ag + q * lda32 + k0, As + (q * 32 + w * 8) * 64);
    }
    __syncthreads();
    short8 afr[4][2], bfr[4][2];
#pragma unroll
    for (int i = 0; i < 4; i++) {
      const int ra = wm + i * 16 + lrow;
#pragma unroll
      for (int ks = 0; ks < 2; ks++)
        afr[i][ks] = *(const short8*)(As + ra * 64 + (((ks * 4 + kg) ^ rx) << 3));
    }
#pragma unroll
    for (int j = 0; j < 4; j++) {
      const int rb = wn + j * 16 + lrow;
#pragma unroll
      for (int ks = 0; ks < 2; ks++)
        bfr[j][ks] = *(const short8*)(Bs + rb * 64 + (((ks * 4 + kg) ^ rx) << 3));
    }
#pragma unroll
    for (int i = 0; i < 4; i++)
#pragma unroll
      for (int j = 0; j < 4; j++)
#pragma unroll
        for (int ks = 0; ks < 2; ks++)
          acc[i][j] = __builtin_amdgcn_mfma_f32_16x16x32_bf16(afr[i][ks], bfr[j][ks], acc[i][j], 0, 0, 0);
    __syncthreads();
  }

  float* Cf = (float*)Cp;
  unsigned short* Cb = (unsigned short*)Cp;
#pragma unroll
  for (int i = 0; i < 4; i++) {
#pragma unroll
    for (int j = 0; j < 4; j++) {
      const int col = n0 + wn + j * 16 + lrow;
      const float bv = bias[col];
#pragma unroll
      for (int q = 0; q < 4; q++) {
        const long row = m0 + wm + i * 16 + kg * 4 + q;
        float v = acc[i][j][q] + bv;
        if constexpr (RMODE == 1) v = fmaxf(v, 0.0f);
        if constexpr (PRODF) {
          int gr = (col < 512) ? subp[row] : objp[row];
          v *= b2f(fusedp[(long)gr * 1024 + col]);
        }
        if constexpr (ACCUM) v += Cin[row * (long)N + col];
        if constexpr (RMODE == 2) v = fmaxf(v, 0.0f);
        if constexpr (OUTB) Cb[row * (long)ldc + col] = f2bs(v);
        else Cf[row * (long)ldc + col] = v;
      }
    }
  }
}

// ===================== small kernels =====================

__global__ void cvt_pad4(const float* __restrict__ src, unsigned short* __restrict__ dst,
                         int rows, int K0, int Kp)
{
  const int kp4 = Kp >> 2;
  const long total = (long)rows * kp4;
  for (long i = blockIdx.x * (long)blockDim.x + threadIdx.x; i < total; i += (long)gridDim.x * blockDim.x) {
    int r = (int)(i / kp4), k = (int)(i - (long)r * kp4) << 2;
    ushort4v o;
    if (k < K0) {
      f32x4 v = *(const f32x4*)(src + (long)r * K0 + k);
      o[0] = f2bs(v[0]); o[1] = f2bs(v[1]); o[2] = f2bs(v[2]); o[3] = f2bs(v[3]);
    } else {
      o[0] = 0; o[1] = 0; o[2] = 0; o[3] = 0;
    }
    *(ushort4v*)(dst + (long)r * Kp + k) = o;
  }
}

__global__ void cvt4(const float* __restrict__ src, unsigned short* __restrict__ dst, long n4)
{
  for (long i = blockIdx.x * (long)blockDim.x + threadIdx.x; i < n4; i += (long)gridDim.x * blockDim.x) {
    f32x4 v = ((const f32x4*)src)[i];
    ushort4v o;
    o[0] = f2bs(v[0]); o[1] = f2bs(v[1]); o[2] = f2bs(v[2]); o[3] = f2bs(v[3]);
    ((ushort4v*)dst)[i] = o;
  }
}

__global__ void transpose_cvt(const float* __restrict__ src, unsigned short* __restrict__ dst,
                              int R, int C)
{
  __shared__ float tile[32][33];
  int c0 = blockIdx.x * 32, r0 = blockIdx.y * 32;
  for (int i = threadIdx.y; i < 32; i += 8)
    tile[i][threadIdx.x] = src[(long)(r0 + i) * C + c0 + threadIdx.x];
  __syncthreads();
  for (int i = threadIdx.y; i < 32; i += 8)
    dst[(long)(c0 + i) * R + r0 + threadIdx.x] = f2bs(tile[threadIdx.x][i]);
}

__global__ void comp_bias(const float* __restrict__ edgeU_W, const float* __restrict__ up_b,
                          const float* __restrict__ edgeU_b, float* __restrict__ b_comp)
{
  int j = (int)((blockIdx.x * (long)blockDim.x + threadIdx.x) >> 6);
  int l = threadIdx.x & 63;
  if (j >= 512) return;
  float s = 0.0f;
  for (int k = l; k < 2048; k += 64) s += edgeU_W[(long)j * 2048 + k] * up_b[k];
#pragma unroll
  for (int off = 32; off > 0; off >>= 1) s += __shfl_xor(s, off);
  if (l == 0) b_comp[j] = s + edgeU_b[j];
}

// vgbias[j] = j<1536 ? 0 : ngru_bhh[j-1536]
__global__ void bias_cat(const float* __restrict__ bhh, float* __restrict__ out)
{
  int j = blockIdx.x * blockDim.x + threadIdx.x;
  if (j < 3072) out[j] = (j < 1536) ? 0.0f : bhh[j - 1536];
}

__global__ void obox_k(const float* __restrict__ boxes, float* __restrict__ obox)
{
  int i = blockIdx.x * blockDim.x + threadIdx.x;
  if (i >= NOBJ) return;
  float x1 = boxes[i*4], y1 = boxes[i*4+1], x2 = boxes[i*4+2], y2 = boxes[i*4+3];
  float wdt = x2 - x1 + 1.0f, hgt = y2 - y1 + 1.0f;
  float cx = x1 + 0.5f * wdt, cy = y1 + 0.5f * hgt;
  const float inv = 1.0f / 1024.0f;
  float* o = obox + i * 8;
  o[0]=x1*inv; o[1]=y1*inv; o[2]=x2*inv; o[3]=y2*inv;
  o[4]=cx*inv; o[5]=cy*inv; o[6]=wdt*inv; o[7]=hgt*inv;
}

__global__ void posembed_k(const float* __restrict__ boxes,
                           const float* __restrict__ w1, const float* __restrict__ b1,
                           const float* __restrict__ g, const float* __restrict__ bb,
                           const float* __restrict__ mm, const float* __restrict__ vv,
                           const float* __restrict__ w2, const float* __restrict__ b2,
                           float* __restrict__ out)
{
  int o = blockIdx.x, t = threadIdx.x;
  __shared__ float e[9];
  __shared__ float p[32];
  if (t == 0) {
    float x1 = boxes[o*4], y1 = boxes[o*4+1], x2 = boxes[o*4+2], y2 = boxes[o*4+3];
    float wdt = x2 - x1 + 1.0f, hgt = y2 - y1 + 1.0f;
    float cx = x1 + 0.5f * wdt, cy = y1 + 0.5f * hgt;
    e[0]=wdt/1024.0f; e[1]=hgt/768.0f; e[2]=cx/1024.0f; e[3]=cy/768.0f;
    e[4]=x1/1024.0f;  e[5]=y1/768.0f;  e[6]=x2/1024.0f; e[7]=y2/768.0f;
    e[8]=wdt*hgt/(1024.0f*768.0f);
  }
  __syncthreads();
  if (t < 32) {
    float s = b1[t];
#pragma unroll
    for (int j = 0; j < 9; j++) s += w1[t*9+j] * e[j];
    s = (s - mm[t]) * g[t] / sqrtf(vv[t] + 1e-5f) + bb[t];
    p[t] = s;
  }
  __syncthreads();
  float s = b2[t];
#pragma unroll
  for (int j = 0; j < 32; j++) s += w2[t*32+j] * p[j];
  out[o*128 + t] = fmaxf(s, 0.0f);
}

__device__ __forceinline__ void pack8_store(unsigned short* dst, f32x4 a, f32x4 b)
{
  ushort4v o0, o1;
  o0[0]=f2bs(a[0]); o0[1]=f2bs(a[1]); o0[2]=f2bs(a[2]); o0[3]=f2bs(a[3]);
  o1[0]=f2bs(b[0]); o1[1]=f2bs(b[1]); o1[2]=f2bs(b[2]); o1[3]=f2bs(b[3]);
  *(ushort4v*)dst = o0;
  *(ushort4v*)(dst + 4) = o1;
}

__global__ void build_x1(const float* __restrict__ inst, const float* __restrict__ embd,
                         const int* __restrict__ labels, const float* __restrict__ pose,
                         unsigned short* __restrict__ X1b)
{
  const long total = (long)NOBJ * 560;
  for (long i = blockIdx.x * (long)blockDim.x + threadIdx.x; i < total; i += (long)gridDim.x * blockDim.x) {
    int r = (int)(i / 560), c = ((int)(i - (long)r * 560)) << 3;
    unsigned short* dst = X1b + (long)r * 4480 + c;
    const float* src;
    if (c < 4096)      src = inst + (long)r * 4096 + c;
    else if (c < 4296) src = embd + (long)labels[r] * 200 + (c - 4096);
    else if (c < 4424) src = pose + r * 128 + (c - 4296);
    else { ushort4v z = {0,0,0,0}; *(ushort4v*)dst = z; *(ushort4v*)(dst+4) = z; continue; }
    pack8_store(dst, *(const f32x4*)src, *((const f32x4*)src + 1));
  }
}

__global__ void build_aug(const float* __restrict__ embl, const int* __restrict__ labels,
                          const float* __restrict__ inst, unsigned short* __restrict__ augb)
{
  const long total = (long)NOBJ * 608;
  for (long i = blockIdx.x * (long)blockDim.x + threadIdx.x; i < total; i += (long)gridDim.x * blockDim.x) {
    int r = (int)(i / 608), c = ((int)(i - (long)r * 608)) << 3;
    if (c >= 4296 && c < 4808) continue;
    unsigned short* dst = augb + (long)r * 4864 + c;
    const float* src;
    if (c < 200)       src = embl + (long)labels[r] * 200 + c;
    else if (c < 4296) src = inst + (long)r * 4096 + (c - 200);
    else { ushort4v z = {0,0,0,0}; *(ushort4v*)dst = z; *(ushort4v*)(dst+4) = z; continue; }
    pack8_store(dst, *(const f32x4*)src, *((const f32x4*)src + 1));
  }
}

__global__ void build_geo(const float* __restrict__ obox, const int* __restrict__ sub,
                          const int* __restrict__ obj, unsigned short* __restrict__ geob)
{
  int r = blockIdx.x * blockDim.x + threadIdx.x;
  if (r >= NREL) return;
  const float* b1 = obox + sub[r] * 8;
  const float* b2 = obox + obj[r] * 8;
  float o[32];
#pragma unroll
  for (int j = 0; j < 8; j++) { o[j] = b1[j]; o[8+j] = b2[j]; }
  float ux1 = fminf(b1[0], b2[0]), uy1 = fminf(b1[1], b2[1]);
  float ux2 = fmaxf(b1[2], b2[2]), uy2 = fmaxf(b1[3], b2[3]);
  float uw = ux2 - ux1 + 1.0f, uh = uy2 - uy1 + 1.0f;
  o[16]=ux1; o[17]=uy1; o[18]=ux2; o[19]=uy2;
  o[20]=ux1+0.5f*uw; o[21]=uy1+0.5f*uh; o[22]=uw; o[23]=uh;
  float ix1 = fmaxf(b1[0], b2[0]), iy1 = fmaxf(b1[1], b2[1]);
  float ix2 = fminf(b1[2], b2[2]), iy2 = fminf(b1[3], b2[3]);
  bool bad = (ix2 < ix1) || (iy2 < iy1);
  float iw = ix2 - ix1 + 1.0f, ih = iy2 - iy1 + 1.0f;
  if (bad) {
#pragma unroll
    for (int j = 24; j < 32; j++) o[j] = 0.0f;
  } else {
    o[24]=ix1; o[25]=iy1; o[26]=ix2; o[27]=iy2;
    o[28]=ix1+0.5f*iw; o[29]=iy1+0.5f*ih; o[30]=iw; o[31]=ih;
  }
  unsigned short* gp = geob + (long)r * 64;
#pragma unroll
  for (int j = 0; j < 32; j++) gp[j] = f2bs(o[j]);
#pragma unroll
  for (int j = 32; j < 64; j++) gp[j] = 0;
}

// vertex GRU init: h f32 + bf16 mirror
__global__ void gru_init_v(const unsigned short* __restrict__ gi, const float* __restrict__ bhh,
                           float* __restrict__ h, unsigned short* __restrict__ hb, int n)
{
  const long total = (long)n * 64;
  for (long i = blockIdx.x * (long)blockDim.x + threadIdx.x; i < total; i += (long)gridDim.x * blockDim.x) {
    int r = (int)(i >> 6), c = ((int)(i & 63)) << 3;
    const unsigned short* gr = gi + (long)r * 1536;
    short8 vr = *(const short8*)(gr + c);
    short8 vz = *(const short8*)(gr + 512 + c);
    short8 vn = *(const short8*)(gr + 1024 + c);
    float hv[8];
#pragma unroll
    for (int k = 0; k < 8; k++) {
      float rr = sigf(b2f((unsigned short)vr[k]) + bhh[c + k]);
      float z  = sigf(b2f((unsigned short)vz[k]) + bhh[512 + c + k]);
      float nn = tanhf(b2f((unsigned short)vn[k]) + rr * bhh[1024 + c + k]);
      hv[k] = (1.0f - z) * nn;
    }
    float* hp = h + (long)r * 512 + c;
    *(f32x4*)hp = *(f32x4*)hv;
    *(f32x4*)(hp + 4) = *(f32x4*)(hv + 4);
    pack8_store(hb + (long)r * 512 + c, *(f32x4*)hv, *(f32x4*)(hv + 4));
  }
}

// edge GRU init: bf16 state only
__global__ void gru_init_e(const unsigned short* __restrict__ gi, const float* __restrict__ bhh,
                           unsigned short* __restrict__ hb, int n)
{
  const long total = (long)n * 64;
  for (long i = blockIdx.x * (long)blockDim.x + threadIdx.x; i < total; i += (long)gridDim.x * blockDim.x) {
    int r = (int)(i >> 6), c = ((int)(i & 63)) << 3;
    const unsigned short* gr = gi + (long)r * 1536;
    short8 vr = *(const short8*)(gr + c);
    short8 vz = *(const short8*)(gr + 512 + c);
    short8 vn = *(const short8*)(gr + 1024 + c);
    float hv[8];
#pragma unroll
    for (int k = 0; k < 8; k++) {
      float rr = sigf(b2f((unsigned short)vr[k]) + bhh[c + k]);
      float z  = sigf(b2f((unsigned short)vz[k]) + bhh[512 + c + k]);
      float nn = tanhf(b2f((unsigned short)vn[k]) + rr * bhh[1024 + c + k]);
      hv[k] = (1.0f - z) * nn;
    }
    pack8_store(hb + (long)r * 512 + c, *(f32x4*)hv, *(f32x4*)(hv + 4));
  }
}

// vertex GRU step: gi stride 1536, gh stride ghs (VG layout), vert f32 io + bf16 mirror.
__global__ void gru_step_v(const unsigned short* __restrict__ gi, const unsigned short* __restrict__ gh,
                           int ghs, const float* __restrict__ hin, float* __restrict__ hout,
                           unsigned short* __restrict__ hb, int n)
{
  const long total = (long)n * 64;
  for (long i = blockIdx.x * (long)blockDim.x + threadIdx.x; i < total; i += (long)gridDim.x * blockDim.x) {
    int r = (int)(i >> 6), c = ((int)(i & 63)) << 3;
    const unsigned short* gr = gi + (long)r * 1536;
    const unsigned short* hr = gh + (long)r * ghs;
    short8 ir = *(const short8*)(gr + c);
    short8 iz = *(const short8*)(gr + 512 + c);
    short8 in_ = *(const short8*)(gr + 1024 + c);
    short8 hrr = *(const short8*)(hr + c);
    short8 hz = *(const short8*)(hr + 512 + c);
    short8 hn = *(const short8*)(hr + 1024 + c);
    const float* hi = hin + (long)r * 512 + c;
    f32x4 h0 = *(const f32x4*)hi;
    f32x4 h1 = *(const f32x4*)(hi + 4);
    float hv[8];
#pragma unroll
    for (int k = 0; k < 8; k++) {
      float rr = sigf(b2f((unsigned short)ir[k]) + b2f((unsigned short)hrr[k]));
      float z  = sigf(b2f((unsigned short)iz[k]) + b2f((unsigned short)hz[k]));
      float nn = tanhf(b2f((unsigned short)in_[k]) + rr * b2f((unsigned short)hn[k]));
      float old = (k < 4) ? h0[k] : h1[k - 4];
      hv[k] = (1.0f - z) * nn + z * old;
    }
    float* hp = hout + (long)r * 512 + c;
    *(f32x4*)hp = *(f32x4*)hv;
    *(f32x4*)(hp + 4) = *(f32x4*)(hv + 4);
    pack8_store(hb + (long)r * 512 + c, *(f32x4*)hv, *(f32x4*)(hv + 4));
  }
}

// edge GRU step + fused next-iter ws/wo. One wave == one relation (64 lanes x 8 cols).
// gi = ws*VG[sub] + wo*VG[obj] + bih (VG stride 3072); gh = GH (incl bhh, stride 1536).
// h state bf16 in edgeb (in-place); optional f32 out; optional next ws/wo (needs NEW vertb).
__global__ __launch_bounds__(256)
void gru_step_e2(const unsigned short* __restrict__ GH, const unsigned short* __restrict__ VG,
                 const float* __restrict__ ws_arr_in, const float* __restrict__ wo_arr_in,
                 float* __restrict__ ws_arr_out, float* __restrict__ wo_arr_out,
                 const int* __restrict__ sub, const int* __restrict__ obj,
                 const float* __restrict__ bih,
                 unsigned short* __restrict__ edgeb, float* __restrict__ fout,
                 const unsigned short* __restrict__ vertb,
                 const float* __restrict__ svwW, const float* __restrict__ svwb,
                 const float* __restrict__ ovwW, const float* __restrict__ ovwb,
                 int compute_w, int n)
{
  long gid = blockIdx.x * 256L + threadIdx.x;
  int r = (int)(gid >> 6);
  int l = (int)(gid & 63);
  if (r >= n) return;
  const int c = l << 3;
  int s = sub[r], o = obj[r];
  float ws = ws_arr_in[r], wo = wo_arr_in[r];
  const unsigned short* gh = GH + (long)r * 1536;
  const unsigned short* vs = VG + (long)s * 3072;
  const unsigned short* vo = VG + (long)o * 3072;
  short8 ghr = *(const short8*)(gh + c);
  short8 ghz = *(const short8*)(gh + 512 + c);
  short8 ghn = *(const short8*)(gh + 1024 + c);
  short8 vsr = *(const short8*)(vs + c);
  short8 vsz = *(const short8*)(vs + 512 + c);
  short8 vsn = *(const short8*)(vs + 1024 + c);
  short8 vor_ = *(const short8*)(vo + c);
  short8 voz = *(const short8*)(vo + 512 + c);
  short8 von = *(const short8*)(vo + 1024 + c);
  short8 hold = *(const short8*)(edgeb + (long)r * 512 + c);
  float hv[8];
#pragma unroll
  for (int k = 0; k < 8; k++) {
    float gir = ws * b2f((unsigned short)vsr[k]) + wo * b2f((unsigned short)vor_[k]) + bih[c + k];
    float giz = ws * b2f((unsigned short)vsz[k]) + wo * b2f((unsigned short)voz[k]) + bih[512 + c + k];
    float gin = ws * b2f((unsigned short)vsn[k]) + wo * b2f((unsigned short)von[k]) + bih[1024 + c + k];
    float rr = sigf(gir + b2f((unsigned short)ghr[k]));
    float z  = sigf(giz + b2f((unsigned short)ghz[k]));
    float nn = tanhf(gin + rr * b2f((unsigned short)ghn[k]));
    hv[k] = (1.0f - z) * nn + z * b2f((unsigned short)hold[k]);
  }
  pack8_store(edgeb + (long)r * 512 + c, *(f32x4*)hv, *(f32x4*)(hv + 4));
  if (fout) {
    float* fp = fout + (long)r * 512 + c;
    *(f32x4*)fp = *(f32x4*)hv;
    *(f32x4*)(fp + 4) = *(f32x4*)(hv + 4);
  }
  if (compute_w) {
    short8 svv = *(const short8*)(vertb + (long)s * 512 + c);
    short8 ovv = *(const short8*)(vertb + (long)o * 512 + c);
    float as = 0.0f, ao = 0.0f;
#pragma unroll
    for (int k = 0; k < 8; k++) {
      float e = hv[k];
      as += svwW[c + k] * b2f((unsigned short)svv[k]) + svwW[512 + c + k] * e;
      ao += ovwW[c + k] * b2f((unsigned short)ovv[k]) + ovwW[512 + c + k] * e;
    }
#pragma unroll
    for (int off = 32; off > 0; off >>= 1) {
      as += __shfl_xor(as, off);
      ao += __shfl_xor(ao, off);
    }
    if (l == 0) {
      ws_arr_out[r] = sigf(as + svwb[0]);
      wo_arr_out[r] = sigf(ao + ovwb[0]);
    }
  }
}

// Standalone ws/wo (first iteration only)
__global__ __launch_bounds__(256)
void edge_weights(const unsigned short* __restrict__ vertb, const unsigned short* __restrict__ edgeb,
                  const int* __restrict__ sub, const int* __restrict__ obj,
                  const float* __restrict__ svwW, const float* __restrict__ svwb,
                  const float* __restrict__ ovwW, const float* __restrict__ ovwb,
                  float* __restrict__ ws_arr, float* __restrict__ wo_arr)
{
  long gid = blockIdx.x * 256L + threadIdx.x;
  int r = (int)(gid >> 6);
  int l = (int)(gid & 63);
  if (r >= NREL) return;
  int s = sub[r], o = obj[r];
  const unsigned short* sv = vertb + (long)s * 512;
  const unsigned short* ov = vertb + (long)o * 512;
  const unsigned short* e  = edgeb + (long)r * 512;
  float as = 0.0f, ao = 0.0f;
#pragma unroll
  for (int k = 0; k < 8; k++) {
    int c = l + k * 64;
    float svv = b2f(sv[c]), ovv = b2f(ov[c]), ev = b2f(e[c]);
    as += svwW[c] * svv + svwW[512 + c] * ev;
    ao += ovwW[c] * ovv + ovwW[512 + c] * ev;
  }
#pragma unroll
  for (int off = 32; off > 0; off >>= 1) {
    as += __shfl_xor(as, off);
    ao += __shfl_xor(ao, off);
  }
  if (l == 0) {
    ws_arr[r] = sigf(as + svwb[0]);
    wo_arr[r] = sigf(ao + ovwb[0]);
  }
}

// ===================== CSR =====================

__global__ void csr_count(const int* __restrict__ sub, const int* __restrict__ obj,
                          int* __restrict__ cnt)
{
  int r = blockIdx.x * blockDim.x + threadIdx.x;
  if (r >= NREL) return;
  atomicAdd(&cnt[sub[r]], 1);
  atomicAdd(&cnt[obj[r]], 1);
}

__global__ __launch_bounds__(1024)
void csr_scan(const int* __restrict__ cnt, int* __restrict__ off)
{
  __shared__ int a[1024], b[1024];
  int t = threadIdx.x;
  int c0 = cnt[2*t], c1 = cnt[2*t+1];
  a[t] = c0 + c1;
  __syncthreads();
  int* src = a; int* dst = b;
  for (int s = 1; s < 1024; s <<= 1) {
    int v = src[t];
    if (t >= s) v += src[t - s];
    dst[t] = v;
    __syncthreads();
    int* tmp = src; src = dst; dst = tmp;
  }
  int incl = src[t];
  int excl = incl - (c0 + c1);
  off[2*t] = excl;
  off[2*t+1] = excl + c0;
  if (t == 1023) off[2048] = incl;
}

__global__ void csr_fill(const int* __restrict__ sub, const int* __restrict__ obj,
                         const int* __restrict__ off, int* __restrict__ rcur,
                         int* __restrict__ lists)
{
  int r = blockIdx.x * blockDim.x + threadIdx.x;
  if (r >= NREL) return;
  int s = sub[r];
  int p = atomicAdd(&rcur[s], 1);
  lists[off[s] + p] = (r << 1);
  int o = obj[r];
  int q = atomicAdd(&rcur[o], 1);
  lists[off[o] + q] = (r << 1) | 1;
}

__global__ __launch_bounds__(128)
void ctx_gather(const unsigned short* __restrict__ edgeb, const float* __restrict__ ws,
                const float* __restrict__ wo, const int* __restrict__ off,
                const int* __restrict__ lists, unsigned short* __restrict__ ctxb)
{
  __shared__ float part[512];
  int o = blockIdx.x;
  int l = threadIdx.x & 63;
  int w = threadIdx.x >> 6;
  int i0 = off[o], i1 = off[o + 1];
  float acc[8] = {0.f,0.f,0.f,0.f,0.f,0.f,0.f,0.f};
  for (int i = i0 + w; i < i1; i += 2) {
    int e = lists[i];
    int r = e >> 1;
    float sc = (e & 1) ? wo[r] : ws[r];
    short8 row = *(const short8*)(edgeb + (long)r * 512 + l * 8);
#pragma unroll
    for (int k = 0; k < 8; k++) acc[k] += sc * b2f((unsigned short)row[k]);
  }
  if (w == 1) {
    *(f32x4*)&part[l*8]     = *(f32x4*)&acc[0];
    *(f32x4*)&part[l*8 + 4] = *(f32x4*)&acc[4];
  }
  __syncthreads();
  if (w == 0) {
#pragma unroll
    for (int k = 0; k < 8; k++) acc[k] += part[l*8 + k];
    pack8_store(ctxb + (long)o * 512 + l * 8, *(f32x4*)&acc[0], *(f32x4*)&acc[4]);
  }
}

// ===================== driver =====================

static inline int nblk(long total) {
  long b = (total + 255) / 256;
  return (int)(b > 16384 ? 16384 : b);
}

#define GEMM(RM, AC, OB, PF, grid, Aa, Bb, bb, Ci, Cc, Mm, Nn, Kk, ldA, ldC, fp, sp, op) \
  gemm_bt<RM, AC, OB, PF, false><<<grid, 256, 0, stream>>>(Aa, Bb, bb, Ci, Cc, Mm, Nn, Kk, ldA, ldC, fp, sp, op)
#define GEMMF(RM, AC, OB, grid, Aa, Bb, bb, Ci, Cc, Mm, Nn, Kk, ldA, ldC) \
  gemm_bt<RM, AC, OB, false, true><<<grid, 256, 0, stream>>>(Aa, Bb, bb, Ci, Cc, Mm, Nn, Kk, ldA, ldC, nullptr, nullptr, nullptr)

extern "C" void kernel_launch(void* const* d_in, const int* in_sizes, int n_in,
                              void* d_out, int out_size, void* d_ws, size_t ws_size,
                              hipStream_t stream)
{
  const float* inst     = (const float*)d_in[0];
  const float* unionf   = (const float*)d_in[1];
  const float* boxes    = (const float*)d_in[2];
  const float* embd_W   = (const float*)d_in[3];
  const float* embl_W   = (const float*)d_in[4];
  const float* up_W     = (const float*)d_in[5];
  const float* up_b     = (const float*)d_in[6];
  const float* pairup_W = (const float*)d_in[7];
  const float* pairup_b = (const float*)d_in[8];
  const float* pos1_W   = (const float*)d_in[9];
  const float* pos1_b   = (const float*)d_in[10];
  const float* bn_g     = (const float*)d_in[11];
  const float* bn_b     = (const float*)d_in[12];
  const float* bn_m     = (const float*)d_in[13];
  const float* bn_v     = (const float*)d_in[14];
  const float* pos2_W   = (const float*)d_in[15];
  const float* pos2_b   = (const float*)d_in[16];
  const float* spt1_W   = (const float*)d_in[17];
  const float* spt1_b   = (const float*)d_in[18];
  const float* spt2_W   = (const float*)d_in[19];
  const float* spt2_b   = (const float*)d_in[20];
  const float* pairfin_W= (const float*)d_in[21];
  const float* pairfin_b= (const float*)d_in[22];
  const float* objhid_W = (const float*)d_in[23];
  const float* objhid_b = (const float*)d_in[24];
  const float* objfin_W = (const float*)d_in[25];
  const float* objfin_b = (const float*)d_in[26];
  const float* objU_W   = (const float*)d_in[27];
  const float* objU_b   = (const float*)d_in[28];
  const float* edgeU_W  = (const float*)d_in[29];
  const float* edgeU_b  = (const float*)d_in[30];
  const float* egru_Wih = (const float*)d_in[31];
  const float* egru_Whh = (const float*)d_in[32];
  const float* egru_bih = (const float*)d_in[33];
  const float* egru_bhh = (const float*)d_in[34];
  const float* ngru_Wih = (const float*)d_in[35];
  const float* ngru_Whh = (const float*)d_in[36];
  const float* ngru_bih = (const float*)d_in[37];
  const float* ngru_bhh = (const float*)d_in[38];
  const float* svw_W    = (const float*)d_in[39];
  const float* svw_b    = (const float*)d_in[40];
  const float* ovw_W    = (const float*)d_in[41];
  const float* ovw_b    = (const float*)d_in[42];
  const int*   labels   = (const int*)d_in[43];
  const int*   sub      = (const int*)d_in[44];
  const int*   obj      = (const int*)d_in[45];
  (void)in_sizes; (void)n_in; (void)out_size; (void)ws_size;

  char* base = (char*)d_ws;
  size_t off = 0;
  auto alloc = [&](size_t bytes) -> void* {
    void* p = base + off;
    off += (bytes + 255) & ~(size_t)255;
    return p;
  };

  // ---- weights (bf16) ----
  unsigned short* objhid_Wb  = (unsigned short*)alloc(512L  * 4480 * 2);
  unsigned short* pairup_Wb  = (unsigned short*)alloc(1024L * 4864 * 2);
  unsigned short* objfin_Wb  = (unsigned short*)alloc(2048L * 4864 * 2);
  unsigned short* up_Wtb     = (unsigned short*)alloc(4096L * 2048 * 2);
  unsigned short* pairfin_Wb = (unsigned short*)alloc(2048L * 1024 * 2);
  unsigned short* spt1_Wb    = (unsigned short*)alloc(512L  * 64   * 2);
  unsigned short* spt2_Wb    = (unsigned short*)alloc(1024L * 512  * 2);
  unsigned short* objU_Wb    = (unsigned short*)alloc(512L  * 2048 * 2);
  unsigned short* edgeU_Wb   = (unsigned short*)alloc(512L  * 2048 * 2);
  unsigned short* egru_Wihb  = (unsigned short*)alloc(1536L * 512  * 2);
  unsigned short* egru_Whhb  = (unsigned short*)alloc(1536L * 512  * 2);
  unsigned short* ngru_Wihb  = (unsigned short*)alloc(1536L * 512  * 2);
  unsigned short* vg_Wb      = (unsigned short*)alloc(3072L * 512  * 2);   // [egru_Wih ; ngru_Whh]
  unsigned short* W_compb    = (unsigned short*)alloc(512L  * 4096 * 2);
  float*          b_comp     = (float*)alloc(512L * 4);
  float*          zbias      = (float*)alloc(4096L * 4);
  float*          vgbias     = (float*)alloc(3072L * 4);

  // ---- activations ----
  float*          obox      = (float*)alloc(NOBJ * 8L * 4);
  float*          pose      = (float*)alloc(NOBJ * 128L * 4);
  unsigned short* obj_featsb= (unsigned short*)alloc((long)NOBJ * 2048 * 2);
  unsigned short* obj_repb  = (unsigned short*)alloc((long)NOBJ * 512 * 2);
  unsigned short* giv       = (unsigned short*)alloc((long)NOBJ * 1536 * 2);
  unsigned short* VGb       = (unsigned short*)alloc((long)NOBJ * 3072 * 2);  // [VW | gh_v]
  float*          vert      = (float*)alloc((long)NOBJ * 512 * 4);
  unsigned short* vertb     = (unsigned short*)alloc((long)NOBJ * 512 * 2);
  unsigned short* ctxb      = (unsigned short*)alloc((long)NOBJ * 512 * 2);
  unsigned short* geob      = (unsigned short*)alloc((long)NREL * 64 * 2);
  unsigned short* edgeb     = (unsigned short*)alloc((long)NREL * 512 * 2);
  float*          ws_arr    = (float*)alloc((long)NREL * 4);
  float*          wo_arr    = (float*)alloc((long)NREL * 4);

  // CSR
  int* cnt   = (int*)alloc(NOBJ * 4);
  int* coff  = (int*)alloc((NOBJ + 1) * 4);
  int* rcur  = (int*)alloc(NOBJ * 4);
  int* lists = (int*)alloc(2L * NREL * 4);

  // REGION_A: X1b -> T1 (f32 64MB)
  char* regA = (char*)alloc((long)NREL * 512 * 4);
  unsigned short* X1b = (unsigned short*)regA;
  float*          T1  = (float*)regA;
  // REGION_B: augb -> rel_repb
  char* regB = (char*)alloc((long)NOBJ * 4864 * 2 > (long)NREL * 512 * 2
                            ? (long)NOBJ * 4864 * 2 : (long)NREL * 512 * 2);
  unsigned short* augb     = (unsigned short*)regB;
  unsigned short* rel_repb = (unsigned short*)regB;
  unsigned short* fusedb = (unsigned short*)alloc((long)NOBJ * 1024 * 2);
  unsigned short* spt1b  = (unsigned short*)alloc((long)NREL * 512 * 2);
  // BIG1: [G1 128MB | prodb 64MB] -> gi_e(init) -> GH (96MB per loop iter)
  char* big1 = (char*)alloc((long)NREL * 1536 * 4);
  unsigned short* G1    = (unsigned short*)big1;
  unsigned short* prodb = (unsigned short*)(big1 + (long)NREL * 1024 * 4);
  unsigned short* gi_e  = (unsigned short*)big1;
  unsigned short* GHb   = (unsigned short*)big1;

  float* d_out_vert = (float*)d_out;
  float* d_out_edge = (float*)d_out + (long)NOBJ * 512;

  // ---- weight conversions ----
  cvt_pad4<<<nblk(512L*4480/4),  256, 0, stream>>>(objhid_W,  objhid_Wb,  512,  4424, 4480);
  cvt_pad4<<<nblk(1024L*4864/4), 256, 0, stream>>>(pairup_W,  pairup_Wb,  1024, 4808, 4864);
  cvt_pad4<<<nblk(2048L*4864/4), 256, 0, stream>>>(objfin_W,  objfin_Wb,  2048, 4808, 4864);
  cvt_pad4<<<nblk(512L*64/4),    256, 0, stream>>>(spt1_W,    spt1_Wb,    512,  32,   64);
  cvt4<<<nblk(2048L*1024/4), 256, 0, stream>>>(pairfin_W, pairfin_Wb, 2048L*1024/4);
  cvt4<<<nblk(1024L*512/4),  256, 0, stream>>>(spt2_W,    spt2_Wb,    1024L*512/4);
  cvt4<<<nblk(512L*2048/4),  256, 0, stream>>>(objU_W,    objU_Wb,    512L*2048/4);
  cvt4<<<nblk(512L*2048/4),  256, 0, stream>>>(edgeU_W,   edgeU_Wb,   512L*2048/4);
  cvt4<<<nblk(1536L*512/4),  256, 0, stream>>>(egru_Wih,  egru_Wihb,  1536L*512/4);
  cvt4<<<nblk(1536L*512/4),  256, 0, stream>>>(egru_Whh,  egru_Whhb,  1536L*512/4);
  cvt4<<<nblk(1536L*512/4),  256, 0, stream>>>(ngru_Wih,  ngru_Wihb,  1536L*512/4);
  cvt4<<<nblk(1536L*512/4),  256, 0, stream>>>(egru_Wih,  vg_Wb,               1536L*512/4);
  cvt4<<<nblk(1536L*512/4),  256, 0, stream>>>(ngru_Whh,  vg_Wb + 1536L*512,   1536L*512/4);
  bias_cat<<<12, 256, 0, stream>>>(ngru_bhh, vgbias);
  transpose_cvt<<<dim3(4096/32, 2048/32), dim3(32, 8), 0, stream>>>(up_W, up_Wtb, 2048, 4096);
  hipMemsetAsync(zbias, 0, 4096L * 4, stream);
  comp_bias<<<128, 256, 0, stream>>>(edgeU_W, up_b, edgeU_b, b_comp);
  GEMM(0,false,true,false, dim3((512>>7)*(4096>>7)), edgeU_Wb, up_Wtb, zbias, nullptr, W_compb, 512, 4096, 2048, 2048, 4096, nullptr, nullptr, nullptr);

  // ---- CSR build ----
  hipMemsetAsync(cnt, 0, NOBJ * 4, stream);
  hipMemsetAsync(rcur, 0, NOBJ * 4, stream);
  csr_count<<<NREL/256, 256, 0, stream>>>(sub, obj, cnt);
  csr_scan<<<1, 1024, 0, stream>>>(cnt, coff);
  csr_fill<<<NREL/256, 256, 0, stream>>>(sub, obj, coff, rcur, lists);

  // ---- object stream ----
  obox_k<<<(NOBJ + 255) / 256, 256, 0, stream>>>(boxes, obox);
  posembed_k<<<NOBJ, 128, 0, stream>>>(boxes, pos1_W, pos1_b, bn_g, bn_b, bn_m, bn_v,
                                       pos2_W, pos2_b, pose);
  build_x1<<<nblk((long)NOBJ*560), 256, 0, stream>>>(inst, embd_W, labels, pose, X1b);
  build_aug<<<nblk((long)NOBJ*608), 256, 0, stream>>>(embl_W, labels, inst, augb);
  GEMM(0,false,true ,false, dim3((NOBJ>>7)*(512>>7)),  X1b, objhid_Wb, objhid_b, nullptr, augb + 4296, NOBJ, 512, 4480, 4480, 4864, nullptr, nullptr, nullptr);
  GEMM(0,false,true ,false, dim3((NOBJ>>7)*(1024>>7)), augb, pairup_Wb, pairup_b, nullptr, fusedb, NOBJ, 1024, 4864, 4864, 1024, nullptr, nullptr, nullptr);
  GEMM(1,false,true ,false, dim3((NOBJ>>7)*(2048>>7)), augb, objfin_Wb, objfin_b, nullptr, obj_featsb, NOBJ, 2048, 4864, 4864, 2048, nullptr, nullptr, nullptr);
  GEMM(0,false,true ,false, dim3((NOBJ>>7)*(512>>7)),  obj_featsb, objU_Wb, objU_b, nullptr, obj_repb, NOBJ, 512, 2048, 2048, 512, nullptr, nullptr, nullptr);
  GEMM(0,false,true ,false, dim3((NOBJ>>7)*(1536>>7)), obj_repb, ngru_Wihb, ngru_bih, nullptr, giv, NOBJ, 1536, 512, 512, 1536, nullptr, nullptr, nullptr);
  gru_init_v<<<nblk((long)NOBJ*64), 256, 0, stream>>>(giv, ngru_bhh, vert, vertb, NOBJ);

  // ---- relation stream ----
  build_geo<<<(NREL + 255) / 256, 256, 0, stream>>>(obox, sub, obj, geob);
  GEMM(1,false,true ,false, dim3((NREL>>7)*(512>>7)),  geob, spt1_Wb, spt1_b, nullptr, spt1b, NREL, 512, 64, 64, 512, nullptr, nullptr, nullptr);
  GEMM(1,false,true ,true , dim3((NREL>>7)*(1024>>7)), spt1b, spt2_Wb, spt2_b, nullptr, prodb, NREL, 1024, 512, 512, 1024, fusedb, sub, obj);
  GEMM(1,false,true ,false, dim3((NREL>>7)*(2048>>7)), prodb, pairfin_Wb, pairfin_b, nullptr, G1, NREL, 2048, 1024, 1024, 2048, nullptr, nullptr, nullptr);
  GEMMF(0,false,false, dim3((NREL>>7)*(512>>7)), unionf, W_compb, b_comp, nullptr, T1, NREL, 512, 4096, 4096, 512);
  GEMM(2,true ,true ,false, dim3((NREL>>7)*(512>>7)),  G1, edgeU_Wb, zbias, T1, rel_repb, NREL, 512, 2048, 2048, 512, nullptr, nullptr, nullptr);
  GEMM(0,false,true ,false, dim3((NREL>>7)*(1536>>7)), rel_repb, egru_Wihb, egru_bih, nullptr, gi_e, NREL, 1536, 512, 512, 1536, nullptr, nullptr, nullptr);
  gru_init_e<<<nblk((long)NREL*64), 256, 0, stream>>>(gi_e, egru_bhh, edgeb, NREL);

  // initial ws/wo
  edge_weights<<<NREL*64/256, 256, 0, stream>>>(vertb, edgeb, sub, obj,
                                                svw_W, svw_b, ovw_W, ovw_b, ws_arr, wo_arr);

  // ---- message-passing loop ----
  for (int it = 0; it < 3; it++) {
    const bool last = (it == 2);
    ctx_gather<<<NOBJ, 128, 0, stream>>>(edgeb, ws_arr, wo_arr, coff, lists, ctxb);
    // VG = vertb @ [eWih ; nWhh]^T   (cols 0..1535 = VW, no bias; cols 1536.. = gh_v + bhh)
    GEMM(0,false,true,false, dim3((NOBJ>>7)*(3072>>7)), vertb, vg_Wb, vgbias, nullptr, VGb, NOBJ, 3072, 512, 512, 3072, nullptr, nullptr, nullptr);
    // GH = edgeb @ eWhh^T + bhh
    GEMM(0,false,true,false, dim3((NREL>>7)*(1536>>7)), edgeb, egru_Whhb, egru_bhh, nullptr, GHb, NREL, 1536, 512, 512, 1536, nullptr, nullptr, nullptr);
    // giv = ctxb @ nWih^T + bih
    GEMM(0,false,true,false, dim3((NOBJ>>7)*(1536>>7)), ctxb, ngru_Wihb, ngru_bih, nullptr, giv, NOBJ, 1536, 512, 512, 1536, nullptr, nullptr, nullptr);
    // vertex update first (gru_step_e2's fused ws/wo needs NEW vertb)
    gru_step_v<<<nblk((long)NOBJ*64), 256, 0, stream>>>(giv, VGb + 1536, 3072, vert,
                                                        last ? d_out_vert : vert, vertb, NOBJ);
    gru_step_e2<<<NREL*64/256, 256, 0, stream>>>(GHb, VGb, ws_arr, wo_arr, ws_arr, wo_arr,
                                                 sub, obj, egru_bih, edgeb,
                                                 last ? d_out_edge : nullptr, vertb,
                                                 svw_W, svw_b, ovw_W, ovw_b,
                                                 last ? 0 : 1, NREL);
  }
}

// Round 9
// 1820.140 us; speedup vs baseline: 2.6165x; 1.0634x over previous
//
#include <hip/hip_runtime.h>
#include <stdint.h>

#define NOBJ 2048
#define NREL 32768

typedef __attribute__((ext_vector_type(8))) short short8;
typedef __attribute__((ext_vector_type(4))) float f32x4;
typedef __attribute__((ext_vector_type(4))) unsigned short ushort4v;

__device__ __forceinline__ unsigned short f2bs(float x){
  unsigned u = __float_as_uint(x);
  unsigned v = u + 0x7fffu + ((u >> 16) & 1u);
  return (unsigned short)(v >> 16);
}
__device__ __forceinline__ float b2f(unsigned short u){
  return __uint_as_float(((unsigned)u) << 16);
}
__device__ __forceinline__ float sigf(float x){ return 1.0f / (1.0f + expf(-x)); }

// async global->LDS, 16B per lane. LDS dest = wave-uniform base + lane*16.
__device__ __forceinline__ void gload16(const unsigned short* g, unsigned short* l) {
  __builtin_amdgcn_global_load_lds(
      (const __attribute__((address_space(1))) unsigned int*)(uintptr_t)g,
      (__attribute__((address_space(3))) unsigned int*)(uintptr_t)l,
      16, 0, 0);
}

// ============ 128x128 BK=64 engine: 32 MFMA per barrier pair, 32 KiB LDS ============
// A: MxK(lda) bf16 (gload_lds) or f32 (AF32: coalesced reg-staged cvt, swizzled ds_write).
// B: NxK bf16 packed. LDS [128][64]; slot s of row r holds global slot s^(r&7)
// (both-sides swizzle, rule #21); read xor = lrow&7 -> 2 lanes/bank (free, m136).
// AF32 staging (fixed r8): lane t covers 16-B f32 chunk (t&15) of rows (t>>4)+16j --
// per instruction each 16-lane group reads a contiguous 256-B row segment (coalesced).
// RMODE: 0 none; 1 relu [then PRODF]; 2 relu(acc+bias+Cin). ACCUM: +Cin (f32, stride N).
template<int RMODE, bool ACCUM, bool OUTB, bool PRODF, bool AF32>
__global__ __launch_bounds__(256, 2)
void gemm_bt(const void* __restrict__ Ap, const unsigned short* __restrict__ B,
             const float* __restrict__ bias, const float* __restrict__ Cin,
             void* __restrict__ Cp, int M, int N, int K, int lda, int ldc,
             const unsigned short* __restrict__ fusedp,
             const int* __restrict__ subp, const int* __restrict__ objp)
{
  __shared__ __align__(16) unsigned short As[128 * 64];
  __shared__ __align__(16) unsigned short Bs[128 * 64];
  const int t = threadIdx.x;
  const int lane = t & 63;
  const int w = t >> 6;
  // XCD bijective swizzle (m204)
  const int nwg = gridDim.x;
  const int q8 = nwg >> 3, r8 = nwg & 7;
  const int xcd = blockIdx.x & 7, bidx = blockIdx.x >> 3;
  const int wgid = (xcd < r8 ? xcd * (q8 + 1) : r8 * (q8 + 1) + (xcd - r8) * q8) + bidx;
  const int ntile = N >> 7;
  const int bm = wgid / ntile;
  const int bn = wgid - bm * ntile;
  const int m0 = bm << 7, n0 = bn << 7;
  const int wm = (w & 1) << 6, wn = (w >> 1) << 6;
  const int lrow = lane & 15, kg = lane >> 4;
  const int rx = lrow & 7;                    // read-side slot xor

  // gload staging: wave w, call q covers rows q*32 + w*8 + (lane>>3), slot lane&7,
  // source slot pre-swizzled by (lane>>3) == (row&7).
  const int srow8 = lane >> 3;
  const int sslot = ((lane & 7) ^ srow8) << 3;   // in shorts
  const unsigned short* Bg = B + (long)(n0 + w * 8 + srow8) * K + sslot;
  const long ldb32 = (long)32 * K;

  const unsigned short* Ag = nullptr;
  const float* afp = nullptr;
  long lda32 = 0;
  int ar0 = 0;
  unsigned short* abase = nullptr;
  if constexpr (AF32) {
    ar0 = t >> 4;                               // 0..15
    const int ac4 = t & 15;                     // 16-B chunk within row
    afp = (const float*)Ap + (long)(m0 + ar0) * lda + (ac4 << 2);
    abase = As + ((((ac4 >> 1) ^ (ar0 & 7)) << 3) + ((ac4 & 1) << 2));
  } else {
    Ag = (const unsigned short*)Ap + (long)(m0 + w * 8 + srow8) * lda + sslot;
    lda32 = (long)32 * lda;
  }

  f32x4 acc[4][4] = {};

  for (int k0 = 0; k0 < K; k0 += 64) {
#pragma unroll
    for (int q = 0; q < 4; q++)
      gload16(Bg + q * ldb32 + k0, Bs + (q * 32 + w * 8) * 64);
    if constexpr (AF32) {
      const float* ap = afp + k0;
#pragma unroll
      for (int j = 0; j < 8; j++) {
        f32x4 v = *(const f32x4*)(ap + (long)j * 16 * lda);
        ushort4v o;
        o[0] = f2bs(v[0]); o[1] = f2bs(v[1]); o[2] = f2bs(v[2]); o[3] = f2bs(v[3]);
        *(ushort4v*)(abase + (ar0 + j * 16) * 64) = o;
      }
    } else {
#pragma unroll
      for (int q = 0; q < 4; q++)
        gload16(Ag + q * lda32 + k0, As + (q * 32 + w * 8) * 64);
    }
    __syncthreads();
    short8 afr[4][2], bfr[4][2];
#pragma unroll
    for (int i = 0; i < 4; i++) {
      const int ra = wm + i * 16 + lrow;
#pragma unroll
      for (int ks = 0; ks < 2; ks++)
        afr[i][ks] = *(const short8*)(As + ra * 64 + (((ks * 4 + kg) ^ rx) << 3));
    }
#pragma unroll
    for (int j = 0; j < 4; j++) {
      const int rb = wn + j * 16 + lrow;
#pragma unroll
      for (int ks = 0; ks < 2; ks++)
        bfr[j][ks] = *(const short8*)(Bs + rb * 64 + (((ks * 4 + kg) ^ rx) << 3));
    }
#pragma unroll
    for (int i = 0; i < 4; i++)
#pragma unroll
      for (int j = 0; j < 4; j++)
#pragma unroll
        for (int ks = 0; ks < 2; ks++)
          acc[i][j] = __builtin_amdgcn_mfma_f32_16x16x32_bf16(afr[i][ks], bfr[j][ks], acc[i][j], 0, 0, 0);
    __syncthreads();
  }

  float* Cf = (float*)Cp;
  unsigned short* Cb = (unsigned short*)Cp;
#pragma unroll
  for (int i = 0; i < 4; i++) {
#pragma unroll
    for (int j = 0; j < 4; j++) {
      const int col = n0 + wn + j * 16 + lrow;
      const float bv = bias[col];
#pragma unroll
      for (int q = 0; q < 4; q++) {
        const long row = m0 + wm + i * 16 + kg * 4 + q;
        float v = acc[i][j][q] + bv;
        if constexpr (RMODE == 1) v = fmaxf(v, 0.0f);
        if constexpr (PRODF) {
          int gr = (col < 512) ? subp[row] : objp[row];
          v *= b2f(fusedp[(long)gr * 1024 + col]);
        }
        if constexpr (ACCUM) v += Cin[row * (long)N + col];
        if constexpr (RMODE == 2) v = fmaxf(v, 0.0f);
        if constexpr (OUTB) Cb[row * (long)ldc + col] = f2bs(v);
        else Cf[row * (long)ldc + col] = v;
      }
    }
  }
}

// ===================== small kernels =====================

__global__ void cvt_pad4(const float* __restrict__ src, unsigned short* __restrict__ dst,
                         int rows, int K0, int Kp)
{
  const int kp4 = Kp >> 2;
  const long total = (long)rows * kp4;
  for (long i = blockIdx.x * (long)blockDim.x + threadIdx.x; i < total; i += (long)gridDim.x * blockDim.x) {
    int r = (int)(i / kp4), k = (int)(i - (long)r * kp4) << 2;
    ushort4v o;
    if (k < K0) {
      f32x4 v = *(const f32x4*)(src + (long)r * K0 + k);
      o[0] = f2bs(v[0]); o[1] = f2bs(v[1]); o[2] = f2bs(v[2]); o[3] = f2bs(v[3]);
    } else {
      o[0] = 0; o[1] = 0; o[2] = 0; o[3] = 0;
    }
    *(ushort4v*)(dst + (long)r * Kp + k) = o;
  }
}

__global__ void cvt4(const float* __restrict__ src, unsigned short* __restrict__ dst, long n4)
{
  for (long i = blockIdx.x * (long)blockDim.x + threadIdx.x; i < n4; i += (long)gridDim.x * blockDim.x) {
    f32x4 v = ((const f32x4*)src)[i];
    ushort4v o;
    o[0] = f2bs(v[0]); o[1] = f2bs(v[1]); o[2] = f2bs(v[2]); o[3] = f2bs(v[3]);
    ((ushort4v*)dst)[i] = o;
  }
}

__global__ void transpose_cvt(const float* __restrict__ src, unsigned short* __restrict__ dst,
                              int R, int C)
{
  __shared__ float tile[32][33];
  int c0 = blockIdx.x * 32, r0 = blockIdx.y * 32;
  for (int i = threadIdx.y; i < 32; i += 8)
    tile[i][threadIdx.x] = src[(long)(r0 + i) * C + c0 + threadIdx.x];
  __syncthreads();
  for (int i = threadIdx.y; i < 32; i += 8)
    dst[(long)(c0 + i) * R + r0 + threadIdx.x] = f2bs(tile[threadIdx.x][i]);
}

__global__ void comp_bias(const float* __restrict__ edgeU_W, const float* __restrict__ up_b,
                          const float* __restrict__ edgeU_b, float* __restrict__ b_comp)
{
  int j = (int)((blockIdx.x * (long)blockDim.x + threadIdx.x) >> 6);
  int l = threadIdx.x & 63;
  if (j >= 512) return;
  float s = 0.0f;
  for (int k = l; k < 2048; k += 64) s += edgeU_W[(long)j * 2048 + k] * up_b[k];
#pragma unroll
  for (int off = 32; off > 0; off >>= 1) s += __shfl_xor(s, off);
  if (l == 0) b_comp[j] = s + edgeU_b[j];
}

// vgbias[j] = j<1536 ? 0 : ngru_bhh[j-1536]
__global__ void bias_cat(const float* __restrict__ bhh, float* __restrict__ out)
{
  int j = blockIdx.x * blockDim.x + threadIdx.x;
  if (j < 3072) out[j] = (j < 1536) ? 0.0f : bhh[j - 1536];
}

__global__ void obox_k(const float* __restrict__ boxes, float* __restrict__ obox)
{
  int i = blockIdx.x * blockDim.x + threadIdx.x;
  if (i >= NOBJ) return;
  float x1 = boxes[i*4], y1 = boxes[i*4+1], x2 = boxes[i*4+2], y2 = boxes[i*4+3];
  float wdt = x2 - x1 + 1.0f, hgt = y2 - y1 + 1.0f;
  float cx = x1 + 0.5f * wdt, cy = y1 + 0.5f * hgt;
  const float inv = 1.0f / 1024.0f;
  float* o = obox + i * 8;
  o[0]=x1*inv; o[1]=y1*inv; o[2]=x2*inv; o[3]=y2*inv;
  o[4]=cx*inv; o[5]=cy*inv; o[6]=wdt*inv; o[7]=hgt*inv;
}

__global__ void posembed_k(const float* __restrict__ boxes,
                           const float* __restrict__ w1, const float* __restrict__ b1,
                           const float* __restrict__ g, const float* __restrict__ bb,
                           const float* __restrict__ mm, const float* __restrict__ vv,
                           const float* __restrict__ w2, const float* __restrict__ b2,
                           float* __restrict__ out)
{
  int o = blockIdx.x, t = threadIdx.x;
  __shared__ float e[9];
  __shared__ float p[32];
  if (t == 0) {
    float x1 = boxes[o*4], y1 = boxes[o*4+1], x2 = boxes[o*4+2], y2 = boxes[o*4+3];
    float wdt = x2 - x1 + 1.0f, hgt = y2 - y1 + 1.0f;
    float cx = x1 + 0.5f * wdt, cy = y1 + 0.5f * hgt;
    e[0]=wdt/1024.0f; e[1]=hgt/768.0f; e[2]=cx/1024.0f; e[3]=cy/768.0f;
    e[4]=x1/1024.0f;  e[5]=y1/768.0f;  e[6]=x2/1024.0f; e[7]=y2/768.0f;
    e[8]=wdt*hgt/(1024.0f*768.0f);
  }
  __syncthreads();
  if (t < 32) {
    float s = b1[t];
#pragma unroll
    for (int j = 0; j < 9; j++) s += w1[t*9+j] * e[j];
    s = (s - mm[t]) * g[t] / sqrtf(vv[t] + 1e-5f) + bb[t];
    p[t] = s;
  }
  __syncthreads();
  float s = b2[t];
#pragma unroll
  for (int j = 0; j < 32; j++) s += w2[t*32+j] * p[j];
  out[o*128 + t] = fmaxf(s, 0.0f);
}

__device__ __forceinline__ void pack8_store(unsigned short* dst, f32x4 a, f32x4 b)
{
  ushort4v o0, o1;
  o0[0]=f2bs(a[0]); o0[1]=f2bs(a[1]); o0[2]=f2bs(a[2]); o0[3]=f2bs(a[3]);
  o1[0]=f2bs(b[0]); o1[1]=f2bs(b[1]); o1[2]=f2bs(b[2]); o1[3]=f2bs(b[3]);
  *(ushort4v*)dst = o0;
  *(ushort4v*)(dst + 4) = o1;
}

__global__ void build_x1(const float* __restrict__ inst, const float* __restrict__ embd,
                         const int* __restrict__ labels, const float* __restrict__ pose,
                         unsigned short* __restrict__ X1b)
{
  const long total = (long)NOBJ * 560;
  for (long i = blockIdx.x * (long)blockDim.x + threadIdx.x; i < total; i += (long)gridDim.x * blockDim.x) {
    int r = (int)(i / 560), c = ((int)(i - (long)r * 560)) << 3;
    unsigned short* dst = X1b + (long)r * 4480 + c;
    const float* src;
    if (c < 4096)      src = inst + (long)r * 4096 + c;
    else if (c < 4296) src = embd + (long)labels[r] * 200 + (c - 4096);
    else if (c < 4424) src = pose + r * 128 + (c - 4296);
    else { ushort4v z = {0,0,0,0}; *(ushort4v*)dst = z; *(ushort4v*)(dst+4) = z; continue; }
    pack8_store(dst, *(const f32x4*)src, *((const f32x4*)src + 1));
  }
}

__global__ void build_aug(const float* __restrict__ embl, const int* __restrict__ labels,
                          const float* __restrict__ inst, unsigned short* __restrict__ augb)
{
  const long total = (long)NOBJ * 608;
  for (long i = blockIdx.x * (long)blockDim.x + threadIdx.x; i < total; i += (long)gridDim.x * blockDim.x) {
    int r = (int)(i / 608), c = ((int)(i - (long)r * 608)) << 3;
    if (c >= 4296 && c < 4808) continue;
    unsigned short* dst = augb + (long)r * 4864 + c;
    const float* src;
    if (c < 200)       src = embl + (long)labels[r] * 200 + c;
    else if (c < 4296) src = inst + (long)r * 4096 + (c - 200);
    else { ushort4v z = {0,0,0,0}; *(ushort4v*)dst = z; *(ushort4v*)(dst+4) = z; continue; }
    pack8_store(dst, *(const f32x4*)src, *((const f32x4*)src + 1));
  }
}

__global__ void build_geo(const float* __restrict__ obox, const int* __restrict__ sub,
                          const int* __restrict__ obj, unsigned short* __restrict__ geob)
{
  int r = blockIdx.x * blockDim.x + threadIdx.x;
  if (r >= NREL) return;
  const float* b1 = obox + sub[r] * 8;
  const float* b2 = obox + obj[r] * 8;
  float o[32];
#pragma unroll
  for (int j = 0; j < 8; j++) { o[j] = b1[j]; o[8+j] = b2[j]; }
  float ux1 = fminf(b1[0], b2[0]), uy1 = fminf(b1[1], b2[1]);
  float ux2 = fmaxf(b1[2], b2[2]), uy2 = fmaxf(b1[3], b2[3]);
  float uw = ux2 - ux1 + 1.0f, uh = uy2 - uy1 + 1.0f;
  o[16]=ux1; o[17]=uy1; o[18]=ux2; o[19]=uy2;
  o[20]=ux1+0.5f*uw; o[21]=uy1+0.5f*uh; o[22]=uw; o[23]=uh;
  float ix1 = fmaxf(b1[0], b2[0]), iy1 = fmaxf(b1[1], b2[1]);
  float ix2 = fminf(b1[2], b2[2]), iy2 = fminf(b1[3], b2[3]);
  bool bad = (ix2 < ix1) || (iy2 < iy1);
  float iw = ix2 - ix1 + 1.0f, ih = iy2 - iy1 + 1.0f;
  if (bad) {
#pragma unroll
    for (int j = 24; j < 32; j++) o[j] = 0.0f;
  } else {
    o[24]=ix1; o[25]=iy1; o[26]=ix2; o[27]=iy2;
    o[28]=ix1+0.5f*iw; o[29]=iy1+0.5f*ih; o[30]=iw; o[31]=ih;
  }
  unsigned short* gp = geob + (long)r * 64;
#pragma unroll
  for (int j = 0; j < 32; j++) gp[j] = f2bs(o[j]);
#pragma unroll
  for (int j = 32; j < 64; j++) gp[j] = 0;
}

// vertex GRU init: h f32 + bf16 mirror
__global__ void gru_init_v(const unsigned short* __restrict__ gi, const float* __restrict__ bhh,
                           float* __restrict__ h, unsigned short* __restrict__ hb, int n)
{
  const long total = (long)n * 64;
  for (long i = blockIdx.x * (long)blockDim.x + threadIdx.x; i < total; i += (long)gridDim.x * blockDim.x) {
    int r = (int)(i >> 6), c = ((int)(i & 63)) << 3;
    const unsigned short* gr = gi + (long)r * 1536;
    short8 vr = *(const short8*)(gr + c);
    short8 vz = *(const short8*)(gr + 512 + c);
    short8 vn = *(const short8*)(gr + 1024 + c);
    float hv[8];
#pragma unroll
    for (int k = 0; k < 8; k++) {
      float rr = sigf(b2f((unsigned short)vr[k]) + bhh[c + k]);
      float z  = sigf(b2f((unsigned short)vz[k]) + bhh[512 + c + k]);
      float nn = tanhf(b2f((unsigned short)vn[k]) + rr * bhh[1024 + c + k]);
      hv[k] = (1.0f - z) * nn;
    }
    float* hp = h + (long)r * 512 + c;
    *(f32x4*)hp = *(f32x4*)hv;
    *(f32x4*)(hp + 4) = *(f32x4*)(hv + 4);
    pack8_store(hb + (long)r * 512 + c, *(f32x4*)hv, *(f32x4*)(hv + 4));
  }
}

// edge GRU init: bf16 state only
__global__ void gru_init_e(const unsigned short* __restrict__ gi, const float* __restrict__ bhh,
                           unsigned short* __restrict__ hb, int n)
{
  const long total = (long)n * 64;
  for (long i = blockIdx.x * (long)blockDim.x + threadIdx.x; i < total; i += (long)gridDim.x * blockDim.x) {
    int r = (int)(i >> 6), c = ((int)(i & 63)) << 3;
    const unsigned short* gr = gi + (long)r * 1536;
    short8 vr = *(const short8*)(gr + c);
    short8 vz = *(const short8*)(gr + 512 + c);
    short8 vn = *(const short8*)(gr + 1024 + c);
    float hv[8];
#pragma unroll
    for (int k = 0; k < 8; k++) {
      float rr = sigf(b2f((unsigned short)vr[k]) + bhh[c + k]);
      float z  = sigf(b2f((unsigned short)vz[k]) + bhh[512 + c + k]);
      float nn = tanhf(b2f((unsigned short)vn[k]) + rr * bhh[1024 + c + k]);
      hv[k] = (1.0f - z) * nn;
    }
    pack8_store(hb + (long)r * 512 + c, *(f32x4*)hv, *(f32x4*)(hv + 4));
  }
}

// vertex GRU step: gi stride 1536, gh stride ghs (VG layout), vert f32 io + bf16 mirror.
__global__ void gru_step_v(const unsigned short* __restrict__ gi, const unsigned short* __restrict__ gh,
                           int ghs, const float* __restrict__ hin, float* __restrict__ hout,
                           unsigned short* __restrict__ hb, int n)
{
  const long total = (long)n * 64;
  for (long i = blockIdx.x * (long)blockDim.x + threadIdx.x; i < total; i += (long)gridDim.x * blockDim.x) {
    int r = (int)(i >> 6), c = ((int)(i & 63)) << 3;
    const unsigned short* gr = gi + (long)r * 1536;
    const unsigned short* hr = gh + (long)r * ghs;
    short8 ir = *(const short8*)(gr + c);
    short8 iz = *(const short8*)(gr + 512 + c);
    short8 in_ = *(const short8*)(gr + 1024 + c);
    short8 hrr = *(const short8*)(hr + c);
    short8 hz = *(const short8*)(hr + 512 + c);
    short8 hn = *(const short8*)(hr + 1024 + c);
    const float* hi = hin + (long)r * 512 + c;
    f32x4 h0 = *(const f32x4*)hi;
    f32x4 h1 = *(const f32x4*)(hi + 4);
    float hv[8];
#pragma unroll
    for (int k = 0; k < 8; k++) {
      float rr = sigf(b2f((unsigned short)ir[k]) + b2f((unsigned short)hrr[k]));
      float z  = sigf(b2f((unsigned short)iz[k]) + b2f((unsigned short)hz[k]));
      float nn = tanhf(b2f((unsigned short)in_[k]) + rr * b2f((unsigned short)hn[k]));
      float old = (k < 4) ? h0[k] : h1[k - 4];
      hv[k] = (1.0f - z) * nn + z * old;
    }
    float* hp = hout + (long)r * 512 + c;
    *(f32x4*)hp = *(f32x4*)hv;
    *(f32x4*)(hp + 4) = *(f32x4*)(hv + 4);
    pack8_store(hb + (long)r * 512 + c, *(f32x4*)hv, *(f32x4*)(hv + 4));
  }
}

// edge GRU step + fused next-iter ws/wo. One wave == one relation (64 lanes x 8 cols).
// gi = ws*VG[sub] + wo*VG[obj] + bih (VG stride 3072); gh = GH (incl bhh, stride 1536).
// h state bf16 in edgeb (in-place); optional f32 out; optional next ws/wo (needs NEW vertb).
__global__ __launch_bounds__(256)
void gru_step_e2(const unsigned short* __restrict__ GH, const unsigned short* __restrict__ VG,
                 const float* __restrict__ ws_arr_in, const float* __restrict__ wo_arr_in,
                 float* __restrict__ ws_arr_out, float* __restrict__ wo_arr_out,
                 const int* __restrict__ sub, const int* __restrict__ obj,
                 const float* __restrict__ bih,
                 unsigned short* __restrict__ edgeb, float* __restrict__ fout,
                 const unsigned short* __restrict__ vertb,
                 const float* __restrict__ svwW, const float* __restrict__ svwb,
                 const float* __restrict__ ovwW, const float* __restrict__ ovwb,
                 int compute_w, int n)
{
  long gid = blockIdx.x * 256L + threadIdx.x;
  int r = (int)(gid >> 6);
  int l = (int)(gid & 63);
  if (r >= n) return;
  const int c = l << 3;
  int s = sub[r], o = obj[r];
  float ws = ws_arr_in[r], wo = wo_arr_in[r];
  const unsigned short* gh = GH + (long)r * 1536;
  const unsigned short* vs = VG + (long)s * 3072;
  const unsigned short* vo = VG + (long)o * 3072;
  short8 ghr = *(const short8*)(gh + c);
  short8 ghz = *(const short8*)(gh + 512 + c);
  short8 ghn = *(const short8*)(gh + 1024 + c);
  short8 vsr = *(const short8*)(vs + c);
  short8 vsz = *(const short8*)(vs + 512 + c);
  short8 vsn = *(const short8*)(vs + 1024 + c);
  short8 vor_ = *(const short8*)(vo + c);
  short8 voz = *(const short8*)(vo + 512 + c);
  short8 von = *(const short8*)(vo + 1024 + c);
  short8 hold = *(const short8*)(edgeb + (long)r * 512 + c);
  float hv[8];
#pragma unroll
  for (int k = 0; k < 8; k++) {
    float gir = ws * b2f((unsigned short)vsr[k]) + wo * b2f((unsigned short)vor_[k]) + bih[c + k];
    float giz = ws * b2f((unsigned short)vsz[k]) + wo * b2f((unsigned short)voz[k]) + bih[512 + c + k];
    float gin = ws * b2f((unsigned short)vsn[k]) + wo * b2f((unsigned short)von[k]) + bih[1024 + c + k];
    float rr = sigf(gir + b2f((unsigned short)ghr[k]));
    float z  = sigf(giz + b2f((unsigned short)ghz[k]));
    float nn = tanhf(gin + rr * b2f((unsigned short)ghn[k]));
    hv[k] = (1.0f - z) * nn + z * b2f((unsigned short)hold[k]);
  }
  pack8_store(edgeb + (long)r * 512 + c, *(f32x4*)hv, *(f32x4*)(hv + 4));
  if (fout) {
    float* fp = fout + (long)r * 512 + c;
    *(f32x4*)fp = *(f32x4*)hv;
    *(f32x4*)(fp + 4) = *(f32x4*)(hv + 4);
  }
  if (compute_w) {
    short8 svv = *(const short8*)(vertb + (long)s * 512 + c);
    short8 ovv = *(const short8*)(vertb + (long)o * 512 + c);
    float as = 0.0f, ao = 0.0f;
#pragma unroll
    for (int k = 0; k < 8; k++) {
      float e = hv[k];
      as += svwW[c + k] * b2f((unsigned short)svv[k]) + svwW[512 + c + k] * e;
      ao += ovwW[c + k] * b2f((unsigned short)ovv[k]) + ovwW[512 + c + k] * e;
    }
#pragma unroll
    for (int off = 32; off > 0; off >>= 1) {
      as += __shfl_xor(as, off);
      ao += __shfl_xor(ao, off);
    }
    if (l == 0) {
      ws_arr_out[r] = sigf(as + svwb[0]);
      wo_arr_out[r] = sigf(ao + ovwb[0]);
    }
  }
}

// Standalone ws/wo (first iteration only)
__global__ __launch_bounds__(256)
void edge_weights(const unsigned short* __restrict__ vertb, const unsigned short* __restrict__ edgeb,
                  const int* __restrict__ sub, const int* __restrict__ obj,
                  const float* __restrict__ svwW, const float* __restrict__ svwb,
                  const float* __restrict__ ovwW, const float* __restrict__ ovwb,
                  float* __restrict__ ws_arr, float* __restrict__ wo_arr)
{
  long gid = blockIdx.x * 256L + threadIdx.x;
  int r = (int)(gid >> 6);
  int l = (int)(gid & 63);
  if (r >= NREL) return;
  int s = sub[r], o = obj[r];
  const unsigned short* sv = vertb + (long)s * 512;
  const unsigned short* ov = vertb + (long)o * 512;
  const unsigned short* e  = edgeb + (long)r * 512;
  float as = 0.0f, ao = 0.0f;
#pragma unroll
  for (int k = 0; k < 8; k++) {
    int c = l + k * 64;
    float svv = b2f(sv[c]), ovv = b2f(ov[c]), ev = b2f(e[c]);
    as += svwW[c] * svv + svwW[512 + c] * ev;
    ao += ovwW[c] * ovv + ovwW[512 + c] * ev;
  }
#pragma unroll
  for (int off = 32; off > 0; off >>= 1) {
    as += __shfl_xor(as, off);
    ao += __shfl_xor(ao, off);
  }
  if (l == 0) {
    ws_arr[r] = sigf(as + svwb[0]);
    wo_arr[r] = sigf(ao + ovwb[0]);
  }
}

// ===================== CSR =====================

__global__ void csr_count(const int* __restrict__ sub, const int* __restrict__ obj,
                          int* __restrict__ cnt)
{
  int r = blockIdx.x * blockDim.x + threadIdx.x;
  if (r >= NREL) return;
  atomicAdd(&cnt[sub[r]], 1);
  atomicAdd(&cnt[obj[r]], 1);
}

__global__ __launch_bounds__(1024)
void csr_scan(const int* __restrict__ cnt, int* __restrict__ off)
{
  __shared__ int a[1024], b[1024];
  int t = threadIdx.x;
  int c0 = cnt[2*t], c1 = cnt[2*t+1];
  a[t] = c0 + c1;
  __syncthreads();
  int* src = a; int* dst = b;
  for (int s = 1; s < 1024; s <<= 1) {
    int v = src[t];
    if (t >= s) v += src[t - s];
    dst[t] = v;
    __syncthreads();
    int* tmp = src; src = dst; dst = tmp;
  }
  int incl = src[t];
  int excl = incl - (c0 + c1);
  off[2*t] = excl;
  off[2*t+1] = excl + c0;
  if (t == 1023) off[2048] = incl;
}

__global__ void csr_fill(const int* __restrict__ sub, const int* __restrict__ obj,
                         const int* __restrict__ off, int* __restrict__ rcur,
                         int* __restrict__ lists)
{
  int r = blockIdx.x * blockDim.x + threadIdx.x;
  if (r >= NREL) return;
  int s = sub[r];
  int p = atomicAdd(&rcur[s], 1);
  lists[off[s] + p] = (r << 1);
  int o = obj[r];
  int q = atomicAdd(&rcur[o], 1);
  lists[off[o] + q] = (r << 1) | 1;
}

__global__ __launch_bounds__(128)
void ctx_gather(const unsigned short* __restrict__ edgeb, const float* __restrict__ ws,
                const float* __restrict__ wo, const int* __restrict__ off,
                const int* __restrict__ lists, unsigned short* __restrict__ ctxb)
{
  __shared__ float part[512];
  int o = blockIdx.x;
  int l = threadIdx.x & 63;
  int w = threadIdx.x >> 6;
  int i0 = off[o], i1 = off[o + 1];
  float acc[8] = {0.f,0.f,0.f,0.f,0.f,0.f,0.f,0.f};
  for (int i = i0 + w; i < i1; i += 2) {
    int e = lists[i];
    int r = e >> 1;
    float sc = (e & 1) ? wo[r] : ws[r];
    short8 row = *(const short8*)(edgeb + (long)r * 512 + l * 8);
#pragma unroll
    for (int k = 0; k < 8; k++) acc[k] += sc * b2f((unsigned short)row[k]);
  }
  if (w == 1) {
    *(f32x4*)&part[l*8]     = *(f32x4*)&acc[0];
    *(f32x4*)&part[l*8 + 4] = *(f32x4*)&acc[4];
  }
  __syncthreads();
  if (w == 0) {
#pragma unroll
    for (int k = 0; k < 8; k++) acc[k] += part[l*8 + k];
    pack8_store(ctxb + (long)o * 512 + l * 8, *(f32x4*)&acc[0], *(f32x4*)&acc[4]);
  }
}

// ===================== driver =====================

static inline int nblk(long total) {
  long b = (total + 255) / 256;
  return (int)(b > 16384 ? 16384 : b);
}

#define GEMM(RM, AC, OB, PF, grid, Aa, Bb, bb, Ci, Cc, Mm, Nn, Kk, ldA, ldC, fp, sp, op) \
  gemm_bt<RM, AC, OB, PF, false><<<grid, 256, 0, stream>>>(Aa, Bb, bb, Ci, Cc, Mm, Nn, Kk, ldA, ldC, fp, sp, op)
#define GEMMF(RM, AC, OB, grid, Aa, Bb, bb, Ci, Cc, Mm, Nn, Kk, ldA, ldC) \
  gemm_bt<RM, AC, OB, false, true><<<grid, 256, 0, stream>>>(Aa, Bb, bb, Ci, Cc, Mm, Nn, Kk, ldA, ldC, nullptr, nullptr, nullptr)

extern "C" void kernel_launch(void* const* d_in, const int* in_sizes, int n_in,
                              void* d_out, int out_size, void* d_ws, size_t ws_size,
                              hipStream_t stream)
{
  const float* inst     = (const float*)d_in[0];
  const float* unionf   = (const float*)d_in[1];
  const float* boxes    = (const float*)d_in[2];
  const float* embd_W   = (const float*)d_in[3];
  const float* embl_W   = (const float*)d_in[4];
  const float* up_W     = (const float*)d_in[5];
  const float* up_b     = (const float*)d_in[6];
  const float* pairup_W = (const float*)d_in[7];
  const float* pairup_b = (const float*)d_in[8];
  const float* pos1_W   = (const float*)d_in[9];
  const float* pos1_b   = (const float*)d_in[10];
  const float* bn_g     = (const float*)d_in[11];
  const float* bn_b     = (const float*)d_in[12];
  const float* bn_m     = (const float*)d_in[13];
  const float* bn_v     = (const float*)d_in[14];
  const float* pos2_W   = (const float*)d_in[15];
  const float* pos2_b   = (const float*)d_in[16];
  const float* spt1_W   = (const float*)d_in[17];
  const float* spt1_b   = (const float*)d_in[18];
  const float* spt2_W   = (const float*)d_in[19];
  const float* spt2_b   = (const float*)d_in[20];
  const float* pairfin_W= (const float*)d_in[21];
  const float* pairfin_b= (const float*)d_in[22];
  const float* objhid_W = (const float*)d_in[23];
  const float* objhid_b = (const float*)d_in[24];
  const float* objfin_W = (const float*)d_in[25];
  const float* objfin_b = (const float*)d_in[26];
  const float* objU_W   = (const float*)d_in[27];
  const float* objU_b   = (const float*)d_in[28];
  const float* edgeU_W  = (const float*)d_in[29];
  const float* edgeU_b  = (const float*)d_in[30];
  const float* egru_Wih = (const float*)d_in[31];
  const float* egru_Whh = (const float*)d_in[32];
  const float* egru_bih = (const float*)d_in[33];
  const float* egru_bhh = (const float*)d_in[34];
  const float* ngru_Wih = (const float*)d_in[35];
  const float* ngru_Whh = (const float*)d_in[36];
  const float* ngru_bih = (const float*)d_in[37];
  const float* ngru_bhh = (const float*)d_in[38];
  const float* svw_W    = (const float*)d_in[39];
  const float* svw_b    = (const float*)d_in[40];
  const float* ovw_W    = (const float*)d_in[41];
  const float* ovw_b    = (const float*)d_in[42];
  const int*   labels   = (const int*)d_in[43];
  const int*   sub      = (const int*)d_in[44];
  const int*   obj      = (const int*)d_in[45];
  (void)in_sizes; (void)n_in; (void)out_size; (void)ws_size;

  char* base = (char*)d_ws;
  size_t off = 0;
  auto alloc = [&](size_t bytes) -> void* {
    void* p = base + off;
    off += (bytes + 255) & ~(size_t)255;
    return p;
  };

  // ---- weights (bf16) ----
  unsigned short* objhid_Wb  = (unsigned short*)alloc(512L  * 4480 * 2);
  unsigned short* pairup_Wb  = (unsigned short*)alloc(1024L * 4864 * 2);
  unsigned short* objfin_Wb  = (unsigned short*)alloc(2048L * 4864 * 2);
  unsigned short* up_Wtb     = (unsigned short*)alloc(4096L * 2048 * 2);
  unsigned short* pairfin_Wb = (unsigned short*)alloc(2048L * 1024 * 2);
  unsigned short* spt1_Wb    = (unsigned short*)alloc(512L  * 64   * 2);
  unsigned short* spt2_Wb    = (unsigned short*)alloc(1024L * 512  * 2);
  unsigned short* objU_Wb    = (unsigned short*)alloc(512L  * 2048 * 2);
  unsigned short* edgeU_Wb   = (unsigned short*)alloc(512L  * 2048 * 2);
  unsigned short* egru_Wihb  = (unsigned short*)alloc(1536L * 512  * 2);
  unsigned short* egru_Whhb  = (unsigned short*)alloc(1536L * 512  * 2);
  unsigned short* ngru_Wihb  = (unsigned short*)alloc(1536L * 512  * 2);
  unsigned short* vg_Wb      = (unsigned short*)alloc(3072L * 512  * 2);   // [egru_Wih ; ngru_Whh]
  unsigned short* W_compb    = (unsigned short*)alloc(512L  * 4096 * 2);
  float*          b_comp     = (float*)alloc(512L * 4);
  float*          zbias      = (float*)alloc(4096L * 4);
  float*          vgbias     = (float*)alloc(3072L * 4);

  // ---- activations ----
  float*          obox      = (float*)alloc(NOBJ * 8L * 4);
  float*          pose      = (float*)alloc(NOBJ * 128L * 4);
  unsigned short* obj_featsb= (unsigned short*)alloc((long)NOBJ * 2048 * 2);
  unsigned short* obj_repb  = (unsigned short*)alloc((long)NOBJ * 512 * 2);
  unsigned short* giv       = (unsigned short*)alloc((long)NOBJ * 1536 * 2);
  unsigned short* VGb       = (unsigned short*)alloc((long)NOBJ * 3072 * 2);  // [VW | gh_v]
  float*          vert      = (float*)alloc((long)NOBJ * 512 * 4);
  unsigned short* vertb     = (unsigned short*)alloc((long)NOBJ * 512 * 2);
  unsigned short* ctxb      = (unsigned short*)alloc((long)NOBJ * 512 * 2);
  unsigned short* geob      = (unsigned short*)alloc((long)NREL * 64 * 2);
  unsigned short* edgeb     = (unsigned short*)alloc((long)NREL * 512 * 2);
  float*          ws_arr    = (float*)alloc((long)NREL * 4);
  float*          wo_arr    = (float*)alloc((long)NREL * 4);

  // CSR
  int* cnt   = (int*)alloc(NOBJ * 4);
  int* coff  = (int*)alloc((NOBJ + 1) * 4);
  int* rcur  = (int*)alloc(NOBJ * 4);
  int* lists = (int*)alloc(2L * NREL * 4);

  // REGION_A: X1b -> T1 (f32 64MB)
  char* regA = (char*)alloc((long)NREL * 512 * 4);
  unsigned short* X1b = (unsigned short*)regA;
  float*          T1  = (float*)regA;
  // REGION_B: augb -> rel_repb
  char* regB = (char*)alloc((long)NOBJ * 4864 * 2 > (long)NREL * 512 * 2
                            ? (long)NOBJ * 4864 * 2 : (long)NREL * 512 * 2);
  unsigned short* augb     = (unsigned short*)regB;
  unsigned short* rel_repb = (unsigned short*)regB;
  unsigned short* fusedb = (unsigned short*)alloc((long)NOBJ * 1024 * 2);
  unsigned short* spt1b  = (unsigned short*)alloc((long)NREL * 512 * 2);
  // BIG1: [G1 128MB | prodb 64MB] -> gi_e(init) -> GH (96MB per loop iter)
  char* big1 = (char*)alloc((long)NREL * 1536 * 4);
  unsigned short* G1    = (unsigned short*)big1;
  unsigned short* prodb = (unsigned short*)(big1 + (long)NREL * 1024 * 4);
  unsigned short* gi_e  = (unsigned short*)big1;
  unsigned short* GHb   = (unsigned short*)big1;

  float* d_out_vert = (float*)d_out;
  float* d_out_edge = (float*)d_out + (long)NOBJ * 512;

  // ---- weight conversions ----
  cvt_pad4<<<nblk(512L*4480/4),  256, 0, stream>>>(objhid_W,  objhid_Wb,  512,  4424, 4480);
  cvt_pad4<<<nblk(1024L*4864/4), 256, 0, stream>>>(pairup_W,  pairup_Wb,  1024, 4808, 4864);
  cvt_pad4<<<nblk(2048L*4864/4), 256, 0, stream>>>(objfin_W,  objfin_Wb,  2048, 4808, 4864);
  cvt_pad4<<<nblk(512L*64/4),    256, 0, stream>>>(spt1_W,    spt1_Wb,    512,  32,   64);
  cvt4<<<nblk(2048L*1024/4), 256, 0, stream>>>(pairfin_W, pairfin_Wb, 2048L*1024/4);
  cvt4<<<nblk(1024L*512/4),  256, 0, stream>>>(spt2_W,    spt2_Wb,    1024L*512/4);
  cvt4<<<nblk(512L*2048/4),  256, 0, stream>>>(objU_W,    objU_Wb,    512L*2048/4);
  cvt4<<<nblk(512L*2048/4),  256, 0, stream>>>(edgeU_W,   edgeU_Wb,   512L*2048/4);
  cvt4<<<nblk(1536L*512/4),  256, 0, stream>>>(egru_Wih,  egru_Wihb,  1536L*512/4);
  cvt4<<<nblk(1536L*512/4),  256, 0, stream>>>(egru_Whh,  egru_Whhb,  1536L*512/4);
  cvt4<<<nblk(1536L*512/4),  256, 0, stream>>>(ngru_Wih,  ngru_Wihb,  1536L*512/4);
  cvt4<<<nblk(1536L*512/4),  256, 0, stream>>>(egru_Wih,  vg_Wb,               1536L*512/4);
  cvt4<<<nblk(1536L*512/4),  256, 0, stream>>>(ngru_Whh,  vg_Wb + 1536L*512,   1536L*512/4);
  bias_cat<<<12, 256, 0, stream>>>(ngru_bhh, vgbias);
  transpose_cvt<<<dim3(4096/32, 2048/32), dim3(32, 8), 0, stream>>>(up_W, up_Wtb, 2048, 4096);
  hipMemsetAsync(zbias, 0, 4096L * 4, stream);
  comp_bias<<<128, 256, 0, stream>>>(edgeU_W, up_b, edgeU_b, b_comp);
  GEMM(0,false,true,false, dim3((512>>7)*(4096>>7)), edgeU_Wb, up_Wtb, zbias, nullptr, W_compb, 512, 4096, 2048, 2048, 4096, nullptr, nullptr, nullptr);

  // ---- CSR build ----
  hipMemsetAsync(cnt, 0, NOBJ * 4, stream);
  hipMemsetAsync(rcur, 0, NOBJ * 4, stream);
  csr_count<<<NREL/256, 256, 0, stream>>>(sub, obj, cnt);
  csr_scan<<<1, 1024, 0, stream>>>(cnt, coff);
  csr_fill<<<NREL/256, 256, 0, stream>>>(sub, obj, coff, rcur, lists);

  // ---- object stream ----
  obox_k<<<(NOBJ + 255) / 256, 256, 0, stream>>>(boxes, obox);
  posembed_k<<<NOBJ, 128, 0, stream>>>(boxes, pos1_W, pos1_b, bn_g, bn_b, bn_m, bn_v,
                                       pos2_W, pos2_b, pose);
  build_x1<<<nblk((long)NOBJ*560), 256, 0, stream>>>(inst, embd_W, labels, pose, X1b);
  build_aug<<<nblk((long)NOBJ*608), 256, 0, stream>>>(embl_W, labels, inst, augb);
  GEMM(0,false,true ,false, dim3((NOBJ>>7)*(512>>7)),  X1b, objhid_Wb, objhid_b, nullptr, augb + 4296, NOBJ, 512, 4480, 4480, 4864, nullptr, nullptr, nullptr);
  GEMM(0,false,true ,false, dim3((NOBJ>>7)*(1024>>7)), augb, pairup_Wb, pairup_b, nullptr, fusedb, NOBJ, 1024, 4864, 4864, 1024, nullptr, nullptr, nullptr);
  GEMM(1,false,true ,false, dim3((NOBJ>>7)*(2048>>7)), augb, objfin_Wb, objfin_b, nullptr, obj_featsb, NOBJ, 2048, 4864, 4864, 2048, nullptr, nullptr, nullptr);
  GEMM(0,false,true ,false, dim3((NOBJ>>7)*(512>>7)),  obj_featsb, objU_Wb, objU_b, nullptr, obj_repb, NOBJ, 512, 2048, 2048, 512, nullptr, nullptr, nullptr);
  GEMM(0,false,true ,false, dim3((NOBJ>>7)*(1536>>7)), obj_repb, ngru_Wihb, ngru_bih, nullptr, giv, NOBJ, 1536, 512, 512, 1536, nullptr, nullptr, nullptr);
  gru_init_v<<<nblk((long)NOBJ*64), 256, 0, stream>>>(giv, ngru_bhh, vert, vertb, NOBJ);

  // ---- relation stream ----
  build_geo<<<(NREL + 255) / 256, 256, 0, stream>>>(obox, sub, obj, geob);
  GEMM(1,false,true ,false, dim3((NREL>>7)*(512>>7)),  geob, spt1_Wb, spt1_b, nullptr, spt1b, NREL, 512, 64, 64, 512, nullptr, nullptr, nullptr);
  GEMM(1,false,true ,true , dim3((NREL>>7)*(1024>>7)), spt1b, spt2_Wb, spt2_b, nullptr, prodb, NREL, 1024, 512, 512, 1024, fusedb, sub, obj);
  GEMM(1,false,true ,false, dim3((NREL>>7)*(2048>>7)), prodb, pairfin_Wb, pairfin_b, nullptr, G1, NREL, 2048, 1024, 1024, 2048, nullptr, nullptr, nullptr);
  GEMMF(0,false,false, dim3((NREL>>7)*(512>>7)), unionf, W_compb, b_comp, nullptr, T1, NREL, 512, 4096, 4096, 512);
  GEMM(2,true ,true ,false, dim3((NREL>>7)*(512>>7)),  G1, edgeU_Wb, zbias, T1, rel_repb, NREL, 512, 2048, 2048, 512, nullptr, nullptr, nullptr);
  GEMM(0,false,true ,false, dim3((NREL>>7)*(1536>>7)), rel_repb, egru_Wihb, egru_bih, nullptr, gi_e, NREL, 1536, 512, 512, 1536, nullptr, nullptr, nullptr);
  gru_init_e<<<nblk((long)NREL*64), 256, 0, stream>>>(gi_e, egru_bhh, edgeb, NREL);

  // initial ws/wo
  edge_weights<<<NREL*64/256, 256, 0, stream>>>(vertb, edgeb, sub, obj,
                                                svw_W, svw_b, ovw_W, ovw_b, ws_arr, wo_arr);

  // ---- message-passing loop ----
  for (int it = 0; it < 3; it++) {
    const bool last = (it == 2);
    ctx_gather<<<NOBJ, 128, 0, stream>>>(edgeb, ws_arr, wo_arr, coff, lists, ctxb);
    // VG = vertb @ [eWih ; nWhh]^T   (cols 0..1535 = VW, no bias; cols 1536.. = gh_v + bhh)
    GEMM(0,false,true,false, dim3((NOBJ>>7)*(3072>>7)), vertb, vg_Wb, vgbias, nullptr, VGb, NOBJ, 3072, 512, 512, 3072, nullptr, nullptr, nullptr);
    // GH = edgeb @ eWhh^T + bhh
    GEMM(0,false,true,false, dim3((NREL>>7)*(1536>>7)), edgeb, egru_Whhb, egru_bhh, nullptr, GHb, NREL, 1536, 512, 512, 1536, nullptr, nullptr, nullptr);
    // giv = ctxb @ nWih^T + bih
    GEMM(0,false,true,false, dim3((NOBJ>>7)*(1536>>7)), ctxb, ngru_Wihb, ngru_bih, nullptr, giv, NOBJ, 1536, 512, 512, 1536, nullptr, nullptr, nullptr);
    // vertex update first (gru_step_e2's fused ws/wo needs NEW vertb)
    gru_step_v<<<nblk((long)NOBJ*64), 256, 0, stream>>>(giv, VGb + 1536, 3072, vert,
                                                        last ? d_out_vert : vert, vertb, NOBJ);
    gru_step_e2<<<NREL*64/256, 256, 0, stream>>>(GHb, VGb, ws_arr, wo_arr, ws_arr, wo_arr,
                                                 sub, obj, egru_bih, edgeb,
                                                 last ? d_out_edge : nullptr, vertb,
                                                 svw_W, svw_b, ovw_W, ovw_b,
                                                 last ? 0 : 1, NREL);
  }
}

// Round 10
// 1695.408 us; speedup vs baseline: 2.8090x; 1.0736x over previous
//
#include <hip/hip_runtime.h>
#include <stdint.h>

#define NOBJ 2048
#define NREL 32768

typedef __attribute__((ext_vector_type(8))) short short8;
typedef __attribute__((ext_vector_type(4))) float f32x4;
typedef __attribute__((ext_vector_type(4))) unsigned short ushort4v;

__device__ __forceinline__ unsigned short f2bs(float x){
  unsigned u = __float_as_uint(x);
  unsigned v = u + 0x7fffu + ((u >> 16) & 1u);
  return (unsigned short)(v >> 16);
}
__device__ __forceinline__ float b2f(unsigned short u){
  return __uint_as_float(((unsigned)u) << 16);
}
__device__ __forceinline__ float sigf(float x){ return 1.0f / (1.0f + expf(-x)); }

// async global->LDS, 16B per lane. LDS dest = wave-uniform base + lane*16.
__device__ __forceinline__ void gload16(const unsigned short* g, unsigned short* l) {
  __builtin_amdgcn_global_load_lds(
      (const __attribute__((address_space(1))) unsigned int*)(uintptr_t)g,
      (__attribute__((address_space(3))) unsigned int*)(uintptr_t)l,
      16, 0, 0);
}

// ============ 128x128 BK=64 engine: 32 MFMA per barrier pair, 32 KiB LDS ============
// A: MxK(lda) bf16 (gload_lds) or f32 (AF32: coalesced reg-staged cvt, swizzled ds_write).
// B: NxK bf16 packed. LDS [128][64]; slot s of row r holds global slot s^(r&7)
// (both-sides swizzle, rule #21); read xor = lrow&7 -> 2 lanes/bank (free, m136).
// RMODE: 0 none; 1 relu [then PRODF]; 2 relu(acc+bias+Cin). ACCUM: +Cin (f32, stride N).
template<int RMODE, bool ACCUM, bool OUTB, bool PRODF, bool AF32>
__global__ __launch_bounds__(256, 2)
void gemm_bt(const void* __restrict__ Ap, const unsigned short* __restrict__ B,
             const float* __restrict__ bias, const float* __restrict__ Cin,
             void* __restrict__ Cp, int M, int N, int K, int lda, int ldc,
             const unsigned short* __restrict__ fusedp,
             const int* __restrict__ subp, const int* __restrict__ objp)
{
  __shared__ __align__(16) unsigned short As[128 * 64];
  __shared__ __align__(16) unsigned short Bs[128 * 64];
  const int t = threadIdx.x;
  const int lane = t & 63;
  const int w = t >> 6;
  const int nwg = gridDim.x;
  const int q8 = nwg >> 3, r8 = nwg & 7;
  const int xcd = blockIdx.x & 7, bidx = blockIdx.x >> 3;
  const int wgid = (xcd < r8 ? xcd * (q8 + 1) : r8 * (q8 + 1) + (xcd - r8) * q8) + bidx;
  const int ntile = N >> 7;
  const int bm = wgid / ntile;
  const int bn = wgid - bm * ntile;
  const int m0 = bm << 7, n0 = bn << 7;
  const int wm = (w & 1) << 6, wn = (w >> 1) << 6;
  const int lrow = lane & 15, kg = lane >> 4;
  const int rx = lrow & 7;

  const int srow8 = lane >> 3;
  const int sslot = ((lane & 7) ^ srow8) << 3;
  const unsigned short* Bg = B + (long)(n0 + w * 8 + srow8) * K + sslot;
  const long ldb32 = (long)32 * K;

  const unsigned short* Ag = nullptr;
  const float* afp = nullptr;
  long lda32 = 0;
  int ar0 = 0;
  unsigned short* abase = nullptr;
  if constexpr (AF32) {
    ar0 = t >> 4;
    const int ac4 = t & 15;
    afp = (const float*)Ap + (long)(m0 + ar0) * lda + (ac4 << 2);
    abase = As + ((((ac4 >> 1) ^ (ar0 & 7)) << 3) + ((ac4 & 1) << 2));
  } else {
    Ag = (const unsigned short*)Ap + (long)(m0 + w * 8 + srow8) * lda + sslot;
    lda32 = (long)32 * lda;
  }

  f32x4 acc[4][4] = {};

  for (int k0 = 0; k0 < K; k0 += 64) {
#pragma unroll
    for (int q = 0; q < 4; q++)
      gload16(Bg + q * ldb32 + k0, Bs + (q * 32 + w * 8) * 64);
    if constexpr (AF32) {
      const float* ap = afp + k0;
#pragma unroll
      for (int j = 0; j < 8; j++) {
        f32x4 v = *(const f32x4*)(ap + (long)j * 16 * lda);
        ushort4v o;
        o[0] = f2bs(v[0]); o[1] = f2bs(v[1]); o[2] = f2bs(v[2]); o[3] = f2bs(v[3]);
        *(ushort4v*)(abase + (ar0 + j * 16) * 64) = o;
      }
    } else {
#pragma unroll
      for (int q = 0; q < 4; q++)
        gload16(Ag + q * lda32 + k0, As + (q * 32 + w * 8) * 64);
    }
    __syncthreads();
    short8 afr[4][2], bfr[4][2];
#pragma unroll
    for (int i = 0; i < 4; i++) {
      const int ra = wm + i * 16 + lrow;
#pragma unroll
      for (int ks = 0; ks < 2; ks++)
        afr[i][ks] = *(const short8*)(As + ra * 64 + (((ks * 4 + kg) ^ rx) << 3));
    }
#pragma unroll
    for (int j = 0; j < 4; j++) {
      const int rb = wn + j * 16 + lrow;
#pragma unroll
      for (int ks = 0; ks < 2; ks++)
        bfr[j][ks] = *(const short8*)(Bs + rb * 64 + (((ks * 4 + kg) ^ rx) << 3));
    }
#pragma unroll
    for (int i = 0; i < 4; i++)
#pragma unroll
      for (int j = 0; j < 4; j++)
#pragma unroll
        for (int ks = 0; ks < 2; ks++)
          acc[i][j] = __builtin_amdgcn_mfma_f32_16x16x32_bf16(afr[i][ks], bfr[j][ks], acc[i][j], 0, 0, 0);
    __syncthreads();
  }

  float* Cf = (float*)Cp;
  unsigned short* Cb = (unsigned short*)Cp;
#pragma unroll
  for (int i = 0; i < 4; i++) {
#pragma unroll
    for (int j = 0; j < 4; j++) {
      const int col = n0 + wn + j * 16 + lrow;
      const float bv = bias[col];
#pragma unroll
      for (int q = 0; q < 4; q++) {
        const long row = m0 + wm + i * 16 + kg * 4 + q;
        float v = acc[i][j][q] + bv;
        if constexpr (RMODE == 1) v = fmaxf(v, 0.0f);
        if constexpr (PRODF) {
          int gr = (col < 512) ? subp[row] : objp[row];
          v *= b2f(fusedp[(long)gr * 1024 + col]);
        }
        if constexpr (ACCUM) v += Cin[row * (long)N + col];
        if constexpr (RMODE == 2) v = fmaxf(v, 0.0f);
        if constexpr (OUTB) Cb[row * (long)ldc + col] = f2bs(v);
        else Cf[row * (long)ldc + col] = v;
      }
    }
  }
}

// ============ 64x64 mini engine for grid-starved M=2048-class GEMMs ============
// Same staging/swizzle invariant as BK=64 engine (8-row gload groups: row&7 == lane>>3;
// read xor = lrow&7). 4 waves x 32x32. bf16 A/B/out. 16 KiB LDS.
template<int RMODE>
__global__ __launch_bounds__(256, 2)
void gemm64(const unsigned short* __restrict__ A, const unsigned short* __restrict__ B,
            const float* __restrict__ bias, unsigned short* __restrict__ C,
            int M, int N, int K, int lda, int ldc)
{
  __shared__ __align__(16) unsigned short As[64 * 64];
  __shared__ __align__(16) unsigned short Bs[64 * 64];
  const int t = threadIdx.x;
  const int lane = t & 63;
  const int w = t >> 6;
  const int nwg = gridDim.x;
  const int q8 = nwg >> 3, r8 = nwg & 7;
  const int xcd = blockIdx.x & 7, bidx = blockIdx.x >> 3;
  const int wgid = (xcd < r8 ? xcd * (q8 + 1) : r8 * (q8 + 1) + (xcd - r8) * q8) + bidx;
  const int ntile = N >> 6;
  const int bm = wgid / ntile, bn = wgid - bm * ntile;
  const int m0 = bm << 6, n0 = bn << 6;
  const int wm = (w & 1) << 5, wn = (w >> 1) << 5;
  const int lrow = lane & 15, kg = lane >> 4;
  const int rx = lrow & 7;

  const int srow8 = lane >> 3;
  const int sslot = ((lane & 7) ^ srow8) << 3;
  const unsigned short* Ag = A + (long)(m0 + w * 16 + srow8) * lda + sslot;
  const unsigned short* Bg = B + (long)(n0 + w * 16 + srow8) * K + sslot;
  const long lda8 = 8L * lda, ldb8 = 8L * K;

  f32x4 acc[2][2] = {};

  for (int k0 = 0; k0 < K; k0 += 64) {
    gload16(Ag + k0,        As + (w * 16) * 64);
    gload16(Ag + lda8 + k0, As + (w * 16 + 8) * 64);
    gload16(Bg + k0,        Bs + (w * 16) * 64);
    gload16(Bg + ldb8 + k0, Bs + (w * 16 + 8) * 64);
    __syncthreads();
    short8 afr[2][2], bfr[2][2];
#pragma unroll
    for (int i = 0; i < 2; i++) {
      const int ra = wm + i * 16 + lrow;
#pragma unroll
      for (int ks = 0; ks < 2; ks++)
        afr[i][ks] = *(const short8*)(As + ra * 64 + (((ks * 4 + kg) ^ rx) << 3));
    }
#pragma unroll
    for (int j = 0; j < 2; j++) {
      const int rb = wn + j * 16 + lrow;
#pragma unroll
      for (int ks = 0; ks < 2; ks++)
        bfr[j][ks] = *(const short8*)(Bs + rb * 64 + (((ks * 4 + kg) ^ rx) << 3));
    }
#pragma unroll
    for (int i = 0; i < 2; i++)
#pragma unroll
      for (int j = 0; j < 2; j++)
#pragma unroll
        for (int ks = 0; ks < 2; ks++)
          acc[i][j] = __builtin_amdgcn_mfma_f32_16x16x32_bf16(afr[i][ks], bfr[j][ks], acc[i][j], 0, 0, 0);
    __syncthreads();
  }

#pragma unroll
  for (int i = 0; i < 2; i++) {
#pragma unroll
    for (int j = 0; j < 2; j++) {
      const int col = n0 + wn + j * 16 + lrow;
      const float bv = bias[col];
#pragma unroll
      for (int q = 0; q < 4; q++) {
        const long row = m0 + wm + i * 16 + kg * 4 + q;
        float v = acc[i][j][q] + bv;
        if constexpr (RMODE == 1) v = fmaxf(v, 0.0f);
        C[row * (long)ldc + col] = f2bs(v);
      }
    }
  }
}

// ===================== small kernels =====================

__global__ void cvt_pad4(const float* __restrict__ src, unsigned short* __restrict__ dst,
                         int rows, int K0, int Kp)
{
  const int kp4 = Kp >> 2;
  const long total = (long)rows * kp4;
  for (long i = blockIdx.x * (long)blockDim.x + threadIdx.x; i < total; i += (long)gridDim.x * blockDim.x) {
    int r = (int)(i / kp4), k = (int)(i - (long)r * kp4) << 2;
    ushort4v o;
    if (k < K0) {
      f32x4 v = *(const f32x4*)(src + (long)r * K0 + k);
      o[0] = f2bs(v[0]); o[1] = f2bs(v[1]); o[2] = f2bs(v[2]); o[3] = f2bs(v[3]);
    } else {
      o[0] = 0; o[1] = 0; o[2] = 0; o[3] = 0;
    }
    *(ushort4v*)(dst + (long)r * Kp + k) = o;
  }
}

struct CvtSeg { const float* src; unsigned short* dst; long base; long n4; };
struct Cvt9 { CvtSeg s[9]; long total; };

__global__ void cvt4_multi(Cvt9 cfg)
{
  for (long i = blockIdx.x * (long)blockDim.x + threadIdx.x; i < cfg.total;
       i += (long)gridDim.x * blockDim.x) {
#pragma unroll
    for (int k = 0; k < 9; k++) {
      if (i >= cfg.s[k].base && i < cfg.s[k].base + cfg.s[k].n4) {
        long j = i - cfg.s[k].base;
        f32x4 v = ((const f32x4*)cfg.s[k].src)[j];
        ushort4v o;
        o[0] = f2bs(v[0]); o[1] = f2bs(v[1]); o[2] = f2bs(v[2]); o[3] = f2bs(v[3]);
        ((ushort4v*)cfg.s[k].dst)[j] = o;
        break;
      }
    }
  }
}

__global__ void transpose_cvt(const float* __restrict__ src, unsigned short* __restrict__ dst,
                              int R, int C)
{
  __shared__ float tile[32][33];
  int c0 = blockIdx.x * 32, r0 = blockIdx.y * 32;
  for (int i = threadIdx.y; i < 32; i += 8)
    tile[i][threadIdx.x] = src[(long)(r0 + i) * C + c0 + threadIdx.x];
  __syncthreads();
  for (int i = threadIdx.y; i < 32; i += 8)
    dst[(long)(c0 + i) * R + r0 + threadIdx.x] = f2bs(tile[threadIdx.x][i]);
}

__global__ void comp_bias(const float* __restrict__ edgeU_W, const float* __restrict__ up_b,
                          const float* __restrict__ edgeU_b, float* __restrict__ b_comp)
{
  int j = (int)((blockIdx.x * (long)blockDim.x + threadIdx.x) >> 6);
  int l = threadIdx.x & 63;
  if (j >= 512) return;
  float s = 0.0f;
  for (int k = l; k < 2048; k += 64) s += edgeU_W[(long)j * 2048 + k] * up_b[k];
#pragma unroll
  for (int off = 32; off > 0; off >>= 1) s += __shfl_xor(s, off);
  if (l == 0) b_comp[j] = s + edgeU_b[j];
}

// vgbias[j] = j<1536 ? 0 : ngru_bhh[j-1536]
__global__ void bias_cat(const float* __restrict__ bhh, float* __restrict__ out)
{
  int j = blockIdx.x * blockDim.x + threadIdx.x;
  if (j < 3072) out[j] = (j < 1536) ? 0.0f : bhh[j - 1536];
}

__global__ void obox_k(const float* __restrict__ boxes, float* __restrict__ obox)
{
  int i = blockIdx.x * blockDim.x + threadIdx.x;
  if (i >= NOBJ) return;
  float x1 = boxes[i*4], y1 = boxes[i*4+1], x2 = boxes[i*4+2], y2 = boxes[i*4+3];
  float wdt = x2 - x1 + 1.0f, hgt = y2 - y1 + 1.0f;
  float cx = x1 + 0.5f * wdt, cy = y1 + 0.5f * hgt;
  const float inv = 1.0f / 1024.0f;
  float* o = obox + i * 8;
  o[0]=x1*inv; o[1]=y1*inv; o[2]=x2*inv; o[3]=y2*inv;
  o[4]=cx*inv; o[5]=cy*inv; o[6]=wdt*inv; o[7]=hgt*inv;
}

__global__ void posembed_k(const float* __restrict__ boxes,
                           const float* __restrict__ w1, const float* __restrict__ b1,
                           const float* __restrict__ g, const float* __restrict__ bb,
                           const float* __restrict__ mm, const float* __restrict__ vv,
                           const float* __restrict__ w2, const float* __restrict__ b2,
                           float* __restrict__ out)
{
  int o = blockIdx.x, t = threadIdx.x;
  __shared__ float e[9];
  __shared__ float p[32];
  if (t == 0) {
    float x1 = boxes[o*4], y1 = boxes[o*4+1], x2 = boxes[o*4+2], y2 = boxes[o*4+3];
    float wdt = x2 - x1 + 1.0f, hgt = y2 - y1 + 1.0f;
    float cx = x1 + 0.5f * wdt, cy = y1 + 0.5f * hgt;
    e[0]=wdt/1024.0f; e[1]=hgt/768.0f; e[2]=cx/1024.0f; e[3]=cy/768.0f;
    e[4]=x1/1024.0f;  e[5]=y1/768.0f;  e[6]=x2/1024.0f; e[7]=y2/768.0f;
    e[8]=wdt*hgt/(1024.0f*768.0f);
  }
  __syncthreads();
  if (t < 32) {
    float s = b1[t];
#pragma unroll
    for (int j = 0; j < 9; j++) s += w1[t*9+j] * e[j];
    s = (s - mm[t]) * g[t] / sqrtf(vv[t] + 1e-5f) + bb[t];
    p[t] = s;
  }
  __syncthreads();
  float s = b2[t];
#pragma unroll
  for (int j = 0; j < 32; j++) s += w2[t*32+j] * p[j];
  out[o*128 + t] = fmaxf(s, 0.0f);
}

__device__ __forceinline__ void pack8_store(unsigned short* dst, f32x4 a, f32x4 b)
{
  ushort4v o0, o1;
  o0[0]=f2bs(a[0]); o0[1]=f2bs(a[1]); o0[2]=f2bs(a[2]); o0[3]=f2bs(a[3]);
  o1[0]=f2bs(b[0]); o1[1]=f2bs(b[1]); o1[2]=f2bs(b[2]); o1[3]=f2bs(b[3]);
  *(ushort4v*)dst = o0;
  *(ushort4v*)(dst + 4) = o1;
}

__global__ void build_x1(const float* __restrict__ inst, const float* __restrict__ embd,
                         const int* __restrict__ labels, const float* __restrict__ pose,
                         unsigned short* __restrict__ X1b)
{
  const long total = (long)NOBJ * 560;
  for (long i = blockIdx.x * (long)blockDim.x + threadIdx.x; i < total; i += (long)gridDim.x * blockDim.x) {
    int r = (int)(i / 560), c = ((int)(i - (long)r * 560)) << 3;
    unsigned short* dst = X1b + (long)r * 4480 + c;
    const float* src;
    if (c < 4096)      src = inst + (long)r * 4096 + c;
    else if (c < 4296) src = embd + (long)labels[r] * 200 + (c - 4096);
    else if (c < 4424) src = pose + r * 128 + (c - 4296);
    else { ushort4v z = {0,0,0,0}; *(ushort4v*)dst = z; *(ushort4v*)(dst+4) = z; continue; }
    pack8_store(dst, *(const f32x4*)src, *((const f32x4*)src + 1));
  }
}

__global__ void build_aug(const float* __restrict__ embl, const int* __restrict__ labels,
                          const float* __restrict__ inst, unsigned short* __restrict__ augb)
{
  const long total = (long)NOBJ * 608;
  for (long i = blockIdx.x * (long)blockDim.x + threadIdx.x; i < total; i += (long)gridDim.x * blockDim.x) {
    int r = (int)(i / 608), c = ((int)(i - (long)r * 608)) << 3;
    if (c >= 4296 && c < 4808) continue;
    unsigned short* dst = augb + (long)r * 4864 + c;
    const float* src;
    if (c < 200)       src = embl + (long)labels[r] * 200 + c;
    else if (c < 4296) src = inst + (long)r * 4096 + (c - 200);
    else { ushort4v z = {0,0,0,0}; *(ushort4v*)dst = z; *(ushort4v*)(dst+4) = z; continue; }
    pack8_store(dst, *(const f32x4*)src, *((const f32x4*)src + 1));
  }
}

__global__ void build_geo(const float* __restrict__ obox, const int* __restrict__ sub,
                          const int* __restrict__ obj, unsigned short* __restrict__ geob)
{
  int r = blockIdx.x * blockDim.x + threadIdx.x;
  if (r >= NREL) return;
  const float* b1 = obox + sub[r] * 8;
  const float* b2 = obox + obj[r] * 8;
  float o[32];
#pragma unroll
  for (int j = 0; j < 8; j++) { o[j] = b1[j]; o[8+j] = b2[j]; }
  float ux1 = fminf(b1[0], b2[0]), uy1 = fminf(b1[1], b2[1]);
  float ux2 = fmaxf(b1[2], b2[2]), uy2 = fmaxf(b1[3], b2[3]);
  float uw = ux2 - ux1 + 1.0f, uh = uy2 - uy1 + 1.0f;
  o[16]=ux1; o[17]=uy1; o[18]=ux2; o[19]=uy2;
  o[20]=ux1+0.5f*uw; o[21]=uy1+0.5f*uh; o[22]=uw; o[23]=uh;
  float ix1 = fmaxf(b1[0], b2[0]), iy1 = fmaxf(b1[1], b2[1]);
  float ix2 = fminf(b1[2], b2[2]), iy2 = fminf(b1[3], b2[3]);
  bool bad = (ix2 < ix1) || (iy2 < iy1);
  float iw = ix2 - ix1 + 1.0f, ih = iy2 - iy1 + 1.0f;
  if (bad) {
#pragma unroll
    for (int j = 24; j < 32; j++) o[j] = 0.0f;
  } else {
    o[24]=ix1; o[25]=iy1; o[26]=ix2; o[27]=iy2;
    o[28]=ix1+0.5f*iw; o[29]=iy1+0.5f*ih; o[30]=iw; o[31]=ih;
  }
  unsigned short* gp = geob + (long)r * 64;
#pragma unroll
  for (int j = 0; j < 32; j++) gp[j] = f2bs(o[j]);
#pragma unroll
  for (int j = 32; j < 64; j++) gp[j] = 0;
}

// vertex GRU init: h f32 + bf16 mirror
__global__ void gru_init_v(const unsigned short* __restrict__ gi, const float* __restrict__ bhh,
                           float* __restrict__ h, unsigned short* __restrict__ hb, int n)
{
  const long total = (long)n * 64;
  for (long i = blockIdx.x * (long)blockDim.x + threadIdx.x; i < total; i += (long)gridDim.x * blockDim.x) {
    int r = (int)(i >> 6), c = ((int)(i & 63)) << 3;
    const unsigned short* gr = gi + (long)r * 1536;
    short8 vr = *(const short8*)(gr + c);
    short8 vz = *(const short8*)(gr + 512 + c);
    short8 vn = *(const short8*)(gr + 1024 + c);
    float hv[8];
#pragma unroll
    for (int k = 0; k < 8; k++) {
      float rr = sigf(b2f((unsigned short)vr[k]) + bhh[c + k]);
      float z  = sigf(b2f((unsigned short)vz[k]) + bhh[512 + c + k]);
      float nn = tanhf(b2f((unsigned short)vn[k]) + rr * bhh[1024 + c + k]);
      hv[k] = (1.0f - z) * nn;
    }
    float* hp = h + (long)r * 512 + c;
    *(f32x4*)hp = *(f32x4*)hv;
    *(f32x4*)(hp + 4) = *(f32x4*)(hv + 4);
    pack8_store(hb + (long)r * 512 + c, *(f32x4*)hv, *(f32x4*)(hv + 4));
  }
}

// edge GRU init: bf16 state only
__global__ void gru_init_e(const unsigned short* __restrict__ gi, const float* __restrict__ bhh,
                           unsigned short* __restrict__ hb, int n)
{
  const long total = (long)n * 64;
  for (long i = blockIdx.x * (long)blockDim.x + threadIdx.x; i < total; i += (long)gridDim.x * blockDim.x) {
    int r = (int)(i >> 6), c = ((int)(i & 63)) << 3;
    const unsigned short* gr = gi + (long)r * 1536;
    short8 vr = *(const short8*)(gr + c);
    short8 vz = *(const short8*)(gr + 512 + c);
    short8 vn = *(const short8*)(gr + 1024 + c);
    float hv[8];
#pragma unroll
    for (int k = 0; k < 8; k++) {
      float rr = sigf(b2f((unsigned short)vr[k]) + bhh[c + k]);
      float z  = sigf(b2f((unsigned short)vz[k]) + bhh[512 + c + k]);
      float nn = tanhf(b2f((unsigned short)vn[k]) + rr * bhh[1024 + c + k]);
      hv[k] = (1.0f - z) * nn;
    }
    pack8_store(hb + (long)r * 512 + c, *(f32x4*)hv, *(f32x4*)(hv + 4));
  }
}

// vertex GRU step: gi stride 1536, gh stride ghs (VG layout), vert f32 io + bf16 mirror.
__global__ void gru_step_v(const unsigned short* __restrict__ gi, const unsigned short* __restrict__ gh,
                           int ghs, const float* __restrict__ hin, float* __restrict__ hout,
                           unsigned short* __restrict__ hb, int n)
{
  const long total = (long)n * 64;
  for (long i = blockIdx.x * (long)blockDim.x + threadIdx.x; i < total; i += (long)gridDim.x * blockDim.x) {
    int r = (int)(i >> 6), c = ((int)(i & 63)) << 3;
    const unsigned short* gr = gi + (long)r * 1536;
    const unsigned short* hr = gh + (long)r * ghs;
    short8 ir = *(const short8*)(gr + c);
    short8 iz = *(const short8*)(gr + 512 + c);
    short8 in_ = *(const short8*)(gr + 1024 + c);
    short8 hrr = *(const short8*)(hr + c);
    short8 hz = *(const short8*)(hr + 512 + c);
    short8 hn = *(const short8*)(hr + 1024 + c);
    const float* hi = hin + (long)r * 512 + c;
    f32x4 h0 = *(const f32x4*)hi;
    f32x4 h1 = *(const f32x4*)(hi + 4);
    float hv[8];
#pragma unroll
    for (int k = 0; k < 8; k++) {
      float rr = sigf(b2f((unsigned short)ir[k]) + b2f((unsigned short)hrr[k]));
      float z  = sigf(b2f((unsigned short)iz[k]) + b2f((unsigned short)hz[k]));
      float nn = tanhf(b2f((unsigned short)in_[k]) + rr * b2f((unsigned short)hn[k]));
      float old = (k < 4) ? h0[k] : h1[k - 4];
      hv[k] = (1.0f - z) * nn + z * old;
    }
    float* hp = hout + (long)r * 512 + c;
    *(f32x4*)hp = *(f32x4*)hv;
    *(f32x4*)(hp + 4) = *(f32x4*)(hv + 4);
    pack8_store(hb + (long)r * 512 + c, *(f32x4*)hv, *(f32x4*)(hv + 4));
  }
}

// edge GRU step + fused next-iter ws/wo. One wave == one relation.
__global__ __launch_bounds__(256)
void gru_step_e2(const unsigned short* __restrict__ GH, const unsigned short* __restrict__ VG,
                 const float* __restrict__ ws_arr_in, const float* __restrict__ wo_arr_in,
                 float* __restrict__ ws_arr_out, float* __restrict__ wo_arr_out,
                 const int* __restrict__ sub, const int* __restrict__ obj,
                 const float* __restrict__ bih,
                 unsigned short* __restrict__ edgeb, float* __restrict__ fout,
                 const unsigned short* __restrict__ vertb,
                 const float* __restrict__ svwW, const float* __restrict__ svwb,
                 const float* __restrict__ ovwW, const float* __restrict__ ovwb,
                 int compute_w, int n)
{
  long gid = blockIdx.x * 256L + threadIdx.x;
  int r = (int)(gid >> 6);
  int l = (int)(gid & 63);
  if (r >= n) return;
  const int c = l << 3;
  int s = sub[r], o = obj[r];
  float ws = ws_arr_in[r], wo = wo_arr_in[r];
  const unsigned short* gh = GH + (long)r * 1536;
  const unsigned short* vs = VG + (long)s * 3072;
  const unsigned short* vo = VG + (long)o * 3072;
  short8 ghr = *(const short8*)(gh + c);
  short8 ghz = *(const short8*)(gh + 512 + c);
  short8 ghn = *(const short8*)(gh + 1024 + c);
  short8 vsr = *(const short8*)(vs + c);
  short8 vsz = *(const short8*)(vs + 512 + c);
  short8 vsn = *(const short8*)(vs + 1024 + c);
  short8 vor_ = *(const short8*)(vo + c);
  short8 voz = *(const short8*)(vo + 512 + c);
  short8 von = *(const short8*)(vo + 1024 + c);
  short8 hold = *(const short8*)(edgeb + (long)r * 512 + c);
  float hv[8];
#pragma unroll
  for (int k = 0; k < 8; k++) {
    float gir = ws * b2f((unsigned short)vsr[k]) + wo * b2f((unsigned short)vor_[k]) + bih[c + k];
    float giz = ws * b2f((unsigned short)vsz[k]) + wo * b2f((unsigned short)voz[k]) + bih[512 + c + k];
    float gin = ws * b2f((unsigned short)vsn[k]) + wo * b2f((unsigned short)von[k]) + bih[1024 + c + k];
    float rr = sigf(gir + b2f((unsigned short)ghr[k]));
    float z  = sigf(giz + b2f((unsigned short)ghz[k]));
    float nn = tanhf(gin + rr * b2f((unsigned short)ghn[k]));
    hv[k] = (1.0f - z) * nn + z * b2f((unsigned short)hold[k]);
  }
  pack8_store(edgeb + (long)r * 512 + c, *(f32x4*)hv, *(f32x4*)(hv + 4));
  if (fout) {
    float* fp = fout + (long)r * 512 + c;
    *(f32x4*)fp = *(f32x4*)hv;
    *(f32x4*)(fp + 4) = *(f32x4*)(hv + 4);
  }
  if (compute_w) {
    short8 svv = *(const short8*)(vertb + (long)s * 512 + c);
    short8 ovv = *(const short8*)(vertb + (long)o * 512 + c);
    float as = 0.0f, ao = 0.0f;
#pragma unroll
    for (int k = 0; k < 8; k++) {
      float e = hv[k];
      as += svwW[c + k] * b2f((unsigned short)svv[k]) + svwW[512 + c + k] * e;
      ao += ovwW[c + k] * b2f((unsigned short)ovv[k]) + ovwW[512 + c + k] * e;
    }
#pragma unroll
    for (int off = 32; off > 0; off >>= 1) {
      as += __shfl_xor(as, off);
      ao += __shfl_xor(ao, off);
    }
    if (l == 0) {
      ws_arr_out[r] = sigf(as + svwb[0]);
      wo_arr_out[r] = sigf(ao + ovwb[0]);
    }
  }
}

// Standalone ws/wo (first iteration only)
__global__ __launch_bounds__(256)
void edge_weights(const unsigned short* __restrict__ vertb, const unsigned short* __restrict__ edgeb,
                  const int* __restrict__ sub, const int* __restrict__ obj,
                  const float* __restrict__ svwW, const float* __restrict__ svwb,
                  const float* __restrict__ ovwW, const float* __restrict__ ovwb,
                  float* __restrict__ ws_arr, float* __restrict__ wo_arr)
{
  long gid = blockIdx.x * 256L + threadIdx.x;
  int r = (int)(gid >> 6);
  int l = (int)(gid & 63);
  if (r >= NREL) return;
  int s = sub[r], o = obj[r];
  const unsigned short* sv = vertb + (long)s * 512;
  const unsigned short* ov = vertb + (long)o * 512;
  const unsigned short* e  = edgeb + (long)r * 512;
  float as = 0.0f, ao = 0.0f;
#pragma unroll
  for (int k = 0; k < 8; k++) {
    int c = l + k * 64;
    float svv = b2f(sv[c]), ovv = b2f(ov[c]), ev = b2f(e[c]);
    as += svwW[c] * svv + svwW[512 + c] * ev;
    ao += ovwW[c] * ovv + ovwW[512 + c] * ev;
  }
#pragma unroll
  for (int off = 32; off > 0; off >>= 1) {
    as += __shfl_xor(as, off);
    ao += __shfl_xor(ao, off);
  }
  if (l == 0) {
    ws_arr[r] = sigf(as + svwb[0]);
    wo_arr[r] = sigf(ao + ovwb[0]);
  }
}

// ===================== CSR =====================

__global__ void csr_count(const int* __restrict__ sub, const int* __restrict__ obj,
                          int* __restrict__ cnt)
{
  int r = blockIdx.x * blockDim.x + threadIdx.x;
  if (r >= NREL) return;
  atomicAdd(&cnt[sub[r]], 1);
  atomicAdd(&cnt[obj[r]], 1);
}

__global__ __launch_bounds__(1024)
void csr_scan(const int* __restrict__ cnt, int* __restrict__ off)
{
  __shared__ int a[1024], b[1024];
  int t = threadIdx.x;
  int c0 = cnt[2*t], c1 = cnt[2*t+1];
  a[t] = c0 + c1;
  __syncthreads();
  int* src = a; int* dst = b;
  for (int s = 1; s < 1024; s <<= 1) {
    int v = src[t];
    if (t >= s) v += src[t - s];
    dst[t] = v;
    __syncthreads();
    int* tmp = src; src = dst; dst = tmp;
  }
  int incl = src[t];
  int excl = incl - (c0 + c1);
  off[2*t] = excl;
  off[2*t+1] = excl + c0;
  if (t == 1023) off[2048] = incl;
}

__global__ void csr_fill(const int* __restrict__ sub, const int* __restrict__ obj,
                         const int* __restrict__ off, int* __restrict__ rcur,
                         int* __restrict__ lists)
{
  int r = blockIdx.x * blockDim.x + threadIdx.x;
  if (r >= NREL) return;
  int s = sub[r];
  int p = atomicAdd(&rcur[s], 1);
  lists[off[s] + p] = (r << 1);
  int o = obj[r];
  int q = atomicAdd(&rcur[o], 1);
  lists[off[o] + q] = (r << 1) | 1;
}

__global__ __launch_bounds__(128)
void ctx_gather(const unsigned short* __restrict__ edgeb, const float* __restrict__ ws,
                const float* __restrict__ wo, const int* __restrict__ off,
                const int* __restrict__ lists, unsigned short* __restrict__ ctxb)
{
  __shared__ float part[512];
  int o = blockIdx.x;
  int l = threadIdx.x & 63;
  int w = threadIdx.x >> 6;
  int i0 = off[o], i1 = off[o + 1];
  float acc[8] = {0.f,0.f,0.f,0.f,0.f,0.f,0.f,0.f};
  for (int i = i0 + w; i < i1; i += 2) {
    int e = lists[i];
    int r = e >> 1;
    float sc = (e & 1) ? wo[r] : ws[r];
    short8 row = *(const short8*)(edgeb + (long)r * 512 + l * 8);
#pragma unroll
    for (int k = 0; k < 8; k++) acc[k] += sc * b2f((unsigned short)row[k]);
  }
  if (w == 1) {
    *(f32x4*)&part[l*8]     = *(f32x4*)&acc[0];
    *(f32x4*)&part[l*8 + 4] = *(f32x4*)&acc[4];
  }
  __syncthreads();
  if (w == 0) {
#pragma unroll
    for (int k = 0; k < 8; k++) acc[k] += part[l*8 + k];
    pack8_store(ctxb + (long)o * 512 + l * 8, *(f32x4*)&acc[0], *(f32x4*)&acc[4]);
  }
}

// ===================== driver =====================

static inline int nblk(long total) {
  long b = (total + 255) / 256;
  return (int)(b > 16384 ? 16384 : b);
}

#define GEMM(RM, AC, OB, PF, grid, Aa, Bb, bb, Ci, Cc, Mm, Nn, Kk, ldA, ldC, fp, sp, op) \
  gemm_bt<RM, AC, OB, PF, false><<<grid, 256, 0, stream>>>(Aa, Bb, bb, Ci, Cc, Mm, Nn, Kk, ldA, ldC, fp, sp, op)
#define GEMMF(RM, AC, OB, grid, Aa, Bb, bb, Ci, Cc, Mm, Nn, Kk, ldA, ldC) \
  gemm_bt<RM, AC, OB, false, true><<<grid, 256, 0, stream>>>(Aa, Bb, bb, Ci, Cc, Mm, Nn, Kk, ldA, ldC, nullptr, nullptr, nullptr)
#define G64(RM, Aa, Bb, bb, Cc, Mm, Nn, Kk, ldA, ldC) \
  gemm64<RM><<<dim3(((Mm) >> 6) * ((Nn) >> 6)), 256, 0, stream>>>(Aa, Bb, bb, Cc, Mm, Nn, Kk, ldA, ldC)

extern "C" void kernel_launch(void* const* d_in, const int* in_sizes, int n_in,
                              void* d_out, int out_size, void* d_ws, size_t ws_size,
                              hipStream_t stream)
{
  const float* inst     = (const float*)d_in[0];
  const float* unionf   = (const float*)d_in[1];
  const float* boxes    = (const float*)d_in[2];
  const float* embd_W   = (const float*)d_in[3];
  const float* embl_W   = (const float*)d_in[4];
  const float* up_W     = (const float*)d_in[5];
  const float* up_b     = (const float*)d_in[6];
  const float* pairup_W = (const float*)d_in[7];
  const float* pairup_b = (const float*)d_in[8];
  const float* pos1_W   = (const float*)d_in[9];
  const float* pos1_b   = (const float*)d_in[10];
  const float* bn_g     = (const float*)d_in[11];
  const float* bn_b     = (const float*)d_in[12];
  const float* bn_m     = (const float*)d_in[13];
  const float* bn_v     = (const float*)d_in[14];
  const float* pos2_W   = (const float*)d_in[15];
  const float* pos2_b   = (const float*)d_in[16];
  const float* spt1_W   = (const float*)d_in[17];
  const float* spt1_b   = (const float*)d_in[18];
  const float* spt2_W   = (const float*)d_in[19];
  const float* spt2_b   = (const float*)d_in[20];
  const float* pairfin_W= (const float*)d_in[21];
  const float* pairfin_b= (const float*)d_in[22];
  const float* objhid_W = (const float*)d_in[23];
  const float* objhid_b = (const float*)d_in[24];
  const float* objfin_W = (const float*)d_in[25];
  const float* objfin_b = (const float*)d_in[26];
  const float* objU_W   = (const float*)d_in[27];
  const float* objU_b   = (const float*)d_in[28];
  const float* edgeU_W  = (const float*)d_in[29];
  const float* edgeU_b  = (const float*)d_in[30];
  const float* egru_Wih = (const float*)d_in[31];
  const float* egru_Whh = (const float*)d_in[32];
  const float* egru_bih = (const float*)d_in[33];
  const float* egru_bhh = (const float*)d_in[34];
  const float* ngru_Wih = (const float*)d_in[35];
  const float* ngru_Whh = (const float*)d_in[36];
  const float* ngru_bih = (const float*)d_in[37];
  const float* ngru_bhh = (const float*)d_in[38];
  const float* svw_W    = (const float*)d_in[39];
  const float* svw_b    = (const float*)d_in[40];
  const float* ovw_W    = (const float*)d_in[41];
  const float* ovw_b    = (const float*)d_in[42];
  const int*   labels   = (const int*)d_in[43];
  const int*   sub      = (const int*)d_in[44];
  const int*   obj      = (const int*)d_in[45];
  (void)in_sizes; (void)n_in; (void)out_size; (void)ws_size;

  char* base = (char*)d_ws;
  size_t off = 0;
  auto alloc = [&](size_t bytes) -> void* {
    void* p = base + off;
    off += (bytes + 255) & ~(size_t)255;
    return p;
  };

  // ---- weights (bf16) ----
  unsigned short* objhid_Wb  = (unsigned short*)alloc(512L  * 4480 * 2);
  unsigned short* pairup_Wb  = (unsigned short*)alloc(1024L * 4864 * 2);
  unsigned short* objfin_Wb  = (unsigned short*)alloc(2048L * 4864 * 2);
  unsigned short* up_Wtb     = (unsigned short*)alloc(4096L * 2048 * 2);
  unsigned short* pairfin_Wb = (unsigned short*)alloc(2048L * 1024 * 2);
  unsigned short* spt1_Wb    = (unsigned short*)alloc(512L  * 64   * 2);
  unsigned short* spt2_Wb    = (unsigned short*)alloc(1024L * 512  * 2);
  unsigned short* objU_Wb    = (unsigned short*)alloc(512L  * 2048 * 2);
  unsigned short* edgeU_Wb   = (unsigned short*)alloc(512L  * 2048 * 2);
  unsigned short* egru_Wihb  = (unsigned short*)alloc(1536L * 512  * 2);
  unsigned short* egru_Whhb  = (unsigned short*)alloc(1536L * 512  * 2);
  unsigned short* ngru_Wihb  = (unsigned short*)alloc(1536L * 512  * 2);
  unsigned short* vg_Wb      = (unsigned short*)alloc(3072L * 512  * 2);   // [egru_Wih ; ngru_Whh]
  unsigned short* W_compb    = (unsigned short*)alloc(512L  * 4096 * 2);
  float*          b_comp     = (float*)alloc(512L * 4);
  float*          zbias      = (float*)alloc(4096L * 4);
  float*          vgbias     = (float*)alloc(3072L * 4);

  // ---- activations ----
  float*          obox      = (float*)alloc(NOBJ * 8L * 4);
  float*          pose      = (float*)alloc(NOBJ * 128L * 4);
  unsigned short* obj_featsb= (unsigned short*)alloc((long)NOBJ * 2048 * 2);
  unsigned short* obj_repb  = (unsigned short*)alloc((long)NOBJ * 512 * 2);
  unsigned short* giv       = (unsigned short*)alloc((long)NOBJ * 1536 * 2);
  unsigned short* VGb       = (unsigned short*)alloc((long)NOBJ * 3072 * 2);  // [VW | gh_v]
  float*          vert      = (float*)alloc((long)NOBJ * 512 * 4);
  unsigned short* vertb     = (unsigned short*)alloc((long)NOBJ * 512 * 2);
  unsigned short* ctxb      = (unsigned short*)alloc((long)NOBJ * 512 * 2);
  unsigned short* geob      = (unsigned short*)alloc((long)NREL * 64 * 2);
  unsigned short* edgeb     = (unsigned short*)alloc((long)NREL * 512 * 2);
  float*          ws_arr    = (float*)alloc((long)NREL * 4);
  float*          wo_arr    = (float*)alloc((long)NREL * 4);

  // CSR
  int* cnt   = (int*)alloc(NOBJ * 4);
  int* coff  = (int*)alloc((NOBJ + 1) * 4);
  int* rcur  = (int*)alloc(NOBJ * 4);
  int* lists = (int*)alloc(2L * NREL * 4);

  // REGION_A: X1b -> T1 (f32 64MB)
  char* regA = (char*)alloc((long)NREL * 512 * 4);
  unsigned short* X1b = (unsigned short*)regA;
  float*          T1  = (float*)regA;
  // REGION_B: augb -> rel_repb
  char* regB = (char*)alloc((long)NOBJ * 4864 * 2 > (long)NREL * 512 * 2
                            ? (long)NOBJ * 4864 * 2 : (long)NREL * 512 * 2);
  unsigned short* augb     = (unsigned short*)regB;
  unsigned short* rel_repb = (unsigned short*)regB;
  unsigned short* fusedb = (unsigned short*)alloc((long)NOBJ * 1024 * 2);
  unsigned short* spt1b  = (unsigned short*)alloc((long)NREL * 512 * 2);
  // BIG1: [G1 128MB | prodb 64MB] -> gi_e(init) -> GH (96MB per loop iter)
  char* big1 = (char*)alloc((long)NREL * 1536 * 4);
  unsigned short* G1    = (unsigned short*)big1;
  unsigned short* prodb = (unsigned short*)(big1 + (long)NREL * 1024 * 4);
  unsigned short* gi_e  = (unsigned short*)big1;
  unsigned short* GHb   = (unsigned short*)big1;

  float* d_out_vert = (float*)d_out;
  float* d_out_edge = (float*)d_out + (long)NOBJ * 512;

  // ---- weight conversions ----
  cvt_pad4<<<nblk(512L*4480/4),  256, 0, stream>>>(objhid_W,  objhid_Wb,  512,  4424, 4480);
  cvt_pad4<<<nblk(1024L*4864/4), 256, 0, stream>>>(pairup_W,  pairup_Wb,  1024, 4808, 4864);
  cvt_pad4<<<nblk(2048L*4864/4), 256, 0, stream>>>(objfin_W,  objfin_Wb,  2048, 4808, 4864);
  cvt_pad4<<<nblk(512L*64/4),    256, 0, stream>>>(spt1_W,    spt1_Wb,    512,  32,   64);
  {
    Cvt9 cfg;
    long b = 0;
    auto seg = [&](int k, const float* s, unsigned short* d, long n4) {
      cfg.s[k].src = s; cfg.s[k].dst = d; cfg.s[k].base = b; cfg.s[k].n4 = n4; b += n4;
    };
    seg(0, pairfin_W, pairfin_Wb, 2048L*1024/4);
    seg(1, spt2_W,    spt2_Wb,    1024L*512/4);
    seg(2, objU_W,    objU_Wb,    512L*2048/4);
    seg(3, edgeU_W,   edgeU_Wb,   512L*2048/4);
    seg(4, egru_Wih,  egru_Wihb,  1536L*512/4);
    seg(5, egru_Whh,  egru_Whhb,  1536L*512/4);
    seg(6, ngru_Wih,  ngru_Wihb,  1536L*512/4);
    seg(7, egru_Wih,  vg_Wb,              1536L*512/4);
    seg(8, ngru_Whh,  vg_Wb + 1536L*512,  1536L*512/4);
    cfg.total = b;
    cvt4_multi<<<nblk(b), 256, 0, stream>>>(cfg);
  }
  bias_cat<<<12, 256, 0, stream>>>(ngru_bhh, vgbias);
  transpose_cvt<<<dim3(4096/32, 2048/32), dim3(32, 8), 0, stream>>>(up_W, up_Wtb, 2048, 4096);
  hipMemsetAsync(zbias, 0, 4096L * 4, stream);
  comp_bias<<<128, 256, 0, stream>>>(edgeU_W, up_b, edgeU_b, b_comp);
  G64(0, edgeU_Wb, up_Wtb, zbias, W_compb, 512, 4096, 2048, 2048, 4096);

  // ---- CSR build ----
  hipMemsetAsync(cnt, 0, NOBJ * 4, stream);
  hipMemsetAsync(rcur, 0, NOBJ * 4, stream);
  csr_count<<<NREL/256, 256, 0, stream>>>(sub, obj, cnt);
  csr_scan<<<1, 1024, 0, stream>>>(cnt, coff);
  csr_fill<<<NREL/256, 256, 0, stream>>>(sub, obj, coff, rcur, lists);

  // ---- object stream (gemm64 mini-engine: 4-8x more blocks than 128^2) ----
  obox_k<<<(NOBJ + 255) / 256, 256, 0, stream>>>(boxes, obox);
  posembed_k<<<NOBJ, 128, 0, stream>>>(boxes, pos1_W, pos1_b, bn_g, bn_b, bn_m, bn_v,
                                       pos2_W, pos2_b, pose);
  build_x1<<<nblk((long)NOBJ*560), 256, 0, stream>>>(inst, embd_W, labels, pose, X1b);
  build_aug<<<nblk((long)NOBJ*608), 256, 0, stream>>>(embl_W, labels, inst, augb);
  G64(0, X1b, objhid_Wb, objhid_b, augb + 4296, NOBJ, 512, 4480, 4480, 4864);
  G64(0, augb, pairup_Wb, pairup_b, fusedb, NOBJ, 1024, 4864, 4864, 1024);
  G64(1, augb, objfin_Wb, objfin_b, obj_featsb, NOBJ, 2048, 4864, 4864, 2048);
  G64(0, obj_featsb, objU_Wb, objU_b, obj_repb, NOBJ, 512, 2048, 2048, 512);
  G64(0, obj_repb, ngru_Wihb, ngru_bih, giv, NOBJ, 1536, 512, 512, 1536);
  gru_init_v<<<nblk((long)NOBJ*64), 256, 0, stream>>>(giv, ngru_bhh, vert, vertb, NOBJ);

  // ---- relation stream (128^2 BK=64 engine) ----
  build_geo<<<(NREL + 255) / 256, 256, 0, stream>>>(obox, sub, obj, geob);
  GEMM(1,false,true ,false, dim3((NREL>>7)*(512>>7)),  geob, spt1_Wb, spt1_b, nullptr, spt1b, NREL, 512, 64, 64, 512, nullptr, nullptr, nullptr);
  GEMM(1,false,true ,true , dim3((NREL>>7)*(1024>>7)), spt1b, spt2_Wb, spt2_b, nullptr, prodb, NREL, 1024, 512, 512, 1024, fusedb, sub, obj);
  GEMM(1,false,true ,false, dim3((NREL>>7)*(2048>>7)), prodb, pairfin_Wb, pairfin_b, nullptr, G1, NREL, 2048, 1024, 1024, 2048, nullptr, nullptr, nullptr);
  GEMMF(0,false,false, dim3((NREL>>7)*(512>>7)), unionf, W_compb, b_comp, nullptr, T1, NREL, 512, 4096, 4096, 512);
  GEMM(2,true ,true ,false, dim3((NREL>>7)*(512>>7)),  G1, edgeU_Wb, zbias, T1, rel_repb, NREL, 512, 2048, 2048, 512, nullptr, nullptr, nullptr);
  GEMM(0,false,true ,false, dim3((NREL>>7)*(1536>>7)), rel_repb, egru_Wihb, egru_bih, nullptr, gi_e, NREL, 1536, 512, 512, 1536, nullptr, nullptr, nullptr);
  gru_init_e<<<nblk((long)NREL*64), 256, 0, stream>>>(gi_e, egru_bhh, edgeb, NREL);

  // initial ws/wo
  edge_weights<<<NREL*64/256, 256, 0, stream>>>(vertb, edgeb, sub, obj,
                                                svw_W, svw_b, ovw_W, ovw_b, ws_arr, wo_arr);

  // ---- message-passing loop ----
  for (int it = 0; it < 3; it++) {
    const bool last = (it == 2);
    ctx_gather<<<NOBJ, 128, 0, stream>>>(edgeb, ws_arr, wo_arr, coff, lists, ctxb);
    // VG = vertb @ [eWih ; nWhh]^T
    G64(0, vertb, vg_Wb, vgbias, VGb, NOBJ, 3072, 512, 512, 3072);
    // GH = edgeb @ eWhh^T + bhh  (big: 128^2 engine)
    GEMM(0,false,true,false, dim3((NREL>>7)*(1536>>7)), edgeb, egru_Whhb, egru_bhh, nullptr, GHb, NREL, 1536, 512, 512, 1536, nullptr, nullptr, nullptr);
    // giv = ctxb @ nWih^T + bih
    G64(0, ctxb, ngru_Wihb, ngru_bih, giv, NOBJ, 1536, 512, 512, 1536);
    // vertex update first (gru_step_e2's fused ws/wo needs NEW vertb)
    gru_step_v<<<nblk((long)NOBJ*64), 256, 0, stream>>>(giv, VGb + 1536, 3072, vert,
                                                        last ? d_out_vert : vert, vertb, NOBJ);
    gru_step_e2<<<NREL*64/256, 256, 0, stream>>>(GHb, VGb, ws_arr, wo_arr, ws_arr, wo_arr,
                                                 sub, obj, egru_bih, edgeb,
                                                 last ? d_out_edge : nullptr, vertb,
                                                 svw_W, svw_b, ovw_W, ovw_b,
                                                 last ? 0 : 1, NREL);
  }
}

// Round 11
// 1672.358 us; speedup vs baseline: 2.8478x; 1.0138x over previous
//
#include <hip/hip_runtime.h>
#include <stdint.h>

#define NOBJ 2048
#define NREL 32768

typedef __attribute__((ext_vector_type(8))) short short8;
typedef __attribute__((ext_vector_type(4))) float f32x4;
typedef __attribute__((ext_vector_type(4))) unsigned short ushort4v;

__device__ __forceinline__ unsigned short f2bs(float x){
  unsigned u = __float_as_uint(x);
  unsigned v = u + 0x7fffu + ((u >> 16) & 1u);
  return (unsigned short)(v >> 16);
}
__device__ __forceinline__ float b2f(unsigned short u){
  return __uint_as_float(((unsigned)u) << 16);
}
__device__ __forceinline__ float sigf(float x){ return 1.0f / (1.0f + expf(-x)); }

// async global->LDS, 16B per lane. LDS dest = wave-uniform base + lane*16.
__device__ __forceinline__ void gload16(const unsigned short* g, unsigned short* l) {
  __builtin_amdgcn_global_load_lds(
      (const __attribute__((address_space(1))) unsigned int*)(uintptr_t)g,
      (__attribute__((address_space(3))) unsigned int*)(uintptr_t)l,
      16, 0, 0);
}

// ====== 128x128 BK=64 engine, DEPTH-2 PREFETCH (counted vmcnt, never 0 mid-loop) ======
// LDS double buffer 64 KiB -> still 2 blocks/CU. Per K-tile: vmcnt(8 bf16 / 4 AF32)
// [tile kt's loads complete; kt+1 stays in flight] + lgkmcnt(0) + barrier -> ds_read+MFMA
// -> barrier (read release) -> STAGE(kt+2). Sync pattern (counted vmcnt + raw barrier +
// memory clobbers) correctness-validated in rounds 6/7; occupancy preserved this time.
// Swizzle: slot s of row r holds global slot s^(r&7) (both sides); read xor lrow&7.
template<int RMODE, bool ACCUM, bool OUTB, bool PRODF, bool AF32, bool CINB>
__global__ __launch_bounds__(256, 2)
void gemm_bt(const void* __restrict__ Ap, const unsigned short* __restrict__ B,
             const float* __restrict__ bias, const void* __restrict__ Cin,
             void* __restrict__ Cp, int M, int N, int K, int lda, int ldc,
             const unsigned short* __restrict__ fusedp,
             const int* __restrict__ subp, const int* __restrict__ objp)
{
  __shared__ __align__(16) unsigned short As[2][128 * 64];
  __shared__ __align__(16) unsigned short Bs[2][128 * 64];
  const int t = threadIdx.x;
  const int lane = t & 63;
  const int w = t >> 6;
  const int nwg = gridDim.x;
  const int q8 = nwg >> 3, r8 = nwg & 7;
  const int xcd = blockIdx.x & 7, bidx = blockIdx.x >> 3;
  const int wgid = (xcd < r8 ? xcd * (q8 + 1) : r8 * (q8 + 1) + (xcd - r8) * q8) + bidx;
  const int ntile = N >> 7;
  const int bm = wgid / ntile;
  const int bn = wgid - bm * ntile;
  const int m0 = bm << 7, n0 = bn << 7;
  const int wm = (w & 1) << 6, wn = (w >> 1) << 6;
  const int lrow = lane & 15, kg = lane >> 4;
  const int rx = lrow & 7;

  const int srow8 = lane >> 3;
  const int sslot = ((lane & 7) ^ srow8) << 3;
  const unsigned short* Bg = B + (long)(n0 + w * 8 + srow8) * K + sslot;
  const long ldb32 = (long)32 * K;

  const unsigned short* Ag = nullptr;
  const float* afp = nullptr;
  long lda32 = 0;
  int ar0 = 0, aoff = 0;
  if constexpr (AF32) {
    ar0 = t >> 4;
    const int ac4 = t & 15;
    afp = (const float*)Ap + (long)(m0 + ar0) * lda + (ac4 << 2);
    aoff = (((ac4 >> 1) ^ (ar0 & 7)) << 3) + ((ac4 & 1) << 2);
  } else {
    Ag = (const unsigned short*)Ap + (long)(m0 + w * 8 + srow8) * lda + sslot;
    lda32 = (long)32 * lda;
  }

  const int NT = K >> 6;

  auto stage = [&](int buf, int kt) {
    const unsigned short* bsrc = Bg + (long)kt * 64;
#pragma unroll
    for (int q = 0; q < 4; q++)
      gload16(bsrc + q * ldb32, Bs[buf] + (q * 32 + w * 8) * 64);
    if constexpr (AF32) {
      const float* ap = afp + (long)kt * 64;
#pragma unroll
      for (int j = 0; j < 8; j++) {
        f32x4 v = *(const f32x4*)(ap + (long)j * 16 * lda);
        ushort4v o;
        o[0] = f2bs(v[0]); o[1] = f2bs(v[1]); o[2] = f2bs(v[2]); o[3] = f2bs(v[3]);
        *(ushort4v*)(As[buf] + aoff + (ar0 + j * 16) * 64) = o;
      }
    } else {
      const unsigned short* asrc = Ag + (long)kt * 64;
#pragma unroll
      for (int q = 0; q < 4; q++)
        gload16(asrc + q * lda32, As[buf] + (q * 32 + w * 8) * 64);
    }
  };

  f32x4 acc[4][4] = {};

  stage(0, 0);
  if (NT > 1) stage(1, 1);

  for (int kt = 0; kt < NT; ++kt) {
    const int cur = kt & 1;
    if (kt + 1 < NT) {
      if constexpr (AF32) asm volatile("s_waitcnt vmcnt(4)" ::: "memory");
      else                asm volatile("s_waitcnt vmcnt(8)" ::: "memory");
    } else {
      asm volatile("s_waitcnt vmcnt(0)" ::: "memory");
    }
    asm volatile("s_waitcnt lgkmcnt(0)" ::: "memory");
    __builtin_amdgcn_s_barrier();
    asm volatile("" ::: "memory");

    const unsigned short* As_ = As[cur];
    const unsigned short* Bs_ = Bs[cur];
    short8 afr[4][2], bfr[4][2];
#pragma unroll
    for (int i = 0; i < 4; i++) {
      const int ra = wm + i * 16 + lrow;
#pragma unroll
      for (int ks = 0; ks < 2; ks++)
        afr[i][ks] = *(const short8*)(As_ + ra * 64 + (((ks * 4 + kg) ^ rx) << 3));
    }
#pragma unroll
    for (int j = 0; j < 4; j++) {
      const int rb = wn + j * 16 + lrow;
#pragma unroll
      for (int ks = 0; ks < 2; ks++)
        bfr[j][ks] = *(const short8*)(Bs_ + rb * 64 + (((ks * 4 + kg) ^ rx) << 3));
    }
#pragma unroll
    for (int i = 0; i < 4; i++)
#pragma unroll
      for (int j = 0; j < 4; j++)
#pragma unroll
        for (int ks = 0; ks < 2; ks++)
          acc[i][j] = __builtin_amdgcn_mfma_f32_16x16x32_bf16(afr[i][ks], bfr[j][ks], acc[i][j], 0, 0, 0);
    asm volatile("" ::: "memory");
    __builtin_amdgcn_s_barrier();   // all waves done reading buf[cur]
    asm volatile("" ::: "memory");
    if (kt + 2 < NT) stage(cur, kt + 2);   // overlaps next tile's compute
  }

  float* Cf = (float*)Cp;
  unsigned short* Cb = (unsigned short*)Cp;
#pragma unroll
  for (int i = 0; i < 4; i++) {
#pragma unroll
    for (int j = 0; j < 4; j++) {
      const int col = n0 + wn + j * 16 + lrow;
      const float bv = bias[col];
#pragma unroll
      for (int q = 0; q < 4; q++) {
        const long row = m0 + wm + i * 16 + kg * 4 + q;
        float v = acc[i][j][q] + bv;
        if constexpr (RMODE == 1) v = fmaxf(v, 0.0f);
        if constexpr (PRODF) {
          int gr = (col < 512) ? subp[row] : objp[row];
          v *= b2f(fusedp[(long)gr * 1024 + col]);
        }
        if constexpr (ACCUM) {
          if constexpr (CINB) v += b2f(((const unsigned short*)Cin)[row * (long)N + col]);
          else                v += ((const float*)Cin)[row * (long)N + col];
        }
        if constexpr (RMODE == 2) v = fmaxf(v, 0.0f);
        if constexpr (OUTB) Cb[row * (long)ldc + col] = f2bs(v);
        else Cf[row * (long)ldc + col] = v;
      }
    }
  }
}

// ============ 64x64 mini engine, same depth-2 prefetch (vmcnt(4)) ============
template<int RMODE>
__global__ __launch_bounds__(256, 4)
void gemm64(const unsigned short* __restrict__ A, const unsigned short* __restrict__ B,
            const float* __restrict__ bias, unsigned short* __restrict__ C,
            int M, int N, int K, int lda, int ldc)
{
  __shared__ __align__(16) unsigned short As[2][64 * 64];
  __shared__ __align__(16) unsigned short Bs[2][64 * 64];
  const int t = threadIdx.x;
  const int lane = t & 63;
  const int w = t >> 6;
  const int nwg = gridDim.x;
  const int q8 = nwg >> 3, r8 = nwg & 7;
  const int xcd = blockIdx.x & 7, bidx = blockIdx.x >> 3;
  const int wgid = (xcd < r8 ? xcd * (q8 + 1) : r8 * (q8 + 1) + (xcd - r8) * q8) + bidx;
  const int ntile = N >> 6;
  const int bm = wgid / ntile, bn = wgid - bm * ntile;
  const int m0 = bm << 6, n0 = bn << 6;
  const int wm = (w & 1) << 5, wn = (w >> 1) << 5;
  const int lrow = lane & 15, kg = lane >> 4;
  const int rx = lrow & 7;

  const int srow8 = lane >> 3;
  const int sslot = ((lane & 7) ^ srow8) << 3;
  const unsigned short* Ag = A + (long)(m0 + w * 16 + srow8) * lda + sslot;
  const unsigned short* Bg = B + (long)(n0 + w * 16 + srow8) * K + sslot;
  const long lda8 = 8L * lda, ldb8 = 8L * K;
  const int NT = K >> 6;

  auto stage = [&](int buf, int kt) {
    const unsigned short* a_ = Ag + (long)kt * 64;
    const unsigned short* b_ = Bg + (long)kt * 64;
    gload16(a_,        As[buf] + (w * 16) * 64);
    gload16(a_ + lda8, As[buf] + (w * 16 + 8) * 64);
    gload16(b_,        Bs[buf] + (w * 16) * 64);
    gload16(b_ + ldb8, Bs[buf] + (w * 16 + 8) * 64);
  };

  f32x4 acc[2][2] = {};

  stage(0, 0);
  if (NT > 1) stage(1, 1);

  for (int kt = 0; kt < NT; ++kt) {
    const int cur = kt & 1;
    if (kt + 1 < NT) asm volatile("s_waitcnt vmcnt(4)" ::: "memory");
    else             asm volatile("s_waitcnt vmcnt(0)" ::: "memory");
    __builtin_amdgcn_s_barrier();
    asm volatile("" ::: "memory");

    const unsigned short* As_ = As[cur];
    const unsigned short* Bs_ = Bs[cur];
    short8 afr[2][2], bfr[2][2];
#pragma unroll
    for (int i = 0; i < 2; i++) {
      const int ra = wm + i * 16 + lrow;
#pragma unroll
      for (int ks = 0; ks < 2; ks++)
        afr[i][ks] = *(const short8*)(As_ + ra * 64 + (((ks * 4 + kg) ^ rx) << 3));
    }
#pragma unroll
    for (int j = 0; j < 2; j++) {
      const int rb = wn + j * 16 + lrow;
#pragma unroll
      for (int ks = 0; ks < 2; ks++)
        bfr[j][ks] = *(const short8*)(Bs_ + rb * 64 + (((ks * 4 + kg) ^ rx) << 3));
    }
#pragma unroll
    for (int i = 0; i < 2; i++)
#pragma unroll
      for (int j = 0; j < 2; j++)
#pragma unroll
        for (int ks = 0; ks < 2; ks++)
          acc[i][j] = __builtin_amdgcn_mfma_f32_16x16x32_bf16(afr[i][ks], bfr[j][ks], acc[i][j], 0, 0, 0);
    asm volatile("" ::: "memory");
    __builtin_amdgcn_s_barrier();
    asm volatile("" ::: "memory");
    if (kt + 2 < NT) stage(cur, kt + 2);
  }

#pragma unroll
  for (int i = 0; i < 2; i++) {
#pragma unroll
    for (int j = 0; j < 2; j++) {
      const int col = n0 + wn + j * 16 + lrow;
      const float bv = bias[col];
#pragma unroll
      for (int q = 0; q < 4; q++) {
        const long row = m0 + wm + i * 16 + kg * 4 + q;
        float v = acc[i][j][q] + bv;
        if constexpr (RMODE == 1) v = fmaxf(v, 0.0f);
        C[row * (long)ldc + col] = f2bs(v);
      }
    }
  }
}

// ===================== small kernels =====================

__global__ void cvt_pad4(const float* __restrict__ src, unsigned short* __restrict__ dst,
                         int rows, int K0, int Kp)
{
  const int kp4 = Kp >> 2;
  const long total = (long)rows * kp4;
  for (long i = blockIdx.x * (long)blockDim.x + threadIdx.x; i < total; i += (long)gridDim.x * blockDim.x) {
    int r = (int)(i / kp4), k = (int)(i - (long)r * kp4) << 2;
    ushort4v o;
    if (k < K0) {
      f32x4 v = *(const f32x4*)(src + (long)r * K0 + k);
      o[0] = f2bs(v[0]); o[1] = f2bs(v[1]); o[2] = f2bs(v[2]); o[3] = f2bs(v[3]);
    } else {
      o[0] = 0; o[1] = 0; o[2] = 0; o[3] = 0;
    }
    *(ushort4v*)(dst + (long)r * Kp + k) = o;
  }
}

struct CvtSeg { const float* src; unsigned short* dst; long base; long n4; };
struct Cvt9 { CvtSeg s[9]; long total; };

__global__ void cvt4_multi(Cvt9 cfg)
{
  for (long i = blockIdx.x * (long)blockDim.x + threadIdx.x; i < cfg.total;
       i += (long)gridDim.x * blockDim.x) {
#pragma unroll
    for (int k = 0; k < 9; k++) {
      if (i >= cfg.s[k].base && i < cfg.s[k].base + cfg.s[k].n4) {
        long j = i - cfg.s[k].base;
        f32x4 v = ((const f32x4*)cfg.s[k].src)[j];
        ushort4v o;
        o[0] = f2bs(v[0]); o[1] = f2bs(v[1]); o[2] = f2bs(v[2]); o[3] = f2bs(v[3]);
        ((ushort4v*)cfg.s[k].dst)[j] = o;
        break;
      }
    }
  }
}

__global__ void transpose_cvt(const float* __restrict__ src, unsigned short* __restrict__ dst,
                              int R, int C)
{
  __shared__ float tile[32][33];
  int c0 = blockIdx.x * 32, r0 = blockIdx.y * 32;
  for (int i = threadIdx.y; i < 32; i += 8)
    tile[i][threadIdx.x] = src[(long)(r0 + i) * C + c0 + threadIdx.x];
  __syncthreads();
  for (int i = threadIdx.y; i < 32; i += 8)
    dst[(long)(c0 + i) * R + r0 + threadIdx.x] = f2bs(tile[threadIdx.x][i]);
}

__global__ void comp_bias(const float* __restrict__ edgeU_W, const float* __restrict__ up_b,
                          const float* __restrict__ edgeU_b, float* __restrict__ b_comp)
{
  int j = (int)((blockIdx.x * (long)blockDim.x + threadIdx.x) >> 6);
  int l = threadIdx.x & 63;
  if (j >= 512) return;
  float s = 0.0f;
  for (int k = l; k < 2048; k += 64) s += edgeU_W[(long)j * 2048 + k] * up_b[k];
#pragma unroll
  for (int off = 32; off > 0; off >>= 1) s += __shfl_xor(s, off);
  if (l == 0) b_comp[j] = s + edgeU_b[j];
}

__global__ void bias_cat(const float* __restrict__ bhh, float* __restrict__ out)
{
  int j = blockIdx.x * blockDim.x + threadIdx.x;
  if (j < 3072) out[j] = (j < 1536) ? 0.0f : bhh[j - 1536];
}

__global__ void obox_k(const float* __restrict__ boxes, float* __restrict__ obox)
{
  int i = blockIdx.x * blockDim.x + threadIdx.x;
  if (i >= NOBJ) return;
  float x1 = boxes[i*4], y1 = boxes[i*4+1], x2 = boxes[i*4+2], y2 = boxes[i*4+3];
  float wdt = x2 - x1 + 1.0f, hgt = y2 - y1 + 1.0f;
  float cx = x1 + 0.5f * wdt, cy = y1 + 0.5f * hgt;
  const float inv = 1.0f / 1024.0f;
  float* o = obox + i * 8;
  o[0]=x1*inv; o[1]=y1*inv; o[2]=x2*inv; o[3]=y2*inv;
  o[4]=cx*inv; o[5]=cy*inv; o[6]=wdt*inv; o[7]=hgt*inv;
}

__global__ void posembed_k(const float* __restrict__ boxes,
                           const float* __restrict__ w1, const float* __restrict__ b1,
                           const float* __restrict__ g, const float* __restrict__ bb,
                           const float* __restrict__ mm, const float* __restrict__ vv,
                           const float* __restrict__ w2, const float* __restrict__ b2,
                           float* __restrict__ out)
{
  int o = blockIdx.x, t = threadIdx.x;
  __shared__ float e[9];
  __shared__ float p[32];
  if (t == 0) {
    float x1 = boxes[o*4], y1 = boxes[o*4+1], x2 = boxes[o*4+2], y2 = boxes[o*4+3];
    float wdt = x2 - x1 + 1.0f, hgt = y2 - y1 + 1.0f;
    float cx = x1 + 0.5f * wdt, cy = y1 + 0.5f * hgt;
    e[0]=wdt/1024.0f; e[1]=hgt/768.0f; e[2]=cx/1024.0f; e[3]=cy/768.0f;
    e[4]=x1/1024.0f;  e[5]=y1/768.0f;  e[6]=x2/1024.0f; e[7]=y2/768.0f;
    e[8]=wdt*hgt/(1024.0f*768.0f);
  }
  __syncthreads();
  if (t < 32) {
    float s = b1[t];
#pragma unroll
    for (int j = 0; j < 9; j++) s += w1[t*9+j] * e[j];
    s = (s - mm[t]) * g[t] / sqrtf(vv[t] + 1e-5f) + bb[t];
    p[t] = s;
  }
  __syncthreads();
  float s = b2[t];
#pragma unroll
  for (int j = 0; j < 32; j++) s += w2[t*32+j] * p[j];
  out[o*128 + t] = fmaxf(s, 0.0f);
}

__device__ __forceinline__ void pack8_store(unsigned short* dst, f32x4 a, f32x4 b)
{
  ushort4v o0, o1;
  o0[0]=f2bs(a[0]); o0[1]=f2bs(a[1]); o0[2]=f2bs(a[2]); o0[3]=f2bs(a[3]);
  o1[0]=f2bs(b[0]); o1[1]=f2bs(b[1]); o1[2]=f2bs(b[2]); o1[3]=f2bs(b[3]);
  *(ushort4v*)dst = o0;
  *(ushort4v*)(dst + 4) = o1;
}

__global__ void build_x1(const float* __restrict__ inst, const float* __restrict__ embd,
                         const int* __restrict__ labels, const float* __restrict__ pose,
                         unsigned short* __restrict__ X1b)
{
  const long total = (long)NOBJ * 560;
  for (long i = blockIdx.x * (long)blockDim.x + threadIdx.x; i < total; i += (long)gridDim.x * blockDim.x) {
    int r = (int)(i / 560), c = ((int)(i - (long)r * 560)) << 3;
    unsigned short* dst = X1b + (long)r * 4480 + c;
    const float* src;
    if (c < 4096)      src = inst + (long)r * 4096 + c;
    else if (c < 4296) src = embd + (long)labels[r] * 200 + (c - 4096);
    else if (c < 4424) src = pose + r * 128 + (c - 4296);
    else { ushort4v z = {0,0,0,0}; *(ushort4v*)dst = z; *(ushort4v*)(dst+4) = z; continue; }
    pack8_store(dst, *(const f32x4*)src, *((const f32x4*)src + 1));
  }
}

__global__ void build_aug(const float* __restrict__ embl, const int* __restrict__ labels,
                          const float* __restrict__ inst, unsigned short* __restrict__ augb)
{
  const long total = (long)NOBJ * 608;
  for (long i = blockIdx.x * (long)blockDim.x + threadIdx.x; i < total; i += (long)gridDim.x * blockDim.x) {
    int r = (int)(i / 608), c = ((int)(i - (long)r * 608)) << 3;
    if (c >= 4296 && c < 4808) continue;
    unsigned short* dst = augb + (long)r * 4864 + c;
    const float* src;
    if (c < 200)       src = embl + (long)labels[r] * 200 + c;
    else if (c < 4296) src = inst + (long)r * 4096 + (c - 200);
    else { ushort4v z = {0,0,0,0}; *(ushort4v*)dst = z; *(ushort4v*)(dst+4) = z; continue; }
    pack8_store(dst, *(const f32x4*)src, *((const f32x4*)src + 1));
  }
}

__global__ void build_geo(const float* __restrict__ obox, const int* __restrict__ sub,
                          const int* __restrict__ obj, unsigned short* __restrict__ geob)
{
  int r = blockIdx.x * blockDim.x + threadIdx.x;
  if (r >= NREL) return;
  const float* b1 = obox + sub[r] * 8;
  const float* b2 = obox + obj[r] * 8;
  float o[32];
#pragma unroll
  for (int j = 0; j < 8; j++) { o[j] = b1[j]; o[8+j] = b2[j]; }
  float ux1 = fminf(b1[0], b2[0]), uy1 = fminf(b1[1], b2[1]);
  float ux2 = fmaxf(b1[2], b2[2]), uy2 = fmaxf(b1[3], b2[3]);
  float uw = ux2 - ux1 + 1.0f, uh = uy2 - uy1 + 1.0f;
  o[16]=ux1; o[17]=uy1; o[18]=ux2; o[19]=uy2;
  o[20]=ux1+0.5f*uw; o[21]=uy1+0.5f*uh; o[22]=uw; o[23]=uh;
  float ix1 = fmaxf(b1[0], b2[0]), iy1 = fmaxf(b1[1], b2[1]);
  float ix2 = fminf(b1[2], b2[2]), iy2 = fminf(b1[3], b2[3]);
  bool bad = (ix2 < ix1) || (iy2 < iy1);
  float iw = ix2 - ix1 + 1.0f, ih = iy2 - iy1 + 1.0f;
  if (bad) {
#pragma unroll
    for (int j = 24; j < 32; j++) o[j] = 0.0f;
  } else {
    o[24]=ix1; o[25]=iy1; o[26]=ix2; o[27]=iy2;
    o[28]=ix1+0.5f*iw; o[29]=iy1+0.5f*ih; o[30]=iw; o[31]=ih;
  }
  unsigned short* gp = geob + (long)r * 64;
#pragma unroll
  for (int j = 0; j < 32; j++) gp[j] = f2bs(o[j]);
#pragma unroll
  for (int j = 32; j < 64; j++) gp[j] = 0;
}

__global__ void gru_init_v(const unsigned short* __restrict__ gi, const float* __restrict__ bhh,
                           float* __restrict__ h, unsigned short* __restrict__ hb, int n)
{
  const long total = (long)n * 64;
  for (long i = blockIdx.x * (long)blockDim.x + threadIdx.x; i < total; i += (long)gridDim.x * blockDim.x) {
    int r = (int)(i >> 6), c = ((int)(i & 63)) << 3;
    const unsigned short* gr = gi + (long)r * 1536;
    short8 vr = *(const short8*)(gr + c);
    short8 vz = *(const short8*)(gr + 512 + c);
    short8 vn = *(const short8*)(gr + 1024 + c);
    float hv[8];
#pragma unroll
    for (int k = 0; k < 8; k++) {
      float rr = sigf(b2f((unsigned short)vr[k]) + bhh[c + k]);
      float z  = sigf(b2f((unsigned short)vz[k]) + bhh[512 + c + k]);
      float nn = tanhf(b2f((unsigned short)vn[k]) + rr * bhh[1024 + c + k]);
      hv[k] = (1.0f - z) * nn;
    }
    float* hp = h + (long)r * 512 + c;
    *(f32x4*)hp = *(f32x4*)hv;
    *(f32x4*)(hp + 4) = *(f32x4*)(hv + 4);
    pack8_store(hb + (long)r * 512 + c, *(f32x4*)hv, *(f32x4*)(hv + 4));
  }
}

__global__ void gru_init_e(const unsigned short* __restrict__ gi, const float* __restrict__ bhh,
                           unsigned short* __restrict__ hb, int n)
{
  const long total = (long)n * 64;
  for (long i = blockIdx.x * (long)blockDim.x + threadIdx.x; i < total; i += (long)gridDim.x * blockDim.x) {
    int r = (int)(i >> 6), c = ((int)(i & 63)) << 3;
    const unsigned short* gr = gi + (long)r * 1536;
    short8 vr = *(const short8*)(gr + c);
    short8 vz = *(const short8*)(gr + 512 + c);
    short8 vn = *(const short8*)(gr + 1024 + c);
    float hv[8];
#pragma unroll
    for (int k = 0; k < 8; k++) {
      float rr = sigf(b2f((unsigned short)vr[k]) + bhh[c + k]);
      float z  = sigf(b2f((unsigned short)vz[k]) + bhh[512 + c + k]);
      float nn = tanhf(b2f((unsigned short)vn[k]) + rr * bhh[1024 + c + k]);
      hv[k] = (1.0f - z) * nn;
    }
    pack8_store(hb + (long)r * 512 + c, *(f32x4*)hv, *(f32x4*)(hv + 4));
  }
}

__global__ void gru_step_v(const unsigned short* __restrict__ gi, const unsigned short* __restrict__ gh,
                           int ghs, const float* __restrict__ hin, float* __restrict__ hout,
                           unsigned short* __restrict__ hb, int n)
{
  const long total = (long)n * 64;
  for (long i = blockIdx.x * (long)blockDim.x + threadIdx.x; i < total; i += (long)gridDim.x * blockDim.x) {
    int r = (int)(i >> 6), c = ((int)(i & 63)) << 3;
    const unsigned short* gr = gi + (long)r * 1536;
    const unsigned short* hr = gh + (long)r * ghs;
    short8 ir = *(const short8*)(gr + c);
    short8 iz = *(const short8*)(gr + 512 + c);
    short8 in_ = *(const short8*)(gr + 1024 + c);
    short8 hrr = *(const short8*)(hr + c);
    short8 hz = *(const short8*)(hr + 512 + c);
    short8 hn = *(const short8*)(hr + 1024 + c);
    const float* hi = hin + (long)r * 512 + c;
    f32x4 h0 = *(const f32x4*)hi;
    f32x4 h1 = *(const f32x4*)(hi + 4);
    float hv[8];
#pragma unroll
    for (int k = 0; k < 8; k++) {
      float rr = sigf(b2f((unsigned short)ir[k]) + b2f((unsigned short)hrr[k]));
      float z  = sigf(b2f((unsigned short)iz[k]) + b2f((unsigned short)hz[k]));
      float nn = tanhf(b2f((unsigned short)in_[k]) + rr * b2f((unsigned short)hn[k]));
      float old = (k < 4) ? h0[k] : h1[k - 4];
      hv[k] = (1.0f - z) * nn + z * old;
    }
    float* hp = hout + (long)r * 512 + c;
    *(f32x4*)hp = *(f32x4*)hv;
    *(f32x4*)(hp + 4) = *(f32x4*)(hv + 4);
    pack8_store(hb + (long)r * 512 + c, *(f32x4*)hv, *(f32x4*)(hv + 4));
  }
}

__global__ __launch_bounds__(256)
void gru_step_e2(const unsigned short* __restrict__ GH, const unsigned short* __restrict__ VG,
                 const float* __restrict__ ws_arr_in, const float* __restrict__ wo_arr_in,
                 float* __restrict__ ws_arr_out, float* __restrict__ wo_arr_out,
                 const int* __restrict__ sub, const int* __restrict__ obj,
                 const float* __restrict__ bih,
                 unsigned short* __restrict__ edgeb, float* __restrict__ fout,
                 const unsigned short* __restrict__ vertb,
                 const float* __restrict__ svwW, const float* __restrict__ svwb,
                 const float* __restrict__ ovwW, const float* __restrict__ ovwb,
                 int compute_w, int n)
{
  long gid = blockIdx.x * 256L + threadIdx.x;
  int r = (int)(gid >> 6);
  int l = (int)(gid & 63);
  if (r >= n) return;
  const int c = l << 3;
  int s = sub[r], o = obj[r];
  float ws = ws_arr_in[r], wo = wo_arr_in[r];
  const unsigned short* gh = GH + (long)r * 1536;
  const unsigned short* vs = VG + (long)s * 3072;
  const unsigned short* vo = VG + (long)o * 3072;
  short8 ghr = *(const short8*)(gh + c);
  short8 ghz = *(const short8*)(gh + 512 + c);
  short8 ghn = *(const short8*)(gh + 1024 + c);
  short8 vsr = *(const short8*)(vs + c);
  short8 vsz = *(const short8*)(vs + 512 + c);
  short8 vsn = *(const short8*)(vs + 1024 + c);
  short8 vor_ = *(const short8*)(vo + c);
  short8 voz = *(const short8*)(vo + 512 + c);
  short8 von = *(const short8*)(vo + 1024 + c);
  short8 hold = *(const short8*)(edgeb + (long)r * 512 + c);
  float hv[8];
#pragma unroll
  for (int k = 0; k < 8; k++) {
    float gir = ws * b2f((unsigned short)vsr[k]) + wo * b2f((unsigned short)vor_[k]) + bih[c + k];
    float giz = ws * b2f((unsigned short)vsz[k]) + wo * b2f((unsigned short)voz[k]) + bih[512 + c + k];
    float gin = ws * b2f((unsigned short)vsn[k]) + wo * b2f((unsigned short)von[k]) + bih[1024 + c + k];
    float rr = sigf(gir + b2f((unsigned short)ghr[k]));
    float z  = sigf(giz + b2f((unsigned short)ghz[k]));
    float nn = tanhf(gin + rr * b2f((unsigned short)ghn[k]));
    hv[k] = (1.0f - z) * nn + z * b2f((unsigned short)hold[k]);
  }
  pack8_store(edgeb + (long)r * 512 + c, *(f32x4*)hv, *(f32x4*)(hv + 4));
  if (fout) {
    float* fp = fout + (long)r * 512 + c;
    *(f32x4*)fp = *(f32x4*)hv;
    *(f32x4*)(fp + 4) = *(f32x4*)(hv + 4);
  }
  if (compute_w) {
    short8 svv = *(const short8*)(vertb + (long)s * 512 + c);
    short8 ovv = *(const short8*)(vertb + (long)o * 512 + c);
    float as = 0.0f, ao = 0.0f;
#pragma unroll
    for (int k = 0; k < 8; k++) {
      float e = hv[k];
      as += svwW[c + k] * b2f((unsigned short)svv[k]) + svwW[512 + c + k] * e;
      ao += ovwW[c + k] * b2f((unsigned short)ovv[k]) + ovwW[512 + c + k] * e;
    }
#pragma unroll
    for (int off = 32; off > 0; off >>= 1) {
      as += __shfl_xor(as, off);
      ao += __shfl_xor(ao, off);
    }
    if (l == 0) {
      ws_arr_out[r] = sigf(as + svwb[0]);
      wo_arr_out[r] = sigf(ao + ovwb[0]);
    }
  }
}

__global__ __launch_bounds__(256)
void edge_weights(const unsigned short* __restrict__ vertb, const unsigned short* __restrict__ edgeb,
                  const int* __restrict__ sub, const int* __restrict__ obj,
                  const float* __restrict__ svwW, const float* __restrict__ svwb,
                  const float* __restrict__ ovwW, const float* __restrict__ ovwb,
                  float* __restrict__ ws_arr, float* __restrict__ wo_arr)
{
  long gid = blockIdx.x * 256L + threadIdx.x;
  int r = (int)(gid >> 6);
  int l = (int)(gid & 63);
  if (r >= NREL) return;
  int s = sub[r], o = obj[r];
  const unsigned short* sv = vertb + (long)s * 512;
  const unsigned short* ov = vertb + (long)o * 512;
  const unsigned short* e  = edgeb + (long)r * 512;
  float as = 0.0f, ao = 0.0f;
#pragma unroll
  for (int k = 0; k < 8; k++) {
    int c = l + k * 64;
    float svv = b2f(sv[c]), ovv = b2f(ov[c]), ev = b2f(e[c]);
    as += svwW[c] * svv + svwW[512 + c] * ev;
    ao += ovwW[c] * ovv + ovwW[512 + c] * ev;
  }
#pragma unroll
  for (int off = 32; off > 0; off >>= 1) {
    as += __shfl_xor(as, off);
    ao += __shfl_xor(ao, off);
  }
  if (l == 0) {
    ws_arr[r] = sigf(as + svwb[0]);
    wo_arr[r] = sigf(ao + ovwb[0]);
  }
}

// ===================== CSR =====================

__global__ void csr_count(const int* __restrict__ sub, const int* __restrict__ obj,
                          int* __restrict__ cnt)
{
  int r = blockIdx.x * blockDim.x + threadIdx.x;
  if (r >= NREL) return;
  atomicAdd(&cnt[sub[r]], 1);
  atomicAdd(&cnt[obj[r]], 1);
}

__global__ __launch_bounds__(1024)
void csr_scan(const int* __restrict__ cnt, int* __restrict__ off)
{
  __shared__ int a[1024], b[1024];
  int t = threadIdx.x;
  int c0 = cnt[2*t], c1 = cnt[2*t+1];
  a[t] = c0 + c1;
  __syncthreads();
  int* src = a; int* dst = b;
  for (int s = 1; s < 1024; s <<= 1) {
    int v = src[t];
    if (t >= s) v += src[t - s];
    dst[t] = v;
    __syncthreads();
    int* tmp = src; src = dst; dst = tmp;
  }
  int incl = src[t];
  int excl = incl - (c0 + c1);
  off[2*t] = excl;
  off[2*t+1] = excl + c0;
  if (t == 1023) off[2048] = incl;
}

__global__ void csr_fill(const int* __restrict__ sub, const int* __restrict__ obj,
                         const int* __restrict__ off, int* __restrict__ rcur,
                         int* __restrict__ lists)
{
  int r = blockIdx.x * blockDim.x + threadIdx.x;
  if (r >= NREL) return;
  int s = sub[r];
  int p = atomicAdd(&rcur[s], 1);
  lists[off[s] + p] = (r << 1);
  int o = obj[r];
  int q = atomicAdd(&rcur[o], 1);
  lists[off[o] + q] = (r << 1) | 1;
}

__global__ __launch_bounds__(128)
void ctx_gather(const unsigned short* __restrict__ edgeb, const float* __restrict__ ws,
                const float* __restrict__ wo, const int* __restrict__ off,
                const int* __restrict__ lists, unsigned short* __restrict__ ctxb)
{
  __shared__ float part[512];
  int o = blockIdx.x;
  int l = threadIdx.x & 63;
  int w = threadIdx.x >> 6;
  int i0 = off[o], i1 = off[o + 1];
  float acc[8] = {0.f,0.f,0.f,0.f,0.f,0.f,0.f,0.f};
  for (int i = i0 + w; i < i1; i += 2) {
    int e = lists[i];
    int r = e >> 1;
    float sc = (e & 1) ? wo[r] : ws[r];
    short8 row = *(const short8*)(edgeb + (long)r * 512 + l * 8);
#pragma unroll
    for (int k = 0; k < 8; k++) acc[k] += sc * b2f((unsigned short)row[k]);
  }
  if (w == 1) {
    *(f32x4*)&part[l*8]     = *(f32x4*)&acc[0];
    *(f32x4*)&part[l*8 + 4] = *(f32x4*)&acc[4];
  }
  __syncthreads();
  if (w == 0) {
#pragma unroll
    for (int k = 0; k < 8; k++) acc[k] += part[l*8 + k];
    pack8_store(ctxb + (long)o * 512 + l * 8, *(f32x4*)&acc[0], *(f32x4*)&acc[4]);
  }
}

// ===================== driver =====================

static inline int nblk(long total) {
  long b = (total + 255) / 256;
  return (int)(b > 16384 ? 16384 : b);
}

#define GEMM(RM, AC, OB, PF, grid, Aa, Bb, bb, Ci, Cc, Mm, Nn, Kk, ldA, ldC, fp, sp, op) \
  gemm_bt<RM, AC, OB, PF, false, false><<<grid, 256, 0, stream>>>(Aa, Bb, bb, Ci, Cc, Mm, Nn, Kk, ldA, ldC, fp, sp, op)
#define GEMMCB(RM, grid, Aa, Bb, bb, Ci, Cc, Mm, Nn, Kk, ldA, ldC) \
  gemm_bt<RM, true, true, false, false, true><<<grid, 256, 0, stream>>>(Aa, Bb, bb, Ci, Cc, Mm, Nn, Kk, ldA, ldC, nullptr, nullptr, nullptr)
#define GEMMF(RM, grid, Aa, Bb, bb, Cc, Mm, Nn, Kk, ldA, ldC) \
  gemm_bt<RM, false, true, false, true, false><<<grid, 256, 0, stream>>>(Aa, Bb, bb, nullptr, Cc, Mm, Nn, Kk, ldA, ldC, nullptr, nullptr, nullptr)
#define G64(RM, Aa, Bb, bb, Cc, Mm, Nn, Kk, ldA, ldC) \
  gemm64<RM><<<dim3(((Mm) >> 6) * ((Nn) >> 6)), 256, 0, stream>>>(Aa, Bb, bb, Cc, Mm, Nn, Kk, ldA, ldC)

extern "C" void kernel_launch(void* const* d_in, const int* in_sizes, int n_in,
                              void* d_out, int out_size, void* d_ws, size_t ws_size,
                              hipStream_t stream)
{
  const float* inst     = (const float*)d_in[0];
  const float* unionf   = (const float*)d_in[1];
  const float* boxes    = (const float*)d_in[2];
  const float* embd_W   = (const float*)d_in[3];
  const float* embl_W   = (const float*)d_in[4];
  const float* up_W     = (const float*)d_in[5];
  const float* up_b     = (const float*)d_in[6];
  const float* pairup_W = (const float*)d_in[7];
  const float* pairup_b = (const float*)d_in[8];
  const float* pos1_W   = (const float*)d_in[9];
  const float* pos1_b   = (const float*)d_in[10];
  const float* bn_g     = (const float*)d_in[11];
  const float* bn_b     = (const float*)d_in[12];
  const float* bn_m     = (const float*)d_in[13];
  const float* bn_v     = (const float*)d_in[14];
  const float* pos2_W   = (const float*)d_in[15];
  const float* pos2_b   = (const float*)d_in[16];
  const float* spt1_W   = (const float*)d_in[17];
  const float* spt1_b   = (const float*)d_in[18];
  const float* spt2_W   = (const float*)d_in[19];
  const float* spt2_b   = (const float*)d_in[20];
  const float* pairfin_W= (const float*)d_in[21];
  const float* pairfin_b= (const float*)d_in[22];
  const float* objhid_W = (const float*)d_in[23];
  const float* objhid_b = (const float*)d_in[24];
  const float* objfin_W = (const float*)d_in[25];
  const float* objfin_b = (const float*)d_in[26];
  const float* objU_W   = (const float*)d_in[27];
  const float* objU_b   = (const float*)d_in[28];
  const float* edgeU_W  = (const float*)d_in[29];
  const float* edgeU_b  = (const float*)d_in[30];
  const float* egru_Wih = (const float*)d_in[31];
  const float* egru_Whh = (const float*)d_in[32];
  const float* egru_bih = (const float*)d_in[33];
  const float* egru_bhh = (const float*)d_in[34];
  const float* ngru_Wih = (const float*)d_in[35];
  const float* ngru_Whh = (const float*)d_in[36];
  const float* ngru_bih = (const float*)d_in[37];
  const float* ngru_bhh = (const float*)d_in[38];
  const float* svw_W    = (const float*)d_in[39];
  const float* svw_b    = (const float*)d_in[40];
  const float* ovw_W    = (const float*)d_in[41];
  const float* ovw_b    = (const float*)d_in[42];
  const int*   labels   = (const int*)d_in[43];
  const int*   sub      = (const int*)d_in[44];
  const int*   obj      = (const int*)d_in[45];
  (void)in_sizes; (void)n_in; (void)out_size; (void)ws_size;

  char* base = (char*)d_ws;
  size_t off = 0;
  auto alloc = [&](size_t bytes) -> void* {
    void* p = base + off;
    off += (bytes + 255) & ~(size_t)255;
    return p;
  };

  // ---- weights (bf16) ----
  unsigned short* objhid_Wb  = (unsigned short*)alloc(512L  * 4480 * 2);
  unsigned short* pairup_Wb  = (unsigned short*)alloc(1024L * 4864 * 2);
  unsigned short* objfin_Wb  = (unsigned short*)alloc(2048L * 4864 * 2);
  unsigned short* up_Wtb     = (unsigned short*)alloc(4096L * 2048 * 2);
  unsigned short* pairfin_Wb = (unsigned short*)alloc(2048L * 1024 * 2);
  unsigned short* spt1_Wb    = (unsigned short*)alloc(512L  * 64   * 2);
  unsigned short* spt2_Wb    = (unsigned short*)alloc(1024L * 512  * 2);
  unsigned short* objU_Wb    = (unsigned short*)alloc(512L  * 2048 * 2);
  unsigned short* edgeU_Wb   = (unsigned short*)alloc(512L  * 2048 * 2);
  unsigned short* egru_Wihb  = (unsigned short*)alloc(1536L * 512  * 2);
  unsigned short* egru_Whhb  = (unsigned short*)alloc(1536L * 512  * 2);
  unsigned short* ngru_Wihb  = (unsigned short*)alloc(1536L * 512  * 2);
  unsigned short* vg_Wb      = (unsigned short*)alloc(3072L * 512  * 2);
  unsigned short* W_compb    = (unsigned short*)alloc(512L  * 4096 * 2);
  float*          b_comp     = (float*)alloc(512L * 4);
  float*          zbias      = (float*)alloc(4096L * 4);
  float*          vgbias     = (float*)alloc(3072L * 4);

  // ---- activations ----
  float*          obox      = (float*)alloc(NOBJ * 8L * 4);
  float*          pose      = (float*)alloc(NOBJ * 128L * 4);
  unsigned short* obj_featsb= (unsigned short*)alloc((long)NOBJ * 2048 * 2);
  unsigned short* obj_repb  = (unsigned short*)alloc((long)NOBJ * 512 * 2);
  unsigned short* giv       = (unsigned short*)alloc((long)NOBJ * 1536 * 2);
  unsigned short* VGb       = (unsigned short*)alloc((long)NOBJ * 3072 * 2);
  float*          vert      = (float*)alloc((long)NOBJ * 512 * 4);
  unsigned short* vertb     = (unsigned short*)alloc((long)NOBJ * 512 * 2);
  unsigned short* ctxb      = (unsigned short*)alloc((long)NOBJ * 512 * 2);
  unsigned short* geob      = (unsigned short*)alloc((long)NREL * 64 * 2);
  unsigned short* edgeb     = (unsigned short*)alloc((long)NREL * 512 * 2);
  float*          ws_arr    = (float*)alloc((long)NREL * 4);
  float*          wo_arr    = (float*)alloc((long)NREL * 4);

  // CSR
  int* cnt   = (int*)alloc(NOBJ * 4);
  int* coff  = (int*)alloc((NOBJ + 1) * 4);
  int* rcur  = (int*)alloc(NOBJ * 4);
  int* lists = (int*)alloc(2L * NREL * 4);

  // REGION_A: X1b -> T1b (bf16 NRELx512)
  char* regA = (char*)alloc((long)NREL * 512 * 4);
  unsigned short* X1b = (unsigned short*)regA;
  unsigned short* T1b = (unsigned short*)regA;
  // REGION_B: augb -> rel_repb
  char* regB = (char*)alloc((long)NOBJ * 4864 * 2 > (long)NREL * 512 * 2
                            ? (long)NOBJ * 4864 * 2 : (long)NREL * 512 * 2);
  unsigned short* augb     = (unsigned short*)regB;
  unsigned short* rel_repb = (unsigned short*)regB;
  unsigned short* fusedb = (unsigned short*)alloc((long)NOBJ * 1024 * 2);
  unsigned short* spt1b  = (unsigned short*)alloc((long)NREL * 512 * 2);
  // BIG1: [G1 128MB | prodb 64MB] -> gi_e(init) -> GH
  char* big1 = (char*)alloc((long)NREL * 1536 * 4);
  unsigned short* G1    = (unsigned short*)big1;
  unsigned short* prodb = (unsigned short*)(big1 + (long)NREL * 1024 * 4);
  unsigned short* gi_e  = (unsigned short*)big1;
  unsigned short* GHb   = (unsigned short*)big1;

  float* d_out_vert = (float*)d_out;
  float* d_out_edge = (float*)d_out + (long)NOBJ * 512;

  // ---- weight conversions ----
  cvt_pad4<<<nblk(512L*4480/4),  256, 0, stream>>>(objhid_W,  objhid_Wb,  512,  4424, 4480);
  cvt_pad4<<<nblk(1024L*4864/4), 256, 0, stream>>>(pairup_W,  pairup_Wb,  1024, 4808, 4864);
  cvt_pad4<<<nblk(2048L*4864/4), 256, 0, stream>>>(objfin_W,  objfin_Wb,  2048, 4808, 4864);
  cvt_pad4<<<nblk(512L*64/4),    256, 0, stream>>>(spt1_W,    spt1_Wb,    512,  32,   64);
  {
    Cvt9 cfg;
    long b = 0;
    auto seg = [&](int k, const float* s, unsigned short* d, long n4) {
      cfg.s[k].src = s; cfg.s[k].dst = d; cfg.s[k].base = b; cfg.s[k].n4 = n4; b += n4;
    };
    seg(0, pairfin_W, pairfin_Wb, 2048L*1024/4);
    seg(1, spt2_W,    spt2_Wb,    1024L*512/4);
    seg(2, objU_W,    objU_Wb,    512L*2048/4);
    seg(3, edgeU_W,   edgeU_Wb,   512L*2048/4);
    seg(4, egru_Wih,  egru_Wihb,  1536L*512/4);
    seg(5, egru_Whh,  egru_Whhb,  1536L*512/4);
    seg(6, ngru_Wih,  ngru_Wihb,  1536L*512/4);
    seg(7, egru_Wih,  vg_Wb,              1536L*512/4);
    seg(8, ngru_Whh,  vg_Wb + 1536L*512,  1536L*512/4);
    cfg.total = b;
    cvt4_multi<<<nblk(b), 256, 0, stream>>>(cfg);
  }
  bias_cat<<<12, 256, 0, stream>>>(ngru_bhh, vgbias);
  transpose_cvt<<<dim3(4096/32, 2048/32), dim3(32, 8), 0, stream>>>(up_W, up_Wtb, 2048, 4096);
  hipMemsetAsync(zbias, 0, 4096L * 4, stream);
  comp_bias<<<128, 256, 0, stream>>>(edgeU_W, up_b, edgeU_b, b_comp);
  G64(0, edgeU_Wb, up_Wtb, zbias, W_compb, 512, 4096, 2048, 2048, 4096);

  // ---- CSR build ----
  hipMemsetAsync(cnt, 0, NOBJ * 4, stream);
  hipMemsetAsync(rcur, 0, NOBJ * 4, stream);
  csr_count<<<NREL/256, 256, 0, stream>>>(sub, obj, cnt);
  csr_scan<<<1, 1024, 0, stream>>>(cnt, coff);
  csr_fill<<<NREL/256, 256, 0, stream>>>(sub, obj, coff, rcur, lists);

  // ---- object stream ----
  obox_k<<<(NOBJ + 255) / 256, 256, 0, stream>>>(boxes, obox);
  posembed_k<<<NOBJ, 128, 0, stream>>>(boxes, pos1_W, pos1_b, bn_g, bn_b, bn_m, bn_v,
                                       pos2_W, pos2_b, pose);
  build_x1<<<nblk((long)NOBJ*560), 256, 0, stream>>>(inst, embd_W, labels, pose, X1b);
  build_aug<<<nblk((long)NOBJ*608), 256, 0, stream>>>(embl_W, labels, inst, augb);
  G64(0, X1b, objhid_Wb, objhid_b, augb + 4296, NOBJ, 512, 4480, 4480, 4864);
  G64(0, augb, pairup_Wb, pairup_b, fusedb, NOBJ, 1024, 4864, 4864, 1024);
  G64(1, augb, objfin_Wb, objfin_b, obj_featsb, NOBJ, 2048, 4864, 4864, 2048);
  G64(0, obj_featsb, objU_Wb, objU_b, obj_repb, NOBJ, 512, 2048, 2048, 512);
  G64(0, obj_repb, ngru_Wihb, ngru_bih, giv, NOBJ, 1536, 512, 512, 1536);
  gru_init_v<<<nblk((long)NOBJ*64), 256, 0, stream>>>(giv, ngru_bhh, vert, vertb, NOBJ);

  // ---- relation stream (depth-2 prefetch 128^2 engine) ----
  build_geo<<<(NREL + 255) / 256, 256, 0, stream>>>(obox, sub, obj, geob);
  GEMM(1,false,true ,false, dim3((NREL>>7)*(512>>7)),  geob, spt1_Wb, spt1_b, nullptr, spt1b, NREL, 512, 64, 64, 512, nullptr, nullptr, nullptr);
  GEMM(1,false,true ,true , dim3((NREL>>7)*(1024>>7)), spt1b, spt2_Wb, spt2_b, nullptr, prodb, NREL, 1024, 512, 512, 1024, fusedb, sub, obj);
  GEMM(1,false,true ,false, dim3((NREL>>7)*(2048>>7)), prodb, pairfin_Wb, pairfin_b, nullptr, G1, NREL, 2048, 1024, 1024, 2048, nullptr, nullptr, nullptr);
  GEMMF(0, dim3((NREL>>7)*(512>>7)), unionf, W_compb, b_comp, T1b, NREL, 512, 4096, 4096, 512);
  GEMMCB(2, dim3((NREL>>7)*(512>>7)), G1, edgeU_Wb, zbias, T1b, rel_repb, NREL, 512, 2048, 2048, 512);
  GEMM(0,false,true ,false, dim3((NREL>>7)*(1536>>7)), rel_repb, egru_Wihb, egru_bih, nullptr, gi_e, NREL, 1536, 512, 512, 1536, nullptr, nullptr, nullptr);
  gru_init_e<<<nblk((long)NREL*64), 256, 0, stream>>>(gi_e, egru_bhh, edgeb, NREL);

  // initial ws/wo
  edge_weights<<<NREL*64/256, 256, 0, stream>>>(vertb, edgeb, sub, obj,
                                                svw_W, svw_b, ovw_W, ovw_b, ws_arr, wo_arr);

  // ---- message-passing loop ----
  for (int it = 0; it < 3; it++) {
    const bool last = (it == 2);
    ctx_gather<<<NOBJ, 128, 0, stream>>>(edgeb, ws_arr, wo_arr, coff, lists, ctxb);
    G64(0, vertb, vg_Wb, vgbias, VGb, NOBJ, 3072, 512, 512, 3072);
    GEMM(0,false,true,false, dim3((NREL>>7)*(1536>>7)), edgeb, egru_Whhb, egru_bhh, nullptr, GHb, NREL, 1536, 512, 512, 1536, nullptr, nullptr, nullptr);
    G64(0, ctxb, ngru_Wihb, ngru_bih, giv, NOBJ, 1536, 512, 512, 1536);
    gru_step_v<<<nblk((long)NOBJ*64), 256, 0, stream>>>(giv, VGb + 1536, 3072, vert,
                                                        last ? d_out_vert : vert, vertb, NOBJ);
    gru_step_e2<<<NREL*64/256, 256, 0, stream>>>(GHb, VGb, ws_arr, wo_arr, ws_arr, wo_arr,
                                                 sub, obj, egru_bih, edgeb,
                                                 last ? d_out_edge : nullptr, vertb,
                                                 svw_W, svw_b, ovw_W, ovw_b,
                                                 last ? 0 : 1, NREL);
  }
}